// Round 1
// baseline (418.484 us; speedup 1.0000x reference)
//
#include <hip/hip_runtime.h>
#include <math.h>

#define NB 32
#define QQ 100
#define CC 256
#define HH 8
#define DH 32
#define SM 101   // kv_ext rows per batch (100 points + mean)
#define TT 200   // branch queries per batch

// ---------------- prep: sums, mean center, far point, centers, kv_ext ----------------
__global__ void prep_kernel(const float* __restrict__ hs, float* __restrict__ sum_all,
                            float* __restrict__ c1mean, float* __restrict__ centB,
                            float* __restrict__ kv_ext) {
    int n = blockIdx.x;
    int c = threadIdx.x; // 0..255
    const float* h = hs + (size_t)n * QQ * CC;
    float s = 0.f;
    for (int q = 0; q < QQ; ++q) s += h[q * CC + c];
    float c1 = s * (1.0f / QQ);
    sum_all[n * CC + c] = s;
    c1mean[n * CC + c] = c1;
    __shared__ float c1s[CC];
    __shared__ float dls[QQ];
    c1s[c] = c1;
    // kv_ext = [hs rows, mean row]
    float* kve = kv_ext + (size_t)n * SM * CC;
    for (int idx = c; idx < QQ * CC; idx += CC) kve[idx] = h[idx];
    kve[QQ * CC + c] = c1;
    __syncthreads();
    int wave = c >> 6, lane = c & 63;
    for (int q = wave; q < QQ; q += 4) {
        float p = 0.f;
        for (int cc = lane; cc < CC; cc += 64) {
            float d = c1s[cc] - h[q * CC + cc];
            p += d * d;
        }
        for (int off = 32; off > 0; off >>= 1) p += __shfl_down(p, off);
        if (lane == 0) dls[q] = p;
    }
    __syncthreads();
    __shared__ int fars;
    if (c == 0) {
        int best = 0; float bv = dls[0];
        for (int q = 1; q < QQ; ++q) if (dls[q] > bv) { bv = dls[q]; best = q; }
        fars = best;
    }
    __syncthreads();
    int far = fars;
    centB[(size_t)n * 2 * CC + c] = c1s[c];
    centB[(size_t)n * 2 * CC + CC + c] = h[(size_t)far * CC + c];
}

// ---------------- generic fp32 tiled GEMM: out = A @ W^T + bias ----------------
// A: M x 256 row-major; W: Nout x 256 row-major; out: M x Nout
#define BK 16
__global__ void gemm_bias(const float* __restrict__ A, const float* __restrict__ W,
                          const float* __restrict__ bias, float* __restrict__ out,
                          int M, int Nout) {
    __shared__ float As[BK][64];
    __shared__ float Ws[BK][64];
    int bm = blockIdx.x * 64;
    int bn = blockIdx.y * 64;
    int tid = threadIdx.x;
    int tn = tid & 15, tm = tid >> 4;
    int lr = tid >> 2;          // row within tile 0..63
    int lk = (tid & 3) * 4;     // k offset {0,4,8,12}
    float acc[4][4] = {};
    for (int k0 = 0; k0 < 256; k0 += BK) {
        int am = bm + lr; if (am >= M) am = M - 1;
        const float4 av = *(const float4*)&A[(size_t)am * 256 + k0 + lk];
        const float4 wv = *(const float4*)&W[(size_t)(bn + lr) * 256 + k0 + lk];
        __syncthreads();
        As[lk + 0][lr] = av.x; As[lk + 1][lr] = av.y; As[lk + 2][lr] = av.z; As[lk + 3][lr] = av.w;
        Ws[lk + 0][lr] = wv.x; Ws[lk + 1][lr] = wv.y; Ws[lk + 2][lr] = wv.z; Ws[lk + 3][lr] = wv.w;
        __syncthreads();
#pragma unroll
        for (int kk = 0; kk < BK; ++kk) {
            float a0 = As[kk][tm * 4 + 0], a1 = As[kk][tm * 4 + 1];
            float a2 = As[kk][tm * 4 + 2], a3 = As[kk][tm * 4 + 3];
            float b0 = Ws[kk][tn * 4 + 0], b1 = Ws[kk][tn * 4 + 1];
            float b2 = Ws[kk][tn * 4 + 2], b3 = Ws[kk][tn * 4 + 3];
            acc[0][0] += a0 * b0; acc[0][1] += a0 * b1; acc[0][2] += a0 * b2; acc[0][3] += a0 * b3;
            acc[1][0] += a1 * b0; acc[1][1] += a1 * b1; acc[1][2] += a1 * b2; acc[1][3] += a1 * b3;
            acc[2][0] += a2 * b0; acc[2][1] += a2 * b1; acc[2][2] += a2 * b2; acc[2][3] += a2 * b3;
            acc[3][0] += a3 * b0; acc[3][1] += a3 * b1; acc[3][2] += a3 * b2; acc[3][3] += a3 * b3;
        }
    }
#pragma unroll
    for (int i = 0; i < 4; ++i) {
        int m = bm + tm * 4 + i;
        if (m < M) {
#pragma unroll
            for (int j = 0; j < 4; ++j) {
                int o = bn + tn * 4 + j;
                out[(size_t)m * Nout + o] = acc[i][j] + bias[o];
            }
        }
    }
}

// ---------------- stage B: small SMHA (2 queries), fused ----------------
__global__ void smhaB_kernel(const float* __restrict__ centB, const float* __restrict__ kvh,
                             const float* __restrict__ ipw, const float* __restrict__ ipb,
                             const float* __restrict__ ow, const float* __restrict__ ob,
                             float* __restrict__ out_assign, float* __restrict__ out_sidx,
                             float* __restrict__ out_didx, float* __restrict__ cd,
                             float* __restrict__ cs) {
    int n = blockIdx.x;
    int tid = threadIdx.x;
    __shared__ float qh[2][CC];
    __shared__ float attn[HH][2][QQ];
    __shared__ float pvB[2][CC];
    __shared__ float rs[16];
    __shared__ float mf[2][CC];
    __shared__ int sdi[2];
    const float* cen = centB + (size_t)n * 2 * CC;
    {   // q projection (wq = ipw rows 0..255)
        const float* wr = ipw + (size_t)tid * CC;
        float a0 = ipb[tid], a1 = ipb[tid];
        for (int k = 0; k < CC; ++k) { float w = wr[k]; a0 += cen[k] * w; a1 += cen[CC + k] * w; }
        qh[0][tid] = a0; qh[1][tid] = a1;
    }
    __syncthreads();
    const float* kh = kvh + (size_t)n * SM * 512;
    const float scl = 0.17677669529663687f; // 1/sqrt(32)
    for (int idx = tid; idx < HH * 2 * QQ; idx += 256) {
        int h = idx / 200; int r = idx % 200; int t = r / QQ; int s2 = r % QQ;
        float sc = 0.f;
        const float* kr = kh + (size_t)s2 * 512 + h * DH;
        const float* qr = &qh[t][h * DH];
        for (int d = 0; d < DH; ++d) sc += qr[d] * kr[d];
        attn[h][t][s2] = 1.f / (1.f + __expf(-sc * scl));
    }
    __syncthreads();
    if (tid < 16) {
        int h = tid >> 1, t = tid & 1; float s = 0.f;
        for (int s2 = 0; s2 < QQ; ++s2) s += attn[h][t][s2];
        rs[tid] = s;
    }
    __syncthreads();
    for (int idx = tid; idx < 2 * QQ; idx += 256) {
        int t = idx / QQ, s2 = idx % QQ;
        float m = 0.f;
        for (int h = 0; h < HH; ++h) m += attn[h][t][s2];
        out_assign[(size_t)n * 2 * QQ + idx] = m * 0.125f;
    }
    if (tid == 0) {
        float c0 = 0.f, c1v = 0.f;
        for (int h = 0; h < HH; ++h) { c0 += rs[h * 2 + 0]; c1v += rs[h * 2 + 1]; }
        int si = (c1v < c0) ? 1 : 0;  // argmin, first index on tie
        int di = (c1v > c0) ? 1 : 0;  // argmax, first index on tie
        sdi[0] = si; sdi[1] = di;
        out_sidx[n] = (float)si;
        out_didx[n] = (float)di;
    }
    // PV (normalized)
    for (int idx = tid; idx < 512; idx += 256) {
        int t = idx >> 8; int hd = idx & 255; int h = hd >> 5;
        float inv = 1.f / (rs[h * 2 + t] + 1e-4f);
        float a = 0.f;
        const float* vr = kh + 256 + hd;
        for (int s2 = 0; s2 < QQ; ++s2) a += attn[h][t][s2] * vr[(size_t)s2 * 512];
        pvB[t][hd] = a * inv;
    }
    __syncthreads();
    {   // out projection
        const float* wr = ow + (size_t)tid * CC;
        float a0 = ob[tid], a1 = ob[tid];
        for (int k = 0; k < CC; ++k) { float w = wr[k]; a0 += pvB[0][k] * w; a1 += pvB[1][k] * w; }
        mf[0][tid] = a0; mf[1][tid] = a1;
    }
    __syncthreads();
    cd[(size_t)n * CC + tid] = mf[sdi[1]][tid];
    cs[(size_t)n * CC + tid] = mf[sdi[0]][tid];
}

// ---------------- branch prep: c1 row, far selection, cen rows ----------------
__global__ void branch_prep(const float* __restrict__ hs, const float* __restrict__ sum_all,
                            const float* __restrict__ c1mean, const float* __restrict__ kv_ext,
                            float* __restrict__ cen, int Sb, int md) {
    int n = blockIdx.x / QQ; int q = blockIdx.x % QQ;
    int c = threadIdx.x;
    int qm1 = (q + QQ - 1) % QQ;
    const float* h = hs + (size_t)n * QQ * CC;
    float c1;
    if (md) c1 = (sum_all[n * CC + c] - h[(size_t)qm1 * CC + c] + c1mean[n * CC + c]) * (1.f / 100.f);
    else    c1 = (sum_all[n * CC + c] - h[(size_t)qm1 * CC + c]) * (1.f / 99.f);
    __shared__ float c1s[CC];
    __shared__ float dls[SM];
    __shared__ int fars;
    c1s[c] = c1;
    __syncthreads();
    const float* kve = kv_ext + (size_t)n * SM * CC;
    int wave = c >> 6, lane = c & 63;
    for (int s = wave; s < Sb; s += 4) {
        float p = 0.f;
        for (int cc = lane; cc < CC; cc += 64) {
            float d = c1s[cc] - kve[(size_t)s * CC + cc];
            p += d * d;
        }
        for (int off = 32; off > 0; off >>= 1) p += __shfl_down(p, off);
        if (lane == 0) dls[s] = p;
    }
    __syncthreads();
    if (c == 0) {
        int best = -1; float bv = -1e30f;
        for (int s = 0; s < Sb; ++s) {
            if (s == qm1) continue;            // em mask: excluded from far
            if (dls[s] > bv) { bv = dls[s]; best = s; }
        }
        fars = best;
    }
    __syncthreads();
    int far = fars;
    float* cr = cen + ((size_t)n * TT + 2 * q) * CC;
    cr[c] = c1s[c];
    cr[CC + c] = kve[(size_t)far * CC + c];
}

// ---------------- branch attention: sigmoid scores + PV, per (n,h) ----------------
__global__ void attn_kernel(const float* __restrict__ qh, const float* __restrict__ kvh,
                            float* __restrict__ pv, float* __restrict__ rowsum, int Sb) {
    int n = blockIdx.x >> 3; int h = blockIdx.x & 7;
    int tid = threadIdx.x;
    __shared__ float ks[SM][DH];
    __shared__ float vs[SM][DH];
    const float* base = kvh + (size_t)n * SM * 512;
    for (int idx = tid; idx < Sb * DH; idx += 256) {
        int s = idx >> 5; int d = idx & 31;
        ks[s][d] = base[(size_t)s * 512 + h * DH + d];
        vs[s][d] = base[(size_t)s * 512 + 256 + h * DH + d];
    }
    __syncthreads();
    if (tid < TT) {
        int t = tid;
        const float* qr = qh + ((size_t)n * TT + t) * CC + h * DH;
        float qreg[DH];
#pragma unroll
        for (int d = 0; d < DH; ++d) qreg[d] = qr[d];
        float acc[DH] = {};
        float rsum = 0.f;
        int mk = t >> 1;                     // mask key index (m[2q,q], m[2q+1,q])
        const float scl = 0.17677669529663687f;
        for (int s = 0; s < Sb; ++s) {
            float sc = 0.f;
#pragma unroll
            for (int d = 0; d < DH; ++d) sc += qreg[d] * ks[s][d];
            float a = 1.f / (1.f + __expf(-sc * scl));
            if (s == mk) a = 0.f;
            rsum += a;
#pragma unroll
            for (int d = 0; d < DH; ++d) acc[d] += a * vs[s][d];
        }
        rowsum[((size_t)n * HH + h) * TT + t] = rsum;
        float inv = 1.f / (rsum + 1e-4f);
        float* pr = pv + ((size_t)n * TT + t) * CC + h * DH;
#pragma unroll
        for (int d = 0; d < DH; ++d) pr[d] = acc[d] * inv;
    }
}

// ---------------- shift: card argmin/argmax + distances ----------------
__global__ void shift_kernel(const float* __restrict__ rowsum, const float* __restrict__ mfx,
                             const float* __restrict__ cd, const float* __restrict__ cs,
                             float* __restrict__ out_shift) {
    int n = blockIdx.x / QQ; int q = blockIdx.x % QQ;
    int tid = threadIdx.x;
    __shared__ float red[256];
    __shared__ int sdi[2];
    if (tid == 0) {
        float c0 = 0.f, c1v = 0.f;
        for (int h = 0; h < HH; ++h) {
            c0  += rowsum[((size_t)n * HH + h) * TT + 2 * q];
            c1v += rowsum[((size_t)n * HH + h) * TT + 2 * q + 1];
        }
        sdi[0] = (c1v < c0) ? 1 : 0;  // argmin
        sdi[1] = (c1v > c0) ? 1 : 0;  // argmax
    }
    __syncthreads();
    int si = sdi[0], di = sdi[1];
    const float* mdp = mfx + ((size_t)n * TT + 2 * q + di) * CC;
    const float* msp = mfx + ((size_t)n * TT + 2 * q + si) * CC;
    float dd = mdp[tid] - cd[(size_t)n * CC + tid];
    float ds = msp[tid] - cs[(size_t)n * CC + tid];
    red[tid] = dd * dd;
    __syncthreads();
    for (int off = 128; off > 0; off >>= 1) { if (tid < off) red[tid] += red[tid + off]; __syncthreads(); }
    float distd = sqrtf(red[0] + 1e-12f);
    __syncthreads();
    red[tid] = ds * ds;
    __syncthreads();
    for (int off = 128; off > 0; off >>= 1) { if (tid < off) red[tid] += red[tid + off]; __syncthreads(); }
    if (tid == 0) out_shift[blockIdx.x] = distd + sqrtf(red[0] + 1e-12f);
}

extern "C" void kernel_launch(void* const* d_in, const int* in_sizes, int n_in,
                              void* d_out, int out_size, void* d_ws, size_t ws_size,
                              hipStream_t stream) {
    const float* hs_pair = (const float*)d_in[0];
    const float* ipw = (const float*)d_in[1];
    const float* ipb = (const float*)d_in[2];
    const float* ow  = (const float*)d_in[3];
    const float* ob  = (const float*)d_in[4];
    const float* hs = hs_pair + (size_t)5 * NB * QQ * CC;  // hs_pair[-1]

    float* ws = (float*)d_ws;
    size_t o = 0;
    float* sum_all = ws + o; o += NB * CC;
    float* c1mean  = ws + o; o += NB * CC;
    float* centB   = ws + o; o += (size_t)NB * 2 * CC;
    float* kv_ext  = ws + o; o += (size_t)NB * SM * CC;
    float* kvh     = ws + o; o += (size_t)NB * SM * 512;   // cols 0..255 = kh, 256..511 = vh
    float* cd      = ws + o; o += NB * CC;
    float* cs      = ws + o; o += NB * CC;
    float* cen     = ws + o; o += (size_t)NB * TT * CC;
    float* qh      = ws + o; o += (size_t)NB * TT * CC;
    float* pv      = ws + o; o += (size_t)NB * TT * CC;
    float* rowsum  = ws + o; o += (size_t)NB * HH * TT;
    float* mfx     = ws + o; o += (size_t)NB * TT * CC;
    if (o * sizeof(float) > ws_size) return;  // insufficient workspace -> visible failure

    float* out = (float*)d_out;
    float* out_assign = out;              // (N,2,100) = 6400
    float* out_sidx   = out + 6400;       // 32
    float* out_didx   = out + 6432;       // 32
    float* out_srm    = out + 6464;       // 3200
    float* out_smd    = out + 9664;       // 3200

    prep_kernel<<<NB, 256, 0, stream>>>(hs, sum_all, c1mean, centB, kv_ext);
    // fused K+V projection: W rows 256..767 of in_proj_w
    gemm_bias<<<dim3((NB * SM + 63) / 64, 512 / 64), 256, 0, stream>>>(
        kv_ext, ipw + 256 * 256, ipb + 256, kvh, NB * SM, 512);
    smhaB_kernel<<<NB, 256, 0, stream>>>(centB, kvh, ipw, ipb, ow, ob,
                                         out_assign, out_sidx, out_didx, cd, cs);
    for (int b = 0; b < 2; ++b) {
        int Sb = b ? SM : QQ;
        branch_prep<<<NB * QQ, 256, 0, stream>>>(hs, sum_all, c1mean, kv_ext, cen, Sb, b);
        gemm_bias<<<dim3(NB * TT / 64, 256 / 64), 256, 0, stream>>>(cen, ipw, ipb, qh, NB * TT, 256);
        attn_kernel<<<NB * HH, 256, 0, stream>>>(qh, kvh, pv, rowsum, Sb);
        gemm_bias<<<dim3(NB * TT / 64, 256 / 64), 256, 0, stream>>>(pv, ow, ob, mfx, NB * TT, 256);
        shift_kernel<<<NB * QQ, 256, 0, stream>>>(rowsum, mfx, cd, cs, b ? out_smd : out_srm);
    }
}

// Round 2
// 264.029 us; speedup vs baseline: 1.5850x; 1.5850x over previous
//
#include <hip/hip_runtime.h>
#include <math.h>

#define NB 32
#define QQ 100
#define CC 256
#define HH 8
#define DH 32
#define SM 101   // kv_ext rows per batch (100 points + mean)
#define TT 200   // branch queries per batch
#define PW 768   // P_all row width (q|k|v projections)

// ---------------- prep: sums, mean center, far point, centers, kv_ext ----------------
__global__ void prep_kernel(const float* __restrict__ hs, float* __restrict__ sum_all,
                            float* __restrict__ c1mean, float* __restrict__ centB,
                            float* __restrict__ kv_ext) {
    int n = blockIdx.x;
    int c = threadIdx.x; // 0..255
    const float* h = hs + (size_t)n * QQ * CC;
    float s = 0.f;
    for (int q = 0; q < QQ; ++q) s += h[q * CC + c];
    float c1 = s * (1.0f / QQ);
    sum_all[n * CC + c] = s;
    c1mean[n * CC + c] = c1;
    __shared__ float c1s[CC];
    __shared__ float dls[QQ];
    c1s[c] = c1;
    float* kve = kv_ext + (size_t)n * SM * CC;
    for (int idx = c; idx < QQ * CC; idx += CC) kve[idx] = h[idx];
    kve[QQ * CC + c] = c1;
    __syncthreads();
    int wave = c >> 6, lane = c & 63;
    for (int q = wave; q < QQ; q += 4) {
        float p = 0.f;
        for (int cc = lane; cc < CC; cc += 64) {
            float d = c1s[cc] - h[q * CC + cc];
            p += d * d;
        }
        for (int off = 32; off > 0; off >>= 1) p += __shfl_down(p, off);
        if (lane == 0) dls[q] = p;
    }
    __syncthreads();
    __shared__ int fars;
    if (c == 0) {
        int best = 0; float bv = dls[0];
        for (int q = 1; q < QQ; ++q) if (dls[q] > bv) { bv = dls[q]; best = q; }
        fars = best;
    }
    __syncthreads();
    int far = fars;
    centB[(size_t)n * 2 * CC + c] = c1s[c];
    centB[(size_t)n * 2 * CC + CC + c] = h[(size_t)far * CC + c];
}

// ---------------- generic fp32 tiled GEMM: out = A @ W^T + bias ----------------
#define BK 16
__global__ void gemm_bias(const float* __restrict__ A, const float* __restrict__ W,
                          const float* __restrict__ bias, float* __restrict__ out,
                          int M, int Nout) {
    __shared__ float As[BK][64];
    __shared__ float Ws[BK][64];
    int bm = blockIdx.x * 64;
    int bn = blockIdx.y * 64;
    int tid = threadIdx.x;
    int tn = tid & 15, tm = tid >> 4;
    int lr = tid >> 2;
    int lk = (tid & 3) * 4;
    float acc[4][4] = {};
    for (int k0 = 0; k0 < 256; k0 += BK) {
        int am = bm + lr; if (am >= M) am = M - 1;
        const float4 av = *(const float4*)&A[(size_t)am * 256 + k0 + lk];
        const float4 wv = *(const float4*)&W[(size_t)(bn + lr) * 256 + k0 + lk];
        __syncthreads();
        As[lk + 0][lr] = av.x; As[lk + 1][lr] = av.y; As[lk + 2][lr] = av.z; As[lk + 3][lr] = av.w;
        Ws[lk + 0][lr] = wv.x; Ws[lk + 1][lr] = wv.y; Ws[lk + 2][lr] = wv.z; Ws[lk + 3][lr] = wv.w;
        __syncthreads();
#pragma unroll
        for (int kk = 0; kk < BK; ++kk) {
            float a0 = As[kk][tm * 4 + 0], a1 = As[kk][tm * 4 + 1];
            float a2 = As[kk][tm * 4 + 2], a3 = As[kk][tm * 4 + 3];
            float b0 = Ws[kk][tn * 4 + 0], b1 = Ws[kk][tn * 4 + 1];
            float b2 = Ws[kk][tn * 4 + 2], b3 = Ws[kk][tn * 4 + 3];
            acc[0][0] += a0 * b0; acc[0][1] += a0 * b1; acc[0][2] += a0 * b2; acc[0][3] += a0 * b3;
            acc[1][0] += a1 * b0; acc[1][1] += a1 * b1; acc[1][2] += a1 * b2; acc[1][3] += a1 * b3;
            acc[2][0] += a2 * b0; acc[2][1] += a2 * b1; acc[2][2] += a2 * b2; acc[2][3] += a2 * b3;
            acc[3][0] += a3 * b0; acc[3][1] += a3 * b1; acc[3][2] += a3 * b2; acc[3][3] += a3 * b3;
        }
    }
#pragma unroll
    for (int i = 0; i < 4; ++i) {
        int m = bm + tm * 4 + i;
        if (m < M) {
#pragma unroll
            for (int j = 0; j < 4; ++j) {
                int o = bn + tn * 4 + j;
                out[(size_t)m * Nout + o] = acc[i][j] + bias[o];
            }
        }
    }
}

// ---------------- batched Gram: Gfull[n] = kv_ext[n] @ kv_ext[n]^T (101x101) ----------------
__global__ void gram_kernel(const float* __restrict__ kv_ext, float* __restrict__ Gfull) {
    int n = blockIdx.z;
    __shared__ float As[BK][64];
    __shared__ float Ws[BK][64];
    const float* A = kv_ext + (size_t)n * SM * CC;
    float* G = Gfull + (size_t)n * SM * SM;
    int bm = blockIdx.x * 64;
    int bn = blockIdx.y * 64;
    int tid = threadIdx.x;
    int tn = tid & 15, tm = tid >> 4;
    int lr = tid >> 2;
    int lk = (tid & 3) * 4;
    float acc[4][4] = {};
    for (int k0 = 0; k0 < 256; k0 += BK) {
        int am = bm + lr; if (am >= SM) am = SM - 1;
        int wm = bn + lr; if (wm >= SM) wm = SM - 1;
        const float4 av = *(const float4*)&A[(size_t)am * CC + k0 + lk];
        const float4 wv = *(const float4*)&A[(size_t)wm * CC + k0 + lk];
        __syncthreads();
        As[lk + 0][lr] = av.x; As[lk + 1][lr] = av.y; As[lk + 2][lr] = av.z; As[lk + 3][lr] = av.w;
        Ws[lk + 0][lr] = wv.x; Ws[lk + 1][lr] = wv.y; Ws[lk + 2][lr] = wv.z; Ws[lk + 3][lr] = wv.w;
        __syncthreads();
#pragma unroll
        for (int kk = 0; kk < BK; ++kk) {
            float a0 = As[kk][tm * 4 + 0], a1 = As[kk][tm * 4 + 1];
            float a2 = As[kk][tm * 4 + 2], a3 = As[kk][tm * 4 + 3];
            float b0 = Ws[kk][tn * 4 + 0], b1 = Ws[kk][tn * 4 + 1];
            float b2 = Ws[kk][tn * 4 + 2], b3 = Ws[kk][tn * 4 + 3];
            acc[0][0] += a0 * b0; acc[0][1] += a0 * b1; acc[0][2] += a0 * b2; acc[0][3] += a0 * b3;
            acc[1][0] += a1 * b0; acc[1][1] += a1 * b1; acc[1][2] += a1 * b2; acc[1][3] += a1 * b3;
            acc[2][0] += a2 * b0; acc[2][1] += a2 * b1; acc[2][2] += a2 * b2; acc[2][3] += a2 * b3;
            acc[3][0] += a3 * b0; acc[3][1] += a3 * b1; acc[3][2] += a3 * b2; acc[3][3] += a3 * b3;
        }
    }
#pragma unroll
    for (int i = 0; i < 4; ++i) {
        int m = bm + tm * 4 + i;
        if (m < SM) {
#pragma unroll
            for (int j = 0; j < 4; ++j) {
                int o = bn + tn * 4 + j;
                if (o < SM) G[(size_t)m * SM + o] = acc[i][j];
            }
        }
    }
}

// ---------------- far selection from Gram (both branches) ----------------
__global__ void far_kernel(const float* __restrict__ Gfull, int* __restrict__ far_rm,
                           int* __restrict__ far_md) {
    int n = blockIdx.x; int tid = threadIdx.x;
    __shared__ float sumdot[SM], meandot[SM], norm[SM];
    const float* G = Gfull + (size_t)n * SM * SM;
    for (int s = tid; s < SM; s += 256) {
        const float* row = G + (size_t)s * SM;
        float acc = 0.f;
        for (int q = 0; q < QQ; ++q) acc += row[q];   // symmetric: row sum = column sum
        sumdot[s] = acc; meandot[s] = row[QQ]; norm[s] = row[s];
    }
    __syncthreads();
    if (tid < QQ) {           // rm branch: Sb=100
        int q = tid, qm1 = (q + QQ - 1) % QQ;
        const float* gq = G + (size_t)qm1 * SM;
        int best = -1; float bv = -1e30f;
        for (int s = 0; s < QQ; ++s) {
            if (s == qm1) continue;
            float val = norm[s] - (sumdot[s] - gq[s]) * (2.f / 99.f);
            if (val > bv) { bv = val; best = s; }
        }
        far_rm[n * QQ + q] = best;
    } else if (tid >= 128 && tid < 128 + QQ) {  // md branch: Sb=101
        int q = tid - 128, qm1 = (q + QQ - 1) % QQ;
        const float* gq = G + (size_t)qm1 * SM;
        int best = -1; float bv = -1e30f;
        for (int s = 0; s < SM; ++s) {
            if (s == qm1) continue;
            float val = norm[s] - (sumdot[s] - gq[s] + meandot[s]) * (2.f / 100.f);
            if (val > bv) { bv = val; best = s; }
        }
        far_md[n * QQ + q] = best;
    }
}

// ---------------- Psum0[n][c] = sum_{q<100} P_all[n][q][c], c<256 ----------------
__global__ void psum_kernel(const float* __restrict__ P_all, float* __restrict__ Psum0) {
    int n = blockIdx.x; int c = threadIdx.x;
    const float* base = P_all + (size_t)n * SM * PW + c;
    float acc = 0.f;
    for (int q = 0; q < QQ; ++q) acc += base[(size_t)q * PW];
    Psum0[n * CC + c] = acc;
}

// ---------------- stage B: small SMHA (2 queries), fused ----------------
__global__ void smhaB_kernel(const float* __restrict__ centB, const float* __restrict__ P_all,
                             const float* __restrict__ ipw, const float* __restrict__ ipb,
                             const float* __restrict__ ow, const float* __restrict__ ob,
                             float* __restrict__ out_assign, float* __restrict__ out_sidx,
                             float* __restrict__ out_didx, float* __restrict__ cd,
                             float* __restrict__ cs) {
    int n = blockIdx.x;
    int tid = threadIdx.x;
    __shared__ float qh[2][CC];
    __shared__ float attn[HH][2][QQ];
    __shared__ float pvB[2][CC];
    __shared__ float rs[16];
    __shared__ float mf[2][CC];
    __shared__ int sdi[2];
    const float* cen = centB + (size_t)n * 2 * CC;
    {
        const float* wr = ipw + (size_t)tid * CC;
        float a0 = ipb[tid], a1 = ipb[tid];
        for (int k = 0; k < CC; ++k) { float w = wr[k]; a0 += cen[k] * w; a1 += cen[CC + k] * w; }
        qh[0][tid] = a0; qh[1][tid] = a1;
    }
    __syncthreads();
    const float* base = P_all + (size_t)n * SM * PW;
    const float scl = 0.17677669529663687f;
    for (int idx = tid; idx < HH * 2 * QQ; idx += 256) {
        int h = idx / 200; int r = idx % 200; int t = r / QQ; int s2 = r % QQ;
        float sc = 0.f;
        const float* kr = base + (size_t)s2 * PW + 256 + h * DH;
        const float* qr = &qh[t][h * DH];
        for (int d = 0; d < DH; ++d) sc += qr[d] * kr[d];
        attn[h][t][s2] = 1.f / (1.f + __expf(-sc * scl));
    }
    __syncthreads();
    if (tid < 16) {
        int h = tid >> 1, t = tid & 1; float s = 0.f;
        for (int s2 = 0; s2 < QQ; ++s2) s += attn[h][t][s2];
        rs[tid] = s;
    }
    __syncthreads();
    for (int idx = tid; idx < 2 * QQ; idx += 256) {
        int t = idx / QQ, s2 = idx % QQ;
        float m = 0.f;
        for (int h = 0; h < HH; ++h) m += attn[h][t][s2];
        out_assign[(size_t)n * 2 * QQ + idx] = m * 0.125f;
    }
    if (tid == 0) {
        float c0 = 0.f, c1v = 0.f;
        for (int h = 0; h < HH; ++h) { c0 += rs[h * 2 + 0]; c1v += rs[h * 2 + 1]; }
        int si = (c1v < c0) ? 1 : 0;
        int di = (c1v > c0) ? 1 : 0;
        sdi[0] = si; sdi[1] = di;
        out_sidx[n] = (float)si;
        out_didx[n] = (float)di;
    }
    for (int idx = tid; idx < 512; idx += 256) {
        int t = idx >> 8; int hd = idx & 255; int h = hd >> 5;
        float inv = 1.f / (rs[h * 2 + t] + 1e-4f);
        float a = 0.f;
        const float* vr = base + 512 + hd;
        for (int s2 = 0; s2 < QQ; ++s2) a += attn[h][t][s2] * vr[(size_t)s2 * PW];
        pvB[t][hd] = a * inv;
    }
    __syncthreads();
    {
        const float* wr = ow + (size_t)tid * CC;
        float a0 = ob[tid], a1 = ob[tid];
        for (int k = 0; k < CC; ++k) { float w = wr[k]; a0 += pvB[0][k] * w; a1 += pvB[1][k] * w; }
        mf[0][tid] = a0; mf[1][tid] = a1;
    }
    __syncthreads();
    cd[(size_t)n * CC + tid] = mf[sdi[1]][tid];
    cs[(size_t)n * CC + tid] = mf[sdi[0]][tid];
}

// ---------------- branch attention: in-register Q gather + sigmoid scores + PV ----------------
__global__ void attn_fused(const float* __restrict__ P_all, const float* __restrict__ Psum0,
                           const int* __restrict__ far, float* __restrict__ pv,
                           float* __restrict__ rowsum, int Sb, float invdenom, int b) {
    int n = blockIdx.x >> 3; int h = blockIdx.x & 7;
    int tid = threadIdx.x;
    __shared__ float ks[SM][DH];
    __shared__ float vs[SM][DH];
    const float* base = P_all + (size_t)n * SM * PW;
    for (int idx = tid; idx < Sb * DH; idx += 256) {
        int s = idx >> 5; int d = idx & 31;
        ks[s][d] = base[(size_t)s * PW + 256 + h * DH + d];
        vs[s][d] = base[(size_t)s * PW + 512 + h * DH + d];
    }
    __syncthreads();
    if (tid < TT) {
        int t = tid; int q = t >> 1;
        int qm1 = (q + QQ - 1) % QQ;
        float qreg[DH];
        if (t & 1) {
            int f = far[n * QQ + q];
            const float* pr = base + (size_t)f * PW + h * DH;
#pragma unroll
            for (int d = 0; d < DH; ++d) qreg[d] = pr[d];
        } else {
            const float* ps = Psum0 + n * CC + h * DH;
            const float* pm = base + (size_t)qm1 * PW + h * DH;
            const float* pmean = base + (size_t)QQ * PW + h * DH;
#pragma unroll
            for (int d = 0; d < DH; ++d)
                qreg[d] = (ps[d] - pm[d] + (b ? pmean[d] : 0.f)) * invdenom;
        }
        float acc[DH] = {};
        float rsum = 0.f;
        int mk = q;  // attention mask: key s == q
        const float scl = 0.17677669529663687f;
        for (int s = 0; s < Sb; ++s) {
            float sc = 0.f;
#pragma unroll
            for (int d = 0; d < DH; ++d) sc += qreg[d] * ks[s][d];
            float a = 1.f / (1.f + __expf(-sc * scl));
            if (s == mk) a = 0.f;
            rsum += a;
#pragma unroll
            for (int d = 0; d < DH; ++d) acc[d] += a * vs[s][d];
        }
        rowsum[((size_t)n * HH + h) * TT + t] = rsum;
        float inv = 1.f / (rsum + 1e-4f);
        float* pr = pv + ((size_t)n * TT + t) * CC + h * DH;
#pragma unroll
        for (int d = 0; d < DH; ++d) pr[d] = acc[d] * inv;
    }
}

// ---------------- shift: card argmin/argmax + distances ----------------
__global__ void shift_kernel(const float* __restrict__ rowsum, const float* __restrict__ mfx,
                             const float* __restrict__ cd, const float* __restrict__ cs,
                             float* __restrict__ out_shift) {
    int n = blockIdx.x / QQ; int q = blockIdx.x % QQ;
    int tid = threadIdx.x;
    __shared__ float red[256];
    __shared__ int sdi[2];
    if (tid == 0) {
        float c0 = 0.f, c1v = 0.f;
        for (int h = 0; h < HH; ++h) {
            c0  += rowsum[((size_t)n * HH + h) * TT + 2 * q];
            c1v += rowsum[((size_t)n * HH + h) * TT + 2 * q + 1];
        }
        sdi[0] = (c1v < c0) ? 1 : 0;
        sdi[1] = (c1v > c0) ? 1 : 0;
    }
    __syncthreads();
    int si = sdi[0], di = sdi[1];
    const float* mdp = mfx + ((size_t)n * TT + 2 * q + di) * CC;
    const float* msp = mfx + ((size_t)n * TT + 2 * q + si) * CC;
    float dd = mdp[tid] - cd[(size_t)n * CC + tid];
    float ds = msp[tid] - cs[(size_t)n * CC + tid];
    red[tid] = dd * dd;
    __syncthreads();
    for (int off = 128; off > 0; off >>= 1) { if (tid < off) red[tid] += red[tid + off]; __syncthreads(); }
    float distd = sqrtf(red[0] + 1e-12f);
    __syncthreads();
    red[tid] = ds * ds;
    __syncthreads();
    for (int off = 128; off > 0; off >>= 1) { if (tid < off) red[tid] += red[tid + off]; __syncthreads(); }
    if (tid == 0) out_shift[blockIdx.x] = distd + sqrtf(red[0] + 1e-12f);
}

extern "C" void kernel_launch(void* const* d_in, const int* in_sizes, int n_in,
                              void* d_out, int out_size, void* d_ws, size_t ws_size,
                              hipStream_t stream) {
    const float* hs_pair = (const float*)d_in[0];
    const float* ipw = (const float*)d_in[1];
    const float* ipb = (const float*)d_in[2];
    const float* ow  = (const float*)d_in[3];
    const float* ob  = (const float*)d_in[4];
    const float* hs = hs_pair + (size_t)5 * NB * QQ * CC;  // hs_pair[-1]

    float* ws = (float*)d_ws;
    size_t o = 0;
    float* sum_all = ws + o; o += NB * CC;
    float* c1mean  = ws + o; o += NB * CC;
    float* centB   = ws + o; o += (size_t)NB * 2 * CC;
    float* kv_ext  = ws + o; o += (size_t)NB * SM * CC;
    float* P_all   = ws + o; o += (size_t)NB * SM * PW;
    float* Psum0   = ws + o; o += NB * CC;
    float* Gfull   = ws + o; o += (size_t)NB * SM * SM;
    int*   far_rm  = (int*)(ws + o); o += NB * QQ;
    int*   far_md  = (int*)(ws + o); o += NB * QQ;
    float* cd      = ws + o; o += NB * CC;
    float* cs      = ws + o; o += NB * CC;
    float* pv      = ws + o; o += (size_t)NB * TT * CC;
    float* rowsum  = ws + o; o += (size_t)NB * HH * TT;
    float* mfx     = ws + o; o += (size_t)NB * TT * CC;
    if (o * sizeof(float) > ws_size) return;

    float* out = (float*)d_out;
    float* out_assign = out;
    float* out_sidx   = out + 6400;
    float* out_didx   = out + 6432;
    float* out_srm    = out + 6464;
    float* out_smd    = out + 9664;

    prep_kernel<<<NB, 256, 0, stream>>>(hs, sum_all, c1mean, centB, kv_ext);
    // fused Q+K+V projection: full in_proj
    gemm_bias<<<dim3((NB * SM + 63) / 64, PW / 64), 256, 0, stream>>>(
        kv_ext, ipw, ipb, P_all, NB * SM, PW);
    psum_kernel<<<NB, 256, 0, stream>>>(P_all, Psum0);
    gram_kernel<<<dim3(2, 2, NB), 256, 0, stream>>>(kv_ext, Gfull);
    far_kernel<<<NB, 256, 0, stream>>>(Gfull, far_rm, far_md);
    smhaB_kernel<<<NB, 256, 0, stream>>>(centB, P_all, ipw, ipb, ow, ob,
                                         out_assign, out_sidx, out_didx, cd, cs);
    for (int b = 0; b < 2; ++b) {
        int Sb = b ? SM : QQ;
        attn_fused<<<NB * HH, 256, 0, stream>>>(P_all, Psum0, b ? far_md : far_rm,
                                                pv, rowsum, Sb, b ? (1.f / 100.f) : (1.f / 99.f), b);
        gemm_bias<<<dim3(NB * TT / 64, 256 / 64), 256, 0, stream>>>(pv, ow, ob, mfx, NB * TT, 256);
        shift_kernel<<<NB * QQ, 256, 0, stream>>>(rowsum, mfx, cd, cs, b ? out_smd : out_srm);
    }
}

// Round 3
// 231.082 us; speedup vs baseline: 1.8110x; 1.1426x over previous
//
#include <hip/hip_runtime.h>
#include <math.h>

#define NB 32
#define QQ 100
#define CC 256
#define HH 8
#define DH 32
#define SM 101   // kv rows per batch (100 points + mean)
#define TT 200   // branch queries per batch
#define TB 400   // both branches
#define PW 768   // P_all row width (q|k|v projections)

// ---------------- prep: sums, mean center, far point, centers, kv_ext ----------------
__global__ void prep_kernel(const float* __restrict__ hs, float* __restrict__ sum_all,
                            float* __restrict__ c1mean, float* __restrict__ centB,
                            float* __restrict__ kv_ext) {
    int n = blockIdx.x;
    int c = threadIdx.x; // 0..255
    const float* h = hs + (size_t)n * QQ * CC;
    float s = 0.f;
    for (int q = 0; q < QQ; ++q) s += h[q * CC + c];
    float c1 = s * (1.0f / QQ);
    sum_all[n * CC + c] = s;
    c1mean[n * CC + c] = c1;
    __shared__ float c1s[CC];
    __shared__ float dls[QQ];
    c1s[c] = c1;
    float* kve = kv_ext + (size_t)n * SM * CC;
    for (int idx = c; idx < QQ * CC; idx += CC) kve[idx] = h[idx];
    kve[QQ * CC + c] = c1;
    __syncthreads();
    int wave = c >> 6, lane = c & 63;
    for (int q = wave; q < QQ; q += 4) {
        float p = 0.f;
        for (int cc = lane; cc < CC; cc += 64) {
            float d = c1s[cc] - h[q * CC + cc];
            p += d * d;
        }
        for (int off = 32; off > 0; off >>= 1) p += __shfl_down(p, off);
        if (lane == 0) dls[q] = p;
    }
    __syncthreads();
    __shared__ int fars;
    if (c == 0) {
        int best = 0; float bv = dls[0];
        for (int q = 1; q < QQ; ++q) if (dls[q] > bv) { bv = dls[q]; best = q; }
        fars = best;
    }
    __syncthreads();
    int far = fars;
    centB[(size_t)n * 2 * CC + c] = c1s[c];
    centB[(size_t)n * 2 * CC + CC + c] = h[(size_t)far * CC + c];
}

// ---------------- generic fp32 tiled GEMM: out = A @ W^T + bias ----------------
#define BK 32
__global__ void gemm_bias(const float* __restrict__ A, const float* __restrict__ W,
                          const float* __restrict__ bias, float* __restrict__ out,
                          int M, int Nout) {
    __shared__ float As[BK][64];
    __shared__ float Ws[BK][64];
    int bm = blockIdx.x * 64;
    int bn = blockIdx.y * 64;
    int tid = threadIdx.x;
    int tn = tid & 15, tm = tid >> 4;
    int lr = tid >> 2;
    int lk = (tid & 3) * 8;
    float acc[4][4] = {};
    for (int k0 = 0; k0 < 256; k0 += BK) {
        int am = bm + lr; if (am >= M) am = M - 1;
        const float4 a0 = *(const float4*)&A[(size_t)am * 256 + k0 + lk];
        const float4 a1 = *(const float4*)&A[(size_t)am * 256 + k0 + lk + 4];
        const float4 w0 = *(const float4*)&W[(size_t)(bn + lr) * 256 + k0 + lk];
        const float4 w1 = *(const float4*)&W[(size_t)(bn + lr) * 256 + k0 + lk + 4];
        __syncthreads();
        As[lk + 0][lr] = a0.x; As[lk + 1][lr] = a0.y; As[lk + 2][lr] = a0.z; As[lk + 3][lr] = a0.w;
        As[lk + 4][lr] = a1.x; As[lk + 5][lr] = a1.y; As[lk + 6][lr] = a1.z; As[lk + 7][lr] = a1.w;
        Ws[lk + 0][lr] = w0.x; Ws[lk + 1][lr] = w0.y; Ws[lk + 2][lr] = w0.z; Ws[lk + 3][lr] = w0.w;
        Ws[lk + 4][lr] = w1.x; Ws[lk + 5][lr] = w1.y; Ws[lk + 6][lr] = w1.z; Ws[lk + 7][lr] = w1.w;
        __syncthreads();
#pragma unroll
        for (int kk = 0; kk < BK; ++kk) {
            float a0r = As[kk][tm * 4 + 0], a1r = As[kk][tm * 4 + 1];
            float a2r = As[kk][tm * 4 + 2], a3r = As[kk][tm * 4 + 3];
            float b0 = Ws[kk][tn * 4 + 0], b1 = Ws[kk][tn * 4 + 1];
            float b2 = Ws[kk][tn * 4 + 2], b3 = Ws[kk][tn * 4 + 3];
            acc[0][0] += a0r * b0; acc[0][1] += a0r * b1; acc[0][2] += a0r * b2; acc[0][3] += a0r * b3;
            acc[1][0] += a1r * b0; acc[1][1] += a1r * b1; acc[1][2] += a1r * b2; acc[1][3] += a1r * b3;
            acc[2][0] += a2r * b0; acc[2][1] += a2r * b1; acc[2][2] += a2r * b2; acc[2][3] += a2r * b3;
            acc[3][0] += a3r * b0; acc[3][1] += a3r * b1; acc[3][2] += a3r * b2; acc[3][3] += a3r * b3;
        }
    }
#pragma unroll
    for (int i = 0; i < 4; ++i) {
        int m = bm + tm * 4 + i;
        if (m < M) {
#pragma unroll
            for (int j = 0; j < 4; ++j) {
                int o = bn + tn * 4 + j;
                out[(size_t)m * Nout + o] = acc[i][j] + bias[o];
            }
        }
    }
}

// ---------------- batched Gram: Gfull[n] = kv_ext[n] @ kv_ext[n]^T (101x101) ----------------
#define GBK 16
__global__ void gram_kernel(const float* __restrict__ kv_ext, float* __restrict__ Gfull) {
    int n = blockIdx.z;
    __shared__ float As[GBK][64];
    __shared__ float Ws[GBK][64];
    const float* A = kv_ext + (size_t)n * SM * CC;
    float* G = Gfull + (size_t)n * SM * SM;
    int bm = blockIdx.x * 64;
    int bn = blockIdx.y * 64;
    int tid = threadIdx.x;
    int tn = tid & 15, tm = tid >> 4;
    int lr = tid >> 2;
    int lk = (tid & 3) * 4;
    float acc[4][4] = {};
    for (int k0 = 0; k0 < 256; k0 += GBK) {
        int am = bm + lr; if (am >= SM) am = SM - 1;
        int wm = bn + lr; if (wm >= SM) wm = SM - 1;
        const float4 av = *(const float4*)&A[(size_t)am * CC + k0 + lk];
        const float4 wv = *(const float4*)&A[(size_t)wm * CC + k0 + lk];
        __syncthreads();
        As[lk + 0][lr] = av.x; As[lk + 1][lr] = av.y; As[lk + 2][lr] = av.z; As[lk + 3][lr] = av.w;
        Ws[lk + 0][lr] = wv.x; Ws[lk + 1][lr] = wv.y; Ws[lk + 2][lr] = wv.z; Ws[lk + 3][lr] = wv.w;
        __syncthreads();
#pragma unroll
        for (int kk = 0; kk < GBK; ++kk) {
            float a0 = As[kk][tm * 4 + 0], a1 = As[kk][tm * 4 + 1];
            float a2 = As[kk][tm * 4 + 2], a3 = As[kk][tm * 4 + 3];
            float b0 = Ws[kk][tn * 4 + 0], b1 = Ws[kk][tn * 4 + 1];
            float b2 = Ws[kk][tn * 4 + 2], b3 = Ws[kk][tn * 4 + 3];
            acc[0][0] += a0 * b0; acc[0][1] += a0 * b1; acc[0][2] += a0 * b2; acc[0][3] += a0 * b3;
            acc[1][0] += a1 * b0; acc[1][1] += a1 * b1; acc[1][2] += a1 * b2; acc[1][3] += a1 * b3;
            acc[2][0] += a2 * b0; acc[2][1] += a2 * b1; acc[2][2] += a2 * b2; acc[2][3] += a2 * b3;
            acc[3][0] += a3 * b0; acc[3][1] += a3 * b1; acc[3][2] += a3 * b2; acc[3][3] += a3 * b3;
        }
    }
#pragma unroll
    for (int i = 0; i < 4; ++i) {
        int m = bm + tm * 4 + i;
        if (m < SM) {
#pragma unroll
            for (int j = 0; j < 4; ++j) {
                int o = bn + tn * 4 + j;
                if (o < SM) G[(size_t)m * SM + o] = acc[i][j];
            }
        }
    }
}

// ---------------- far selection from Gram (both branches) ----------------
__global__ void far_kernel(const float* __restrict__ Gfull, int* __restrict__ far_rm,
                           int* __restrict__ far_md) {
    int n = blockIdx.x; int tid = threadIdx.x;
    __shared__ float sumdot[SM], meandot[SM], norm[SM];
    const float* G = Gfull + (size_t)n * SM * SM;
    for (int s = tid; s < SM; s += 256) {
        const float* row = G + (size_t)s * SM;
        float acc = 0.f;
        for (int q = 0; q < QQ; ++q) acc += row[q];
        sumdot[s] = acc; meandot[s] = row[QQ]; norm[s] = row[s];
    }
    __syncthreads();
    if (tid < QQ) {
        int q = tid, qm1 = (q + QQ - 1) % QQ;
        const float* gq = G + (size_t)qm1 * SM;
        int best = -1; float bv = -1e30f;
        for (int s = 0; s < QQ; ++s) {
            if (s == qm1) continue;
            float val = norm[s] - (sumdot[s] - gq[s]) * (2.f / 99.f);
            if (val > bv) { bv = val; best = s; }
        }
        far_rm[n * QQ + q] = best;
    } else if (tid >= 128 && tid < 128 + QQ) {
        int q = tid - 128, qm1 = (q + QQ - 1) % QQ;
        const float* gq = G + (size_t)qm1 * SM;
        int best = -1; float bv = -1e30f;
        for (int s = 0; s < SM; ++s) {
            if (s == qm1) continue;
            float val = norm[s] - (sumdot[s] - gq[s] + meandot[s]) * (2.f / 100.f);
            if (val > bv) { bv = val; best = s; }
        }
        far_md[n * QQ + q] = best;
    }
}

// ---------------- Psum0[n][c] = sum_{q<100} P_all[n][q][c], c<256 ----------------
__global__ void psum_kernel(const float* __restrict__ P_all, float* __restrict__ Psum0) {
    int n = blockIdx.x; int c = threadIdx.x;
    const float* base = P_all + (size_t)n * SM * PW + c;
    float acc = 0.f;
    for (int q = 0; q < QQ; ++q) acc += base[(size_t)q * PW];
    Psum0[n * CC + c] = acc;
}

// ---------------- stage B: small SMHA (2 queries), fused ----------------
__global__ void smhaB_kernel(const float* __restrict__ centB, const float* __restrict__ P_all,
                             const float* __restrict__ ipw, const float* __restrict__ ipb,
                             const float* __restrict__ ow, const float* __restrict__ ob,
                             float* __restrict__ out_assign, float* __restrict__ out_sidx,
                             float* __restrict__ out_didx, float* __restrict__ cd,
                             float* __restrict__ cs) {
    int n = blockIdx.x;
    int tid = threadIdx.x;
    __shared__ float qh[2][CC];
    __shared__ float attn[HH][2][QQ];
    __shared__ float pvB[2][CC];
    __shared__ float rs[16];
    __shared__ float mf[2][CC];
    __shared__ int sdi[2];
    const float* cen = centB + (size_t)n * 2 * CC;
    {
        const float* wr = ipw + (size_t)tid * CC;
        float a0 = ipb[tid], a1 = ipb[tid];
        for (int k = 0; k < CC; ++k) { float w = wr[k]; a0 += cen[k] * w; a1 += cen[CC + k] * w; }
        qh[0][tid] = a0; qh[1][tid] = a1;
    }
    __syncthreads();
    const float* base = P_all + (size_t)n * SM * PW;
    const float scl = 0.17677669529663687f;
    for (int idx = tid; idx < HH * 2 * QQ; idx += 256) {
        int h = idx / 200; int r = idx % 200; int t = r / QQ; int s2 = r % QQ;
        float sc = 0.f;
        const float* kr = base + (size_t)s2 * PW + 256 + h * DH;
        const float* qr = &qh[t][h * DH];
        for (int d = 0; d < DH; ++d) sc += qr[d] * kr[d];
        attn[h][t][s2] = 1.f / (1.f + __expf(-sc * scl));
    }
    __syncthreads();
    if (tid < 16) {
        int h = tid >> 1, t = tid & 1; float s = 0.f;
        for (int s2 = 0; s2 < QQ; ++s2) s += attn[h][t][s2];
        rs[tid] = s;
    }
    __syncthreads();
    for (int idx = tid; idx < 2 * QQ; idx += 256) {
        int t = idx / QQ, s2 = idx % QQ;
        float m = 0.f;
        for (int h = 0; h < HH; ++h) m += attn[h][t][s2];
        out_assign[(size_t)n * 2 * QQ + idx] = m * 0.125f;
    }
    if (tid == 0) {
        float c0 = 0.f, c1v = 0.f;
        for (int h = 0; h < HH; ++h) { c0 += rs[h * 2 + 0]; c1v += rs[h * 2 + 1]; }
        int si = (c1v < c0) ? 1 : 0;
        int di = (c1v > c0) ? 1 : 0;
        sdi[0] = si; sdi[1] = di;
        out_sidx[n] = (float)si;
        out_didx[n] = (float)di;
    }
    for (int idx = tid; idx < 512; idx += 256) {
        int t = idx >> 8; int hd = idx & 255; int h = hd >> 5;
        float inv = 1.f / (rs[h * 2 + t] + 1e-4f);
        float a = 0.f;
        const float* vr = base + 512 + hd;
        for (int s2 = 0; s2 < QQ; ++s2) a += attn[h][t][s2] * vr[(size_t)s2 * PW];
        pvB[t][hd] = a * inv;
    }
    __syncthreads();
    {
        const float* wr = ow + (size_t)tid * CC;
        float a0 = ob[tid], a1 = ob[tid];
        for (int k = 0; k < CC; ++k) { float w = wr[k]; a0 += pvB[0][k] * w; a1 += pvB[1][k] * w; }
        mf[0][tid] = a0; mf[1][tid] = a1;
    }
    __syncthreads();
    cd[(size_t)n * CC + tid] = mf[sdi[1]][tid];
    cs[(size_t)n * CC + tid] = mf[sdi[0]][tid];
}

// ---------------- both-branch attention: two-phase cooperative ----------------
// grid (7, HH, NB), 256 threads. 64 query rows per block from the 400 combined rows.
__global__ void attn_both(const float* __restrict__ P_all, const float* __restrict__ Psum0,
                          const int* __restrict__ far_rm, const int* __restrict__ far_md,
                          float* __restrict__ pv, float* __restrict__ rowsum) {
    int n = blockIdx.z, h = blockIdx.y;
    int r0 = blockIdx.x * 64;
    int tid = threadIdx.x;
    __shared__ float ks_t[32][104];     // K transposed, zero-padded s>=101
    __shared__ float vs[SM][32];
    __shared__ float scores[64][103];   // odd stride -> conflict-free columns
    __shared__ float inv[64];
    const float* base = P_all + (size_t)n * SM * PW;
    for (int idx = tid; idx < 32 * 104; idx += 256) {
        int d = idx & 31, s = idx >> 5;
        ks_t[d][s] = (s < SM) ? base[(size_t)s * PW + 256 + h * DH + d] : 0.f;
    }
    for (int idx = tid; idx < SM * 32; idx += 256) {
        int d = idx & 31, s = idx >> 5;
        vs[s][d] = base[(size_t)s * PW + 512 + h * DH + d];
    }
    int tq = tid & 63, sg = tid >> 6;
    int row = r0 + tq;
    int valid = row < TB;
    float qreg[DH];
    int mk = -1, sbrow = 0;
    if (valid) {
        int b = row >= TT;
        int t = row - b * TT;
        int q = t >> 1;
        mk = q; sbrow = b ? SM : QQ;
        if (t & 1) {
            int f = (b ? far_md : far_rm)[n * QQ + q];
            const float4* pr = (const float4*)(base + (size_t)f * PW + h * DH);
#pragma unroll
            for (int j = 0; j < 8; ++j) {
                float4 v = pr[j];
                qreg[4 * j] = v.x; qreg[4 * j + 1] = v.y; qreg[4 * j + 2] = v.z; qreg[4 * j + 3] = v.w;
            }
        } else {
            int qm1 = (q + QQ - 1) % QQ;
            const float* ps = Psum0 + n * CC + h * DH;
            const float* pm = base + (size_t)qm1 * PW + h * DH;
            const float* pmn = base + (size_t)QQ * PW + h * DH;
            float invd = b ? 0.01f : (1.f / 99.f);
#pragma unroll
            for (int d = 0; d < DH; ++d)
                qreg[d] = (ps[d] - pm[d] + (b ? pmn[d] : 0.f)) * invd;
        }
    }
    __syncthreads();
    const float scl = 0.17677669529663687f;
    for (int j = sg; j < 26; j += 4) {   // 4-wide key slices, s0 = 4j
        int s0 = j * 4;
        float sc0 = 0.f, sc1 = 0.f, sc2 = 0.f, sc3 = 0.f;
        if (valid) {
#pragma unroll
            for (int d = 0; d < DH; ++d) {
                float4 kv = *(const float4*)&ks_t[d][s0];
                float qd = qreg[d];
                sc0 += qd * kv.x; sc1 += qd * kv.y; sc2 += qd * kv.z; sc3 += qd * kv.w;
            }
        }
        float scv[4] = {sc0, sc1, sc2, sc3};
#pragma unroll
        for (int jj = 0; jj < 4; ++jj) {
            int s = s0 + jj;
            if (s < SM) {
                float a = 0.f;
                if (valid && s < sbrow && s != mk)
                    a = 1.f / (1.f + __expf(-scv[jj] * scl));
                scores[tq][s] = a;
            }
        }
    }
    __syncthreads();
    if (tid < 64) {
        float rsv = 0.f;
        for (int s = 0; s < SM; ++s) rsv += scores[tid][s];
        inv[tid] = 1.f / (rsv + 1e-4f);
        int rowx = r0 + tid;
        if (rowx < TB) rowsum[((size_t)n * HH + h) * TB + rowx] = rsv;
    }
    __syncthreads();
    float acc[8] = {};
    for (int s = 0; s < SM; ++s) {
        float a = scores[tq][s];
        const float4* vp = (const float4*)&vs[s][sg * 8];
        float4 v0 = vp[0], v1 = vp[1];
        acc[0] += a * v0.x; acc[1] += a * v0.y; acc[2] += a * v0.z; acc[3] += a * v0.w;
        acc[4] += a * v1.x; acc[5] += a * v1.y; acc[6] += a * v1.z; acc[7] += a * v1.w;
    }
    if (valid) {
        float iv = inv[tq];
        float* outp = pv + ((size_t)n * TB + row) * CC + h * DH + sg * 8;
        float4 o0 = {acc[0] * iv, acc[1] * iv, acc[2] * iv, acc[3] * iv};
        float4 o1 = {acc[4] * iv, acc[5] * iv, acc[6] * iv, acc[7] * iv};
        *(float4*)outp = o0; *((float4*)outp + 1) = o1;
    }
}

// ---------------- shift (both branches): card argmin/argmax + distances ----------------
__global__ void shift_both(const float* __restrict__ rowsum, const float* __restrict__ mfx,
                           const float* __restrict__ cd, const float* __restrict__ cs,
                           float* __restrict__ out_srm, float* __restrict__ out_smd) {
    int b = blockIdx.x / (NB * QQ);
    int rem = blockIdx.x % (NB * QQ);
    int n = rem / QQ, q = rem % QQ;
    int tid = threadIdx.x;
    __shared__ float red[256];
    __shared__ int sdi[2];
    if (tid == 0) {
        float c0 = 0.f, c1v = 0.f;
        int rb = b * TT + 2 * q;
        for (int h = 0; h < HH; ++h) {
            c0  += rowsum[((size_t)n * HH + h) * TB + rb];
            c1v += rowsum[((size_t)n * HH + h) * TB + rb + 1];
        }
        sdi[0] = (c1v < c0) ? 1 : 0;
        sdi[1] = (c1v > c0) ? 1 : 0;
    }
    __syncthreads();
    int si = sdi[0], di = sdi[1];
    const float* mdp = mfx + ((size_t)n * TB + b * TT + 2 * q + di) * CC;
    const float* msp = mfx + ((size_t)n * TB + b * TT + 2 * q + si) * CC;
    float dd = mdp[tid] - cd[(size_t)n * CC + tid];
    float ds = msp[tid] - cs[(size_t)n * CC + tid];
    red[tid] = dd * dd;
    __syncthreads();
    for (int off = 128; off > 0; off >>= 1) { if (tid < off) red[tid] += red[tid + off]; __syncthreads(); }
    float distd = sqrtf(red[0] + 1e-12f);
    __syncthreads();
    red[tid] = ds * ds;
    __syncthreads();
    for (int off = 128; off > 0; off >>= 1) { if (tid < off) red[tid] += red[tid + off]; __syncthreads(); }
    if (tid == 0) (b ? out_smd : out_srm)[n * QQ + q] = distd + sqrtf(red[0] + 1e-12f);
}

extern "C" void kernel_launch(void* const* d_in, const int* in_sizes, int n_in,
                              void* d_out, int out_size, void* d_ws, size_t ws_size,
                              hipStream_t stream) {
    const float* hs_pair = (const float*)d_in[0];
    const float* ipw = (const float*)d_in[1];
    const float* ipb = (const float*)d_in[2];
    const float* ow  = (const float*)d_in[3];
    const float* ob  = (const float*)d_in[4];
    const float* hs = hs_pair + (size_t)5 * NB * QQ * CC;  // hs_pair[-1]

    float* ws = (float*)d_ws;
    size_t o = 0;
    // region A: dead after attn_both -> mfx aliases it
    float* kv_ext  = ws + o; o += (size_t)NB * SM * CC;    // 0.827M
    float* P_all   = ws + o; o += (size_t)NB * SM * PW;    // 2.482M
    float* Gfull   = ws + o; o += (size_t)NB * SM * SM;    // 0.326M
    float* mfx     = kv_ext;                               // alias (needs 3.277M <= 3.635M)
    // region B: live throughout
    float* sum_all = ws + o; o += NB * CC;
    float* c1mean  = ws + o; o += NB * CC;
    float* centB   = ws + o; o += (size_t)NB * 2 * CC;
    float* Psum0   = ws + o; o += NB * CC;
    int*   far_rm  = (int*)(ws + o); o += NB * QQ;
    int*   far_md  = (int*)(ws + o); o += NB * QQ;
    float* cd      = ws + o; o += NB * CC;
    float* cs      = ws + o; o += NB * CC;
    float* pv      = ws + o; o += (size_t)NB * TB * CC;
    float* rowsum  = ws + o; o += (size_t)NB * HH * TB;
    if (o * sizeof(float) > ws_size) return;

    float* out = (float*)d_out;
    float* out_assign = out;
    float* out_sidx   = out + 6400;
    float* out_didx   = out + 6432;
    float* out_srm    = out + 6464;
    float* out_smd    = out + 9664;

    prep_kernel<<<NB, 256, 0, stream>>>(hs, sum_all, c1mean, centB, kv_ext);
    gemm_bias<<<dim3((NB * SM + 63) / 64, PW / 64), 256, 0, stream>>>(
        kv_ext, ipw, ipb, P_all, NB * SM, PW);
    psum_kernel<<<NB, 256, 0, stream>>>(P_all, Psum0);
    gram_kernel<<<dim3(2, 2, NB), 256, 0, stream>>>(kv_ext, Gfull);
    far_kernel<<<NB, 256, 0, stream>>>(Gfull, far_rm, far_md);
    smhaB_kernel<<<NB, 256, 0, stream>>>(centB, P_all, ipw, ipb, ow, ob,
                                         out_assign, out_sidx, out_didx, cd, cs);
    attn_both<<<dim3(7, HH, NB), 256, 0, stream>>>(P_all, Psum0, far_rm, far_md, pv, rowsum);
    gemm_bias<<<dim3(NB * TB / 64, CC / 64), 256, 0, stream>>>(pv, ow, ob, mfx, NB * TB, CC);
    shift_both<<<2 * NB * QQ, 256, 0, stream>>>(rowsum, mfx, cd, cs, out_srm, out_smd);
}

// Round 4
// 228.664 us; speedup vs baseline: 1.8301x; 1.0106x over previous
//
#include <hip/hip_runtime.h>
#include <math.h>

#define NB 32
#define QQ 100
#define CC 256
#define HH 8
#define DH 32
#define SM 101   // kv rows per batch (100 points + mean)
#define TT 200   // branch queries per batch
#define TB 400   // both branches
#define PW 768   // P_all row width (q|k|v projections)

// ---------------- prep: sums, mean center, far point, centers, kv_ext ----------------
__global__ void prep_kernel(const float* __restrict__ hs, float* __restrict__ sum_all,
                            float* __restrict__ c1mean, float* __restrict__ centB,
                            float* __restrict__ kv_ext) {
    int n = blockIdx.x;
    int c = threadIdx.x; // 0..255
    const float* h = hs + (size_t)n * QQ * CC;
    float s = 0.f;
    for (int q = 0; q < QQ; ++q) s += h[q * CC + c];
    float c1 = s * (1.0f / QQ);
    sum_all[n * CC + c] = s;
    c1mean[n * CC + c] = c1;
    __shared__ float c1s[CC];
    __shared__ float dls[QQ];
    c1s[c] = c1;
    float* kve = kv_ext + (size_t)n * SM * CC;
    for (int idx = c; idx < QQ * CC; idx += CC) kve[idx] = h[idx];
    kve[QQ * CC + c] = c1;
    __syncthreads();
    int wave = c >> 6, lane = c & 63;
    for (int q = wave; q < QQ; q += 4) {
        float p = 0.f;
        for (int cc = lane; cc < CC; cc += 64) {
            float d = c1s[cc] - h[q * CC + cc];
            p += d * d;
        }
        for (int off = 32; off > 0; off >>= 1) p += __shfl_down(p, off);
        if (lane == 0) dls[q] = p;
    }
    __syncthreads();
    __shared__ int fars;
    if (c == 0) {
        int best = 0; float bv = dls[0];
        for (int q = 1; q < QQ; ++q) if (dls[q] > bv) { bv = dls[q]; best = q; }
        fars = best;
    }
    __syncthreads();
    int far = fars;
    centB[(size_t)n * 2 * CC + c] = c1s[c];
    centB[(size_t)n * 2 * CC + CC + c] = h[(size_t)far * CC + c];
}

// ---------------- fp32 tiled GEMM v2: 128x64 tile, BK=32, out = A @ W^T + bias ----------------
__global__ __launch_bounds__(256, 4)
void gemm_bias(const float* __restrict__ A, const float* __restrict__ W,
               const float* __restrict__ bias, float* __restrict__ out,
               int M, int Nout) {
    __shared__ float As[32][128];
    __shared__ float Ws[32][64];
    int bm = blockIdx.x * 128;
    int bn = blockIdx.y * 64;
    int tid = threadIdx.x;
    int tm = tid & 31, tn = tid >> 5;          // 32x8 thread grid -> 4 rows x 8 cols each
    int ar = tid >> 1, ak = (tid & 1) * 16;    // A staging: 2 threads/row, 16 k each
    int wr = tid >> 2, wk = (tid & 3) * 8;     // W staging: 4 threads/row, 8 k each
    float acc[4][8] = {};
    for (int k0 = 0; k0 < 256; k0 += 32) {
        int am = bm + ar; if (am >= M) am = M - 1;
        float4 av[4], wv[2];
#pragma unroll
        for (int i = 0; i < 4; ++i)
            av[i] = *(const float4*)&A[(size_t)am * 256 + k0 + ak + 4 * i];
#pragma unroll
        for (int i = 0; i < 2; ++i)
            wv[i] = *(const float4*)&W[(size_t)(bn + wr) * 256 + k0 + wk + 4 * i];
        __syncthreads();
#pragma unroll
        for (int i = 0; i < 4; ++i) {
            As[ak + 4 * i + 0][ar] = av[i].x; As[ak + 4 * i + 1][ar] = av[i].y;
            As[ak + 4 * i + 2][ar] = av[i].z; As[ak + 4 * i + 3][ar] = av[i].w;
        }
#pragma unroll
        for (int i = 0; i < 2; ++i) {
            Ws[wk + 4 * i + 0][wr] = wv[i].x; Ws[wk + 4 * i + 1][wr] = wv[i].y;
            Ws[wk + 4 * i + 2][wr] = wv[i].z; Ws[wk + 4 * i + 3][wr] = wv[i].w;
        }
        __syncthreads();
#pragma unroll
        for (int kk = 0; kk < 32; ++kk) {
            float4 a  = *(const float4*)&As[kk][tm * 4];
            float4 b0 = *(const float4*)&Ws[kk][tn * 8];
            float4 b1 = *(const float4*)&Ws[kk][tn * 8 + 4];
            acc[0][0] += a.x * b0.x; acc[0][1] += a.x * b0.y; acc[0][2] += a.x * b0.z; acc[0][3] += a.x * b0.w;
            acc[0][4] += a.x * b1.x; acc[0][5] += a.x * b1.y; acc[0][6] += a.x * b1.z; acc[0][7] += a.x * b1.w;
            acc[1][0] += a.y * b0.x; acc[1][1] += a.y * b0.y; acc[1][2] += a.y * b0.z; acc[1][3] += a.y * b0.w;
            acc[1][4] += a.y * b1.x; acc[1][5] += a.y * b1.y; acc[1][6] += a.y * b1.z; acc[1][7] += a.y * b1.w;
            acc[2][0] += a.z * b0.x; acc[2][1] += a.z * b0.y; acc[2][2] += a.z * b0.z; acc[2][3] += a.z * b0.w;
            acc[2][4] += a.z * b1.x; acc[2][5] += a.z * b1.y; acc[2][6] += a.z * b1.z; acc[2][7] += a.z * b1.w;
            acc[3][0] += a.w * b0.x; acc[3][1] += a.w * b0.y; acc[3][2] += a.w * b0.z; acc[3][3] += a.w * b0.w;
            acc[3][4] += a.w * b1.x; acc[3][5] += a.w * b1.y; acc[3][6] += a.w * b1.z; acc[3][7] += a.w * b1.w;
        }
    }
    float bz[8];
#pragma unroll
    for (int j = 0; j < 8; ++j) bz[j] = bias[bn + tn * 8 + j];
#pragma unroll
    for (int i = 0; i < 4; ++i) {
        int m = bm + tm * 4 + i;
        if (m < M) {
            float4 o0 = {acc[i][0] + bz[0], acc[i][1] + bz[1], acc[i][2] + bz[2], acc[i][3] + bz[3]};
            float4 o1 = {acc[i][4] + bz[4], acc[i][5] + bz[5], acc[i][6] + bz[6], acc[i][7] + bz[7]};
            float* op = out + (size_t)m * Nout + bn + tn * 8;
            *(float4*)op = o0;
            *((float4*)op + 1) = o1;
        }
    }
}

// ---------------- batched Gram: Gfull[n] = kv_ext[n] @ kv_ext[n]^T (101x101) ----------------
#define GBK 16
__global__ void gram_kernel(const float* __restrict__ kv_ext, float* __restrict__ Gfull) {
    int n = blockIdx.z;
    __shared__ float As[GBK][64];
    __shared__ float Ws[GBK][64];
    const float* A = kv_ext + (size_t)n * SM * CC;
    float* G = Gfull + (size_t)n * SM * SM;
    int bm = blockIdx.x * 64;
    int bn = blockIdx.y * 64;
    int tid = threadIdx.x;
    int tn = tid & 15, tm = tid >> 4;
    int lr = tid >> 2;
    int lk = (tid & 3) * 4;
    float acc[4][4] = {};
    for (int k0 = 0; k0 < 256; k0 += GBK) {
        int am = bm + lr; if (am >= SM) am = SM - 1;
        int wm = bn + lr; if (wm >= SM) wm = SM - 1;
        const float4 av = *(const float4*)&A[(size_t)am * CC + k0 + lk];
        const float4 wv = *(const float4*)&A[(size_t)wm * CC + k0 + lk];
        __syncthreads();
        As[lk + 0][lr] = av.x; As[lk + 1][lr] = av.y; As[lk + 2][lr] = av.z; As[lk + 3][lr] = av.w;
        Ws[lk + 0][lr] = wv.x; Ws[lk + 1][lr] = wv.y; Ws[lk + 2][lr] = wv.z; Ws[lk + 3][lr] = wv.w;
        __syncthreads();
#pragma unroll
        for (int kk = 0; kk < GBK; ++kk) {
            float a0 = As[kk][tm * 4 + 0], a1 = As[kk][tm * 4 + 1];
            float a2 = As[kk][tm * 4 + 2], a3 = As[kk][tm * 4 + 3];
            float b0 = Ws[kk][tn * 4 + 0], b1 = Ws[kk][tn * 4 + 1];
            float b2 = Ws[kk][tn * 4 + 2], b3 = Ws[kk][tn * 4 + 3];
            acc[0][0] += a0 * b0; acc[0][1] += a0 * b1; acc[0][2] += a0 * b2; acc[0][3] += a0 * b3;
            acc[1][0] += a1 * b0; acc[1][1] += a1 * b1; acc[1][2] += a1 * b2; acc[1][3] += a1 * b3;
            acc[2][0] += a2 * b0; acc[2][1] += a2 * b1; acc[2][2] += a2 * b2; acc[2][3] += a2 * b3;
            acc[3][0] += a3 * b0; acc[3][1] += a3 * b1; acc[3][2] += a3 * b2; acc[3][3] += a3 * b3;
        }
    }
#pragma unroll
    for (int i = 0; i < 4; ++i) {
        int m = bm + tm * 4 + i;
        if (m < SM) {
#pragma unroll
            for (int j = 0; j < 4; ++j) {
                int o = bn + tn * 4 + j;
                if (o < SM) G[(size_t)m * SM + o] = acc[i][j];
            }
        }
    }
}

// ---------------- far selection from Gram (both branches) ----------------
__global__ void far_kernel(const float* __restrict__ Gfull, int* __restrict__ far_rm,
                           int* __restrict__ far_md) {
    int n = blockIdx.x; int tid = threadIdx.x;
    __shared__ float sumdot[SM], meandot[SM], norm[SM];
    const float* G = Gfull + (size_t)n * SM * SM;
    for (int s = tid; s < SM; s += 256) {
        const float* row = G + (size_t)s * SM;
        float acc = 0.f;
        for (int q = 0; q < QQ; ++q) acc += row[q];
        sumdot[s] = acc; meandot[s] = row[QQ]; norm[s] = row[s];
    }
    __syncthreads();
    if (tid < QQ) {
        int q = tid, qm1 = (q + QQ - 1) % QQ;
        const float* gq = G + (size_t)qm1 * SM;
        int best = -1; float bv = -1e30f;
        for (int s = 0; s < QQ; ++s) {
            if (s == qm1) continue;
            float val = norm[s] - (sumdot[s] - gq[s]) * (2.f / 99.f);
            if (val > bv) { bv = val; best = s; }
        }
        far_rm[n * QQ + q] = best;
    } else if (tid >= 128 && tid < 128 + QQ) {
        int q = tid - 128, qm1 = (q + QQ - 1) % QQ;
        const float* gq = G + (size_t)qm1 * SM;
        int best = -1; float bv = -1e30f;
        for (int s = 0; s < SM; ++s) {
            if (s == qm1) continue;
            float val = norm[s] - (sumdot[s] - gq[s] + meandot[s]) * (2.f / 100.f);
            if (val > bv) { bv = val; best = s; }
        }
        far_md[n * QQ + q] = best;
    }
}

// ---------------- Psum0[n][c] = sum_{q<100} P_all[n][q][c], c<256 ----------------
__global__ void psum_kernel(const float* __restrict__ P_all, float* __restrict__ Psum0) {
    int n = blockIdx.x; int c = threadIdx.x;
    const float* base = P_all + (size_t)n * SM * PW + c;
    float acc = 0.f;
    for (int q = 0; q < QQ; ++q) acc += base[(size_t)q * PW];
    Psum0[n * CC + c] = acc;
}

// ---------------- stage B: small SMHA (2 queries), fused ----------------
__global__ void smhaB_kernel(const float* __restrict__ centB, const float* __restrict__ P_all,
                             const float* __restrict__ ipw, const float* __restrict__ ipb,
                             const float* __restrict__ ow, const float* __restrict__ ob,
                             float* __restrict__ out_assign, float* __restrict__ out_sidx,
                             float* __restrict__ out_didx, float* __restrict__ cd,
                             float* __restrict__ cs) {
    int n = blockIdx.x;
    int tid = threadIdx.x;
    __shared__ float qh[2][CC];
    __shared__ float attn[HH][2][QQ];
    __shared__ float pvB[2][CC];
    __shared__ float rs[16];
    __shared__ float mf[2][CC];
    __shared__ int sdi[2];
    const float* cen = centB + (size_t)n * 2 * CC;
    {
        const float4* wr4 = (const float4*)(ipw + (size_t)tid * CC);
        const float4* c0 = (const float4*)cen;
        const float4* c1 = (const float4*)(cen + CC);
        float a0 = ipb[tid], a1 = ipb[tid];
#pragma unroll 8
        for (int k = 0; k < 64; ++k) {
            float4 w = wr4[k], x0 = c0[k], x1 = c1[k];
            a0 += x0.x * w.x + x0.y * w.y + x0.z * w.z + x0.w * w.w;
            a1 += x1.x * w.x + x1.y * w.y + x1.z * w.z + x1.w * w.w;
        }
        qh[0][tid] = a0; qh[1][tid] = a1;
    }
    __syncthreads();
    const float* base = P_all + (size_t)n * SM * PW;
    const float scl = 0.17677669529663687f;
    for (int idx = tid; idx < HH * 2 * QQ; idx += 256) {
        int h = idx / 200; int r = idx % 200; int t = r / QQ; int s2 = r % QQ;
        const float4* kr = (const float4*)(base + (size_t)s2 * PW + CC + h * DH);
        const float4* qr = (const float4*)&qh[t][h * DH];
        float sc = 0.f;
#pragma unroll
        for (int d = 0; d < 8; ++d) {
            float4 k4 = kr[d], q4 = qr[d];
            sc += q4.x * k4.x + q4.y * k4.y + q4.z * k4.z + q4.w * k4.w;
        }
        attn[h][t][s2] = 1.f / (1.f + __expf(-sc * scl));
    }
    __syncthreads();
    if (tid < 16) {
        int h = tid >> 1, t = tid & 1; float s = 0.f;
        for (int s2 = 0; s2 < QQ; ++s2) s += attn[h][t][s2];
        rs[tid] = s;
    }
    __syncthreads();
    for (int idx = tid; idx < 2 * QQ; idx += 256) {
        int t = idx / QQ, s2 = idx % QQ;
        float m = 0.f;
        for (int h = 0; h < HH; ++h) m += attn[h][t][s2];
        out_assign[(size_t)n * 2 * QQ + idx] = m * 0.125f;
    }
    if (tid == 0) {
        float c0 = 0.f, c1v = 0.f;
        for (int h = 0; h < HH; ++h) { c0 += rs[h * 2 + 0]; c1v += rs[h * 2 + 1]; }
        int si = (c1v < c0) ? 1 : 0;
        int di = (c1v > c0) ? 1 : 0;
        sdi[0] = si; sdi[1] = di;
        out_sidx[n] = (float)si;
        out_didx[n] = (float)di;
    }
    for (int idx = tid; idx < 512; idx += 256) {
        int t = idx >> 8; int hd = idx & 255; int h = hd >> 5;
        float inv = 1.f / (rs[h * 2 + t] + 1e-4f);
        float a = 0.f;
        const float* vr = base + 2 * CC + hd;
        for (int s2 = 0; s2 < QQ; ++s2) a += attn[h][t][s2] * vr[(size_t)s2 * PW];
        pvB[t][hd] = a * inv;
    }
    __syncthreads();
    {
        const float4* wr4 = (const float4*)(ow + (size_t)tid * CC);
        const float4* p0 = (const float4*)&pvB[0][0];
        const float4* p1 = (const float4*)&pvB[1][0];
        float a0 = ob[tid], a1 = ob[tid];
#pragma unroll 8
        for (int k = 0; k < 64; ++k) {
            float4 w = wr4[k], x0 = p0[k], x1 = p1[k];
            a0 += x0.x * w.x + x0.y * w.y + x0.z * w.z + x0.w * w.w;
            a1 += x1.x * w.x + x1.y * w.y + x1.z * w.z + x1.w * w.w;
        }
        mf[0][tid] = a0; mf[1][tid] = a1;
    }
    __syncthreads();
    cd[(size_t)n * CC + tid] = mf[sdi[1]][tid];
    cs[(size_t)n * CC + tid] = mf[sdi[0]][tid];
}

// ---------------- Q gather for branch attention ----------------
__device__ inline void gather_q(const float* __restrict__ base, const float* __restrict__ Psum0n,
                                const int* __restrict__ far_rm, const int* __restrict__ far_md,
                                int n, int h, int row, float* qreg, int& mk, int& sb) {
    int b = row >= TT;
    int t = row - b * TT;
    int q = t >> 1;
    mk = q; sb = b ? SM : QQ;
    if (t & 1) {
        int f = (b ? far_md : far_rm)[n * QQ + q];
        const float4* pr = (const float4*)(base + (size_t)f * PW + h * DH);
#pragma unroll
        for (int j = 0; j < 8; ++j) {
            float4 v = pr[j];
            qreg[4 * j] = v.x; qreg[4 * j + 1] = v.y; qreg[4 * j + 2] = v.z; qreg[4 * j + 3] = v.w;
        }
    } else {
        int qm1 = (q + QQ - 1) % QQ;
        const float4* ps = (const float4*)(Psum0n + h * DH);
        const float4* pm = (const float4*)(base + (size_t)qm1 * PW + h * DH);
        const float4* pmn = (const float4*)(base + (size_t)QQ * PW + h * DH);
        float invd = b ? 0.01f : (1.f / 99.f);
        float bb = b ? 1.f : 0.f;
#pragma unroll
        for (int j = 0; j < 8; ++j) {
            float4 a = ps[j], c = pm[j], m2 = pmn[j];
            qreg[4 * j + 0] = (a.x - c.x + bb * m2.x) * invd;
            qreg[4 * j + 1] = (a.y - c.y + bb * m2.y) * invd;
            qreg[4 * j + 2] = (a.z - c.z + bb * m2.z) * invd;
            qreg[4 * j + 3] = (a.w - c.w + bb * m2.w) * invd;
        }
    }
}

// ---------------- both-branch attention v2: 128 rows/block, 2 rows/lane ----------------
__global__ __launch_bounds__(256, 2)
void attn_both(const float* __restrict__ P_all, const float* __restrict__ Psum0,
               const int* __restrict__ far_rm, const int* __restrict__ far_md,
               float* __restrict__ pv, float* __restrict__ rowsum) {
    int n = blockIdx.z, h = blockIdx.y;
    int r0 = blockIdx.x * 128;
    int tid = threadIdx.x;
    int l = tid & 63, sg = tid >> 6;
    __shared__ float ks_t[DH][104];      // K transposed, zero-padded s>=101
    __shared__ float vs[SM][DH];
    __shared__ float scores[128][103];   // odd stride -> 2-way max on row-indexed access
    const float* base = P_all + (size_t)n * SM * PW;
    for (int idx = tid; idx < DH * 104; idx += 256) {
        int d = idx / 104, s = idx - d * 104;            // s-major: conflict-free writes
        ks_t[d][s] = (s < SM) ? base[(size_t)s * PW + CC + h * DH + d] : 0.f;
    }
    for (int idx = tid; idx < SM * DH; idx += 256) {
        int s = idx >> 5, d = idx & 31;
        vs[s][d] = base[(size_t)s * PW + 2 * CC + h * DH + d];
    }
    int rA = r0 + l, rB = r0 + 64 + l;
    int validA = rA < TB, validB = rB < TB;
    float qA[DH], qB[DH];
    int mkA = -1, sbA = 0, mkB = -1, sbB = 0;
    const float* Psum0n = Psum0 + n * CC;
    if (validA) gather_q(base, Psum0n, far_rm, far_md, n, h, rA, qA, mkA, sbA);
    if (validB) gather_q(base, Psum0n, far_rm, far_md, n, h, rB, qB, mkB, sbB);
    __syncthreads();
    const float scl = 0.17677669529663687f;
    for (int j = sg; j < 26; j += 4) {
        int s0 = j * 4;
        float sA[4] = {0.f, 0.f, 0.f, 0.f}, sB[4] = {0.f, 0.f, 0.f, 0.f};
#pragma unroll
        for (int d = 0; d < DH; ++d) {
            float4 kv = *(const float4*)&ks_t[d][s0];
            float qa = qA[d], qb = qB[d];
            sA[0] += qa * kv.x; sA[1] += qa * kv.y; sA[2] += qa * kv.z; sA[3] += qa * kv.w;
            sB[0] += qb * kv.x; sB[1] += qb * kv.y; sB[2] += qb * kv.z; sB[3] += qb * kv.w;
        }
#pragma unroll
        for (int jj = 0; jj < 4; ++jj) {
            int s = s0 + jj;
            if (s < SM) {
                float aA = 0.f, aB = 0.f;
                if (s < sbA && s != mkA) aA = 1.f / (1.f + __expf(-sA[jj] * scl));
                if (s < sbB && s != mkB) aB = 1.f / (1.f + __expf(-sB[jj] * scl));
                scores[l][s] = aA;
                scores[64 + l][s] = aB;
            }
        }
    }
    __syncthreads();
    float accA[8] = {}, accB[8] = {};
    float rsA = 0.f, rsB = 0.f;
    for (int s = 0; s < SM; ++s) {
        float aA = scores[l][s], aB = scores[64 + l][s];
        const float4* vp = (const float4*)&vs[s][sg * 8];
        float4 v0 = vp[0], v1 = vp[1];
        rsA += aA; rsB += aB;
        accA[0] += aA * v0.x; accA[1] += aA * v0.y; accA[2] += aA * v0.z; accA[3] += aA * v0.w;
        accA[4] += aA * v1.x; accA[5] += aA * v1.y; accA[6] += aA * v1.z; accA[7] += aA * v1.w;
        accB[0] += aB * v0.x; accB[1] += aB * v0.y; accB[2] += aB * v0.z; accB[3] += aB * v0.w;
        accB[4] += aB * v1.x; accB[5] += aB * v1.y; accB[6] += aB * v1.z; accB[7] += aB * v1.w;
    }
    if (validA) {
        if (sg == 0) rowsum[((size_t)n * HH + h) * TB + rA] = rsA;
        float iv = 1.f / (rsA + 1e-4f);
        float* op = pv + ((size_t)n * TB + rA) * CC + h * DH + sg * 8;
        float4 o0 = {accA[0] * iv, accA[1] * iv, accA[2] * iv, accA[3] * iv};
        float4 o1 = {accA[4] * iv, accA[5] * iv, accA[6] * iv, accA[7] * iv};
        *(float4*)op = o0; *((float4*)op + 1) = o1;
    }
    if (validB) {
        if (sg == 0) rowsum[((size_t)n * HH + h) * TB + rB] = rsB;
        float iv = 1.f / (rsB + 1e-4f);
        float* op = pv + ((size_t)n * TB + rB) * CC + h * DH + sg * 8;
        float4 o0 = {accB[0] * iv, accB[1] * iv, accB[2] * iv, accB[3] * iv};
        float4 o1 = {accB[4] * iv, accB[5] * iv, accB[6] * iv, accB[7] * iv};
        *(float4*)op = o0; *((float4*)op + 1) = o1;
    }
}

// ---------------- shift (both branches): card argmin/argmax + distances ----------------
__global__ void shift_both(const float* __restrict__ rowsum, const float* __restrict__ mfx,
                           const float* __restrict__ cd, const float* __restrict__ cs,
                           float* __restrict__ out_srm, float* __restrict__ out_smd) {
    int b = blockIdx.x / (NB * QQ);
    int rem = blockIdx.x % (NB * QQ);
    int n = rem / QQ, q = rem % QQ;
    int tid = threadIdx.x;
    __shared__ float red[256];
    __shared__ int sdi[2];
    if (tid == 0) {
        float c0 = 0.f, c1v = 0.f;
        int rb = b * TT + 2 * q;
        for (int h = 0; h < HH; ++h) {
            c0  += rowsum[((size_t)n * HH + h) * TB + rb];
            c1v += rowsum[((size_t)n * HH + h) * TB + rb + 1];
        }
        sdi[0] = (c1v < c0) ? 1 : 0;
        sdi[1] = (c1v > c0) ? 1 : 0;
    }
    __syncthreads();
    int si = sdi[0], di = sdi[1];
    const float* mdp = mfx + ((size_t)n * TB + b * TT + 2 * q + di) * CC;
    const float* msp = mfx + ((size_t)n * TB + b * TT + 2 * q + si) * CC;
    float dd = mdp[tid] - cd[(size_t)n * CC + tid];
    float ds = msp[tid] - cs[(size_t)n * CC + tid];
    red[tid] = dd * dd;
    __syncthreads();
    for (int off = 128; off > 0; off >>= 1) { if (tid < off) red[tid] += red[tid + off]; __syncthreads(); }
    float distd = sqrtf(red[0] + 1e-12f);
    __syncthreads();
    red[tid] = ds * ds;
    __syncthreads();
    for (int off = 128; off > 0; off >>= 1) { if (tid < off) red[tid] += red[tid + off]; __syncthreads(); }
    if (tid == 0) (b ? out_smd : out_srm)[n * QQ + q] = distd + sqrtf(red[0] + 1e-12f);
}

extern "C" void kernel_launch(void* const* d_in, const int* in_sizes, int n_in,
                              void* d_out, int out_size, void* d_ws, size_t ws_size,
                              hipStream_t stream) {
    const float* hs_pair = (const float*)d_in[0];
    const float* ipw = (const float*)d_in[1];
    const float* ipb = (const float*)d_in[2];
    const float* ow  = (const float*)d_in[3];
    const float* ob  = (const float*)d_in[4];
    const float* hs = hs_pair + (size_t)5 * NB * QQ * CC;  // hs_pair[-1]

    float* ws = (float*)d_ws;
    size_t o = 0;
    // region A: dead after attn_both -> mfx aliases it
    float* kv_ext  = ws + o; o += (size_t)NB * SM * CC;
    float* P_all   = ws + o; o += (size_t)NB * SM * PW;
    float* Gfull   = ws + o; o += (size_t)NB * SM * SM;
    float* mfx     = kv_ext;                               // alias
    // region B: live throughout
    float* sum_all = ws + o; o += NB * CC;
    float* c1mean  = ws + o; o += NB * CC;
    float* centB   = ws + o; o += (size_t)NB * 2 * CC;
    float* Psum0   = ws + o; o += NB * CC;
    int*   far_rm  = (int*)(ws + o); o += NB * QQ;
    int*   far_md  = (int*)(ws + o); o += NB * QQ;
    float* cd      = ws + o; o += NB * CC;
    float* cs      = ws + o; o += NB * CC;
    float* pv      = ws + o; o += (size_t)NB * TB * CC;
    float* rowsum  = ws + o; o += (size_t)NB * HH * TB;
    if (o * sizeof(float) > ws_size) return;

    float* out = (float*)d_out;
    float* out_assign = out;
    float* out_sidx   = out + 6400;
    float* out_didx   = out + 6432;
    float* out_srm    = out + 6464;
    float* out_smd    = out + 9664;

    prep_kernel<<<NB, 256, 0, stream>>>(hs, sum_all, c1mean, centB, kv_ext);
    gemm_bias<<<dim3((NB * SM + 127) / 128, PW / 64), 256, 0, stream>>>(
        kv_ext, ipw, ipb, P_all, NB * SM, PW);
    psum_kernel<<<NB, 256, 0, stream>>>(P_all, Psum0);
    gram_kernel<<<dim3(2, 2, NB), 256, 0, stream>>>(kv_ext, Gfull);
    far_kernel<<<NB, 256, 0, stream>>>(Gfull, far_rm, far_md);
    smhaB_kernel<<<NB, 256, 0, stream>>>(centB, P_all, ipw, ipb, ow, ob,
                                         out_assign, out_sidx, out_didx, cd, cs);
    attn_both<<<dim3(4, HH, NB), 256, 0, stream>>>(P_all, Psum0, far_rm, far_md, pv, rowsum);
    gemm_bias<<<dim3(NB * TB / 128, CC / 64), 256, 0, stream>>>(pv, ow, ob, mfx, NB * TB, CC);
    shift_both<<<2 * NB * QQ, 256, 0, stream>>>(rowsum, mfx, cd, cs, out_srm, out_smd);
}

// Round 5
// 205.814 us; speedup vs baseline: 2.0333x; 1.1110x over previous
//
#include <hip/hip_runtime.h>
#include <math.h>

#define NB 32
#define QQ 100
#define CC 256
#define HH 8
#define DH 32
#define SM 101   // kv rows per batch (100 points + mean)
#define TT 200   // branch queries per batch
#define TB 400   // both branches
#define PW 768   // P_all row width (q|k|v projections)

typedef __attribute__((ext_vector_type(8))) short s16x8;
typedef __attribute__((ext_vector_type(4))) float f32x4;

__device__ inline unsigned short f2bf(float x) {
    unsigned u = __float_as_uint(x);
    return (unsigned short)((u + 0x7fffu + ((u >> 16) & 1u)) >> 16);
}
__device__ inline float bf2f(unsigned short h) {
    return __uint_as_float(((unsigned)h) << 16);
}

// ---------------- prep: sums, mean center, far point, centers, kv_ext ----------------
__global__ void prep_kernel(const float* __restrict__ hs, float* __restrict__ sum_all,
                            float* __restrict__ c1mean, float* __restrict__ centB,
                            float* __restrict__ kv_ext) {
    int n = blockIdx.x;
    int c = threadIdx.x; // 0..255
    const float* h = hs + (size_t)n * QQ * CC;
    float s = 0.f;
    for (int q = 0; q < QQ; ++q) s += h[q * CC + c];
    float c1 = s * (1.0f / QQ);
    sum_all[n * CC + c] = s;
    c1mean[n * CC + c] = c1;
    __shared__ float c1s[CC];
    __shared__ float dls[QQ];
    c1s[c] = c1;
    float* kve = kv_ext + (size_t)n * SM * CC;
    for (int idx = c; idx < QQ * CC; idx += CC) kve[idx] = h[idx];
    kve[QQ * CC + c] = c1;
    __syncthreads();
    int wave = c >> 6, lane = c & 63;
    for (int q = wave; q < QQ; q += 4) {
        float p = 0.f;
        for (int cc = lane; cc < CC; cc += 64) {
            float d = c1s[cc] - h[q * CC + cc];
            p += d * d;
        }
        for (int off = 32; off > 0; off >>= 1) p += __shfl_down(p, off);
        if (lane == 0) dls[q] = p;
    }
    __syncthreads();
    __shared__ int fars;
    if (c == 0) {
        int best = 0; float bv = dls[0];
        for (int q = 1; q < QQ; ++q) if (dls[q] > bv) { bv = dls[q]; best = q; }
        fars = best;
    }
    __syncthreads();
    int far = fars;
    centB[(size_t)n * 2 * CC + c] = c1s[c];
    centB[(size_t)n * 2 * CC + CC + c] = h[(size_t)far * CC + c];
}

// ---------------- decompose fp32 -> bf16 hi/lo for three tensors ----------------
__global__ void decomp3(const float* __restrict__ a, unsigned short* __restrict__ ah,
                        unsigned short* __restrict__ al, int na,
                        const float* __restrict__ b, unsigned short* __restrict__ bh,
                        unsigned short* __restrict__ bl, int nb,
                        const float* __restrict__ c, unsigned short* __restrict__ ch,
                        unsigned short* __restrict__ cl, int nc) {
    int i = (blockIdx.x * 256 + threadIdx.x) * 4;
    const float* s; unsigned short *dh, *dl; int off;
    if (i < na) { s = a; dh = ah; dl = al; off = i; }
    else if (i < na + nb) { s = b; dh = bh; dl = bl; off = i - na; }
    else if (i < na + nb + nc) { s = c; dh = ch; dl = cl; off = i - na - nb; }
    else return;
    float4 v = *(const float4*)(s + off);
    unsigned short h0 = f2bf(v.x), h1 = f2bf(v.y), h2 = f2bf(v.z), h3 = f2bf(v.w);
    unsigned short l0 = f2bf(v.x - bf2f(h0)), l1 = f2bf(v.y - bf2f(h1));
    unsigned short l2 = f2bf(v.z - bf2f(h2)), l3 = f2bf(v.w - bf2f(h3));
    ushort4 hv; hv.x = h0; hv.y = h1; hv.z = h2; hv.w = h3;
    ushort4 lv; lv.x = l0; lv.y = l1; lv.z = l2; lv.w = l3;
    *(ushort4*)(dh + off) = hv;
    *(ushort4*)(dl + off) = lv;
}

// ---------------- split-bf16 MFMA GEMM: out = A @ W^T + bias ----------------
// A: M x 256 (hi/lo bf16), W: Nout x 256 (hi/lo bf16), out: M x Nout fp32.
// Tile 128x128, 4 waves (2x2), wave = 64x64 = 4x4 mfma_16x16x32 tiles, BK=32.
#define LDK 40
__global__ __launch_bounds__(256, 2)
void gemm_mfma(const unsigned short* __restrict__ Ah_g, const unsigned short* __restrict__ Al_g,
               const unsigned short* __restrict__ Bh_g, const unsigned short* __restrict__ Bl_g,
               const float* __restrict__ bias, float* __restrict__ out, int M, int Nout) {
    __shared__ unsigned short Ahs[128][LDK], Als[128][LDK], Bhs[128][LDK], Bls[128][LDK];
    int tid = threadIdx.x;
    int lane = tid & 63, wave = tid >> 6;
    int wm = (wave >> 1) * 64, wn = (wave & 1) * 64;
    int fr = lane & 15, kb = lane >> 4;
    int bm = blockIdx.x * 128, bn = blockIdx.y * 128;
    int srow = tid >> 1, scol = (tid & 1) * 16;
    int am = bm + srow; if (am >= M) am = M - 1;
    const unsigned short* pAh = Ah_g + (size_t)am * CC + scol;
    const unsigned short* pAl = Al_g + (size_t)am * CC + scol;
    const unsigned short* pBh = Bh_g + (size_t)(bn + srow) * CC + scol;
    const unsigned short* pBl = Bl_g + (size_t)(bn + srow) * CC + scol;
    f32x4 acc[4][4];
#pragma unroll
    for (int mi = 0; mi < 4; ++mi)
#pragma unroll
        for (int ni = 0; ni < 4; ++ni)
            acc[mi][ni] = (f32x4){0.f, 0.f, 0.f, 0.f};
    for (int k0 = 0; k0 < CC; k0 += 32) {
        s16x8 a0 = *(const s16x8*)(pAh + k0);
        s16x8 a1 = *(const s16x8*)(pAh + k0 + 8);
        s16x8 a2 = *(const s16x8*)(pAl + k0);
        s16x8 a3 = *(const s16x8*)(pAl + k0 + 8);
        s16x8 b0 = *(const s16x8*)(pBh + k0);
        s16x8 b1 = *(const s16x8*)(pBh + k0 + 8);
        s16x8 b2 = *(const s16x8*)(pBl + k0);
        s16x8 b3 = *(const s16x8*)(pBl + k0 + 8);
        __syncthreads();
        *(s16x8*)&Ahs[srow][scol] = a0; *(s16x8*)&Ahs[srow][scol + 8] = a1;
        *(s16x8*)&Als[srow][scol] = a2; *(s16x8*)&Als[srow][scol + 8] = a3;
        *(s16x8*)&Bhs[srow][scol] = b0; *(s16x8*)&Bhs[srow][scol + 8] = b1;
        *(s16x8*)&Bls[srow][scol] = b2; *(s16x8*)&Bls[srow][scol + 8] = b3;
        __syncthreads();
        s16x8 fah[4], fal[4], fbh[4], fbl[4];
#pragma unroll
        for (int mi = 0; mi < 4; ++mi) {
            fah[mi] = *(const s16x8*)&Ahs[wm + mi * 16 + fr][kb * 8];
            fal[mi] = *(const s16x8*)&Als[wm + mi * 16 + fr][kb * 8];
        }
#pragma unroll
        for (int ni = 0; ni < 4; ++ni) {
            fbh[ni] = *(const s16x8*)&Bhs[wn + ni * 16 + fr][kb * 8];
            fbl[ni] = *(const s16x8*)&Bls[wn + ni * 16 + fr][kb * 8];
        }
#pragma unroll
        for (int mi = 0; mi < 4; ++mi)
#pragma unroll
            for (int ni = 0; ni < 4; ++ni) {
                acc[mi][ni] = __builtin_amdgcn_mfma_f32_16x16x32_bf16(fah[mi], fbh[ni], acc[mi][ni], 0, 0, 0);
                acc[mi][ni] = __builtin_amdgcn_mfma_f32_16x16x32_bf16(fah[mi], fbl[ni], acc[mi][ni], 0, 0, 0);
                acc[mi][ni] = __builtin_amdgcn_mfma_f32_16x16x32_bf16(fal[mi], fbh[ni], acc[mi][ni], 0, 0, 0);
            }
    }
    // D mapping: col = lane&15, row = (lane>>4)*4 + r  (m89-verified)
#pragma unroll
    for (int mi = 0; mi < 4; ++mi) {
        int mb = bm + wm + mi * 16 + kb * 4;
#pragma unroll
        for (int r = 0; r < 4; ++r) {
            int m = mb + r;
            if (m < M) {
#pragma unroll
                for (int ni = 0; ni < 4; ++ni) {
                    int col = bn + wn + ni * 16 + fr;
                    out[(size_t)m * Nout + col] = acc[mi][ni][r] + bias[col];
                }
            }
        }
    }
}

// ---------------- batched Gram: Gfull[n] = kv_ext[n] @ kv_ext[n]^T (101x101) ----------------
#define GBK 16
__global__ void gram_kernel(const float* __restrict__ kv_ext, float* __restrict__ Gfull) {
    int n = blockIdx.z;
    __shared__ float As[GBK][64];
    __shared__ float Ws[GBK][64];
    const float* A = kv_ext + (size_t)n * SM * CC;
    float* G = Gfull + (size_t)n * SM * SM;
    int bm = blockIdx.x * 64;
    int bn = blockIdx.y * 64;
    int tid = threadIdx.x;
    int tn = tid & 15, tm = tid >> 4;
    int lr = tid >> 2;
    int lk = (tid & 3) * 4;
    float acc[4][4] = {};
    for (int k0 = 0; k0 < 256; k0 += GBK) {
        int am = bm + lr; if (am >= SM) am = SM - 1;
        int wm = bn + lr; if (wm >= SM) wm = SM - 1;
        const float4 av = *(const float4*)&A[(size_t)am * CC + k0 + lk];
        const float4 wv = *(const float4*)&A[(size_t)wm * CC + k0 + lk];
        __syncthreads();
        As[lk + 0][lr] = av.x; As[lk + 1][lr] = av.y; As[lk + 2][lr] = av.z; As[lk + 3][lr] = av.w;
        Ws[lk + 0][lr] = wv.x; Ws[lk + 1][lr] = wv.y; Ws[lk + 2][lr] = wv.z; Ws[lk + 3][lr] = wv.w;
        __syncthreads();
#pragma unroll
        for (int kk = 0; kk < GBK; ++kk) {
            float a0 = As[kk][tm * 4 + 0], a1 = As[kk][tm * 4 + 1];
            float a2 = As[kk][tm * 4 + 2], a3 = As[kk][tm * 4 + 3];
            float b0 = Ws[kk][tn * 4 + 0], b1 = Ws[kk][tn * 4 + 1];
            float b2 = Ws[kk][tn * 4 + 2], b3 = Ws[kk][tn * 4 + 3];
            acc[0][0] += a0 * b0; acc[0][1] += a0 * b1; acc[0][2] += a0 * b2; acc[0][3] += a0 * b3;
            acc[1][0] += a1 * b0; acc[1][1] += a1 * b1; acc[1][2] += a1 * b2; acc[1][3] += a1 * b3;
            acc[2][0] += a2 * b0; acc[2][1] += a2 * b1; acc[2][2] += a2 * b2; acc[2][3] += a2 * b3;
            acc[3][0] += a3 * b0; acc[3][1] += a3 * b1; acc[3][2] += a3 * b2; acc[3][3] += a3 * b3;
        }
    }
#pragma unroll
    for (int i = 0; i < 4; ++i) {
        int m = bm + tm * 4 + i;
        if (m < SM) {
#pragma unroll
            for (int j = 0; j < 4; ++j) {
                int o = bn + tn * 4 + j;
                if (o < SM) G[(size_t)m * SM + o] = acc[i][j];
            }
        }
    }
}

// ---------------- far selection from Gram (both branches) ----------------
__global__ void far_kernel(const float* __restrict__ Gfull, int* __restrict__ far_rm,
                           int* __restrict__ far_md) {
    int n = blockIdx.x; int tid = threadIdx.x;
    __shared__ float sumdot[SM], meandot[SM], norm[SM];
    const float* G = Gfull + (size_t)n * SM * SM;
    for (int s = tid; s < SM; s += 256) {
        const float* row = G + (size_t)s * SM;
        float acc = 0.f;
        for (int q = 0; q < QQ; ++q) acc += row[q];
        sumdot[s] = acc; meandot[s] = row[QQ]; norm[s] = row[s];
    }
    __syncthreads();
    if (tid < QQ) {
        int q = tid, qm1 = (q + QQ - 1) % QQ;
        const float* gq = G + (size_t)qm1 * SM;
        int best = -1; float bv = -1e30f;
        for (int s = 0; s < QQ; ++s) {
            if (s == qm1) continue;
            float val = norm[s] - (sumdot[s] - gq[s]) * (2.f / 99.f);
            if (val > bv) { bv = val; best = s; }
        }
        far_rm[n * QQ + q] = best;
    } else if (tid >= 128 && tid < 128 + QQ) {
        int q = tid - 128, qm1 = (q + QQ - 1) % QQ;
        const float* gq = G + (size_t)qm1 * SM;
        int best = -1; float bv = -1e30f;
        for (int s = 0; s < SM; ++s) {
            if (s == qm1) continue;
            float val = norm[s] - (sumdot[s] - gq[s] + meandot[s]) * (2.f / 100.f);
            if (val > bv) { bv = val; best = s; }
        }
        far_md[n * QQ + q] = best;
    }
}

// ---------------- Psum0[n][c] = sum_{q<100} P_all[n][q][c], c<256 ----------------
__global__ void psum_kernel(const float* __restrict__ P_all, float* __restrict__ Psum0) {
    int n = blockIdx.x; int c = threadIdx.x;
    const float* base = P_all + (size_t)n * SM * PW + c;
    float acc = 0.f;
    for (int q = 0; q < QQ; ++q) acc += base[(size_t)q * PW];
    Psum0[n * CC + c] = acc;
}

// ---------------- stage B: small SMHA (2 queries), fused ----------------
__global__ void smhaB_kernel(const float* __restrict__ centB, const float* __restrict__ P_all,
                             const float* __restrict__ ipw, const float* __restrict__ ipb,
                             const float* __restrict__ ow, const float* __restrict__ ob,
                             float* __restrict__ out_assign, float* __restrict__ out_sidx,
                             float* __restrict__ out_didx, float* __restrict__ cd,
                             float* __restrict__ cs) {
    int n = blockIdx.x;
    int tid = threadIdx.x;
    __shared__ float qh[2][CC];
    __shared__ float attn[HH][2][QQ];
    __shared__ float pvB[2][CC];
    __shared__ float rs[16];
    __shared__ float mf[2][CC];
    __shared__ int sdi[2];
    const float* cen = centB + (size_t)n * 2 * CC;
    {
        const float4* wr4 = (const float4*)(ipw + (size_t)tid * CC);
        const float4* c0 = (const float4*)cen;
        const float4* c1 = (const float4*)(cen + CC);
        float a0 = ipb[tid], a1 = ipb[tid];
#pragma unroll 8
        for (int k = 0; k < 64; ++k) {
            float4 w = wr4[k], x0 = c0[k], x1 = c1[k];
            a0 += x0.x * w.x + x0.y * w.y + x0.z * w.z + x0.w * w.w;
            a1 += x1.x * w.x + x1.y * w.y + x1.z * w.z + x1.w * w.w;
        }
        qh[0][tid] = a0; qh[1][tid] = a1;
    }
    __syncthreads();
    const float* base = P_all + (size_t)n * SM * PW;
    const float scl = 0.17677669529663687f;
    for (int idx = tid; idx < HH * 2 * QQ; idx += 256) {
        int h = idx / 200; int r = idx % 200; int t = r / QQ; int s2 = r % QQ;
        const float4* kr = (const float4*)(base + (size_t)s2 * PW + CC + h * DH);
        const float4* qr = (const float4*)&qh[t][h * DH];
        float sc = 0.f;
#pragma unroll
        for (int d = 0; d < 8; ++d) {
            float4 k4 = kr[d], q4 = qr[d];
            sc += q4.x * k4.x + q4.y * k4.y + q4.z * k4.z + q4.w * k4.w;
        }
        attn[h][t][s2] = 1.f / (1.f + __expf(-sc * scl));
    }
    __syncthreads();
    if (tid < 16) {
        int h = tid >> 1, t = tid & 1; float s = 0.f;
        for (int s2 = 0; s2 < QQ; ++s2) s += attn[h][t][s2];
        rs[tid] = s;
    }
    __syncthreads();
    for (int idx = tid; idx < 2 * QQ; idx += 256) {
        int t = idx / QQ, s2 = idx % QQ;
        float m = 0.f;
        for (int h = 0; h < HH; ++h) m += attn[h][t][s2];
        out_assign[(size_t)n * 2 * QQ + idx] = m * 0.125f;
    }
    if (tid == 0) {
        float c0 = 0.f, c1v = 0.f;
        for (int h = 0; h < HH; ++h) { c0 += rs[h * 2 + 0]; c1v += rs[h * 2 + 1]; }
        int si = (c1v < c0) ? 1 : 0;
        int di = (c1v > c0) ? 1 : 0;
        sdi[0] = si; sdi[1] = di;
        out_sidx[n] = (float)si;
        out_didx[n] = (float)di;
    }
    for (int idx = tid; idx < 512; idx += 256) {
        int t = idx >> 8; int hd = idx & 255; int h = hd >> 5;
        float inv = 1.f / (rs[h * 2 + t] + 1e-4f);
        float a = 0.f;
        const float* vr = base + 2 * CC + hd;
        for (int s2 = 0; s2 < QQ; ++s2) a += attn[h][t][s2] * vr[(size_t)s2 * PW];
        pvB[t][hd] = a * inv;
    }
    __syncthreads();
    {
        const float4* wr4 = (const float4*)(ow + (size_t)tid * CC);
        const float4* p0 = (const float4*)&pvB[0][0];
        const float4* p1 = (const float4*)&pvB[1][0];
        float a0 = ob[tid], a1 = ob[tid];
#pragma unroll 8
        for (int k = 0; k < 64; ++k) {
            float4 w = wr4[k], x0 = p0[k], x1 = p1[k];
            a0 += x0.x * w.x + x0.y * w.y + x0.z * w.z + x0.w * w.w;
            a1 += x1.x * w.x + x1.y * w.y + x1.z * w.z + x1.w * w.w;
        }
        mf[0][tid] = a0; mf[1][tid] = a1;
    }
    __syncthreads();
    cd[(size_t)n * CC + tid] = mf[sdi[1]][tid];
    cs[(size_t)n * CC + tid] = mf[sdi[0]][tid];
}

// ---------------- Q gather for branch attention ----------------
__device__ inline void gather_q(const float* __restrict__ base, const float* __restrict__ Psum0n,
                                const int* __restrict__ far_rm, const int* __restrict__ far_md,
                                int n, int h, int row, float* qreg, int& mk, int& sb) {
    int b = row >= TT;
    int t = row - b * TT;
    int q = t >> 1;
    mk = q; sb = b ? SM : QQ;
    if (t & 1) {
        int f = (b ? far_md : far_rm)[n * QQ + q];
        const float4* pr = (const float4*)(base + (size_t)f * PW + h * DH);
#pragma unroll
        for (int j = 0; j < 8; ++j) {
            float4 v = pr[j];
            qreg[4 * j] = v.x; qreg[4 * j + 1] = v.y; qreg[4 * j + 2] = v.z; qreg[4 * j + 3] = v.w;
        }
    } else {
        int qm1 = (q + QQ - 1) % QQ;
        const float4* ps = (const float4*)(Psum0n + h * DH);
        const float4* pm = (const float4*)(base + (size_t)qm1 * PW + h * DH);
        const float4* pmn = (const float4*)(base + (size_t)QQ * PW + h * DH);
        float invd = b ? 0.01f : (1.f / 99.f);
        float bb = b ? 1.f : 0.f;
#pragma unroll
        for (int j = 0; j < 8; ++j) {
            float4 a = ps[j], c = pm[j], m2 = pmn[j];
            qreg[4 * j + 0] = (a.x - c.x + bb * m2.x) * invd;
            qreg[4 * j + 1] = (a.y - c.y + bb * m2.y) * invd;
            qreg[4 * j + 2] = (a.z - c.z + bb * m2.z) * invd;
            qreg[4 * j + 3] = (a.w - c.w + bb * m2.w) * invd;
        }
    }
}

// ---------------- both-branch attention: 128 rows/block, 2 rows/lane, bf16 hi/lo pv out ----------------
__global__ __launch_bounds__(256, 2)
void attn_both(const float* __restrict__ P_all, const float* __restrict__ Psum0,
               const int* __restrict__ far_rm, const int* __restrict__ far_md,
               unsigned short* __restrict__ pvh, unsigned short* __restrict__ pvl,
               float* __restrict__ rowsum) {
    int n = blockIdx.z, h = blockIdx.y;
    int r0 = blockIdx.x * 128;
    int tid = threadIdx.x;
    int l = tid & 63, sg = tid >> 6;
    __shared__ float ks_t[DH][104];      // K transposed, zero-padded s>=101
    __shared__ float vs[SM][DH];
    __shared__ float scores[128][103];   // odd stride
    const float* base = P_all + (size_t)n * SM * PW;
    for (int idx = tid; idx < DH * 104; idx += 256) {
        int d = idx / 104, s = idx - d * 104;
        ks_t[d][s] = (s < SM) ? base[(size_t)s * PW + CC + h * DH + d] : 0.f;
    }
    for (int idx = tid; idx < SM * DH; idx += 256) {
        int s = idx >> 5, d = idx & 31;
        vs[s][d] = base[(size_t)s * PW + 2 * CC + h * DH + d];
    }
    int rA = r0 + l, rB = r0 + 64 + l;
    int validA = rA < TB, validB = rB < TB;
    float qA[DH], qB[DH];
    int mkA = -1, sbA = 0, mkB = -1, sbB = 0;
    const float* Psum0n = Psum0 + n * CC;
    if (validA) gather_q(base, Psum0n, far_rm, far_md, n, h, rA, qA, mkA, sbA);
    if (validB) gather_q(base, Psum0n, far_rm, far_md, n, h, rB, qB, mkB, sbB);
    __syncthreads();
    const float scl = 0.17677669529663687f;
    for (int j = sg; j < 26; j += 4) {
        int s0 = j * 4;
        float sA[4] = {0.f, 0.f, 0.f, 0.f}, sB[4] = {0.f, 0.f, 0.f, 0.f};
#pragma unroll
        for (int d = 0; d < DH; ++d) {
            float4 kv = *(const float4*)&ks_t[d][s0];
            float qa = qA[d], qb = qB[d];
            sA[0] += qa * kv.x; sA[1] += qa * kv.y; sA[2] += qa * kv.z; sA[3] += qa * kv.w;
            sB[0] += qb * kv.x; sB[1] += qb * kv.y; sB[2] += qb * kv.z; sB[3] += qb * kv.w;
        }
#pragma unroll
        for (int jj = 0; jj < 4; ++jj) {
            int s = s0 + jj;
            if (s < SM) {
                float aA = 0.f, aB = 0.f;
                if (s < sbA && s != mkA) aA = 1.f / (1.f + __expf(-sA[jj] * scl));
                if (s < sbB && s != mkB) aB = 1.f / (1.f + __expf(-sB[jj] * scl));
                scores[l][s] = aA;
                scores[64 + l][s] = aB;
            }
        }
    }
    __syncthreads();
    float accA[8] = {}, accB[8] = {};
    float rsA = 0.f, rsB = 0.f;
    for (int s = 0; s < SM; ++s) {
        float aA = scores[l][s], aB = scores[64 + l][s];
        const float4* vp = (const float4*)&vs[s][sg * 8];
        float4 v0 = vp[0], v1 = vp[1];
        rsA += aA; rsB += aB;
        accA[0] += aA * v0.x; accA[1] += aA * v0.y; accA[2] += aA * v0.z; accA[3] += aA * v0.w;
        accA[4] += aA * v1.x; accA[5] += aA * v1.y; accA[6] += aA * v1.z; accA[7] += aA * v1.w;
        accB[0] += aB * v0.x; accB[1] += aB * v0.y; accB[2] += aB * v0.z; accB[3] += aB * v0.w;
        accB[4] += aB * v1.x; accB[5] += aB * v1.y; accB[6] += aB * v1.z; accB[7] += aB * v1.w;
    }
    if (validA) {
        if (sg == 0) rowsum[((size_t)n * HH + h) * TB + rA] = rsA;
        float iv = 1.f / (rsA + 1e-4f);
        size_t off = ((size_t)n * TB + rA) * CC + h * DH + sg * 8;
        unsigned short hh[8], ll[8];
#pragma unroll
        for (int j = 0; j < 8; ++j) {
            float x = accA[j] * iv;
            unsigned short hv = f2bf(x);
            hh[j] = hv; ll[j] = f2bf(x - bf2f(hv));
        }
        ushort4 h0; h0.x = hh[0]; h0.y = hh[1]; h0.z = hh[2]; h0.w = hh[3];
        ushort4 h1; h1.x = hh[4]; h1.y = hh[5]; h1.z = hh[6]; h1.w = hh[7];
        ushort4 l0; l0.x = ll[0]; l0.y = ll[1]; l0.z = ll[2]; l0.w = ll[3];
        ushort4 l1; l1.x = ll[4]; l1.y = ll[5]; l1.z = ll[6]; l1.w = ll[7];
        *(ushort4*)(pvh + off) = h0; *(ushort4*)(pvh + off + 4) = h1;
        *(ushort4*)(pvl + off) = l0; *(ushort4*)(pvl + off + 4) = l1;
    }
    if (validB) {
        if (sg == 0) rowsum[((size_t)n * HH + h) * TB + rB] = rsB;
        float iv = 1.f / (rsB + 1e-4f);
        size_t off = ((size_t)n * TB + rB) * CC + h * DH + sg * 8;
        unsigned short hh[8], ll[8];
#pragma unroll
        for (int j = 0; j < 8; ++j) {
            float x = accB[j] * iv;
            unsigned short hv = f2bf(x);
            hh[j] = hv; ll[j] = f2bf(x - bf2f(hv));
        }
        ushort4 h0; h0.x = hh[0]; h0.y = hh[1]; h0.z = hh[2]; h0.w = hh[3];
        ushort4 h1; h1.x = hh[4]; h1.y = hh[5]; h1.z = hh[6]; h1.w = hh[7];
        ushort4 l0; l0.x = ll[0]; l0.y = ll[1]; l0.z = ll[2]; l0.w = ll[3];
        ushort4 l1; l1.x = ll[4]; l1.y = ll[5]; l1.z = ll[6]; l1.w = ll[7];
        *(ushort4*)(pvh + off) = h0; *(ushort4*)(pvh + off + 4) = h1;
        *(ushort4*)(pvl + off) = l0; *(ushort4*)(pvl + off + 4) = l1;
    }
}

// ---------------- shift (both branches): card argmin/argmax + distances ----------------
__global__ void shift_both(const float* __restrict__ rowsum, const float* __restrict__ mfx,
                           const float* __restrict__ cd, const float* __restrict__ cs,
                           float* __restrict__ out_srm, float* __restrict__ out_smd) {
    int b = blockIdx.x / (NB * QQ);
    int rem = blockIdx.x % (NB * QQ);
    int n = rem / QQ, q = rem % QQ;
    int tid = threadIdx.x;
    __shared__ float red[256];
    __shared__ int sdi[2];
    if (tid == 0) {
        float c0 = 0.f, c1v = 0.f;
        int rb = b * TT + 2 * q;
        for (int h = 0; h < HH; ++h) {
            c0  += rowsum[((size_t)n * HH + h) * TB + rb];
            c1v += rowsum[((size_t)n * HH + h) * TB + rb + 1];
        }
        sdi[0] = (c1v < c0) ? 1 : 0;
        sdi[1] = (c1v > c0) ? 1 : 0;
    }
    __syncthreads();
    int si = sdi[0], di = sdi[1];
    const float* mdp = mfx + ((size_t)n * TB + b * TT + 2 * q + di) * CC;
    const float* msp = mfx + ((size_t)n * TB + b * TT + 2 * q + si) * CC;
    float dd = mdp[tid] - cd[(size_t)n * CC + tid];
    float ds = msp[tid] - cs[(size_t)n * CC + tid];
    red[tid] = dd * dd;
    __syncthreads();
    for (int off = 128; off > 0; off >>= 1) { if (tid < off) red[tid] += red[tid + off]; __syncthreads(); }
    float distd = sqrtf(red[0] + 1e-12f);
    __syncthreads();
    red[tid] = ds * ds;
    __syncthreads();
    for (int off = 128; off > 0; off >>= 1) { if (tid < off) red[tid] += red[tid + off]; __syncthreads(); }
    if (tid == 0) (b ? out_smd : out_srm)[n * QQ + q] = distd + sqrtf(red[0] + 1e-12f);
}

extern "C" void kernel_launch(void* const* d_in, const int* in_sizes, int n_in,
                              void* d_out, int out_size, void* d_ws, size_t ws_size,
                              hipStream_t stream) {
    const float* hs_pair = (const float*)d_in[0];
    const float* ipw = (const float*)d_in[1];
    const float* ipb = (const float*)d_in[2];
    const float* ow  = (const float*)d_in[3];
    const float* ob  = (const float*)d_in[4];
    const float* hs = hs_pair + (size_t)5 * NB * QQ * CC;  // hs_pair[-1]

    float* ws = (float*)d_ws;
    size_t o = 0;
    // region A: dead after attn_both -> mfx aliases it
    float* kv_ext  = ws + o; o += (size_t)NB * SM * CC;       // 827,392
    float* P_all   = ws + o; o += (size_t)NB * SM * PW;       // 2,482,176
    float* Gfull   = ws + o; o += (size_t)NB * SM * SM;       // 326,432
    float* mfx     = kv_ext;                                  // 3,276,800 <= 3,636,000
    // region B: live throughout
    float* sum_all = ws + o; o += NB * CC;
    float* c1mean  = ws + o; o += NB * CC;
    float* centB   = ws + o; o += (size_t)NB * 2 * CC;
    float* Psum0   = ws + o; o += NB * CC;
    int*   far_rm  = (int*)(ws + o); o += NB * QQ;
    int*   far_md  = (int*)(ws + o); o += NB * QQ;
    float* cd      = ws + o; o += NB * CC;
    float* cs      = ws + o; o += NB * CC;
    float* rowsum  = ws + o; o += (size_t)NB * HH * TB;
    // bf16 hi/lo tensors (ushort), counted in float slots (2 ushorts per slot)
    unsigned short* kvh = (unsigned short*)(ws + o); o += (size_t)NB * SM * CC / 2;
    unsigned short* kvl = (unsigned short*)(ws + o); o += (size_t)NB * SM * CC / 2;
    unsigned short* iph = (unsigned short*)(ws + o); o += (size_t)PW * CC / 2;
    unsigned short* ipl = (unsigned short*)(ws + o); o += (size_t)PW * CC / 2;
    unsigned short* owh = (unsigned short*)(ws + o); o += (size_t)CC * CC / 2;
    unsigned short* owl = (unsigned short*)(ws + o); o += (size_t)CC * CC / 2;
    unsigned short* pvh = (unsigned short*)(ws + o); o += (size_t)NB * TB * CC / 2;
    unsigned short* pvl = (unsigned short*)(ws + o); o += (size_t)NB * TB * CC / 2;
    if (o * sizeof(float) > ws_size) return;

    float* out = (float*)d_out;
    float* out_assign = out;
    float* out_sidx   = out + 6400;
    float* out_didx   = out + 6432;
    float* out_srm    = out + 6464;
    float* out_smd    = out + 9664;

    prep_kernel<<<NB, 256, 0, stream>>>(hs, sum_all, c1mean, centB, kv_ext);
    {
        int na = NB * SM * CC, nb = PW * CC, nc = CC * CC;
        int chunks = (na + nb + nc) / 4;
        decomp3<<<(chunks + 255) / 256, 256, 0, stream>>>(kv_ext, kvh, kvl, na,
                                                          ipw, iph, ipl, nb,
                                                          ow, owh, owl, nc);
    }
    gemm_mfma<<<dim3((NB * SM + 127) / 128, PW / 128), 256, 0, stream>>>(
        kvh, kvl, iph, ipl, ipb, P_all, NB * SM, PW);
    psum_kernel<<<NB, 256, 0, stream>>>(P_all, Psum0);
    gram_kernel<<<dim3(2, 2, NB), 256, 0, stream>>>(kv_ext, Gfull);
    far_kernel<<<NB, 256, 0, stream>>>(Gfull, far_rm, far_md);
    smhaB_kernel<<<NB, 256, 0, stream>>>(centB, P_all, ipw, ipb, ow, ob,
                                         out_assign, out_sidx, out_didx, cd, cs);
    attn_both<<<dim3(4, HH, NB), 256, 0, stream>>>(P_all, Psum0, far_rm, far_md, pvh, pvl, rowsum);
    gemm_mfma<<<dim3(NB * TB / 128, CC / 128), 256, 0, stream>>>(
        pvh, pvl, owh, owl, ob, mfx, NB * TB, CC);
    shift_both<<<2 * NB * QQ, 256, 0, stream>>>(rowsum, mfx, cd, cs, out_srm, out_smd);
}

// Round 6
// 202.579 us; speedup vs baseline: 2.0658x; 1.0160x over previous
//
#include <hip/hip_runtime.h>
#include <math.h>

#define NB 32
#define QQ 100
#define CC 256
#define HH 8
#define DH 32
#define SM 101   // kv rows per batch (100 points + mean)
#define TT 200   // branch queries per batch
#define TB 400   // both branches
#define PW 768   // P_all row width (q|k|v projections)

typedef __attribute__((ext_vector_type(8))) short s16x8;
typedef __attribute__((ext_vector_type(4))) float f32x4;

__device__ inline unsigned short f2bf(float x) {
    unsigned u = __float_as_uint(x);
    return (unsigned short)((u + 0x7fffu + ((u >> 16) & 1u)) >> 16);
}
__device__ inline float bf2f(unsigned short h) {
    return __uint_as_float(((unsigned)h) << 16);
}

// ---------------- prep: sums, mean center, far point, centers, kv_ext ----------------
__global__ void prep_kernel(const float* __restrict__ hs, float* __restrict__ sum_all,
                            float* __restrict__ c1mean, float* __restrict__ centB,
                            float* __restrict__ kv_ext) {
    int n = blockIdx.x;
    int c = threadIdx.x; // 0..255
    const float* h = hs + (size_t)n * QQ * CC;
    float s = 0.f;
    for (int q = 0; q < QQ; ++q) s += h[q * CC + c];
    float c1 = s * (1.0f / QQ);
    sum_all[n * CC + c] = s;
    c1mean[n * CC + c] = c1;
    __shared__ float c1s[CC];
    __shared__ float dls[QQ];
    c1s[c] = c1;
    float* kve = kv_ext + (size_t)n * SM * CC;
    for (int idx = c; idx < QQ * CC; idx += CC) kve[idx] = h[idx];
    kve[QQ * CC + c] = c1;
    __syncthreads();
    int wave = c >> 6, lane = c & 63;
    for (int q = wave; q < QQ; q += 4) {
        float p = 0.f;
        for (int cc = lane; cc < CC; cc += 64) {
            float d = c1s[cc] - h[q * CC + cc];
            p += d * d;
        }
        for (int off = 32; off > 0; off >>= 1) p += __shfl_down(p, off);
        if (lane == 0) dls[q] = p;
    }
    __syncthreads();
    __shared__ int fars;
    if (c == 0) {
        int best = 0; float bv = dls[0];
        for (int q = 1; q < QQ; ++q) if (dls[q] > bv) { bv = dls[q]; best = q; }
        fars = best;
    }
    __syncthreads();
    int far = fars;
    centB[(size_t)n * 2 * CC + c] = c1s[c];
    centB[(size_t)n * 2 * CC + CC + c] = h[(size_t)far * CC + c];
}

// ---------------- split-bf16 MFMA GEMM, fp32 inputs (split on stage): out = A @ W^T + bias ----------------
// Tile 128x128, 4 waves (2x2), wave = 64x64 = 4x4 mfma_16x16x32 tiles, BK=32.
#define LDK 40
__global__ __launch_bounds__(256, 2)
void gemm_mfma(const float* __restrict__ A_g, const float* __restrict__ W_g,
               const float* __restrict__ bias, float* __restrict__ out, int M, int Nout) {
    __shared__ unsigned short Ahs[128][LDK], Als[128][LDK], Bhs[128][LDK], Bls[128][LDK];
    int tid = threadIdx.x;
    int lane = tid & 63, wave = tid >> 6;
    int wm = (wave >> 1) * 64, wn = (wave & 1) * 64;
    int fr = lane & 15, kb = lane >> 4;
    int bm = blockIdx.x * 128, bn = blockIdx.y * 128;
    int srow = tid >> 1, scol = (tid & 1) * 16;
    int am = bm + srow; if (am >= M) am = M - 1;
    const float* pA = A_g + (size_t)am * CC + scol;
    const float* pW = W_g + (size_t)(bn + srow) * CC + scol;
    f32x4 acc[4][4];
#pragma unroll
    for (int mi = 0; mi < 4; ++mi)
#pragma unroll
        for (int ni = 0; ni < 4; ++ni)
            acc[mi][ni] = (f32x4){0.f, 0.f, 0.f, 0.f};
    for (int k0 = 0; k0 < CC; k0 += 32) {
        float4 av[4], wv[4];
#pragma unroll
        for (int j = 0; j < 4; ++j) {
            av[j] = *(const float4*)(pA + k0 + 4 * j);
            wv[j] = *(const float4*)(pW + k0 + 4 * j);
        }
        __syncthreads();
#pragma unroll
        for (int j = 0; j < 4; ++j) {
            ushort4 h4, l4, wh4, wl4;
            h4.x = f2bf(av[j].x); l4.x = f2bf(av[j].x - bf2f(h4.x));
            h4.y = f2bf(av[j].y); l4.y = f2bf(av[j].y - bf2f(h4.y));
            h4.z = f2bf(av[j].z); l4.z = f2bf(av[j].z - bf2f(h4.z));
            h4.w = f2bf(av[j].w); l4.w = f2bf(av[j].w - bf2f(h4.w));
            wh4.x = f2bf(wv[j].x); wl4.x = f2bf(wv[j].x - bf2f(wh4.x));
            wh4.y = f2bf(wv[j].y); wl4.y = f2bf(wv[j].y - bf2f(wh4.y));
            wh4.z = f2bf(wv[j].z); wl4.z = f2bf(wv[j].z - bf2f(wh4.z));
            wh4.w = f2bf(wv[j].w); wl4.w = f2bf(wv[j].w - bf2f(wh4.w));
            *(ushort4*)&Ahs[srow][scol + 4 * j] = h4;
            *(ushort4*)&Als[srow][scol + 4 * j] = l4;
            *(ushort4*)&Bhs[srow][scol + 4 * j] = wh4;
            *(ushort4*)&Bls[srow][scol + 4 * j] = wl4;
        }
        __syncthreads();
        s16x8 fah[4], fal[4], fbh[4], fbl[4];
#pragma unroll
        for (int mi = 0; mi < 4; ++mi) {
            fah[mi] = *(const s16x8*)&Ahs[wm + mi * 16 + fr][kb * 8];
            fal[mi] = *(const s16x8*)&Als[wm + mi * 16 + fr][kb * 8];
        }
#pragma unroll
        for (int ni = 0; ni < 4; ++ni) {
            fbh[ni] = *(const s16x8*)&Bhs[wn + ni * 16 + fr][kb * 8];
            fbl[ni] = *(const s16x8*)&Bls[wn + ni * 16 + fr][kb * 8];
        }
#pragma unroll
        for (int mi = 0; mi < 4; ++mi)
#pragma unroll
            for (int ni = 0; ni < 4; ++ni) {
                acc[mi][ni] = __builtin_amdgcn_mfma_f32_16x16x32_bf16(fah[mi], fbh[ni], acc[mi][ni], 0, 0, 0);
                acc[mi][ni] = __builtin_amdgcn_mfma_f32_16x16x32_bf16(fah[mi], fbl[ni], acc[mi][ni], 0, 0, 0);
                acc[mi][ni] = __builtin_amdgcn_mfma_f32_16x16x32_bf16(fal[mi], fbh[ni], acc[mi][ni], 0, 0, 0);
            }
    }
#pragma unroll
    for (int mi = 0; mi < 4; ++mi) {
        int mb = bm + wm + mi * 16 + kb * 4;
#pragma unroll
        for (int r = 0; r < 4; ++r) {
            int m = mb + r;
            if (m < M) {
#pragma unroll
                for (int ni = 0; ni < 4; ++ni) {
                    int col = bn + wn + ni * 16 + fr;
                    out[(size_t)m * Nout + col] = acc[mi][ni][r] + bias[col];
                }
            }
        }
    }
}

// ---------------- batched Gram: Gfull[n] = kv_ext[n] @ kv_ext[n]^T (101x101) ----------------
#define GBK 16
__global__ void gram_kernel(const float* __restrict__ kv_ext, float* __restrict__ Gfull) {
    int n = blockIdx.z;
    __shared__ float As[GBK][64];
    __shared__ float Ws[GBK][64];
    const float* A = kv_ext + (size_t)n * SM * CC;
    float* G = Gfull + (size_t)n * SM * SM;
    int bm = blockIdx.x * 64;
    int bn = blockIdx.y * 64;
    int tid = threadIdx.x;
    int tn = tid & 15, tm = tid >> 4;
    int lr = tid >> 2;
    int lk = (tid & 3) * 4;
    float acc[4][4] = {};
    for (int k0 = 0; k0 < 256; k0 += GBK) {
        int am = bm + lr; if (am >= SM) am = SM - 1;
        int wm = bn + lr; if (wm >= SM) wm = SM - 1;
        const float4 av = *(const float4*)&A[(size_t)am * CC + k0 + lk];
        const float4 wv = *(const float4*)&A[(size_t)wm * CC + k0 + lk];
        __syncthreads();
        As[lk + 0][lr] = av.x; As[lk + 1][lr] = av.y; As[lk + 2][lr] = av.z; As[lk + 3][lr] = av.w;
        Ws[lk + 0][lr] = wv.x; Ws[lk + 1][lr] = wv.y; Ws[lk + 2][lr] = wv.z; Ws[lk + 3][lr] = wv.w;
        __syncthreads();
#pragma unroll
        for (int kk = 0; kk < GBK; ++kk) {
            float a0 = As[kk][tm * 4 + 0], a1 = As[kk][tm * 4 + 1];
            float a2 = As[kk][tm * 4 + 2], a3 = As[kk][tm * 4 + 3];
            float b0 = Ws[kk][tn * 4 + 0], b1 = Ws[kk][tn * 4 + 1];
            float b2 = Ws[kk][tn * 4 + 2], b3 = Ws[kk][tn * 4 + 3];
            acc[0][0] += a0 * b0; acc[0][1] += a0 * b1; acc[0][2] += a0 * b2; acc[0][3] += a0 * b3;
            acc[1][0] += a1 * b0; acc[1][1] += a1 * b1; acc[1][2] += a1 * b2; acc[1][3] += a1 * b3;
            acc[2][0] += a2 * b0; acc[2][1] += a2 * b1; acc[2][2] += a2 * b2; acc[2][3] += a2 * b3;
            acc[3][0] += a3 * b0; acc[3][1] += a3 * b1; acc[3][2] += a3 * b2; acc[3][3] += a3 * b3;
        }
    }
#pragma unroll
    for (int i = 0; i < 4; ++i) {
        int m = bm + tm * 4 + i;
        if (m < SM) {
#pragma unroll
            for (int j = 0; j < 4; ++j) {
                int o = bn + tn * 4 + j;
                if (o < SM) G[(size_t)m * SM + o] = acc[i][j];
            }
        }
    }
}

// ---------------- far selection from Gram (both branches) ----------------
__global__ void far_kernel(const float* __restrict__ Gfull, int* __restrict__ far_rm,
                           int* __restrict__ far_md) {
    int n = blockIdx.x; int tid = threadIdx.x;
    __shared__ float sumdot[SM], meandot[SM], norm[SM];
    const float* G = Gfull + (size_t)n * SM * SM;
    for (int s = tid; s < SM; s += 256) {
        const float* row = G + (size_t)s * SM;
        float acc = 0.f;
        for (int q = 0; q < QQ; ++q) acc += row[q];
        sumdot[s] = acc; meandot[s] = row[QQ]; norm[s] = row[s];
    }
    __syncthreads();
    if (tid < QQ) {
        int q = tid, qm1 = (q + QQ - 1) % QQ;
        const float* gq = G + (size_t)qm1 * SM;
        int best = -1; float bv = -1e30f;
        for (int s = 0; s < QQ; ++s) {
            if (s == qm1) continue;
            float val = norm[s] - (sumdot[s] - gq[s]) * (2.f / 99.f);
            if (val > bv) { bv = val; best = s; }
        }
        far_rm[n * QQ + q] = best;
    } else if (tid >= 128 && tid < 128 + QQ) {
        int q = tid - 128, qm1 = (q + QQ - 1) % QQ;
        const float* gq = G + (size_t)qm1 * SM;
        int best = -1; float bv = -1e30f;
        for (int s = 0; s < SM; ++s) {
            if (s == qm1) continue;
            float val = norm[s] - (sumdot[s] - gq[s] + meandot[s]) * (2.f / 100.f);
            if (val > bv) { bv = val; best = s; }
        }
        far_md[n * QQ + q] = best;
    }
}

// ---------------- Psum0[n][c] = sum_{q<100} P_all[n][q][c], c<256 ----------------
__global__ void psum_kernel(const float* __restrict__ P_all, float* __restrict__ Psum0) {
    int n = blockIdx.x; int c = threadIdx.x;
    const float* base = P_all + (size_t)n * SM * PW + c;
    float acc = 0.f;
    for (int q = 0; q < QQ; ++q) acc += base[(size_t)q * PW];
    Psum0[n * CC + c] = acc;
}

// ---------------- stage B: small SMHA (2 queries), fused ----------------
__global__ void smhaB_kernel(const float* __restrict__ centB, const float* __restrict__ P_all,
                             const float* __restrict__ ipw, const float* __restrict__ ipb,
                             const float* __restrict__ ow, const float* __restrict__ ob,
                             float* __restrict__ out_assign, float* __restrict__ out_sidx,
                             float* __restrict__ out_didx, float* __restrict__ cd,
                             float* __restrict__ cs) {
    int n = blockIdx.x;
    int tid = threadIdx.x;
    __shared__ float qh[2][CC];
    __shared__ float attn[HH][2][QQ];
    __shared__ float pvB[2][CC];
    __shared__ float rs[16];
    __shared__ float mf[2][CC];
    __shared__ int sdi[2];
    const float* cen = centB + (size_t)n * 2 * CC;
    {
        const float4* wr4 = (const float4*)(ipw + (size_t)tid * CC);
        const float4* c0 = (const float4*)cen;
        const float4* c1 = (const float4*)(cen + CC);
        float a0 = ipb[tid], a1 = ipb[tid];
#pragma unroll 8
        for (int k = 0; k < 64; ++k) {
            float4 w = wr4[k], x0 = c0[k], x1 = c1[k];
            a0 += x0.x * w.x + x0.y * w.y + x0.z * w.z + x0.w * w.w;
            a1 += x1.x * w.x + x1.y * w.y + x1.z * w.z + x1.w * w.w;
        }
        qh[0][tid] = a0; qh[1][tid] = a1;
    }
    __syncthreads();
    const float* base = P_all + (size_t)n * SM * PW;
    const float scl = 0.17677669529663687f;
    for (int idx = tid; idx < HH * 2 * QQ; idx += 256) {
        int h = idx / 200; int r = idx % 200; int t = r / QQ; int s2 = r % QQ;
        const float4* kr = (const float4*)(base + (size_t)s2 * PW + CC + h * DH);
        const float4* qr = (const float4*)&qh[t][h * DH];
        float sc = 0.f;
#pragma unroll
        for (int d = 0; d < 8; ++d) {
            float4 k4 = kr[d], q4 = qr[d];
            sc += q4.x * k4.x + q4.y * k4.y + q4.z * k4.z + q4.w * k4.w;
        }
        attn[h][t][s2] = 1.f / (1.f + __expf(-sc * scl));
    }
    __syncthreads();
    if (tid < 16) {
        int h = tid >> 1, t = tid & 1; float s = 0.f;
        for (int s2 = 0; s2 < QQ; ++s2) s += attn[h][t][s2];
        rs[tid] = s;
    }
    __syncthreads();
    for (int idx = tid; idx < 2 * QQ; idx += 256) {
        int t = idx / QQ, s2 = idx % QQ;
        float m = 0.f;
        for (int h = 0; h < HH; ++h) m += attn[h][t][s2];
        out_assign[(size_t)n * 2 * QQ + idx] = m * 0.125f;
    }
    if (tid == 0) {
        float c0 = 0.f, c1v = 0.f;
        for (int h = 0; h < HH; ++h) { c0 += rs[h * 2 + 0]; c1v += rs[h * 2 + 1]; }
        int si = (c1v < c0) ? 1 : 0;
        int di = (c1v > c0) ? 1 : 0;
        sdi[0] = si; sdi[1] = di;
        out_sidx[n] = (float)si;
        out_didx[n] = (float)di;
    }
    for (int idx = tid; idx < 512; idx += 256) {
        int t = idx >> 8; int hd = idx & 255; int h = hd >> 5;
        float inv = 1.f / (rs[h * 2 + t] + 1e-4f);
        float a = 0.f;
        const float* vr = base + 2 * CC + hd;
        for (int s2 = 0; s2 < QQ; ++s2) a += attn[h][t][s2] * vr[(size_t)s2 * PW];
        pvB[t][hd] = a * inv;
    }
    __syncthreads();
    {
        const float4* wr4 = (const float4*)(ow + (size_t)tid * CC);
        const float4* p0 = (const float4*)&pvB[0][0];
        const float4* p1 = (const float4*)&pvB[1][0];
        float a0 = ob[tid], a1 = ob[tid];
#pragma unroll 8
        for (int k = 0; k < 64; ++k) {
            float4 w = wr4[k], x0 = p0[k], x1 = p1[k];
            a0 += x0.x * w.x + x0.y * w.y + x0.z * w.z + x0.w * w.w;
            a1 += x1.x * w.x + x1.y * w.y + x1.z * w.z + x1.w * w.w;
        }
        mf[0][tid] = a0; mf[1][tid] = a1;
    }
    __syncthreads();
    cd[(size_t)n * CC + tid] = mf[sdi[1]][tid];
    cs[(size_t)n * CC + tid] = mf[sdi[0]][tid];
}

// ---------------- MFMA attention (both branches): scores^T = K@Q^T, flash-streamed PV ----------------
// grid (2, HH, NB), 128 threads (2 waves). Wave handles 100 queries (7 padded 16-tiles).
__global__ __launch_bounds__(128, 2)
void attn_mfma(const float* __restrict__ P_all, const float* __restrict__ Psum0,
               const int* __restrict__ far_rm, const int* __restrict__ far_md,
               float* __restrict__ pv, float* __restrict__ rowsum) {
    int n = blockIdx.z, h = blockIdx.y, half = blockIdx.x;
    int tid = threadIdx.x;
    int w = tid >> 6, lane = tid & 63;
    int fr = lane & 15, hi = lane >> 4;
    int d0 = hi * 8;
    __shared__ unsigned short Kh[112 * 40];   // [key][d] hi, stride 40
    __shared__ unsigned short Kl[112 * 40];   // lo
    __shared__ unsigned short Vt[32 * 136];   // [d][key], keys padded to 128 (+stride 136)
    __shared__ unsigned short Pb[2][112 * 40]; // per-wave P chunk [query][32 keys], stride 40
    __shared__ float rsL[2][112];
    const float* base = P_all + (size_t)n * SM * PW;
    // ---- stage K (hi/lo) and V^T (single bf16) ----
    for (int idx = tid; idx < 112 * 8; idx += 128) {
        int key = idx >> 3, d4 = (idx & 7) * 4;
        float4 kv = {0.f, 0.f, 0.f, 0.f}, vv = {0.f, 0.f, 0.f, 0.f};
        if (key < SM) {
            kv = *(const float4*)&base[(size_t)key * PW + CC + h * DH + d4];
            vv = *(const float4*)&base[(size_t)key * PW + 2 * CC + h * DH + d4];
        }
        ushort4 h4, l4;
        h4.x = f2bf(kv.x); l4.x = f2bf(kv.x - bf2f(h4.x));
        h4.y = f2bf(kv.y); l4.y = f2bf(kv.y - bf2f(h4.y));
        h4.z = f2bf(kv.z); l4.z = f2bf(kv.z - bf2f(h4.z));
        h4.w = f2bf(kv.w); l4.w = f2bf(kv.w - bf2f(h4.w));
        *(ushort4*)&Kh[key * 40 + d4] = h4;
        *(ushort4*)&Kl[key * 40 + d4] = l4;
        Vt[(d4 + 0) * 136 + key] = f2bf(vv.x);
        Vt[(d4 + 1) * 136 + key] = f2bf(vv.y);
        Vt[(d4 + 2) * 136 + key] = f2bf(vv.z);
        Vt[(d4 + 3) * 136 + key] = f2bf(vv.w);
    }
    // zero the V pad keys 112..127 (keys 101..111 already zeroed above)
    for (int idx = tid; idx < 32 * 16; idx += 128) {
        int d = idx >> 4, key = 112 + (idx & 15);
        Vt[d * 136 + key] = 0;
    }
    __syncthreads();
    // ---- Q gather: per lane, query col = qt*16+fr, d-range d0..d0+7, split hi/lo ----
    s16x8 qh[7], ql[7];
    int mk[7], sb[7];
    const float* Psum0n = Psum0 + n * CC;
    int rowbase = half * 200 + w * 100;
#pragma unroll
    for (int qt = 0; qt < 7; ++qt) {
        int lq = qt * 16 + fr;
        int row = rowbase + (lq < QQ ? lq : QQ - 1);
        int b = row >= TT;
        int t = row - b * TT;
        int q = t >> 1;
        mk[qt] = q; sb[qt] = b ? SM : QQ;
        float qv[8];
        if (t & 1) {
            int f = (b ? far_md : far_rm)[n * QQ + q];
            const float4* pr = (const float4*)(base + (size_t)f * PW + h * DH + d0);
            float4 v0 = pr[0], v1 = pr[1];
            qv[0] = v0.x; qv[1] = v0.y; qv[2] = v0.z; qv[3] = v0.w;
            qv[4] = v1.x; qv[5] = v1.y; qv[6] = v1.z; qv[7] = v1.w;
        } else {
            int qm1 = (q + QQ - 1) % QQ;
            const float4* ps = (const float4*)(Psum0n + h * DH + d0);
            const float4* pm = (const float4*)(base + (size_t)qm1 * PW + h * DH + d0);
            const float4* pmn = (const float4*)(base + (size_t)QQ * PW + h * DH + d0);
            float invd = b ? 0.01f : (1.f / 99.f);
            float bb = b ? 1.f : 0.f;
            float4 a0 = ps[0], c0 = pm[0], m0 = pmn[0];
            float4 a1 = ps[1], c1 = pm[1], m1 = pmn[1];
            qv[0] = (a0.x - c0.x + bb * m0.x) * invd;
            qv[1] = (a0.y - c0.y + bb * m0.y) * invd;
            qv[2] = (a0.z - c0.z + bb * m0.z) * invd;
            qv[3] = (a0.w - c0.w + bb * m0.w) * invd;
            qv[4] = (a1.x - c1.x + bb * m1.x) * invd;
            qv[5] = (a1.y - c1.y + bb * m1.y) * invd;
            qv[6] = (a1.z - c1.z + bb * m1.z) * invd;
            qv[7] = (a1.w - c1.w + bb * m1.w) * invd;
        }
        s16x8 qhv, qlv;
#pragma unroll
        for (int j = 0; j < 8; ++j) {
            unsigned short hh = f2bf(qv[j]);
            qhv[j] = (short)hh;
            qlv[j] = (short)f2bf(qv[j] - bf2f(hh));
        }
        qh[qt] = qhv; ql[qt] = qlv;
    }
    // ---- main loop over key chunks of 32 ----
    f32x4 pvacc[7][2];
#pragma unroll
    for (int qt = 0; qt < 7; ++qt) {
        pvacc[qt][0] = (f32x4){0.f, 0.f, 0.f, 0.f};
        pvacc[qt][1] = (f32x4){0.f, 0.f, 0.f, 0.f};
    }
    float rs[7] = {0.f, 0.f, 0.f, 0.f, 0.f, 0.f, 0.f};
    unsigned short* Pw = Pb[w];
    const float scl = 0.17677669529663687f;
#pragma unroll
    for (int kc = 0; kc < 4; ++kc) {
        int k0 = kc * 32;
        s16x8 ah0 = *(const s16x8*)&Kh[(k0 + fr) * 40 + d0];
        s16x8 al0 = *(const s16x8*)&Kl[(k0 + fr) * 40 + d0];
        s16x8 ah1 = ah0, al1 = al0;
        if (kc < 3) {
            ah1 = *(const s16x8*)&Kh[(k0 + 16 + fr) * 40 + d0];
            al1 = *(const s16x8*)&Kl[(k0 + 16 + fr) * 40 + d0];
        }
#pragma unroll
        for (int qt = 0; qt < 7; ++qt) {
            f32x4 s0 = (f32x4){0.f, 0.f, 0.f, 0.f};
            s0 = __builtin_amdgcn_mfma_f32_16x16x32_bf16(ah0, qh[qt], s0, 0, 0, 0);
            s0 = __builtin_amdgcn_mfma_f32_16x16x32_bf16(ah0, ql[qt], s0, 0, 0, 0);
            s0 = __builtin_amdgcn_mfma_f32_16x16x32_bf16(al0, qh[qt], s0, 0, 0, 0);
            ushort4 p4;
            int kb0 = k0 + 4 * hi;
            {
                float a0 = (kb0 + 0 < sb[qt] && kb0 + 0 != mk[qt]) ? 1.f / (1.f + __expf(-s0[0] * scl)) : 0.f;
                float a1 = (kb0 + 1 < sb[qt] && kb0 + 1 != mk[qt]) ? 1.f / (1.f + __expf(-s0[1] * scl)) : 0.f;
                float a2 = (kb0 + 2 < sb[qt] && kb0 + 2 != mk[qt]) ? 1.f / (1.f + __expf(-s0[2] * scl)) : 0.f;
                float a3 = (kb0 + 3 < sb[qt] && kb0 + 3 != mk[qt]) ? 1.f / (1.f + __expf(-s0[3] * scl)) : 0.f;
                rs[qt] += a0 + a1 + a2 + a3;
                p4.x = f2bf(a0); p4.y = f2bf(a1); p4.z = f2bf(a2); p4.w = f2bf(a3);
            }
            *(ushort4*)&Pw[(qt * 16 + fr) * 40 + 4 * hi] = p4;
            if (kc < 3) {
                f32x4 s1 = (f32x4){0.f, 0.f, 0.f, 0.f};
                s1 = __builtin_amdgcn_mfma_f32_16x16x32_bf16(ah1, qh[qt], s1, 0, 0, 0);
                s1 = __builtin_amdgcn_mfma_f32_16x16x32_bf16(ah1, ql[qt], s1, 0, 0, 0);
                s1 = __builtin_amdgcn_mfma_f32_16x16x32_bf16(al1, qh[qt], s1, 0, 0, 0);
                ushort4 p4b;
                int kb1 = k0 + 16 + 4 * hi;
                float a0 = (kb1 + 0 < sb[qt] && kb1 + 0 != mk[qt]) ? 1.f / (1.f + __expf(-s1[0] * scl)) : 0.f;
                float a1 = (kb1 + 1 < sb[qt] && kb1 + 1 != mk[qt]) ? 1.f / (1.f + __expf(-s1[1] * scl)) : 0.f;
                float a2 = (kb1 + 2 < sb[qt] && kb1 + 2 != mk[qt]) ? 1.f / (1.f + __expf(-s1[2] * scl)) : 0.f;
                float a3 = (kb1 + 3 < sb[qt] && kb1 + 3 != mk[qt]) ? 1.f / (1.f + __expf(-s1[3] * scl)) : 0.f;
                rs[qt] += a0 + a1 + a2 + a3;
                p4b.x = f2bf(a0); p4b.y = f2bf(a1); p4b.z = f2bf(a2); p4b.w = f2bf(a3);
                *(ushort4*)&Pw[(qt * 16 + fr) * 40 + 16 + 4 * hi] = p4b;
            } else {
                ushort4 z; z.x = 0; z.y = 0; z.z = 0; z.w = 0;
                *(ushort4*)&Pw[(qt * 16 + fr) * 40 + 16 + 4 * hi] = z;
            }
        }
        // PV for this chunk (wave-private LDS; compiler inserts lgkm waits)
        s16x8 vb0 = *(const s16x8*)&Vt[(0 * 16 + fr) * 136 + k0 + d0];
        s16x8 vb1 = *(const s16x8*)&Vt[(1 * 16 + fr) * 136 + k0 + d0];
#pragma unroll
        for (int qt = 0; qt < 7; ++qt) {
            s16x8 pa = *(const s16x8*)&Pw[(qt * 16 + fr) * 40 + d0];
            pvacc[qt][0] = __builtin_amdgcn_mfma_f32_16x16x32_bf16(pa, vb0, pvacc[qt][0], 0, 0, 0);
            pvacc[qt][1] = __builtin_amdgcn_mfma_f32_16x16x32_bf16(pa, vb1, pvacc[qt][1], 0, 0, 0);
        }
    }
    // ---- rowsum reduce across hi-groups, store ----
#pragma unroll
    for (int qt = 0; qt < 7; ++qt) {
        float r2 = rs[qt] + __shfl_xor(rs[qt], 16);
        r2 += __shfl_xor(r2, 32);
        int lq = qt * 16 + fr;
        if (hi == 0) {
            rsL[w][lq] = r2;
            if (lq < QQ) rowsum[((size_t)n * HH + h) * TB + rowbase + lq] = r2;
        }
    }
    // ---- epilogue: normalize and write pv (fp32) ----
#pragma unroll
    for (int qt = 0; qt < 7; ++qt) {
        float iv[4];
#pragma unroll
        for (int r = 0; r < 4; ++r) {
            int lq = qt * 16 + 4 * hi + r;
            iv[r] = 1.f / (rsL[w][lq < 112 ? lq : 111] + 1e-4f);
        }
#pragma unroll
        for (int dt = 0; dt < 2; ++dt) {
#pragma unroll
            for (int r = 0; r < 4; ++r) {
                int lq = qt * 16 + 4 * hi + r;
                if (lq < QQ)
                    pv[((size_t)n * TB + rowbase + lq) * CC + h * DH + dt * 16 + fr] = pvacc[qt][dt][r] * iv[r];
            }
        }
    }
}

// ---------------- shift (both branches): card argmin/argmax + distances ----------------
__global__ void shift_both(const float* __restrict__ rowsum, const float* __restrict__ mfx,
                           const float* __restrict__ cd, const float* __restrict__ cs,
                           float* __restrict__ out_srm, float* __restrict__ out_smd) {
    int b = blockIdx.x / (NB * QQ);
    int rem = blockIdx.x % (NB * QQ);
    int n = rem / QQ, q = rem % QQ;
    int tid = threadIdx.x;
    __shared__ float red[256];
    __shared__ int sdi[2];
    if (tid == 0) {
        float c0 = 0.f, c1v = 0.f;
        int rb = b * TT + 2 * q;
        for (int h = 0; h < HH; ++h) {
            c0  += rowsum[((size_t)n * HH + h) * TB + rb];
            c1v += rowsum[((size_t)n * HH + h) * TB + rb + 1];
        }
        sdi[0] = (c1v < c0) ? 1 : 0;
        sdi[1] = (c1v > c0) ? 1 : 0;
    }
    __syncthreads();
    int si = sdi[0], di = sdi[1];
    const float* mdp = mfx + ((size_t)n * TB + b * TT + 2 * q + di) * CC;
    const float* msp = mfx + ((size_t)n * TB + b * TT + 2 * q + si) * CC;
    float dd = mdp[tid] - cd[(size_t)n * CC + tid];
    float ds = msp[tid] - cs[(size_t)n * CC + tid];
    red[tid] = dd * dd;
    __syncthreads();
    for (int off = 128; off > 0; off >>= 1) { if (tid < off) red[tid] += red[tid + off]; __syncthreads(); }
    float distd = sqrtf(red[0] + 1e-12f);
    __syncthreads();
    red[tid] = ds * ds;
    __syncthreads();
    for (int off = 128; off > 0; off >>= 1) { if (tid < off) red[tid] += red[tid + off]; __syncthreads(); }
    if (tid == 0) (b ? out_smd : out_srm)[n * QQ + q] = distd + sqrtf(red[0] + 1e-12f);
}

extern "C" void kernel_launch(void* const* d_in, const int* in_sizes, int n_in,
                              void* d_out, int out_size, void* d_ws, size_t ws_size,
                              hipStream_t stream) {
    const float* hs_pair = (const float*)d_in[0];
    const float* ipw = (const float*)d_in[1];
    const float* ipb = (const float*)d_in[2];
    const float* ow  = (const float*)d_in[3];
    const float* ob  = (const float*)d_in[4];
    const float* hs = hs_pair + (size_t)5 * NB * QQ * CC;  // hs_pair[-1]

    float* ws = (float*)d_ws;
    size_t o = 0;
    // region A: dead after attn_mfma -> mfx aliases it
    float* kv_ext  = ws + o; o += (size_t)NB * SM * CC;       // 827,392
    float* P_all   = ws + o; o += (size_t)NB * SM * PW;       // 2,482,176
    float* Gfull   = ws + o; o += (size_t)NB * SM * SM;       // 326,432
    float* mfx     = kv_ext;                                  // 3,276,800 <= 3,636,000
    // region B: live throughout
    float* sum_all = ws + o; o += NB * CC;
    float* c1mean  = ws + o; o += NB * CC;
    float* centB   = ws + o; o += (size_t)NB * 2 * CC;
    float* Psum0   = ws + o; o += NB * CC;
    int*   far_rm  = (int*)(ws + o); o += NB * QQ;
    int*   far_md  = (int*)(ws + o); o += NB * QQ;
    float* cd      = ws + o; o += NB * CC;
    float* cs      = ws + o; o += NB * CC;
    float* pv      = ws + o; o += (size_t)NB * TB * CC;       // 3,276,800
    float* rowsum  = ws + o; o += (size_t)NB * HH * TB;
    if (o * sizeof(float) > ws_size) return;

    float* out = (float*)d_out;
    float* out_assign = out;
    float* out_sidx   = out + 6400;
    float* out_didx   = out + 6432;
    float* out_srm    = out + 6464;
    float* out_smd    = out + 9664;

    prep_kernel<<<NB, 256, 0, stream>>>(hs, sum_all, c1mean, centB, kv_ext);
    gemm_mfma<<<dim3((NB * SM + 127) / 128, PW / 128), 256, 0, stream>>>(
        kv_ext, ipw, ipb, P_all, NB * SM, PW);
    psum_kernel<<<NB, 256, 0, stream>>>(P_all, Psum0);
    gram_kernel<<<dim3(2, 2, NB), 256, 0, stream>>>(kv_ext, Gfull);
    far_kernel<<<NB, 256, 0, stream>>>(Gfull, far_rm, far_md);
    smhaB_kernel<<<NB, 256, 0, stream>>>(centB, P_all, ipw, ipb, ow, ob,
                                         out_assign, out_sidx, out_didx, cd, cs);
    attn_mfma<<<dim3(2, HH, NB), 128, 0, stream>>>(P_all, Psum0, far_rm, far_md, pv, rowsum);
    gemm_mfma<<<dim3(NB * TB / 128, CC / 128), 256, 0, stream>>>(
        pv, ow, ob, mfx, NB * TB, CC);
    shift_both<<<2 * NB * QQ, 256, 0, stream>>>(rowsum, mfx, cd, cs, out_srm, out_smd);
}

// Round 7
// 181.937 us; speedup vs baseline: 2.3002x; 1.1135x over previous
//
#include <hip/hip_runtime.h>
#include <math.h>

#define NB 32
#define QQ 100
#define CC 256
#define HH 8
#define DH 32
#define SM 101   // kv rows per batch (100 points + mean)
#define TT 200   // branch queries per batch
#define TB 400   // both branches
#define PW 768   // P_all row width (q|k|v projections)

typedef __attribute__((ext_vector_type(8))) short s16x8;
typedef __attribute__((ext_vector_type(4))) float f32x4;

__device__ inline unsigned short f2bf(float x) {
    unsigned u = __float_as_uint(x);
    return (unsigned short)((u + 0x7fffu + ((u >> 16) & 1u)) >> 16);
}
__device__ inline float bf2f(unsigned short h) {
    return __uint_as_float(((unsigned)h) << 16);
}

// ---------------- prep: sums, mean center, far point, centers, kv_ext ----------------
__global__ void prep_kernel(const float* __restrict__ hs, float* __restrict__ sum_all,
                            float* __restrict__ c1mean, float* __restrict__ centB,
                            float* __restrict__ kv_ext) {
    int n = blockIdx.x;
    int c = threadIdx.x; // 0..255
    const float* h = hs + (size_t)n * QQ * CC;
    float s = 0.f;
    for (int q = 0; q < QQ; ++q) s += h[q * CC + c];
    float c1 = s * (1.0f / QQ);
    sum_all[n * CC + c] = s;
    c1mean[n * CC + c] = c1;
    __shared__ float c1s[CC];
    __shared__ float dls[QQ];
    c1s[c] = c1;
    float* kve = kv_ext + (size_t)n * SM * CC;
    for (int idx = c; idx < QQ * CC; idx += CC) kve[idx] = h[idx];
    kve[QQ * CC + c] = c1;
    __syncthreads();
    int wave = c >> 6, lane = c & 63;
    for (int q = wave; q < QQ; q += 4) {
        float p = 0.f;
        for (int cc = lane; cc < CC; cc += 64) {
            float d = c1s[cc] - h[q * CC + cc];
            p += d * d;
        }
        for (int off = 32; off > 0; off >>= 1) p += __shfl_down(p, off);
        if (lane == 0) dls[q] = p;
    }
    __syncthreads();
    __shared__ int fars;
    if (c == 0) {
        int best = 0; float bv = dls[0];
        for (int q = 1; q < QQ; ++q) if (dls[q] > bv) { bv = dls[q]; best = q; }
        fars = best;
    }
    __syncthreads();
    int far = fars;
    centB[(size_t)n * 2 * CC + c] = c1s[c];
    centB[(size_t)n * 2 * CC + CC + c] = h[(size_t)far * CC + c];
}

// ---------------- split-bf16 MFMA GEMM, fp32 inputs (split on stage): out = A @ W^T + bias ----------------
// Tile 128x128, 4 waves (2x2), wave = 64x64 = 4x4 mfma_16x16x32 tiles, BK=32.
#define LDK 40
__global__ __launch_bounds__(256, 2)
void gemm_mfma(const float* __restrict__ A_g, const float* __restrict__ W_g,
               const float* __restrict__ bias, float* __restrict__ out, int M, int Nout) {
    __shared__ unsigned short Ahs[128][LDK], Als[128][LDK], Bhs[128][LDK], Bls[128][LDK];
    int tid = threadIdx.x;
    int lane = tid & 63, wave = tid >> 6;
    int wm = (wave >> 1) * 64, wn = (wave & 1) * 64;
    int fr = lane & 15, kb = lane >> 4;
    int bm = blockIdx.x * 128, bn = blockIdx.y * 128;
    int srow = tid >> 1, scol = (tid & 1) * 16;
    int am = bm + srow; if (am >= M) am = M - 1;
    const float* pA = A_g + (size_t)am * CC + scol;
    const float* pW = W_g + (size_t)(bn + srow) * CC + scol;
    f32x4 acc[4][4];
#pragma unroll
    for (int mi = 0; mi < 4; ++mi)
#pragma unroll
        for (int ni = 0; ni < 4; ++ni)
            acc[mi][ni] = (f32x4){0.f, 0.f, 0.f, 0.f};
    for (int k0 = 0; k0 < CC; k0 += 32) {
        float4 av[4], wv[4];
#pragma unroll
        for (int j = 0; j < 4; ++j) {
            av[j] = *(const float4*)(pA + k0 + 4 * j);
            wv[j] = *(const float4*)(pW + k0 + 4 * j);
        }
        __syncthreads();
#pragma unroll
        for (int j = 0; j < 4; ++j) {
            ushort4 h4, l4, wh4, wl4;
            h4.x = f2bf(av[j].x); l4.x = f2bf(av[j].x - bf2f(h4.x));
            h4.y = f2bf(av[j].y); l4.y = f2bf(av[j].y - bf2f(h4.y));
            h4.z = f2bf(av[j].z); l4.z = f2bf(av[j].z - bf2f(h4.z));
            h4.w = f2bf(av[j].w); l4.w = f2bf(av[j].w - bf2f(h4.w));
            wh4.x = f2bf(wv[j].x); wl4.x = f2bf(wv[j].x - bf2f(wh4.x));
            wh4.y = f2bf(wv[j].y); wl4.y = f2bf(wv[j].y - bf2f(wh4.y));
            wh4.z = f2bf(wv[j].z); wl4.z = f2bf(wv[j].z - bf2f(wh4.z));
            wh4.w = f2bf(wv[j].w); wl4.w = f2bf(wv[j].w - bf2f(wh4.w));
            *(ushort4*)&Ahs[srow][scol + 4 * j] = h4;
            *(ushort4*)&Als[srow][scol + 4 * j] = l4;
            *(ushort4*)&Bhs[srow][scol + 4 * j] = wh4;
            *(ushort4*)&Bls[srow][scol + 4 * j] = wl4;
        }
        __syncthreads();
        s16x8 fah[4], fal[4], fbh[4], fbl[4];
#pragma unroll
        for (int mi = 0; mi < 4; ++mi) {
            fah[mi] = *(const s16x8*)&Ahs[wm + mi * 16 + fr][kb * 8];
            fal[mi] = *(const s16x8*)&Als[wm + mi * 16 + fr][kb * 8];
        }
#pragma unroll
        for (int ni = 0; ni < 4; ++ni) {
            fbh[ni] = *(const s16x8*)&Bhs[wn + ni * 16 + fr][kb * 8];
            fbl[ni] = *(const s16x8*)&Bls[wn + ni * 16 + fr][kb * 8];
        }
#pragma unroll
        for (int mi = 0; mi < 4; ++mi)
#pragma unroll
            for (int ni = 0; ni < 4; ++ni) {
                acc[mi][ni] = __builtin_amdgcn_mfma_f32_16x16x32_bf16(fah[mi], fbh[ni], acc[mi][ni], 0, 0, 0);
                acc[mi][ni] = __builtin_amdgcn_mfma_f32_16x16x32_bf16(fah[mi], fbl[ni], acc[mi][ni], 0, 0, 0);
                acc[mi][ni] = __builtin_amdgcn_mfma_f32_16x16x32_bf16(fal[mi], fbh[ni], acc[mi][ni], 0, 0, 0);
            }
    }
#pragma unroll
    for (int mi = 0; mi < 4; ++mi) {
        int mb = bm + wm + mi * 16 + kb * 4;
#pragma unroll
        for (int r = 0; r < 4; ++r) {
            int m = mb + r;
            if (m < M) {
#pragma unroll
                for (int ni = 0; ni < 4; ++ni) {
                    int col = bn + wn + ni * 16 + fr;
                    out[(size_t)m * Nout + col] = acc[mi][ni][r] + bias[col];
                }
            }
        }
    }
}

// ---------------- batched Gram: Gfull[n] = kv_ext[n] @ kv_ext[n]^T (101x101) ----------------
#define GBK 16
__global__ void gram_kernel(const float* __restrict__ kv_ext, float* __restrict__ Gfull) {
    int n = blockIdx.z;
    __shared__ float As[GBK][64];
    __shared__ float Ws[GBK][64];
    const float* A = kv_ext + (size_t)n * SM * CC;
    float* G = Gfull + (size_t)n * SM * SM;
    int bm = blockIdx.x * 64;
    int bn = blockIdx.y * 64;
    int tid = threadIdx.x;
    int tn = tid & 15, tm = tid >> 4;
    int lr = tid >> 2;
    int lk = (tid & 3) * 4;
    float acc[4][4] = {};
    for (int k0 = 0; k0 < 256; k0 += GBK) {
        int am = bm + lr; if (am >= SM) am = SM - 1;
        int wm = bn + lr; if (wm >= SM) wm = SM - 1;
        const float4 av = *(const float4*)&A[(size_t)am * CC + k0 + lk];
        const float4 wv = *(const float4*)&A[(size_t)wm * CC + k0 + lk];
        __syncthreads();
        As[lk + 0][lr] = av.x; As[lk + 1][lr] = av.y; As[lk + 2][lr] = av.z; As[lk + 3][lr] = av.w;
        Ws[lk + 0][lr] = wv.x; Ws[lk + 1][lr] = wv.y; Ws[lk + 2][lr] = wv.z; Ws[lk + 3][lr] = wv.w;
        __syncthreads();
#pragma unroll
        for (int kk = 0; kk < GBK; ++kk) {
            float a0 = As[kk][tm * 4 + 0], a1 = As[kk][tm * 4 + 1];
            float a2 = As[kk][tm * 4 + 2], a3 = As[kk][tm * 4 + 3];
            float b0 = Ws[kk][tn * 4 + 0], b1 = Ws[kk][tn * 4 + 1];
            float b2 = Ws[kk][tn * 4 + 2], b3 = Ws[kk][tn * 4 + 3];
            acc[0][0] += a0 * b0; acc[0][1] += a0 * b1; acc[0][2] += a0 * b2; acc[0][3] += a0 * b3;
            acc[1][0] += a1 * b0; acc[1][1] += a1 * b1; acc[1][2] += a1 * b2; acc[1][3] += a1 * b3;
            acc[2][0] += a2 * b0; acc[2][1] += a2 * b1; acc[2][2] += a2 * b2; acc[2][3] += a2 * b3;
            acc[3][0] += a3 * b0; acc[3][1] += a3 * b1; acc[3][2] += a3 * b2; acc[3][3] += a3 * b3;
        }
    }
#pragma unroll
    for (int i = 0; i < 4; ++i) {
        int m = bm + tm * 4 + i;
        if (m < SM) {
#pragma unroll
            for (int j = 0; j < 4; ++j) {
                int o = bn + tn * 4 + j;
                if (o < SM) G[(size_t)m * SM + o] = acc[i][j];
            }
        }
    }
}

// ---------------- far selection from Gram (both branches) ----------------
__global__ void far_kernel(const float* __restrict__ Gfull, int* __restrict__ far_rm,
                           int* __restrict__ far_md) {
    int n = blockIdx.x; int tid = threadIdx.x;
    __shared__ float sumdot[SM], meandot[SM], norm[SM];
    const float* G = Gfull + (size_t)n * SM * SM;
    for (int s = tid; s < SM; s += 256) {
        const float* row = G + (size_t)s * SM;
        float acc = 0.f;
        for (int q = 0; q < QQ; ++q) acc += row[q];
        sumdot[s] = acc; meandot[s] = row[QQ]; norm[s] = row[s];
    }
    __syncthreads();
    if (tid < QQ) {
        int q = tid, qm1 = (q + QQ - 1) % QQ;
        const float* gq = G + (size_t)qm1 * SM;
        int best = -1; float bv = -1e30f;
        for (int s = 0; s < QQ; ++s) {
            if (s == qm1) continue;
            float val = norm[s] - (sumdot[s] - gq[s]) * (2.f / 99.f);
            if (val > bv) { bv = val; best = s; }
        }
        far_rm[n * QQ + q] = best;
    } else if (tid >= 128 && tid < 128 + QQ) {
        int q = tid - 128, qm1 = (q + QQ - 1) % QQ;
        const float* gq = G + (size_t)qm1 * SM;
        int best = -1; float bv = -1e30f;
        for (int s = 0; s < SM; ++s) {
            if (s == qm1) continue;
            float val = norm[s] - (sumdot[s] - gq[s] + meandot[s]) * (2.f / 100.f);
            if (val > bv) { bv = val; best = s; }
        }
        far_md[n * QQ + q] = best;
    }
}

// ---------------- Psum0[n][c] = sum_{q<100} P_all[n][q][c], c<256 ----------------
__global__ void psum_kernel(const float* __restrict__ P_all, float* __restrict__ Psum0) {
    int n = blockIdx.x; int c = threadIdx.x;
    const float* base = P_all + (size_t)n * SM * PW + c;
    float acc = 0.f;
    for (int q = 0; q < QQ; ++q) acc += base[(size_t)q * PW];
    Psum0[n * CC + c] = acc;
}

// ---------------- stage B: small SMHA (2 queries), fused ----------------
__global__ void smhaB_kernel(const float* __restrict__ centB, const float* __restrict__ P_all,
                             const float* __restrict__ ipw, const float* __restrict__ ipb,
                             const float* __restrict__ ow, const float* __restrict__ ob,
                             float* __restrict__ out_assign, float* __restrict__ out_sidx,
                             float* __restrict__ out_didx, float* __restrict__ cd,
                             float* __restrict__ cs) {
    int n = blockIdx.x;
    int tid = threadIdx.x;
    __shared__ float qh[2][CC];
    __shared__ float attn[HH][2][QQ];
    __shared__ float pvB[2][CC];
    __shared__ float rs[16];
    __shared__ float mf[2][CC];
    __shared__ int sdi[2];
    const float* cen = centB + (size_t)n * 2 * CC;
    {
        const float4* wr4 = (const float4*)(ipw + (size_t)tid * CC);
        const float4* c0 = (const float4*)cen;
        const float4* c1 = (const float4*)(cen + CC);
        float a0 = ipb[tid], a1 = ipb[tid];
#pragma unroll 8
        for (int k = 0; k < 64; ++k) {
            float4 w = wr4[k], x0 = c0[k], x1 = c1[k];
            a0 += x0.x * w.x + x0.y * w.y + x0.z * w.z + x0.w * w.w;
            a1 += x1.x * w.x + x1.y * w.y + x1.z * w.z + x1.w * w.w;
        }
        qh[0][tid] = a0; qh[1][tid] = a1;
    }
    __syncthreads();
    const float* base = P_all + (size_t)n * SM * PW;
    const float scl = 0.17677669529663687f;
    for (int idx = tid; idx < HH * 2 * QQ; idx += 256) {
        int h = idx / 200; int r = idx % 200; int t = r / QQ; int s2 = r % QQ;
        const float4* kr = (const float4*)(base + (size_t)s2 * PW + CC + h * DH);
        const float4* qr = (const float4*)&qh[t][h * DH];
        float sc = 0.f;
#pragma unroll
        for (int d = 0; d < 8; ++d) {
            float4 k4 = kr[d], q4 = qr[d];
            sc += q4.x * k4.x + q4.y * k4.y + q4.z * k4.z + q4.w * k4.w;
        }
        attn[h][t][s2] = 1.f / (1.f + __expf(-sc * scl));
    }
    __syncthreads();
    if (tid < 16) {
        int h = tid >> 1, t = tid & 1; float s = 0.f;
        for (int s2 = 0; s2 < QQ; ++s2) s += attn[h][t][s2];
        rs[tid] = s;
    }
    __syncthreads();
    for (int idx = tid; idx < 2 * QQ; idx += 256) {
        int t = idx / QQ, s2 = idx % QQ;
        float m = 0.f;
        for (int h = 0; h < HH; ++h) m += attn[h][t][s2];
        out_assign[(size_t)n * 2 * QQ + idx] = m * 0.125f;
    }
    if (tid == 0) {
        float c0 = 0.f, c1v = 0.f;
        for (int h = 0; h < HH; ++h) { c0 += rs[h * 2 + 0]; c1v += rs[h * 2 + 1]; }
        int si = (c1v < c0) ? 1 : 0;
        int di = (c1v > c0) ? 1 : 0;
        sdi[0] = si; sdi[1] = di;
        out_sidx[n] = (float)si;
        out_didx[n] = (float)di;
    }
    for (int idx = tid; idx < 512; idx += 256) {
        int t = idx >> 8; int hd = idx & 255; int h = hd >> 5;
        float inv = 1.f / (rs[h * 2 + t] + 1e-4f);
        float a = 0.f;
        const float* vr = base + 2 * CC + hd;
        for (int s2 = 0; s2 < QQ; ++s2) a += attn[h][t][s2] * vr[(size_t)s2 * PW];
        pvB[t][hd] = a * inv;
    }
    __syncthreads();
    {
        const float4* wr4 = (const float4*)(ow + (size_t)tid * CC);
        const float4* p0 = (const float4*)&pvB[0][0];
        const float4* p1 = (const float4*)&pvB[1][0];
        float a0 = ob[tid], a1 = ob[tid];
#pragma unroll 8
        for (int k = 0; k < 64; ++k) {
            float4 w = wr4[k], x0 = p0[k], x1 = p1[k];
            a0 += x0.x * w.x + x0.y * w.y + x0.z * w.z + x0.w * w.w;
            a1 += x1.x * w.x + x1.y * w.y + x1.z * w.z + x1.w * w.w;
        }
        mf[0][tid] = a0; mf[1][tid] = a1;
    }
    __syncthreads();
    cd[(size_t)n * CC + tid] = mf[sdi[1]][tid];
    cs[(size_t)n * CC + tid] = mf[sdi[0]][tid];
}

// ---------------- MFMA attention (both branches): scores^T = K@Q^T, flash-streamed PV ----------------
// grid (2, HH, NB), 128 threads (2 waves). Wave handles 100 queries, in 2 groups of
// 4/3 query-tiles to keep the live register set under the 128-VGPR cap (no spills).
__global__ __launch_bounds__(128, 2)
void attn_mfma(const float* __restrict__ P_all, const float* __restrict__ Psum0,
               const int* __restrict__ far_rm, const int* __restrict__ far_md,
               float* __restrict__ pv, float* __restrict__ rowsum) {
    int n = blockIdx.z, h = blockIdx.y, half = blockIdx.x;
    int tid = threadIdx.x;
    int w = tid >> 6, lane = tid & 63;
    int fr = lane & 15, hi = lane >> 4;
    int d0 = hi * 8;
    __shared__ unsigned short Kh[112 * 40];    // [key][d] hi, stride 40
    __shared__ unsigned short Kl[112 * 40];    // lo
    __shared__ unsigned short Vt[32 * 136];    // [d][key], keys padded to 128 (+stride 136)
    __shared__ unsigned short Pb[2][64 * 40];  // per-wave P group [4 qtiles][32 keys], stride 40
    __shared__ float rsL[2][112];
    const float* base = P_all + (size_t)n * SM * PW;
    // ---- stage K (hi/lo) and V^T (single bf16) ----
    for (int idx = tid; idx < 112 * 8; idx += 128) {
        int key = idx >> 3, d4 = (idx & 7) * 4;
        float4 kv = {0.f, 0.f, 0.f, 0.f}, vv = {0.f, 0.f, 0.f, 0.f};
        if (key < SM) {
            kv = *(const float4*)&base[(size_t)key * PW + CC + h * DH + d4];
            vv = *(const float4*)&base[(size_t)key * PW + 2 * CC + h * DH + d4];
        }
        ushort4 h4, l4;
        h4.x = f2bf(kv.x); l4.x = f2bf(kv.x - bf2f(h4.x));
        h4.y = f2bf(kv.y); l4.y = f2bf(kv.y - bf2f(h4.y));
        h4.z = f2bf(kv.z); l4.z = f2bf(kv.z - bf2f(h4.z));
        h4.w = f2bf(kv.w); l4.w = f2bf(kv.w - bf2f(h4.w));
        *(ushort4*)&Kh[key * 40 + d4] = h4;
        *(ushort4*)&Kl[key * 40 + d4] = l4;
        Vt[(d4 + 0) * 136 + key] = f2bf(vv.x);
        Vt[(d4 + 1) * 136 + key] = f2bf(vv.y);
        Vt[(d4 + 2) * 136 + key] = f2bf(vv.z);
        Vt[(d4 + 3) * 136 + key] = f2bf(vv.w);
    }
    for (int idx = tid; idx < 32 * 16; idx += 128) {
        int d = idx >> 4, key = 112 + (idx & 15);
        Vt[d * 136 + key] = 0;
    }
    __syncthreads();
    const float* Psum0n = Psum0 + n * CC;
    int rowbase = half * 200 + w * 100;
    unsigned short* Pw = Pb[w];
    const float scl = 0.17677669529663687f;
#pragma unroll
    for (int qg = 0; qg < 2; ++qg) {
        const int nq = qg ? 3 : 4;
        const int qt0 = qg * 4;
        // ---- Q gather for this group ----
        s16x8 qh[4], ql[4];
        int mk[4], sb[4];
#pragma unroll
        for (int qi = 0; qi < 4; ++qi) {
            if (qi >= nq) { mk[qi] = -1; sb[qi] = 0; continue; }
            int lq = (qt0 + qi) * 16 + fr;
            int row = rowbase + (lq < QQ ? lq : QQ - 1);
            int b = row >= TT;
            int t = row - b * TT;
            int q = t >> 1;
            mk[qi] = q; sb[qi] = b ? SM : QQ;
            float qv[8];
            if (t & 1) {
                int f = (b ? far_md : far_rm)[n * QQ + q];
                const float4* pr = (const float4*)(base + (size_t)f * PW + h * DH + d0);
                float4 v0 = pr[0], v1 = pr[1];
                qv[0] = v0.x; qv[1] = v0.y; qv[2] = v0.z; qv[3] = v0.w;
                qv[4] = v1.x; qv[5] = v1.y; qv[6] = v1.z; qv[7] = v1.w;
            } else {
                int qm1 = (q + QQ - 1) % QQ;
                const float4* ps = (const float4*)(Psum0n + h * DH + d0);
                const float4* pm = (const float4*)(base + (size_t)qm1 * PW + h * DH + d0);
                const float4* pmn = (const float4*)(base + (size_t)QQ * PW + h * DH + d0);
                float invd = b ? 0.01f : (1.f / 99.f);
                float bb = b ? 1.f : 0.f;
                float4 a0 = ps[0], c0 = pm[0], m0 = pmn[0];
                float4 a1 = ps[1], c1 = pm[1], m1 = pmn[1];
                qv[0] = (a0.x - c0.x + bb * m0.x) * invd;
                qv[1] = (a0.y - c0.y + bb * m0.y) * invd;
                qv[2] = (a0.z - c0.z + bb * m0.z) * invd;
                qv[3] = (a0.w - c0.w + bb * m0.w) * invd;
                qv[4] = (a1.x - c1.x + bb * m1.x) * invd;
                qv[5] = (a1.y - c1.y + bb * m1.y) * invd;
                qv[6] = (a1.z - c1.z + bb * m1.z) * invd;
                qv[7] = (a1.w - c1.w + bb * m1.w) * invd;
            }
            s16x8 qhv, qlv;
#pragma unroll
            for (int j = 0; j < 8; ++j) {
                unsigned short hh = f2bf(qv[j]);
                qhv[j] = (short)hh;
                qlv[j] = (short)f2bf(qv[j] - bf2f(hh));
            }
            qh[qi] = qhv; ql[qi] = qlv;
        }
        // ---- key chunks of 32 ----
        f32x4 pvacc[4][2];
#pragma unroll
        for (int qi = 0; qi < 4; ++qi) {
            pvacc[qi][0] = (f32x4){0.f, 0.f, 0.f, 0.f};
            pvacc[qi][1] = (f32x4){0.f, 0.f, 0.f, 0.f};
        }
        float rs[4] = {0.f, 0.f, 0.f, 0.f};
#pragma unroll
        for (int kc = 0; kc < 4; ++kc) {
            int k0 = kc * 32;
            {   // first 16 keys of chunk
                s16x8 ah = *(const s16x8*)&Kh[(k0 + fr) * 40 + d0];
                s16x8 al = *(const s16x8*)&Kl[(k0 + fr) * 40 + d0];
#pragma unroll
                for (int qi = 0; qi < nq; ++qi) {
                    f32x4 s0 = (f32x4){0.f, 0.f, 0.f, 0.f};
                    s0 = __builtin_amdgcn_mfma_f32_16x16x32_bf16(ah, qh[qi], s0, 0, 0, 0);
                    s0 = __builtin_amdgcn_mfma_f32_16x16x32_bf16(ah, ql[qi], s0, 0, 0, 0);
                    s0 = __builtin_amdgcn_mfma_f32_16x16x32_bf16(al, qh[qi], s0, 0, 0, 0);
                    int kb0 = k0 + 4 * hi;
                    float a0 = (kb0 + 0 < sb[qi] && kb0 + 0 != mk[qi]) ? 1.f / (1.f + __expf(-s0[0] * scl)) : 0.f;
                    float a1 = (kb0 + 1 < sb[qi] && kb0 + 1 != mk[qi]) ? 1.f / (1.f + __expf(-s0[1] * scl)) : 0.f;
                    float a2 = (kb0 + 2 < sb[qi] && kb0 + 2 != mk[qi]) ? 1.f / (1.f + __expf(-s0[2] * scl)) : 0.f;
                    float a3 = (kb0 + 3 < sb[qi] && kb0 + 3 != mk[qi]) ? 1.f / (1.f + __expf(-s0[3] * scl)) : 0.f;
                    rs[qi] += a0 + a1 + a2 + a3;
                    ushort4 p4;
                    p4.x = f2bf(a0); p4.y = f2bf(a1); p4.z = f2bf(a2); p4.w = f2bf(a3);
                    *(ushort4*)&Pw[(qi * 16 + fr) * 40 + 4 * hi] = p4;
                }
            }
            if (kc < 3) {   // second 16 keys
                s16x8 ah = *(const s16x8*)&Kh[(k0 + 16 + fr) * 40 + d0];
                s16x8 al = *(const s16x8*)&Kl[(k0 + 16 + fr) * 40 + d0];
#pragma unroll
                for (int qi = 0; qi < nq; ++qi) {
                    f32x4 s1 = (f32x4){0.f, 0.f, 0.f, 0.f};
                    s1 = __builtin_amdgcn_mfma_f32_16x16x32_bf16(ah, qh[qi], s1, 0, 0, 0);
                    s1 = __builtin_amdgcn_mfma_f32_16x16x32_bf16(ah, ql[qi], s1, 0, 0, 0);
                    s1 = __builtin_amdgcn_mfma_f32_16x16x32_bf16(al, qh[qi], s1, 0, 0, 0);
                    int kb1 = k0 + 16 + 4 * hi;
                    float a0 = (kb1 + 0 < sb[qi] && kb1 + 0 != mk[qi]) ? 1.f / (1.f + __expf(-s1[0] * scl)) : 0.f;
                    float a1 = (kb1 + 1 < sb[qi] && kb1 + 1 != mk[qi]) ? 1.f / (1.f + __expf(-s1[1] * scl)) : 0.f;
                    float a2 = (kb1 + 2 < sb[qi] && kb1 + 2 != mk[qi]) ? 1.f / (1.f + __expf(-s1[2] * scl)) : 0.f;
                    float a3 = (kb1 + 3 < sb[qi] && kb1 + 3 != mk[qi]) ? 1.f / (1.f + __expf(-s1[3] * scl)) : 0.f;
                    rs[qi] += a0 + a1 + a2 + a3;
                    ushort4 p4;
                    p4.x = f2bf(a0); p4.y = f2bf(a1); p4.z = f2bf(a2); p4.w = f2bf(a3);
                    *(ushort4*)&Pw[(qi * 16 + fr) * 40 + 16 + 4 * hi] = p4;
                }
            } else {
                ushort4 z; z.x = 0; z.y = 0; z.z = 0; z.w = 0;
#pragma unroll
                for (int qi = 0; qi < nq; ++qi)
                    *(ushort4*)&Pw[(qi * 16 + fr) * 40 + 16 + 4 * hi] = z;
            }
            // PV for this chunk (wave-private LDS; compiler inserts lgkm waits)
            s16x8 vb0 = *(const s16x8*)&Vt[(0 * 16 + fr) * 136 + k0 + d0];
            s16x8 vb1 = *(const s16x8*)&Vt[(1 * 16 + fr) * 136 + k0 + d0];
#pragma unroll
            for (int qi = 0; qi < nq; ++qi) {
                s16x8 pa = *(const s16x8*)&Pw[(qi * 16 + fr) * 40 + d0];
                pvacc[qi][0] = __builtin_amdgcn_mfma_f32_16x16x32_bf16(pa, vb0, pvacc[qi][0], 0, 0, 0);
                pvacc[qi][1] = __builtin_amdgcn_mfma_f32_16x16x32_bf16(pa, vb1, pvacc[qi][1], 0, 0, 0);
            }
        }
        // ---- rowsum reduce across hi-groups, store ----
#pragma unroll
        for (int qi = 0; qi < nq; ++qi) {
            float r2 = rs[qi] + __shfl_xor(rs[qi], 16);
            r2 += __shfl_xor(r2, 32);
            int lq = (qt0 + qi) * 16 + fr;
            if (hi == 0) {
                rsL[w][lq] = r2;
                if (lq < QQ) rowsum[((size_t)n * HH + h) * TB + rowbase + lq] = r2;
            }
        }
        // ---- epilogue: normalize and write pv (fp32) ----
#pragma unroll
        for (int qi = 0; qi < nq; ++qi) {
            float iv[4];
#pragma unroll
            for (int r = 0; r < 4; ++r) {
                int lq = (qt0 + qi) * 16 + 4 * hi + r;
                iv[r] = 1.f / (rsL[w][lq < 112 ? lq : 111] + 1e-4f);
            }
#pragma unroll
            for (int dt = 0; dt < 2; ++dt) {
#pragma unroll
                for (int r = 0; r < 4; ++r) {
                    int lq = (qt0 + qi) * 16 + 4 * hi + r;
                    if (lq < QQ)
                        pv[((size_t)n * TB + rowbase + lq) * CC + h * DH + dt * 16 + fr] = pvacc[qi][dt][r] * iv[r];
                }
            }
        }
    }
}

// ---------------- shift (both branches): card argmin/argmax + distances ----------------
__global__ void shift_both(const float* __restrict__ rowsum, const float* __restrict__ mfx,
                           const float* __restrict__ cd, const float* __restrict__ cs,
                           float* __restrict__ out_srm, float* __restrict__ out_smd) {
    int b = blockIdx.x / (NB * QQ);
    int rem = blockIdx.x % (NB * QQ);
    int n = rem / QQ, q = rem % QQ;
    int tid = threadIdx.x;
    __shared__ float red[256];
    __shared__ int sdi[2];
    if (tid == 0) {
        float c0 = 0.f, c1v = 0.f;
        int rb = b * TT + 2 * q;
        for (int h = 0; h < HH; ++h) {
            c0  += rowsum[((size_t)n * HH + h) * TB + rb];
            c1v += rowsum[((size_t)n * HH + h) * TB + rb + 1];
        }
        sdi[0] = (c1v < c0) ? 1 : 0;
        sdi[1] = (c1v > c0) ? 1 : 0;
    }
    __syncthreads();
    int si = sdi[0], di = sdi[1];
    const float* mdp = mfx + ((size_t)n * TB + b * TT + 2 * q + di) * CC;
    const float* msp = mfx + ((size_t)n * TB + b * TT + 2 * q + si) * CC;
    float dd = mdp[tid] - cd[(size_t)n * CC + tid];
    float ds = msp[tid] - cs[(size_t)n * CC + tid];
    red[tid] = dd * dd;
    __syncthreads();
    for (int off = 128; off > 0; off >>= 1) { if (tid < off) red[tid] += red[tid + off]; __syncthreads(); }
    float distd = sqrtf(red[0] + 1e-12f);
    __syncthreads();
    red[tid] = ds * ds;
    __syncthreads();
    for (int off = 128; off > 0; off >>= 1) { if (tid < off) red[tid] += red[tid + off]; __syncthreads(); }
    if (tid == 0) (b ? out_smd : out_srm)[n * QQ + q] = distd + sqrtf(red[0] + 1e-12f);
}

extern "C" void kernel_launch(void* const* d_in, const int* in_sizes, int n_in,
                              void* d_out, int out_size, void* d_ws, size_t ws_size,
                              hipStream_t stream) {
    const float* hs_pair = (const float*)d_in[0];
    const float* ipw = (const float*)d_in[1];
    const float* ipb = (const float*)d_in[2];
    const float* ow  = (const float*)d_in[3];
    const float* ob  = (const float*)d_in[4];
    const float* hs = hs_pair + (size_t)5 * NB * QQ * CC;  // hs_pair[-1]

    float* ws = (float*)d_ws;
    size_t o = 0;
    // region A: dead after attn_mfma -> mfx aliases it
    float* kv_ext  = ws + o; o += (size_t)NB * SM * CC;       // 827,392
    float* P_all   = ws + o; o += (size_t)NB * SM * PW;       // 2,482,176
    float* Gfull   = ws + o; o += (size_t)NB * SM * SM;       // 326,432
    float* mfx     = kv_ext;                                  // 3,276,800 <= 3,636,000
    // region B: live throughout
    float* sum_all = ws + o; o += NB * CC;
    float* c1mean  = ws + o; o += NB * CC;
    float* centB   = ws + o; o += (size_t)NB * 2 * CC;
    float* Psum0   = ws + o; o += NB * CC;
    int*   far_rm  = (int*)(ws + o); o += NB * QQ;
    int*   far_md  = (int*)(ws + o); o += NB * QQ;
    float* cd      = ws + o; o += NB * CC;
    float* cs      = ws + o; o += NB * CC;
    float* pv      = ws + o; o += (size_t)NB * TB * CC;       // 3,276,800
    float* rowsum  = ws + o; o += (size_t)NB * HH * TB;
    if (o * sizeof(float) > ws_size) return;

    float* out = (float*)d_out;
    float* out_assign = out;
    float* out_sidx   = out + 6400;
    float* out_didx   = out + 6432;
    float* out_srm    = out + 6464;
    float* out_smd    = out + 9664;

    prep_kernel<<<NB, 256, 0, stream>>>(hs, sum_all, c1mean, centB, kv_ext);
    gemm_mfma<<<dim3((NB * SM + 127) / 128, PW / 128), 256, 0, stream>>>(
        kv_ext, ipw, ipb, P_all, NB * SM, PW);
    psum_kernel<<<NB, 256, 0, stream>>>(P_all, Psum0);
    gram_kernel<<<dim3(2, 2, NB), 256, 0, stream>>>(kv_ext, Gfull);
    far_kernel<<<NB, 256, 0, stream>>>(Gfull, far_rm, far_md);
    smhaB_kernel<<<NB, 256, 0, stream>>>(centB, P_all, ipw, ipb, ow, ob,
                                         out_assign, out_sidx, out_didx, cd, cs);
    attn_mfma<<<dim3(2, HH, NB), 128, 0, stream>>>(P_all, Psum0, far_rm, far_md, pv, rowsum);
    gemm_mfma<<<dim3(NB * TB / 128, CC / 128), 256, 0, stream>>>(
        pv, ow, ob, mfx, NB * TB, CC);
    shift_both<<<2 * NB * QQ, 256, 0, stream>>>(rowsum, mfx, cd, cs, out_srm, out_smd);
}

// Round 8
// 179.474 us; speedup vs baseline: 2.3317x; 1.0137x over previous
//
#include <hip/hip_runtime.h>
#include <math.h>

#define NB 32
#define QQ 100
#define CC 256
#define HH 8
#define DH 32
#define SM 101   // kv rows per batch (100 points + mean)
#define TT 200   // branch queries per batch
#define TB 400   // both branches
#define PW 768   // P_all row width (q|k|v projections)

typedef __attribute__((ext_vector_type(8))) short s16x8;
typedef __attribute__((ext_vector_type(4))) float f32x4;

__device__ inline unsigned short f2bf(float x) {
    unsigned u = __float_as_uint(x);
    return (unsigned short)((u + 0x7fffu + ((u >> 16) & 1u)) >> 16);
}
__device__ inline float bf2f(unsigned short h) {
    return __uint_as_float(((unsigned)h) << 16);
}

// ---------------- prep: sums, mean center, far point, centers, kv_ext ----------------
__global__ void prep_kernel(const float* __restrict__ hs, float* __restrict__ sum_all,
                            float* __restrict__ c1mean, float* __restrict__ centB,
                            float* __restrict__ kv_ext) {
    int n = blockIdx.x;
    int c = threadIdx.x; // 0..255
    const float* h = hs + (size_t)n * QQ * CC;
    float s = 0.f;
    for (int q = 0; q < QQ; ++q) s += h[q * CC + c];
    float c1 = s * (1.0f / QQ);
    sum_all[n * CC + c] = s;
    c1mean[n * CC + c] = c1;
    __shared__ float c1s[CC];
    __shared__ float dls[QQ];
    c1s[c] = c1;
    float* kve = kv_ext + (size_t)n * SM * CC;
    for (int idx = c; idx < QQ * CC; idx += CC) kve[idx] = h[idx];
    kve[QQ * CC + c] = c1;
    __syncthreads();
    int wave = c >> 6, lane = c & 63;
    for (int q = wave; q < QQ; q += 4) {
        float p = 0.f;
        for (int cc = lane; cc < CC; cc += 64) {
            float d = c1s[cc] - h[q * CC + cc];
            p += d * d;
        }
        for (int off = 32; off > 0; off >>= 1) p += __shfl_down(p, off);
        if (lane == 0) dls[q] = p;
    }
    __syncthreads();
    __shared__ int fars;
    if (c == 0) {
        int best = 0; float bv = dls[0];
        for (int q = 1; q < QQ; ++q) if (dls[q] > bv) { bv = dls[q]; best = q; }
        fars = best;
    }
    __syncthreads();
    int far = fars;
    centB[(size_t)n * 2 * CC + c] = c1s[c];
    centB[(size_t)n * 2 * CC + CC + c] = h[(size_t)far * CC + c];
}

// ---------------- split-bf16 MFMA GEMM, fp32 inputs (split on stage): out = A @ W^T + bias ----------------
#define LDK 40
__global__ __launch_bounds__(256, 2)
void gemm_mfma(const float* __restrict__ A_g, const float* __restrict__ W_g,
               const float* __restrict__ bias, float* __restrict__ out, int M, int Nout) {
    __shared__ unsigned short Ahs[128][LDK], Als[128][LDK], Bhs[128][LDK], Bls[128][LDK];
    int tid = threadIdx.x;
    int lane = tid & 63, wave = tid >> 6;
    int wm = (wave >> 1) * 64, wn = (wave & 1) * 64;
    int fr = lane & 15, kb = lane >> 4;
    int bm = blockIdx.x * 128, bn = blockIdx.y * 128;
    int srow = tid >> 1, scol = (tid & 1) * 16;
    int am = bm + srow; if (am >= M) am = M - 1;
    const float* pA = A_g + (size_t)am * CC + scol;
    const float* pW = W_g + (size_t)(bn + srow) * CC + scol;
    f32x4 acc[4][4];
#pragma unroll
    for (int mi = 0; mi < 4; ++mi)
#pragma unroll
        for (int ni = 0; ni < 4; ++ni)
            acc[mi][ni] = (f32x4){0.f, 0.f, 0.f, 0.f};
    for (int k0 = 0; k0 < CC; k0 += 32) {
        float4 av[4], wv[4];
#pragma unroll
        for (int j = 0; j < 4; ++j) {
            av[j] = *(const float4*)(pA + k0 + 4 * j);
            wv[j] = *(const float4*)(pW + k0 + 4 * j);
        }
        __syncthreads();
#pragma unroll
        for (int j = 0; j < 4; ++j) {
            ushort4 h4, l4, wh4, wl4;
            h4.x = f2bf(av[j].x); l4.x = f2bf(av[j].x - bf2f(h4.x));
            h4.y = f2bf(av[j].y); l4.y = f2bf(av[j].y - bf2f(h4.y));
            h4.z = f2bf(av[j].z); l4.z = f2bf(av[j].z - bf2f(h4.z));
            h4.w = f2bf(av[j].w); l4.w = f2bf(av[j].w - bf2f(h4.w));
            wh4.x = f2bf(wv[j].x); wl4.x = f2bf(wv[j].x - bf2f(wh4.x));
            wh4.y = f2bf(wv[j].y); wl4.y = f2bf(wv[j].y - bf2f(wh4.y));
            wh4.z = f2bf(wv[j].z); wl4.z = f2bf(wv[j].z - bf2f(wh4.z));
            wh4.w = f2bf(wv[j].w); wl4.w = f2bf(wv[j].w - bf2f(wh4.w));
            *(ushort4*)&Ahs[srow][scol + 4 * j] = h4;
            *(ushort4*)&Als[srow][scol + 4 * j] = l4;
            *(ushort4*)&Bhs[srow][scol + 4 * j] = wh4;
            *(ushort4*)&Bls[srow][scol + 4 * j] = wl4;
        }
        __syncthreads();
        s16x8 fah[4], fal[4], fbh[4], fbl[4];
#pragma unroll
        for (int mi = 0; mi < 4; ++mi) {
            fah[mi] = *(const s16x8*)&Ahs[wm + mi * 16 + fr][kb * 8];
            fal[mi] = *(const s16x8*)&Als[wm + mi * 16 + fr][kb * 8];
        }
#pragma unroll
        for (int ni = 0; ni < 4; ++ni) {
            fbh[ni] = *(const s16x8*)&Bhs[wn + ni * 16 + fr][kb * 8];
            fbl[ni] = *(const s16x8*)&Bls[wn + ni * 16 + fr][kb * 8];
        }
#pragma unroll
        for (int mi = 0; mi < 4; ++mi)
#pragma unroll
            for (int ni = 0; ni < 4; ++ni) {
                acc[mi][ni] = __builtin_amdgcn_mfma_f32_16x16x32_bf16(fah[mi], fbh[ni], acc[mi][ni], 0, 0, 0);
                acc[mi][ni] = __builtin_amdgcn_mfma_f32_16x16x32_bf16(fah[mi], fbl[ni], acc[mi][ni], 0, 0, 0);
                acc[mi][ni] = __builtin_amdgcn_mfma_f32_16x16x32_bf16(fal[mi], fbh[ni], acc[mi][ni], 0, 0, 0);
            }
    }
#pragma unroll
    for (int mi = 0; mi < 4; ++mi) {
        int mb = bm + wm + mi * 16 + kb * 4;
#pragma unroll
        for (int r = 0; r < 4; ++r) {
            int m = mb + r;
            if (m < M) {
#pragma unroll
                for (int ni = 0; ni < 4; ++ni) {
                    int col = bn + wn + ni * 16 + fr;
                    out[(size_t)m * Nout + col] = acc[mi][ni][r] + bias[col];
                }
            }
        }
    }
}

// ---------------- fused Gram + far selection, per batch (MFMA, G in LDS) ----------------
__global__ __launch_bounds__(256, 2)
void gramfar(const float* __restrict__ kv_ext, int* __restrict__ far_rm,
             int* __restrict__ far_md) {
    int n = blockIdx.x;
    int tid = threadIdx.x;
    int wave = tid >> 6, lane = tid & 63;
    int fr = lane & 15, kb = lane >> 4;
    __shared__ float G[SM][104];
    __shared__ unsigned short Ah[112][LDK], Al[112][LDK];
    __shared__ float sumdot[104], meandot[104], norm[104];
    const float* A = kv_ext + (size_t)n * SM * CC;
    f32x4 acc[13];
#pragma unroll
    for (int u = 0; u < 13; ++u) acc[u] = (f32x4){0.f, 0.f, 0.f, 0.f};
    for (int k0 = 0; k0 < CC; k0 += 32) {
        __syncthreads();
        for (int idx = tid; idx < 224; idx += 256) {
            int row = idx >> 1, kk = (idx & 1) * 16;
            float4 v[4];
#pragma unroll
            for (int j = 0; j < 4; ++j)
                v[j] = (row < SM) ? *(const float4*)&A[(size_t)row * CC + k0 + kk + 4 * j]
                                  : (float4){0.f, 0.f, 0.f, 0.f};
#pragma unroll
            for (int j = 0; j < 4; ++j) {
                ushort4 h4, l4;
                h4.x = f2bf(v[j].x); l4.x = f2bf(v[j].x - bf2f(h4.x));
                h4.y = f2bf(v[j].y); l4.y = f2bf(v[j].y - bf2f(h4.y));
                h4.z = f2bf(v[j].z); l4.z = f2bf(v[j].z - bf2f(h4.z));
                h4.w = f2bf(v[j].w); l4.w = f2bf(v[j].w - bf2f(h4.w));
                *(ushort4*)&Ah[row][kk + 4 * j] = h4;
                *(ushort4*)&Al[row][kk + 4 * j] = l4;
            }
        }
        __syncthreads();
#pragma unroll
        for (int u = 0; u < 13; ++u) {
            int tl = wave + u * 4;
            if (tl < 49) {
                int ti = tl / 7, tj = tl % 7;
                s16x8 ah = *(const s16x8*)&Ah[ti * 16 + fr][kb * 8];
                s16x8 al = *(const s16x8*)&Al[ti * 16 + fr][kb * 8];
                s16x8 bh = *(const s16x8*)&Ah[tj * 16 + fr][kb * 8];
                s16x8 bl = *(const s16x8*)&Al[tj * 16 + fr][kb * 8];
                acc[u] = __builtin_amdgcn_mfma_f32_16x16x32_bf16(ah, bh, acc[u], 0, 0, 0);
                acc[u] = __builtin_amdgcn_mfma_f32_16x16x32_bf16(ah, bl, acc[u], 0, 0, 0);
                acc[u] = __builtin_amdgcn_mfma_f32_16x16x32_bf16(al, bh, acc[u], 0, 0, 0);
            }
        }
    }
    __syncthreads();
#pragma unroll
    for (int u = 0; u < 13; ++u) {
        int tl = wave + u * 4;
        if (tl < 49) {
            int ti = tl / 7, tj = tl % 7;
#pragma unroll
            for (int r = 0; r < 4; ++r) {
                int m = ti * 16 + kb * 4 + r;
                int col = tj * 16 + fr;
                if (m < SM && col < SM) G[m][col] = acc[u][r];
            }
        }
    }
    __syncthreads();
    for (int s = tid; s < SM; s += 256) {
        float a = 0.f;
        for (int q = 0; q < QQ; ++q) a += G[s][q];
        sumdot[s] = a; meandot[s] = G[s][QQ]; norm[s] = G[s][s];
    }
    __syncthreads();
    if (tid < QQ) {
        int q = tid, qm1 = (q + QQ - 1) % QQ;
        const float* gq = G[qm1];
        int best = -1; float bv = -1e30f;
        for (int s = 0; s < QQ; ++s) {
            if (s == qm1) continue;
            float val = norm[s] - (sumdot[s] - gq[s]) * (2.f / 99.f);
            if (val > bv) { bv = val; best = s; }
        }
        far_rm[n * QQ + q] = best;
    } else if (tid >= 128 && tid < 128 + QQ) {
        int q = tid - 128, qm1 = (q + QQ - 1) % QQ;
        const float* gq = G[qm1];
        int best = -1; float bv = -1e30f;
        for (int s = 0; s < SM; ++s) {
            if (s == qm1) continue;
            float val = norm[s] - (sumdot[s] - gq[s] + meandot[s]) * (2.f / 100.f);
            if (val > bv) { bv = val; best = s; }
        }
        far_md[n * QQ + q] = best;
    }
}

// ---------------- Psum0[n][c] = sum_{q<100} P_all[n][q][c], c<256 ----------------
__global__ void psum_kernel(const float* __restrict__ P_all, float* __restrict__ Psum0) {
    int n = blockIdx.x; int c = threadIdx.x;
    const float* base = P_all + (size_t)n * SM * PW + c;
    float acc = 0.f;
    for (int q = 0; q < QQ; ++q) acc += base[(size_t)q * PW];
    Psum0[n * CC + c] = acc;
}

// ---------------- stage B: small SMHA (2 queries), fused, 512 threads ----------------
__global__ __launch_bounds__(512)
void smhaB_kernel(const float* __restrict__ centB, const float* __restrict__ P_all,
                  const float* __restrict__ ipw, const float* __restrict__ ipb,
                  const float* __restrict__ ow, const float* __restrict__ ob,
                  float* __restrict__ out_assign, float* __restrict__ out_sidx,
                  float* __restrict__ out_didx, float* __restrict__ cd,
                  float* __restrict__ cs) {
    int n = blockIdx.x;
    int tid = threadIdx.x;
    __shared__ float qh[2][CC];
    __shared__ float attn[HH][2][QQ];
    __shared__ float pvB[2][CC];
    __shared__ float rs[16];
    __shared__ float mf[2][CC];
    __shared__ int sdi[2];
    const float* cen = centB + (size_t)n * 2 * CC;
    {
        int t = tid >> 8, c = tid & 255;
        const float4* wr4 = (const float4*)(ipw + (size_t)c * CC);
        const float4* cv = (const float4*)(cen + t * CC);
        float a = ipb[c];
#pragma unroll 8
        for (int k = 0; k < 64; ++k) {
            float4 w = wr4[k], x = cv[k];
            a += x.x * w.x + x.y * w.y + x.z * w.z + x.w * w.w;
        }
        qh[t][c] = a;
    }
    __syncthreads();
    const float* base = P_all + (size_t)n * SM * PW;
    const float scl = 0.17677669529663687f;
    for (int idx = tid; idx < HH * 2 * QQ; idx += 512) {
        int h = idx / 200; int r = idx % 200; int t = r / QQ; int s2 = r % QQ;
        const float4* kr = (const float4*)(base + (size_t)s2 * PW + CC + h * DH);
        const float4* qr = (const float4*)&qh[t][h * DH];
        float sc = 0.f;
#pragma unroll
        for (int d = 0; d < 8; ++d) {
            float4 k4 = kr[d], q4 = qr[d];
            sc += q4.x * k4.x + q4.y * k4.y + q4.z * k4.z + q4.w * k4.w;
        }
        attn[h][t][s2] = 1.f / (1.f + __expf(-sc * scl));
    }
    __syncthreads();
    if (tid < 16) {
        int h = tid >> 1, t = tid & 1; float s = 0.f;
        for (int s2 = 0; s2 < QQ; ++s2) s += attn[h][t][s2];
        rs[tid] = s;
    }
    __syncthreads();
    for (int idx = tid; idx < 2 * QQ; idx += 512) {
        int t = idx / QQ, s2 = idx % QQ;
        float m = 0.f;
        for (int h = 0; h < HH; ++h) m += attn[h][t][s2];
        out_assign[(size_t)n * 2 * QQ + idx] = m * 0.125f;
    }
    if (tid == 0) {
        float c0 = 0.f, c1v = 0.f;
        for (int h = 0; h < HH; ++h) { c0 += rs[h * 2 + 0]; c1v += rs[h * 2 + 1]; }
        int si = (c1v < c0) ? 1 : 0;
        int di = (c1v > c0) ? 1 : 0;
        sdi[0] = si; sdi[1] = di;
        out_sidx[n] = (float)si;
        out_didx[n] = (float)di;
    }
    {
        int t = tid >> 8; int hd = tid & 255; int h = hd >> 5;
        float inv = 1.f / (rs[h * 2 + t] + 1e-4f);
        float a = 0.f;
        const float* vr = base + 2 * CC + hd;
        for (int s2 = 0; s2 < QQ; ++s2) a += attn[h][t][s2] * vr[(size_t)s2 * PW];
        pvB[t][hd] = a * inv;
    }
    __syncthreads();
    {
        int t = tid >> 8, c = tid & 255;
        const float4* wr4 = (const float4*)(ow + (size_t)c * CC);
        const float4* pz = (const float4*)&pvB[t][0];
        float a = ob[c];
#pragma unroll 8
        for (int k = 0; k < 64; ++k) {
            float4 w = wr4[k], x = pz[k];
            a += x.x * w.x + x.y * w.y + x.z * w.z + x.w * w.w;
        }
        mf[t][c] = a;
    }
    __syncthreads();
    if (tid < 256) {
        cd[(size_t)n * CC + tid] = mf[sdi[1]][tid];
        cs[(size_t)n * CC + tid] = mf[sdi[0]][tid];
    }
}

// ---------------- MFMA attention (both branches): scores^T = K@Q^T, flash-streamed PV ----------------
__global__ __launch_bounds__(128, 2)
void attn_mfma(const float* __restrict__ P_all, const float* __restrict__ Psum0,
               const int* __restrict__ far_rm, const int* __restrict__ far_md,
               float* __restrict__ pv, float* __restrict__ rowsum) {
    int n = blockIdx.z, h = blockIdx.y, half = blockIdx.x;
    int tid = threadIdx.x;
    int w = tid >> 6, lane = tid & 63;
    int fr = lane & 15, hi = lane >> 4;
    int d0 = hi * 8;
    __shared__ unsigned short Kh[112 * 40];
    __shared__ unsigned short Kl[112 * 40];
    __shared__ unsigned short Vt[32 * 136];
    __shared__ unsigned short Pb[2][64 * 40];
    __shared__ float rsL[2][112];
    const float* base = P_all + (size_t)n * SM * PW;
    for (int idx = tid; idx < 112 * 8; idx += 128) {
        int key = idx >> 3, d4 = (idx & 7) * 4;
        float4 kv = {0.f, 0.f, 0.f, 0.f}, vv = {0.f, 0.f, 0.f, 0.f};
        if (key < SM) {
            kv = *(const float4*)&base[(size_t)key * PW + CC + h * DH + d4];
            vv = *(const float4*)&base[(size_t)key * PW + 2 * CC + h * DH + d4];
        }
        ushort4 h4, l4;
        h4.x = f2bf(kv.x); l4.x = f2bf(kv.x - bf2f(h4.x));
        h4.y = f2bf(kv.y); l4.y = f2bf(kv.y - bf2f(h4.y));
        h4.z = f2bf(kv.z); l4.z = f2bf(kv.z - bf2f(h4.z));
        h4.w = f2bf(kv.w); l4.w = f2bf(kv.w - bf2f(h4.w));
        *(ushort4*)&Kh[key * 40 + d4] = h4;
        *(ushort4*)&Kl[key * 40 + d4] = l4;
        Vt[(d4 + 0) * 136 + key] = f2bf(vv.x);
        Vt[(d4 + 1) * 136 + key] = f2bf(vv.y);
        Vt[(d4 + 2) * 136 + key] = f2bf(vv.z);
        Vt[(d4 + 3) * 136 + key] = f2bf(vv.w);
    }
    for (int idx = tid; idx < 32 * 16; idx += 128) {
        int d = idx >> 4, key = 112 + (idx & 15);
        Vt[d * 136 + key] = 0;
    }
    __syncthreads();
    const float* Psum0n = Psum0 + n * CC;
    int rowbase = half * 200 + w * 100;
    unsigned short* Pw = Pb[w];
    const float scl = 0.17677669529663687f;
#pragma unroll
    for (int qg = 0; qg < 2; ++qg) {
        const int nq = qg ? 3 : 4;
        const int qt0 = qg * 4;
        s16x8 qh[4], ql[4];
        int mk[4], sb[4];
#pragma unroll
        for (int qi = 0; qi < 4; ++qi) {
            if (qi >= nq) { mk[qi] = -1; sb[qi] = 0; continue; }
            int lq = (qt0 + qi) * 16 + fr;
            int row = rowbase + (lq < QQ ? lq : QQ - 1);
            int b = row >= TT;
            int t = row - b * TT;
            int q = t >> 1;
            mk[qi] = q; sb[qi] = b ? SM : QQ;
            float qv[8];
            if (t & 1) {
                int f = (b ? far_md : far_rm)[n * QQ + q];
                const float4* pr = (const float4*)(base + (size_t)f * PW + h * DH + d0);
                float4 v0 = pr[0], v1 = pr[1];
                qv[0] = v0.x; qv[1] = v0.y; qv[2] = v0.z; qv[3] = v0.w;
                qv[4] = v1.x; qv[5] = v1.y; qv[6] = v1.z; qv[7] = v1.w;
            } else {
                int qm1 = (q + QQ - 1) % QQ;
                const float4* ps = (const float4*)(Psum0n + h * DH + d0);
                const float4* pm = (const float4*)(base + (size_t)qm1 * PW + h * DH + d0);
                const float4* pmn = (const float4*)(base + (size_t)QQ * PW + h * DH + d0);
                float invd = b ? 0.01f : (1.f / 99.f);
                float bb = b ? 1.f : 0.f;
                float4 a0 = ps[0], c0 = pm[0], m0 = pmn[0];
                float4 a1 = ps[1], c1 = pm[1], m1 = pmn[1];
                qv[0] = (a0.x - c0.x + bb * m0.x) * invd;
                qv[1] = (a0.y - c0.y + bb * m0.y) * invd;
                qv[2] = (a0.z - c0.z + bb * m0.z) * invd;
                qv[3] = (a0.w - c0.w + bb * m0.w) * invd;
                qv[4] = (a1.x - c1.x + bb * m1.x) * invd;
                qv[5] = (a1.y - c1.y + bb * m1.y) * invd;
                qv[6] = (a1.z - c1.z + bb * m1.z) * invd;
                qv[7] = (a1.w - c1.w + bb * m1.w) * invd;
            }
            s16x8 qhv, qlv;
#pragma unroll
            for (int j = 0; j < 8; ++j) {
                unsigned short hh = f2bf(qv[j]);
                qhv[j] = (short)hh;
                qlv[j] = (short)f2bf(qv[j] - bf2f(hh));
            }
            qh[qi] = qhv; ql[qi] = qlv;
        }
        f32x4 pvacc[4][2];
#pragma unroll
        for (int qi = 0; qi < 4; ++qi) {
            pvacc[qi][0] = (f32x4){0.f, 0.f, 0.f, 0.f};
            pvacc[qi][1] = (f32x4){0.f, 0.f, 0.f, 0.f};
        }
        float rs[4] = {0.f, 0.f, 0.f, 0.f};
#pragma unroll
        for (int kc = 0; kc < 4; ++kc) {
            int k0 = kc * 32;
            {
                s16x8 ah = *(const s16x8*)&Kh[(k0 + fr) * 40 + d0];
                s16x8 al = *(const s16x8*)&Kl[(k0 + fr) * 40 + d0];
#pragma unroll
                for (int qi = 0; qi < nq; ++qi) {
                    f32x4 s0 = (f32x4){0.f, 0.f, 0.f, 0.f};
                    s0 = __builtin_amdgcn_mfma_f32_16x16x32_bf16(ah, qh[qi], s0, 0, 0, 0);
                    s0 = __builtin_amdgcn_mfma_f32_16x16x32_bf16(ah, ql[qi], s0, 0, 0, 0);
                    s0 = __builtin_amdgcn_mfma_f32_16x16x32_bf16(al, qh[qi], s0, 0, 0, 0);
                    int kb0 = k0 + 4 * hi;
                    float a0 = (kb0 + 0 < sb[qi] && kb0 + 0 != mk[qi]) ? 1.f / (1.f + __expf(-s0[0] * scl)) : 0.f;
                    float a1 = (kb0 + 1 < sb[qi] && kb0 + 1 != mk[qi]) ? 1.f / (1.f + __expf(-s0[1] * scl)) : 0.f;
                    float a2 = (kb0 + 2 < sb[qi] && kb0 + 2 != mk[qi]) ? 1.f / (1.f + __expf(-s0[2] * scl)) : 0.f;
                    float a3 = (kb0 + 3 < sb[qi] && kb0 + 3 != mk[qi]) ? 1.f / (1.f + __expf(-s0[3] * scl)) : 0.f;
                    rs[qi] += a0 + a1 + a2 + a3;
                    ushort4 p4;
                    p4.x = f2bf(a0); p4.y = f2bf(a1); p4.z = f2bf(a2); p4.w = f2bf(a3);
                    *(ushort4*)&Pw[(qi * 16 + fr) * 40 + 4 * hi] = p4;
                }
            }
            if (kc < 3) {
                s16x8 ah = *(const s16x8*)&Kh[(k0 + 16 + fr) * 40 + d0];
                s16x8 al = *(const s16x8*)&Kl[(k0 + 16 + fr) * 40 + d0];
#pragma unroll
                for (int qi = 0; qi < nq; ++qi) {
                    f32x4 s1 = (f32x4){0.f, 0.f, 0.f, 0.f};
                    s1 = __builtin_amdgcn_mfma_f32_16x16x32_bf16(ah, qh[qi], s1, 0, 0, 0);
                    s1 = __builtin_amdgcn_mfma_f32_16x16x32_bf16(ah, ql[qi], s1, 0, 0, 0);
                    s1 = __builtin_amdgcn_mfma_f32_16x16x32_bf16(al, qh[qi], s1, 0, 0, 0);
                    int kb1 = k0 + 16 + 4 * hi;
                    float a0 = (kb1 + 0 < sb[qi] && kb1 + 0 != mk[qi]) ? 1.f / (1.f + __expf(-s1[0] * scl)) : 0.f;
                    float a1 = (kb1 + 1 < sb[qi] && kb1 + 1 != mk[qi]) ? 1.f / (1.f + __expf(-s1[1] * scl)) : 0.f;
                    float a2 = (kb1 + 2 < sb[qi] && kb1 + 2 != mk[qi]) ? 1.f / (1.f + __expf(-s1[2] * scl)) : 0.f;
                    float a3 = (kb1 + 3 < sb[qi] && kb1 + 3 != mk[qi]) ? 1.f / (1.f + __expf(-s1[3] * scl)) : 0.f;
                    rs[qi] += a0 + a1 + a2 + a3;
                    ushort4 p4;
                    p4.x = f2bf(a0); p4.y = f2bf(a1); p4.z = f2bf(a2); p4.w = f2bf(a3);
                    *(ushort4*)&Pw[(qi * 16 + fr) * 40 + 16 + 4 * hi] = p4;
                }
            } else {
                ushort4 z; z.x = 0; z.y = 0; z.z = 0; z.w = 0;
#pragma unroll
                for (int qi = 0; qi < nq; ++qi)
                    *(ushort4*)&Pw[(qi * 16 + fr) * 40 + 16 + 4 * hi] = z;
            }
            s16x8 vb0 = *(const s16x8*)&Vt[(0 * 16 + fr) * 136 + k0 + d0];
            s16x8 vb1 = *(const s16x8*)&Vt[(1 * 16 + fr) * 136 + k0 + d0];
#pragma unroll
            for (int qi = 0; qi < nq; ++qi) {
                s16x8 pa = *(const s16x8*)&Pw[(qi * 16 + fr) * 40 + d0];
                pvacc[qi][0] = __builtin_amdgcn_mfma_f32_16x16x32_bf16(pa, vb0, pvacc[qi][0], 0, 0, 0);
                pvacc[qi][1] = __builtin_amdgcn_mfma_f32_16x16x32_bf16(pa, vb1, pvacc[qi][1], 0, 0, 0);
            }
        }
#pragma unroll
        for (int qi = 0; qi < nq; ++qi) {
            float r2 = rs[qi] + __shfl_xor(rs[qi], 16);
            r2 += __shfl_xor(r2, 32);
            int lq = (qt0 + qi) * 16 + fr;
            if (hi == 0) {
                rsL[w][lq] = r2;
                if (lq < QQ) rowsum[((size_t)n * HH + h) * TB + rowbase + lq] = r2;
            }
        }
#pragma unroll
        for (int qi = 0; qi < nq; ++qi) {
            float iv[4];
#pragma unroll
            for (int r = 0; r < 4; ++r) {
                int lq = (qt0 + qi) * 16 + 4 * hi + r;
                iv[r] = 1.f / (rsL[w][lq < 112 ? lq : 111] + 1e-4f);
            }
#pragma unroll
            for (int dt = 0; dt < 2; ++dt) {
#pragma unroll
                for (int r = 0; r < 4; ++r) {
                    int lq = (qt0 + qi) * 16 + 4 * hi + r;
                    if (lq < QQ)
                        pv[((size_t)n * TB + rowbase + lq) * CC + h * DH + dt * 16 + fr] = pvacc[qi][dt][r] * iv[r];
                }
            }
        }
    }
}

// ---------------- fused out-projection + shift: 128 rows x 256 cols per block, 8 waves ----------------
__global__ __launch_bounds__(512)
void outshift(const float* __restrict__ pv, const float* __restrict__ ow,
              const float* __restrict__ ob, const float* __restrict__ cd,
              const float* __restrict__ cs, const float* __restrict__ rowsum,
              float* __restrict__ out_srm, float* __restrict__ out_smd) {
    __shared__ unsigned short Ahs[128][LDK], Als[128][LDK];
    __shared__ unsigned short Bhs[256][LDK], Bls[256][LDK];
    __shared__ float redcd[128][4], redcs[128][4];
    int tid = threadIdx.x;
    int lane = tid & 63, wave = tid >> 6;
    int wm = (wave >> 2) * 64, wn = (wave & 3) * 64;
    int fr = lane & 15, kb = lane >> 4;
    int bm = blockIdx.x * 128;
    int arow = tid >> 2, ak = (tid & 3) * 8;
    int brow = tid >> 1, bk = (tid & 1) * 16;
    const float* pA = pv + (size_t)(bm + arow) * CC + ak;
    const float* pB = ow + (size_t)brow * CC + bk;
    f32x4 acc[4][4];
#pragma unroll
    for (int mi = 0; mi < 4; ++mi)
#pragma unroll
        for (int ni = 0; ni < 4; ++ni)
            acc[mi][ni] = (f32x4){0.f, 0.f, 0.f, 0.f};
    for (int k0 = 0; k0 < CC; k0 += 32) {
        float4 av[2], wv[4];
#pragma unroll
        for (int j = 0; j < 2; ++j) av[j] = *(const float4*)(pA + k0 + 4 * j);
#pragma unroll
        for (int j = 0; j < 4; ++j) wv[j] = *(const float4*)(pB + k0 + 4 * j);
        __syncthreads();
#pragma unroll
        for (int j = 0; j < 2; ++j) {
            ushort4 h4, l4;
            h4.x = f2bf(av[j].x); l4.x = f2bf(av[j].x - bf2f(h4.x));
            h4.y = f2bf(av[j].y); l4.y = f2bf(av[j].y - bf2f(h4.y));
            h4.z = f2bf(av[j].z); l4.z = f2bf(av[j].z - bf2f(h4.z));
            h4.w = f2bf(av[j].w); l4.w = f2bf(av[j].w - bf2f(h4.w));
            *(ushort4*)&Ahs[arow][ak + 4 * j] = h4;
            *(ushort4*)&Als[arow][ak + 4 * j] = l4;
        }
#pragma unroll
        for (int j = 0; j < 4; ++j) {
            ushort4 h4, l4;
            h4.x = f2bf(wv[j].x); l4.x = f2bf(wv[j].x - bf2f(h4.x));
            h4.y = f2bf(wv[j].y); l4.y = f2bf(wv[j].y - bf2f(h4.y));
            h4.z = f2bf(wv[j].z); l4.z = f2bf(wv[j].z - bf2f(h4.z));
            h4.w = f2bf(wv[j].w); l4.w = f2bf(wv[j].w - bf2f(h4.w));
            *(ushort4*)&Bhs[brow][bk + 4 * j] = h4;
            *(ushort4*)&Bls[brow][bk + 4 * j] = l4;
        }
        __syncthreads();
        s16x8 fah[4], fal[4], fbh[4], fbl[4];
#pragma unroll
        for (int mi = 0; mi < 4; ++mi) {
            fah[mi] = *(const s16x8*)&Ahs[wm + mi * 16 + fr][kb * 8];
            fal[mi] = *(const s16x8*)&Als[wm + mi * 16 + fr][kb * 8];
        }
#pragma unroll
        for (int ni = 0; ni < 4; ++ni) {
            fbh[ni] = *(const s16x8*)&Bhs[wn + ni * 16 + fr][kb * 8];
            fbl[ni] = *(const s16x8*)&Bls[wn + ni * 16 + fr][kb * 8];
        }
#pragma unroll
        for (int mi = 0; mi < 4; ++mi)
#pragma unroll
            for (int ni = 0; ni < 4; ++ni) {
                acc[mi][ni] = __builtin_amdgcn_mfma_f32_16x16x32_bf16(fah[mi], fbh[ni], acc[mi][ni], 0, 0, 0);
                acc[mi][ni] = __builtin_amdgcn_mfma_f32_16x16x32_bf16(fah[mi], fbl[ni], acc[mi][ni], 0, 0, 0);
                acc[mi][ni] = __builtin_amdgcn_mfma_f32_16x16x32_bf16(fal[mi], fbh[ni], acc[mi][ni], 0, 0, 0);
            }
    }
    // epilogue: per-row partial squared distances vs cd and cs over this wave's 64 cols
#pragma unroll
    for (int mi = 0; mi < 4; ++mi) {
#pragma unroll
        for (int r = 0; r < 4; ++r) {
            int lm = wm + mi * 16 + kb * 4 + r;
            int g = bm + lm;
            int n = g / TB;
            float pcd = 0.f, pcs = 0.f;
#pragma unroll
            for (int ni = 0; ni < 4; ++ni) {
                int col = wn + ni * 16 + fr;
                float val = acc[mi][ni][r] + ob[col];
                float d1 = val - cd[(size_t)n * CC + col];
                float d2 = val - cs[(size_t)n * CC + col];
                pcd += d1 * d1;
                pcs += d2 * d2;
            }
#pragma unroll
            for (int m2 = 1; m2 < 16; m2 <<= 1) {
                pcd += __shfl_xor(pcd, m2);
                pcs += __shfl_xor(pcs, m2);
            }
            if (fr == 0) {
                redcd[lm][wave & 3] = pcd;
                redcs[lm][wave & 3] = pcs;
            }
        }
    }
    __syncthreads();
    if (tid < 64) {
        int g = bm + 2 * tid;
        int n = g / TB;
        int rem = g % TB;
        int b = rem / TT;
        int t = rem % TT;
        int q = t >> 1;
        float c0 = 0.f, c1v = 0.f;
        for (int h = 0; h < HH; ++h) {
            c0  += rowsum[((size_t)n * HH + h) * TB + rem];
            c1v += rowsum[((size_t)n * HH + h) * TB + rem + 1];
        }
        int si = (c1v < c0) ? 1 : 0;
        int di = (c1v > c0) ? 1 : 0;
        int ld = 2 * tid + di, ls = 2 * tid + si;
        float dd = redcd[ld][0] + redcd[ld][1] + redcd[ld][2] + redcd[ld][3];
        float ds = redcs[ls][0] + redcs[ls][1] + redcs[ls][2] + redcs[ls][3];
        (b ? out_smd : out_srm)[n * QQ + q] = sqrtf(dd + 1e-12f) + sqrtf(ds + 1e-12f);
    }
}

extern "C" void kernel_launch(void* const* d_in, const int* in_sizes, int n_in,
                              void* d_out, int out_size, void* d_ws, size_t ws_size,
                              hipStream_t stream) {
    const float* hs_pair = (const float*)d_in[0];
    const float* ipw = (const float*)d_in[1];
    const float* ipb = (const float*)d_in[2];
    const float* ow  = (const float*)d_in[3];
    const float* ob  = (const float*)d_in[4];
    const float* hs = hs_pair + (size_t)5 * NB * QQ * CC;  // hs_pair[-1]

    float* ws = (float*)d_ws;
    size_t o = 0;
    float* kv_ext  = ws + o; o += (size_t)NB * SM * CC;
    float* P_all   = ws + o; o += (size_t)NB * SM * PW;
    float* sum_all = ws + o; o += NB * CC;
    float* c1mean  = ws + o; o += NB * CC;
    float* centB   = ws + o; o += (size_t)NB * 2 * CC;
    float* Psum0   = ws + o; o += NB * CC;
    int*   far_rm  = (int*)(ws + o); o += NB * QQ;
    int*   far_md  = (int*)(ws + o); o += NB * QQ;
    float* cd      = ws + o; o += NB * CC;
    float* cs      = ws + o; o += NB * CC;
    float* pv      = ws + o; o += (size_t)NB * TB * CC;
    float* rowsum  = ws + o; o += (size_t)NB * HH * TB;
    if (o * sizeof(float) > ws_size) return;

    float* out = (float*)d_out;
    float* out_assign = out;
    float* out_sidx   = out + 6400;
    float* out_didx   = out + 6432;
    float* out_srm    = out + 6464;
    float* out_smd    = out + 9664;

    prep_kernel<<<NB, 256, 0, stream>>>(hs, sum_all, c1mean, centB, kv_ext);
    gemm_mfma<<<dim3((NB * SM + 127) / 128, PW / 128), 256, 0, stream>>>(
        kv_ext, ipw, ipb, P_all, NB * SM, PW);
    psum_kernel<<<NB, 256, 0, stream>>>(P_all, Psum0);
    gramfar<<<NB, 256, 0, stream>>>(kv_ext, far_rm, far_md);
    smhaB_kernel<<<NB, 512, 0, stream>>>(centB, P_all, ipw, ipb, ow, ob,
                                         out_assign, out_sidx, out_didx, cd, cs);
    attn_mfma<<<dim3(2, HH, NB), 128, 0, stream>>>(P_all, Psum0, far_rm, far_md, pv, rowsum);
    outshift<<<NB * TB / 128, 512, 0, stream>>>(pv, ow, ob, cd, cs, rowsum, out_srm, out_smd);
}

// Round 9
// 160.886 us; speedup vs baseline: 2.6011x; 1.1155x over previous
//
#include <hip/hip_runtime.h>
#include <math.h>

#define NB 32
#define QQ 100
#define CC 256
#define HH 8
#define DH 32
#define SM 101   // kv rows per batch (100 points + mean)
#define TT 200   // branch queries per batch
#define TB 400   // both branches
#define PW 768   // P_all row width (q|k|v projections)

typedef __attribute__((ext_vector_type(8))) short s16x8;
typedef __attribute__((ext_vector_type(4))) float f32x4;

__device__ inline unsigned short f2bf(float x) {
    unsigned u = __float_as_uint(x);
    return (unsigned short)((u + 0x7fffu + ((u >> 16) & 1u)) >> 16);
}
__device__ inline float bf2f(unsigned short h) {
    return __uint_as_float(((unsigned)h) << 16);
}

// ---------------- prep: kv_ext (hs rows + mean), stage-A far point ----------------
__global__ void prep_kernel(const float* __restrict__ hs, int* __restrict__ far0,
                            float* __restrict__ kv_ext) {
    int n = blockIdx.x;
    int c = threadIdx.x; // 0..255
    const float* h = hs + (size_t)n * QQ * CC;
    float s = 0.f;
    for (int q = 0; q < QQ; ++q) s += h[q * CC + c];
    float c1 = s * (1.0f / QQ);
    __shared__ float c1s[CC];
    __shared__ float dls[QQ];
    c1s[c] = c1;
    float* kve = kv_ext + (size_t)n * SM * CC;
    for (int idx = c; idx < QQ * CC; idx += CC) kve[idx] = h[idx];
    kve[QQ * CC + c] = c1;
    __syncthreads();
    int wave = c >> 6, lane = c & 63;
    for (int q = wave; q < QQ; q += 4) {
        float p = 0.f;
        for (int cc = lane; cc < CC; cc += 64) {
            float d = c1s[cc] - h[q * CC + cc];
            p += d * d;
        }
        for (int off = 32; off > 0; off >>= 1) p += __shfl_down(p, off);
        if (lane == 0) dls[q] = p;
    }
    __syncthreads();
    if (c == 0) {
        int best = 0; float bv = dls[0];
        for (int q = 1; q < QQ; ++q) if (dls[q] > bv) { bv = dls[q]; best = q; }
        far0[n] = best;
    }
}

// ---------------- split-bf16 MFMA GEMM, fp32 inputs (split on stage): out = A @ W^T + bias ----------------
#define LDK 40
__global__ __launch_bounds__(256, 2)
void gemm_mfma(const float* __restrict__ A_g, const float* __restrict__ W_g,
               const float* __restrict__ bias, float* __restrict__ out, int M, int Nout) {
    __shared__ unsigned short Ahs[128][LDK], Als[128][LDK], Bhs[128][LDK], Bls[128][LDK];
    int tid = threadIdx.x;
    int lane = tid & 63, wave = tid >> 6;
    int wm = (wave >> 1) * 64, wn = (wave & 1) * 64;
    int fr = lane & 15, kb = lane >> 4;
    int bm = blockIdx.x * 128, bn = blockIdx.y * 128;
    int srow = tid >> 1, scol = (tid & 1) * 16;
    int am = bm + srow; if (am >= M) am = M - 1;
    const float* pA = A_g + (size_t)am * CC + scol;
    const float* pW = W_g + (size_t)(bn + srow) * CC + scol;
    f32x4 acc[4][4];
#pragma unroll
    for (int mi = 0; mi < 4; ++mi)
#pragma unroll
        for (int ni = 0; ni < 4; ++ni)
            acc[mi][ni] = (f32x4){0.f, 0.f, 0.f, 0.f};
    for (int k0 = 0; k0 < CC; k0 += 32) {
        float4 av[4], wv[4];
#pragma unroll
        for (int j = 0; j < 4; ++j) {
            av[j] = *(const float4*)(pA + k0 + 4 * j);
            wv[j] = *(const float4*)(pW + k0 + 4 * j);
        }
        __syncthreads();
#pragma unroll
        for (int j = 0; j < 4; ++j) {
            ushort4 h4, l4, wh4, wl4;
            h4.x = f2bf(av[j].x); l4.x = f2bf(av[j].x - bf2f(h4.x));
            h4.y = f2bf(av[j].y); l4.y = f2bf(av[j].y - bf2f(h4.y));
            h4.z = f2bf(av[j].z); l4.z = f2bf(av[j].z - bf2f(h4.z));
            h4.w = f2bf(av[j].w); l4.w = f2bf(av[j].w - bf2f(h4.w));
            wh4.x = f2bf(wv[j].x); wl4.x = f2bf(wv[j].x - bf2f(wh4.x));
            wh4.y = f2bf(wv[j].y); wl4.y = f2bf(wv[j].y - bf2f(wh4.y));
            wh4.z = f2bf(wv[j].z); wl4.z = f2bf(wv[j].z - bf2f(wh4.z));
            wh4.w = f2bf(wv[j].w); wl4.w = f2bf(wv[j].w - bf2f(wh4.w));
            *(ushort4*)&Ahs[srow][scol + 4 * j] = h4;
            *(ushort4*)&Als[srow][scol + 4 * j] = l4;
            *(ushort4*)&Bhs[srow][scol + 4 * j] = wh4;
            *(ushort4*)&Bls[srow][scol + 4 * j] = wl4;
        }
        __syncthreads();
        s16x8 fah[4], fal[4], fbh[4], fbl[4];
#pragma unroll
        for (int mi = 0; mi < 4; ++mi) {
            fah[mi] = *(const s16x8*)&Ahs[wm + mi * 16 + fr][kb * 8];
            fal[mi] = *(const s16x8*)&Als[wm + mi * 16 + fr][kb * 8];
        }
#pragma unroll
        for (int ni = 0; ni < 4; ++ni) {
            fbh[ni] = *(const s16x8*)&Bhs[wn + ni * 16 + fr][kb * 8];
            fbl[ni] = *(const s16x8*)&Bls[wn + ni * 16 + fr][kb * 8];
        }
#pragma unroll
        for (int mi = 0; mi < 4; ++mi)
#pragma unroll
            for (int ni = 0; ni < 4; ++ni) {
                acc[mi][ni] = __builtin_amdgcn_mfma_f32_16x16x32_bf16(fah[mi], fbh[ni], acc[mi][ni], 0, 0, 0);
                acc[mi][ni] = __builtin_amdgcn_mfma_f32_16x16x32_bf16(fah[mi], fbl[ni], acc[mi][ni], 0, 0, 0);
                acc[mi][ni] = __builtin_amdgcn_mfma_f32_16x16x32_bf16(fal[mi], fbh[ni], acc[mi][ni], 0, 0, 0);
            }
    }
#pragma unroll
    for (int mi = 0; mi < 4; ++mi) {
        int mb = bm + wm + mi * 16 + kb * 4;
#pragma unroll
        for (int r = 0; r < 4; ++r) {
            int m = mb + r;
            if (m < M) {
#pragma unroll
                for (int ni = 0; ni < 4; ++ni) {
                    int col = bn + wn + ni * 16 + fr;
                    out[(size_t)m * Nout + col] = acc[mi][ni][r] + bias[col];
                }
            }
        }
    }
}

// ---------------- fused Gram + far selection, per batch (MFMA, G in LDS) ----------------
__global__ __launch_bounds__(256, 2)
void gramfar(const float* __restrict__ kv_ext, int* __restrict__ far_rm,
             int* __restrict__ far_md) {
    int n = blockIdx.x;
    int tid = threadIdx.x;
    int wave = tid >> 6, lane = tid & 63;
    int fr = lane & 15, kb = lane >> 4;
    __shared__ float G[SM][104];
    __shared__ unsigned short Ah[112][LDK], Al[112][LDK];
    __shared__ float sumdot[104], meandot[104], norm[104];
    const float* A = kv_ext + (size_t)n * SM * CC;
    f32x4 acc[13];
#pragma unroll
    for (int u = 0; u < 13; ++u) acc[u] = (f32x4){0.f, 0.f, 0.f, 0.f};
    for (int k0 = 0; k0 < CC; k0 += 32) {
        __syncthreads();
        for (int idx = tid; idx < 224; idx += 256) {
            int row = idx >> 1, kk = (idx & 1) * 16;
            float4 v[4];
#pragma unroll
            for (int j = 0; j < 4; ++j)
                v[j] = (row < SM) ? *(const float4*)&A[(size_t)row * CC + k0 + kk + 4 * j]
                                  : (float4){0.f, 0.f, 0.f, 0.f};
#pragma unroll
            for (int j = 0; j < 4; ++j) {
                ushort4 h4, l4;
                h4.x = f2bf(v[j].x); l4.x = f2bf(v[j].x - bf2f(h4.x));
                h4.y = f2bf(v[j].y); l4.y = f2bf(v[j].y - bf2f(h4.y));
                h4.z = f2bf(v[j].z); l4.z = f2bf(v[j].z - bf2f(h4.z));
                h4.w = f2bf(v[j].w); l4.w = f2bf(v[j].w - bf2f(h4.w));
                *(ushort4*)&Ah[row][kk + 4 * j] = h4;
                *(ushort4*)&Al[row][kk + 4 * j] = l4;
            }
        }
        __syncthreads();
#pragma unroll
        for (int u = 0; u < 13; ++u) {
            int tl = wave + u * 4;
            if (tl < 49) {
                int ti = tl / 7, tj = tl % 7;
                s16x8 ah = *(const s16x8*)&Ah[ti * 16 + fr][kb * 8];
                s16x8 al = *(const s16x8*)&Al[ti * 16 + fr][kb * 8];
                s16x8 bh = *(const s16x8*)&Ah[tj * 16 + fr][kb * 8];
                s16x8 bl = *(const s16x8*)&Al[tj * 16 + fr][kb * 8];
                acc[u] = __builtin_amdgcn_mfma_f32_16x16x32_bf16(ah, bh, acc[u], 0, 0, 0);
                acc[u] = __builtin_amdgcn_mfma_f32_16x16x32_bf16(ah, bl, acc[u], 0, 0, 0);
                acc[u] = __builtin_amdgcn_mfma_f32_16x16x32_bf16(al, bh, acc[u], 0, 0, 0);
            }
        }
    }
    __syncthreads();
#pragma unroll
    for (int u = 0; u < 13; ++u) {
        int tl = wave + u * 4;
        if (tl < 49) {
            int ti = tl / 7, tj = tl % 7;
#pragma unroll
            for (int r = 0; r < 4; ++r) {
                int m = ti * 16 + kb * 4 + r;
                int col = tj * 16 + fr;
                if (m < SM && col < SM) G[m][col] = acc[u][r];
            }
        }
    }
    __syncthreads();
    for (int s = tid; s < SM; s += 256) {
        float a = 0.f;
        for (int q = 0; q < QQ; ++q) a += G[s][q];
        sumdot[s] = a; meandot[s] = G[s][QQ]; norm[s] = G[s][s];
    }
    __syncthreads();
    if (tid < QQ) {
        int q = tid, qm1 = (q + QQ - 1) % QQ;
        const float* gq = G[qm1];
        int best = -1; float bv = -1e30f;
        for (int s = 0; s < QQ; ++s) {
            if (s == qm1) continue;
            float val = norm[s] - (sumdot[s] - gq[s]) * (2.f / 99.f);
            if (val > bv) { bv = val; best = s; }
        }
        far_rm[n * QQ + q] = best;
    } else if (tid >= 128 && tid < 128 + QQ) {
        int q = tid - 128, qm1 = (q + QQ - 1) % QQ;
        const float* gq = G[qm1];
        int best = -1; float bv = -1e30f;
        for (int s = 0; s < SM; ++s) {
            if (s == qm1) continue;
            float val = norm[s] - (sumdot[s] - gq[s] + meandot[s]) * (2.f / 100.f);
            if (val > bv) { bv = val; best = s; }
        }
        far_md[n * QQ + q] = best;
    }
}

// ---------------- Psum0[n][c] = sum_{q<100} P_all[n][q][c], c<256 ----------------
__global__ void psum_kernel(const float* __restrict__ P_all, float* __restrict__ Psum0) {
    int n = blockIdx.x; int c = threadIdx.x;
    const float* base = P_all + (size_t)n * SM * PW + c;
    float acc = 0.f;
    for (int q = 0; q < QQ; ++q) acc += base[(size_t)q * PW];
    Psum0[n * CC + c] = acc;
}

// ---------------- stage B scores + PV, per (n,h): q rows come from P_all ----------------
__global__ __launch_bounds__(64)
void smhaB_scores(const float* __restrict__ P_all, const int* __restrict__ far0,
                  float* __restrict__ attnB, float* __restrict__ rsB,
                  float* __restrict__ pvB) {
    int h = blockIdx.x, n = blockIdx.y;
    int lane = threadIdx.x;
    const float* base = P_all + (size_t)n * SM * PW;
    __shared__ float q[2][DH];
    __shared__ float at[2][104];
    __shared__ float rsv[2];
    if (lane < 2 * DH) {
        int t = lane >> 5, d = lane & 31;
        int row = t ? far0[n] : QQ;
        q[t][d] = base[(size_t)row * PW + h * DH + d];
    }
    __syncthreads();
    const float scl = 0.17677669529663687f;
    float p0 = 0.f, p1 = 0.f;
    for (int s = lane; s < 104; s += 64) {
        if (s < QQ) {
            const float4* kr = (const float4*)(base + (size_t)s * PW + CC + h * DH);
            float d0 = 0.f, d1 = 0.f;
#pragma unroll
            for (int j = 0; j < 8; ++j) {
                float4 k4 = kr[j];
                d0 += q[0][4 * j] * k4.x + q[0][4 * j + 1] * k4.y + q[0][4 * j + 2] * k4.z + q[0][4 * j + 3] * k4.w;
                d1 += q[1][4 * j] * k4.x + q[1][4 * j + 1] * k4.y + q[1][4 * j + 2] * k4.z + q[1][4 * j + 3] * k4.w;
            }
            float a0 = 1.f / (1.f + __expf(-d0 * scl));
            float a1 = 1.f / (1.f + __expf(-d1 * scl));
            at[0][s] = a0; at[1][s] = a1;
            p0 += a0; p1 += a1;
            attnB[(((size_t)n * HH + h) * 2 + 0) * 104 + s] = a0;
            attnB[(((size_t)n * HH + h) * 2 + 1) * 104 + s] = a1;
        } else {
            at[0][s] = 0.f; at[1][s] = 0.f;
        }
    }
#pragma unroll
    for (int off = 32; off > 0; off >>= 1) {
        p0 += __shfl_down(p0, off);
        p1 += __shfl_down(p1, off);
    }
    if (lane == 0) {
        rsv[0] = p0; rsv[1] = p1;
        rsB[((size_t)n * HH + h) * 2 + 0] = p0;
        rsB[((size_t)n * HH + h) * 2 + 1] = p1;
    }
    __syncthreads();
    int t = lane >> 5, d = lane & 31;
    float inv = 1.f / (rsv[t] + 1e-4f);
    float acc = 0.f;
    const float* vb = base + 2 * CC + h * DH + d;
    for (int s = 0; s < QQ; ++s) acc += at[t][s] * vb[(size_t)s * PW];
    pvB[((size_t)n * 2 + t) * CC + h * DH + d] = acc * inv;
}

// ---------------- stage B final: assign, si/di, cd/cs ----------------
__global__ void smhaB_final(const float* __restrict__ attnB, const float* __restrict__ rsB,
                            const float* __restrict__ mfB, float* __restrict__ out_assign,
                            float* __restrict__ out_sidx, float* __restrict__ out_didx,
                            float* __restrict__ cd, float* __restrict__ cs) {
    int n = blockIdx.x; int tid = threadIdx.x;
    __shared__ int sdi[2];
    if (tid == 0) {
        float c0 = 0.f, c1v = 0.f;
        for (int h = 0; h < HH; ++h) {
            c0  += rsB[((size_t)n * HH + h) * 2 + 0];
            c1v += rsB[((size_t)n * HH + h) * 2 + 1];
        }
        int si = (c1v < c0) ? 1 : 0;
        int di = (c1v > c0) ? 1 : 0;
        sdi[0] = si; sdi[1] = di;
        out_sidx[n] = (float)si;
        out_didx[n] = (float)di;
    }
    for (int idx = tid; idx < 2 * QQ; idx += 256) {
        int t = idx / QQ, s = idx % QQ;
        float m = 0.f;
        for (int h = 0; h < HH; ++h) m += attnB[(((size_t)n * HH + h) * 2 + t) * 104 + s];
        out_assign[(size_t)n * 2 * QQ + idx] = m * 0.125f;
    }
    __syncthreads();
    cd[(size_t)n * CC + tid] = mfB[((size_t)n * 2 + sdi[1]) * CC + tid];
    cs[(size_t)n * CC + tid] = mfB[((size_t)n * 2 + sdi[0]) * CC + tid];
}

// ---------------- MFMA attention (both branches): scores^T = K@Q^T, flash-streamed PV ----------------
__global__ __launch_bounds__(128, 2)
void attn_mfma(const float* __restrict__ P_all, const float* __restrict__ Psum0,
               const int* __restrict__ far_rm, const int* __restrict__ far_md,
               float* __restrict__ pv, float* __restrict__ rowsum) {
    int n = blockIdx.z, h = blockIdx.y, half = blockIdx.x;
    int tid = threadIdx.x;
    int w = tid >> 6, lane = tid & 63;
    int fr = lane & 15, hi = lane >> 4;
    int d0 = hi * 8;
    __shared__ unsigned short Kh[112 * 40];
    __shared__ unsigned short Kl[112 * 40];
    __shared__ unsigned short Vt[32 * 136];
    __shared__ unsigned short Pb[2][64 * 40];
    __shared__ float rsL[2][112];
    const float* base = P_all + (size_t)n * SM * PW;
    for (int idx = tid; idx < 112 * 8; idx += 128) {
        int key = idx >> 3, d4 = (idx & 7) * 4;
        float4 kv = {0.f, 0.f, 0.f, 0.f}, vv = {0.f, 0.f, 0.f, 0.f};
        if (key < SM) {
            kv = *(const float4*)&base[(size_t)key * PW + CC + h * DH + d4];
            vv = *(const float4*)&base[(size_t)key * PW + 2 * CC + h * DH + d4];
        }
        ushort4 h4, l4;
        h4.x = f2bf(kv.x); l4.x = f2bf(kv.x - bf2f(h4.x));
        h4.y = f2bf(kv.y); l4.y = f2bf(kv.y - bf2f(h4.y));
        h4.z = f2bf(kv.z); l4.z = f2bf(kv.z - bf2f(h4.z));
        h4.w = f2bf(kv.w); l4.w = f2bf(kv.w - bf2f(h4.w));
        *(ushort4*)&Kh[key * 40 + d4] = h4;
        *(ushort4*)&Kl[key * 40 + d4] = l4;
        Vt[(d4 + 0) * 136 + key] = f2bf(vv.x);
        Vt[(d4 + 1) * 136 + key] = f2bf(vv.y);
        Vt[(d4 + 2) * 136 + key] = f2bf(vv.z);
        Vt[(d4 + 3) * 136 + key] = f2bf(vv.w);
    }
    for (int idx = tid; idx < 32 * 16; idx += 128) {
        int d = idx >> 4, key = 112 + (idx & 15);
        Vt[d * 136 + key] = 0;
    }
    __syncthreads();
    const float* Psum0n = Psum0 + n * CC;
    int rowbase = half * 200 + w * 100;
    unsigned short* Pw = Pb[w];
    const float scl = 0.17677669529663687f;
#pragma unroll
    for (int qg = 0; qg < 2; ++qg) {
        const int nq = qg ? 3 : 4;
        const int qt0 = qg * 4;
        s16x8 qh[4], ql[4];
        int mk[4], sb[4];
#pragma unroll
        for (int qi = 0; qi < 4; ++qi) {
            if (qi >= nq) { mk[qi] = -1; sb[qi] = 0; continue; }
            int lq = (qt0 + qi) * 16 + fr;
            int row = rowbase + (lq < QQ ? lq : QQ - 1);
            int b = row >= TT;
            int t = row - b * TT;
            int q = t >> 1;
            mk[qi] = q; sb[qi] = b ? SM : QQ;
            float qv[8];
            if (t & 1) {
                int f = (b ? far_md : far_rm)[n * QQ + q];
                const float4* pr = (const float4*)(base + (size_t)f * PW + h * DH + d0);
                float4 v0 = pr[0], v1 = pr[1];
                qv[0] = v0.x; qv[1] = v0.y; qv[2] = v0.z; qv[3] = v0.w;
                qv[4] = v1.x; qv[5] = v1.y; qv[6] = v1.z; qv[7] = v1.w;
            } else {
                int qm1 = (q + QQ - 1) % QQ;
                const float4* ps = (const float4*)(Psum0n + h * DH + d0);
                const float4* pm = (const float4*)(base + (size_t)qm1 * PW + h * DH + d0);
                const float4* pmn = (const float4*)(base + (size_t)QQ * PW + h * DH + d0);
                float invd = b ? 0.01f : (1.f / 99.f);
                float bb = b ? 1.f : 0.f;
                float4 a0 = ps[0], c0 = pm[0], m0 = pmn[0];
                float4 a1 = ps[1], c1 = pm[1], m1 = pmn[1];
                qv[0] = (a0.x - c0.x + bb * m0.x) * invd;
                qv[1] = (a0.y - c0.y + bb * m0.y) * invd;
                qv[2] = (a0.z - c0.z + bb * m0.z) * invd;
                qv[3] = (a0.w - c0.w + bb * m0.w) * invd;
                qv[4] = (a1.x - c1.x + bb * m1.x) * invd;
                qv[5] = (a1.y - c1.y + bb * m1.y) * invd;
                qv[6] = (a1.z - c1.z + bb * m1.z) * invd;
                qv[7] = (a1.w - c1.w + bb * m1.w) * invd;
            }
            s16x8 qhv, qlv;
#pragma unroll
            for (int j = 0; j < 8; ++j) {
                unsigned short hh = f2bf(qv[j]);
                qhv[j] = (short)hh;
                qlv[j] = (short)f2bf(qv[j] - bf2f(hh));
            }
            qh[qi] = qhv; ql[qi] = qlv;
        }
        f32x4 pvacc[4][2];
#pragma unroll
        for (int qi = 0; qi < 4; ++qi) {
            pvacc[qi][0] = (f32x4){0.f, 0.f, 0.f, 0.f};
            pvacc[qi][1] = (f32x4){0.f, 0.f, 0.f, 0.f};
        }
        float rs[4] = {0.f, 0.f, 0.f, 0.f};
#pragma unroll
        for (int kc = 0; kc < 4; ++kc) {
            int k0 = kc * 32;
            {
                s16x8 ah = *(const s16x8*)&Kh[(k0 + fr) * 40 + d0];
                s16x8 al = *(const s16x8*)&Kl[(k0 + fr) * 40 + d0];
#pragma unroll
                for (int qi = 0; qi < nq; ++qi) {
                    f32x4 s0 = (f32x4){0.f, 0.f, 0.f, 0.f};
                    s0 = __builtin_amdgcn_mfma_f32_16x16x32_bf16(ah, qh[qi], s0, 0, 0, 0);
                    s0 = __builtin_amdgcn_mfma_f32_16x16x32_bf16(ah, ql[qi], s0, 0, 0, 0);
                    s0 = __builtin_amdgcn_mfma_f32_16x16x32_bf16(al, qh[qi], s0, 0, 0, 0);
                    int kb0 = k0 + 4 * hi;
                    float a0 = (kb0 + 0 < sb[qi] && kb0 + 0 != mk[qi]) ? 1.f / (1.f + __expf(-s0[0] * scl)) : 0.f;
                    float a1 = (kb0 + 1 < sb[qi] && kb0 + 1 != mk[qi]) ? 1.f / (1.f + __expf(-s0[1] * scl)) : 0.f;
                    float a2 = (kb0 + 2 < sb[qi] && kb0 + 2 != mk[qi]) ? 1.f / (1.f + __expf(-s0[2] * scl)) : 0.f;
                    float a3 = (kb0 + 3 < sb[qi] && kb0 + 3 != mk[qi]) ? 1.f / (1.f + __expf(-s0[3] * scl)) : 0.f;
                    rs[qi] += a0 + a1 + a2 + a3;
                    ushort4 p4;
                    p4.x = f2bf(a0); p4.y = f2bf(a1); p4.z = f2bf(a2); p4.w = f2bf(a3);
                    *(ushort4*)&Pw[(qi * 16 + fr) * 40 + 4 * hi] = p4;
                }
            }
            if (kc < 3) {
                s16x8 ah = *(const s16x8*)&Kh[(k0 + 16 + fr) * 40 + d0];
                s16x8 al = *(const s16x8*)&Kl[(k0 + 16 + fr) * 40 + d0];
#pragma unroll
                for (int qi = 0; qi < nq; ++qi) {
                    f32x4 s1 = (f32x4){0.f, 0.f, 0.f, 0.f};
                    s1 = __builtin_amdgcn_mfma_f32_16x16x32_bf16(ah, qh[qi], s1, 0, 0, 0);
                    s1 = __builtin_amdgcn_mfma_f32_16x16x32_bf16(ah, ql[qi], s1, 0, 0, 0);
                    s1 = __builtin_amdgcn_mfma_f32_16x16x32_bf16(al, qh[qi], s1, 0, 0, 0);
                    int kb1 = k0 + 16 + 4 * hi;
                    float a0 = (kb1 + 0 < sb[qi] && kb1 + 0 != mk[qi]) ? 1.f / (1.f + __expf(-s1[0] * scl)) : 0.f;
                    float a1 = (kb1 + 1 < sb[qi] && kb1 + 1 != mk[qi]) ? 1.f / (1.f + __expf(-s1[1] * scl)) : 0.f;
                    float a2 = (kb1 + 2 < sb[qi] && kb1 + 2 != mk[qi]) ? 1.f / (1.f + __expf(-s1[2] * scl)) : 0.f;
                    float a3 = (kb1 + 3 < sb[qi] && kb1 + 3 != mk[qi]) ? 1.f / (1.f + __expf(-s1[3] * scl)) : 0.f;
                    rs[qi] += a0 + a1 + a2 + a3;
                    ushort4 p4;
                    p4.x = f2bf(a0); p4.y = f2bf(a1); p4.z = f2bf(a2); p4.w = f2bf(a3);
                    *(ushort4*)&Pw[(qi * 16 + fr) * 40 + 16 + 4 * hi] = p4;
                }
            } else {
                ushort4 z; z.x = 0; z.y = 0; z.z = 0; z.w = 0;
#pragma unroll
                for (int qi = 0; qi < nq; ++qi)
                    *(ushort4*)&Pw[(qi * 16 + fr) * 40 + 16 + 4 * hi] = z;
            }
            s16x8 vb0 = *(const s16x8*)&Vt[(0 * 16 + fr) * 136 + k0 + d0];
            s16x8 vb1 = *(const s16x8*)&Vt[(1 * 16 + fr) * 136 + k0 + d0];
#pragma unroll
            for (int qi = 0; qi < nq; ++qi) {
                s16x8 pa = *(const s16x8*)&Pw[(qi * 16 + fr) * 40 + d0];
                pvacc[qi][0] = __builtin_amdgcn_mfma_f32_16x16x32_bf16(pa, vb0, pvacc[qi][0], 0, 0, 0);
                pvacc[qi][1] = __builtin_amdgcn_mfma_f32_16x16x32_bf16(pa, vb1, pvacc[qi][1], 0, 0, 0);
            }
        }
#pragma unroll
        for (int qi = 0; qi < nq; ++qi) {
            float r2 = rs[qi] + __shfl_xor(rs[qi], 16);
            r2 += __shfl_xor(r2, 32);
            int lq = (qt0 + qi) * 16 + fr;
            if (hi == 0) {
                rsL[w][lq] = r2;
                if (lq < QQ) rowsum[((size_t)n * HH + h) * TB + rowbase + lq] = r2;
            }
        }
#pragma unroll
        for (int qi = 0; qi < nq; ++qi) {
            float iv[4];
#pragma unroll
            for (int r = 0; r < 4; ++r) {
                int lq = (qt0 + qi) * 16 + 4 * hi + r;
                iv[r] = 1.f / (rsL[w][lq < 112 ? lq : 111] + 1e-4f);
            }
#pragma unroll
            for (int dt = 0; dt < 2; ++dt) {
#pragma unroll
                for (int r = 0; r < 4; ++r) {
                    int lq = (qt0 + qi) * 16 + 4 * hi + r;
                    if (lq < QQ)
                        pv[((size_t)n * TB + rowbase + lq) * CC + h * DH + dt * 16 + fr] = pvacc[qi][dt][r] * iv[r];
                }
            }
        }
    }
}

// ---------------- fused out-projection + shift: 128 rows x 256 cols per block, 8 waves ----------------
__global__ __launch_bounds__(512)
void outshift(const float* __restrict__ pv, const float* __restrict__ ow,
              const float* __restrict__ ob, const float* __restrict__ cd,
              const float* __restrict__ cs, const float* __restrict__ rowsum,
              float* __restrict__ out_srm, float* __restrict__ out_smd) {
    __shared__ unsigned short Ahs[128][LDK], Als[128][LDK];
    __shared__ unsigned short Bhs[256][LDK], Bls[256][LDK];
    __shared__ float redcd[128][4], redcs[128][4];
    int tid = threadIdx.x;
    int lane = tid & 63, wave = tid >> 6;
    int wm = (wave >> 2) * 64, wn = (wave & 3) * 64;
    int fr = lane & 15, kb = lane >> 4;
    int bm = blockIdx.x * 128;
    int arow = tid >> 2, ak = (tid & 3) * 8;
    int brow = tid >> 1, bk = (tid & 1) * 16;
    const float* pA = pv + (size_t)(bm + arow) * CC + ak;
    const float* pB = ow + (size_t)brow * CC + bk;
    f32x4 acc[4][4];
#pragma unroll
    for (int mi = 0; mi < 4; ++mi)
#pragma unroll
        for (int ni = 0; ni < 4; ++ni)
            acc[mi][ni] = (f32x4){0.f, 0.f, 0.f, 0.f};
    for (int k0 = 0; k0 < CC; k0 += 32) {
        float4 av[2], wv[4];
#pragma unroll
        for (int j = 0; j < 2; ++j) av[j] = *(const float4*)(pA + k0 + 4 * j);
#pragma unroll
        for (int j = 0; j < 4; ++j) wv[j] = *(const float4*)(pB + k0 + 4 * j);
        __syncthreads();
#pragma unroll
        for (int j = 0; j < 2; ++j) {
            ushort4 h4, l4;
            h4.x = f2bf(av[j].x); l4.x = f2bf(av[j].x - bf2f(h4.x));
            h4.y = f2bf(av[j].y); l4.y = f2bf(av[j].y - bf2f(h4.y));
            h4.z = f2bf(av[j].z); l4.z = f2bf(av[j].z - bf2f(h4.z));
            h4.w = f2bf(av[j].w); l4.w = f2bf(av[j].w - bf2f(h4.w));
            *(ushort4*)&Ahs[arow][ak + 4 * j] = h4;
            *(ushort4*)&Als[arow][ak + 4 * j] = l4;
        }
#pragma unroll
        for (int j = 0; j < 4; ++j) {
            ushort4 h4, l4;
            h4.x = f2bf(wv[j].x); l4.x = f2bf(wv[j].x - bf2f(h4.x));
            h4.y = f2bf(wv[j].y); l4.y = f2bf(wv[j].y - bf2f(h4.y));
            h4.z = f2bf(wv[j].z); l4.z = f2bf(wv[j].z - bf2f(h4.z));
            h4.w = f2bf(wv[j].w); l4.w = f2bf(wv[j].w - bf2f(h4.w));
            *(ushort4*)&Bhs[brow][bk + 4 * j] = h4;
            *(ushort4*)&Bls[brow][bk + 4 * j] = l4;
        }
        __syncthreads();
        s16x8 fah[4], fal[4], fbh[4], fbl[4];
#pragma unroll
        for (int mi = 0; mi < 4; ++mi) {
            fah[mi] = *(const s16x8*)&Ahs[wm + mi * 16 + fr][kb * 8];
            fal[mi] = *(const s16x8*)&Als[wm + mi * 16 + fr][kb * 8];
        }
#pragma unroll
        for (int ni = 0; ni < 4; ++ni) {
            fbh[ni] = *(const s16x8*)&Bhs[wn + ni * 16 + fr][kb * 8];
            fbl[ni] = *(const s16x8*)&Bls[wn + ni * 16 + fr][kb * 8];
        }
#pragma unroll
        for (int mi = 0; mi < 4; ++mi)
#pragma unroll
            for (int ni = 0; ni < 4; ++ni) {
                acc[mi][ni] = __builtin_amdgcn_mfma_f32_16x16x32_bf16(fah[mi], fbh[ni], acc[mi][ni], 0, 0, 0);
                acc[mi][ni] = __builtin_amdgcn_mfma_f32_16x16x32_bf16(fah[mi], fbl[ni], acc[mi][ni], 0, 0, 0);
                acc[mi][ni] = __builtin_amdgcn_mfma_f32_16x16x32_bf16(fal[mi], fbh[ni], acc[mi][ni], 0, 0, 0);
            }
    }
#pragma unroll
    for (int mi = 0; mi < 4; ++mi) {
#pragma unroll
        for (int r = 0; r < 4; ++r) {
            int lm = wm + mi * 16 + kb * 4 + r;
            int g = bm + lm;
            int n = g / TB;
            float pcd = 0.f, pcs = 0.f;
#pragma unroll
            for (int ni = 0; ni < 4; ++ni) {
                int col = wn + ni * 16 + fr;
                float val = acc[mi][ni][r] + ob[col];
                float d1 = val - cd[(size_t)n * CC + col];
                float d2 = val - cs[(size_t)n * CC + col];
                pcd += d1 * d1;
                pcs += d2 * d2;
            }
#pragma unroll
            for (int m2 = 1; m2 < 16; m2 <<= 1) {
                pcd += __shfl_xor(pcd, m2);
                pcs += __shfl_xor(pcs, m2);
            }
            if (fr == 0) {
                redcd[lm][wave & 3] = pcd;
                redcs[lm][wave & 3] = pcs;
            }
        }
    }
    __syncthreads();
    if (tid < 64) {
        int g = bm + 2 * tid;
        int n = g / TB;
        int rem = g % TB;
        int b = rem / TT;
        int t = rem % TT;
        int q = t >> 1;
        float c0 = 0.f, c1v = 0.f;
        for (int h = 0; h < HH; ++h) {
            c0  += rowsum[((size_t)n * HH + h) * TB + rem];
            c1v += rowsum[((size_t)n * HH + h) * TB + rem + 1];
        }
        int si = (c1v < c0) ? 1 : 0;
        int di = (c1v > c0) ? 1 : 0;
        int ld = 2 * tid + di, ls = 2 * tid + si;
        float dd = redcd[ld][0] + redcd[ld][1] + redcd[ld][2] + redcd[ld][3];
        float ds = redcs[ls][0] + redcs[ls][1] + redcs[ls][2] + redcs[ls][3];
        (b ? out_smd : out_srm)[n * QQ + q] = sqrtf(dd + 1e-12f) + sqrtf(ds + 1e-12f);
    }
}

extern "C" void kernel_launch(void* const* d_in, const int* in_sizes, int n_in,
                              void* d_out, int out_size, void* d_ws, size_t ws_size,
                              hipStream_t stream) {
    const float* hs_pair = (const float*)d_in[0];
    const float* ipw = (const float*)d_in[1];
    const float* ipb = (const float*)d_in[2];
    const float* ow  = (const float*)d_in[3];
    const float* ob  = (const float*)d_in[4];
    const float* hs = hs_pair + (size_t)5 * NB * QQ * CC;  // hs_pair[-1]

    float* ws = (float*)d_ws;
    size_t o = 0;
    float* kv_ext  = ws + o; o += (size_t)NB * SM * CC;
    float* P_all   = ws + o; o += (size_t)NB * SM * PW;
    float* Psum0   = ws + o; o += NB * CC;
    int*   far0    = (int*)(ws + o); o += NB;
    int*   far_rm  = (int*)(ws + o); o += NB * QQ;
    int*   far_md  = (int*)(ws + o); o += NB * QQ;
    float* cd      = ws + o; o += NB * CC;
    float* cs      = ws + o; o += NB * CC;
    float* pv      = ws + o; o += (size_t)NB * TB * CC;
    float* rowsum  = ws + o; o += (size_t)NB * HH * TB;
    float* attnB   = ws + o; o += (size_t)NB * HH * 2 * 104;
    float* rsB     = ws + o; o += (size_t)NB * HH * 2;
    float* pvB     = ws + o; o += (size_t)2 * NB * CC;
    float* mfB     = ws + o; o += (size_t)2 * NB * CC;
    if (o * sizeof(float) > ws_size) return;

    float* out = (float*)d_out;
    float* out_assign = out;
    float* out_sidx   = out + 6400;
    float* out_didx   = out + 6432;
    float* out_srm    = out + 6464;
    float* out_smd    = out + 9664;

    prep_kernel<<<NB, 256, 0, stream>>>(hs, far0, kv_ext);
    gemm_mfma<<<dim3((NB * SM + 127) / 128, PW / 128), 256, 0, stream>>>(
        kv_ext, ipw, ipb, P_all, NB * SM, PW);
    psum_kernel<<<NB, 256, 0, stream>>>(P_all, Psum0);
    gramfar<<<NB, 256, 0, stream>>>(kv_ext, far_rm, far_md);
    smhaB_scores<<<dim3(HH, NB), 64, 0, stream>>>(P_all, far0, attnB, rsB, pvB);
    gemm_mfma<<<dim3(1, 2), 256, 0, stream>>>(pvB, ow, ob, mfB, 2 * NB, CC);
    smhaB_final<<<NB, 256, 0, stream>>>(attnB, rsB, mfB, out_assign, out_sidx,
                                        out_didx, cd, cs);
    attn_mfma<<<dim3(2, HH, NB), 128, 0, stream>>>(P_all, Psum0, far_rm, far_md, pv, rowsum);
    outshift<<<NB * TB / 128, 512, 0, stream>>>(pv, ow, ob, cd, cs, rowsum, out_srm, out_smd);
}

// Round 10
// 140.662 us; speedup vs baseline: 2.9751x; 1.1438x over previous
//
#include <hip/hip_runtime.h>
#include <math.h>

#define NB 32
#define QQ 100
#define CC 256
#define HH 8
#define DH 32
#define SM 101   // kv rows per batch (100 points + mean)
#define TT 200   // branch queries per batch
#define TB 400   // both branches
#define PW 768   // P_all row width (q|k|v projections)

typedef __attribute__((ext_vector_type(8))) short s16x8;
typedef __attribute__((ext_vector_type(4))) float f32x4;

__device__ inline unsigned short f2bf(float x) {
    unsigned u = __float_as_uint(x);
    return (unsigned short)((u + 0x7fffu + ((u >> 16) & 1u)) >> 16);
}
__device__ inline float bf2f(unsigned short h) {
    return __uint_as_float(((unsigned)h) << 16);
}

// ---------------- prep: kv_ext (hs rows + mean), stage-A far point ----------------
__global__ void prep_kernel(const float* __restrict__ hs, int* __restrict__ far0,
                            float* __restrict__ kv_ext) {
    int n = blockIdx.x;
    int c = threadIdx.x; // 0..255
    const float* h = hs + (size_t)n * QQ * CC;
    float s = 0.f;
    for (int q = 0; q < QQ; ++q) s += h[q * CC + c];
    float c1 = s * (1.0f / QQ);
    __shared__ float c1s[CC];
    __shared__ float dls[QQ];
    c1s[c] = c1;
    float* kve = kv_ext + (size_t)n * SM * CC;
    for (int idx = c; idx < QQ * CC; idx += CC) kve[idx] = h[idx];
    kve[QQ * CC + c] = c1;
    __syncthreads();
    int wave = c >> 6, lane = c & 63;
    for (int q = wave; q < QQ; q += 4) {
        float p = 0.f;
        for (int cc = lane; cc < CC; cc += 64) {
            float d = c1s[cc] - h[q * CC + cc];
            p += d * d;
        }
        for (int off = 32; off > 0; off >>= 1) p += __shfl_down(p, off);
        if (lane == 0) dls[q] = p;
    }
    __syncthreads();
    if (c == 0) {
        int best = 0; float bv = dls[0];
        for (int q = 1; q < QQ; ++q) if (dls[q] > bv) { bv = dls[q]; best = q; }
        far0[n] = best;
    }
}

// ---------------- split-bf16 MFMA GEMM, fp32 inputs (split on stage): out = A @ W^T + bias ----------------
#define LDK 40
__global__ __launch_bounds__(256, 2)
void gemm_mfma(const float* __restrict__ A_g, const float* __restrict__ W_g,
               const float* __restrict__ bias, float* __restrict__ out, int M, int Nout) {
    __shared__ unsigned short Ahs[128][LDK], Als[128][LDK], Bhs[128][LDK], Bls[128][LDK];
    int tid = threadIdx.x;
    int lane = tid & 63, wave = tid >> 6;
    int wm = (wave >> 1) * 64, wn = (wave & 1) * 64;
    int fr = lane & 15, kb = lane >> 4;
    int bm = blockIdx.x * 128, bn = blockIdx.y * 128;
    int srow = tid >> 1, scol = (tid & 1) * 16;
    int am = bm + srow; if (am >= M) am = M - 1;
    const float* pA = A_g + (size_t)am * CC + scol;
    const float* pW = W_g + (size_t)(bn + srow) * CC + scol;
    f32x4 acc[4][4];
#pragma unroll
    for (int mi = 0; mi < 4; ++mi)
#pragma unroll
        for (int ni = 0; ni < 4; ++ni)
            acc[mi][ni] = (f32x4){0.f, 0.f, 0.f, 0.f};
    for (int k0 = 0; k0 < CC; k0 += 32) {
        float4 av[4], wv[4];
#pragma unroll
        for (int j = 0; j < 4; ++j) {
            av[j] = *(const float4*)(pA + k0 + 4 * j);
            wv[j] = *(const float4*)(pW + k0 + 4 * j);
        }
        __syncthreads();
#pragma unroll
        for (int j = 0; j < 4; ++j) {
            ushort4 h4, l4, wh4, wl4;
            h4.x = f2bf(av[j].x); l4.x = f2bf(av[j].x - bf2f(h4.x));
            h4.y = f2bf(av[j].y); l4.y = f2bf(av[j].y - bf2f(h4.y));
            h4.z = f2bf(av[j].z); l4.z = f2bf(av[j].z - bf2f(h4.z));
            h4.w = f2bf(av[j].w); l4.w = f2bf(av[j].w - bf2f(h4.w));
            wh4.x = f2bf(wv[j].x); wl4.x = f2bf(wv[j].x - bf2f(wh4.x));
            wh4.y = f2bf(wv[j].y); wl4.y = f2bf(wv[j].y - bf2f(wh4.y));
            wh4.z = f2bf(wv[j].z); wl4.z = f2bf(wv[j].z - bf2f(wh4.z));
            wh4.w = f2bf(wv[j].w); wl4.w = f2bf(wv[j].w - bf2f(wh4.w));
            *(ushort4*)&Ahs[srow][scol + 4 * j] = h4;
            *(ushort4*)&Als[srow][scol + 4 * j] = l4;
            *(ushort4*)&Bhs[srow][scol + 4 * j] = wh4;
            *(ushort4*)&Bls[srow][scol + 4 * j] = wl4;
        }
        __syncthreads();
        s16x8 fah[4], fal[4], fbh[4], fbl[4];
#pragma unroll
        for (int mi = 0; mi < 4; ++mi) {
            fah[mi] = *(const s16x8*)&Ahs[wm + mi * 16 + fr][kb * 8];
            fal[mi] = *(const s16x8*)&Als[wm + mi * 16 + fr][kb * 8];
        }
#pragma unroll
        for (int ni = 0; ni < 4; ++ni) {
            fbh[ni] = *(const s16x8*)&Bhs[wn + ni * 16 + fr][kb * 8];
            fbl[ni] = *(const s16x8*)&Bls[wn + ni * 16 + fr][kb * 8];
        }
#pragma unroll
        for (int mi = 0; mi < 4; ++mi)
#pragma unroll
            for (int ni = 0; ni < 4; ++ni) {
                acc[mi][ni] = __builtin_amdgcn_mfma_f32_16x16x32_bf16(fah[mi], fbh[ni], acc[mi][ni], 0, 0, 0);
                acc[mi][ni] = __builtin_amdgcn_mfma_f32_16x16x32_bf16(fah[mi], fbl[ni], acc[mi][ni], 0, 0, 0);
                acc[mi][ni] = __builtin_amdgcn_mfma_f32_16x16x32_bf16(fal[mi], fbh[ni], acc[mi][ni], 0, 0, 0);
            }
    }
#pragma unroll
    for (int mi = 0; mi < 4; ++mi) {
        int mb = bm + wm + mi * 16 + kb * 4;
#pragma unroll
        for (int r = 0; r < 4; ++r) {
            int m = mb + r;
            if (m < M) {
#pragma unroll
                for (int ni = 0; ni < 4; ++ni) {
                    int col = bn + wn + ni * 16 + fr;
                    out[(size_t)m * Nout + col] = acc[mi][ni][r] + bias[col];
                }
            }
        }
    }
}

// ---------------- fused Gram + far selection + psum, per batch ----------------
__global__ __launch_bounds__(256, 2)
void gramfar(const float* __restrict__ kv_ext, const float* __restrict__ P_all,
             float* __restrict__ Psum0, int* __restrict__ far_rm,
             int* __restrict__ far_md) {
    int n = blockIdx.x;
    int tid = threadIdx.x;
    int wave = tid >> 6, lane = tid & 63;
    int fr = lane & 15, kb = lane >> 4;
    __shared__ float G[SM][104];
    __shared__ unsigned short Ah[112][LDK], Al[112][LDK];
    __shared__ float sumdot[104], meandot[104], norm[104];
    // psum phase (independent): Psum0[n][c] = sum_q P_all[n][q][c]
    {
        const float* basep = P_all + (size_t)n * SM * PW + tid;
        float accp = 0.f;
        for (int q = 0; q < QQ; ++q) accp += basep[(size_t)q * PW];
        Psum0[n * CC + tid] = accp;
    }
    const float* A = kv_ext + (size_t)n * SM * CC;
    f32x4 acc[13];
#pragma unroll
    for (int u = 0; u < 13; ++u) acc[u] = (f32x4){0.f, 0.f, 0.f, 0.f};
    for (int k0 = 0; k0 < CC; k0 += 32) {
        __syncthreads();
        for (int idx = tid; idx < 224; idx += 256) {
            int row = idx >> 1, kk = (idx & 1) * 16;
            float4 v[4];
#pragma unroll
            for (int j = 0; j < 4; ++j)
                v[j] = (row < SM) ? *(const float4*)&A[(size_t)row * CC + k0 + kk + 4 * j]
                                  : (float4){0.f, 0.f, 0.f, 0.f};
#pragma unroll
            for (int j = 0; j < 4; ++j) {
                ushort4 h4, l4;
                h4.x = f2bf(v[j].x); l4.x = f2bf(v[j].x - bf2f(h4.x));
                h4.y = f2bf(v[j].y); l4.y = f2bf(v[j].y - bf2f(h4.y));
                h4.z = f2bf(v[j].z); l4.z = f2bf(v[j].z - bf2f(h4.z));
                h4.w = f2bf(v[j].w); l4.w = f2bf(v[j].w - bf2f(h4.w));
                *(ushort4*)&Ah[row][kk + 4 * j] = h4;
                *(ushort4*)&Al[row][kk + 4 * j] = l4;
            }
        }
        __syncthreads();
#pragma unroll
        for (int u = 0; u < 13; ++u) {
            int tl = wave + u * 4;
            if (tl < 49) {
                int ti = tl / 7, tj = tl % 7;
                s16x8 ah = *(const s16x8*)&Ah[ti * 16 + fr][kb * 8];
                s16x8 al = *(const s16x8*)&Al[ti * 16 + fr][kb * 8];
                s16x8 bh = *(const s16x8*)&Ah[tj * 16 + fr][kb * 8];
                s16x8 bl = *(const s16x8*)&Al[tj * 16 + fr][kb * 8];
                acc[u] = __builtin_amdgcn_mfma_f32_16x16x32_bf16(ah, bh, acc[u], 0, 0, 0);
                acc[u] = __builtin_amdgcn_mfma_f32_16x16x32_bf16(ah, bl, acc[u], 0, 0, 0);
                acc[u] = __builtin_amdgcn_mfma_f32_16x16x32_bf16(al, bh, acc[u], 0, 0, 0);
            }
        }
    }
    __syncthreads();
#pragma unroll
    for (int u = 0; u < 13; ++u) {
        int tl = wave + u * 4;
        if (tl < 49) {
            int ti = tl / 7, tj = tl % 7;
#pragma unroll
            for (int r = 0; r < 4; ++r) {
                int m = ti * 16 + kb * 4 + r;
                int col = tj * 16 + fr;
                if (m < SM && col < SM) G[m][col] = acc[u][r];
            }
        }
    }
    __syncthreads();
    for (int s = tid; s < SM; s += 256) {
        float a = 0.f;
        for (int q = 0; q < QQ; ++q) a += G[s][q];
        sumdot[s] = a; meandot[s] = G[s][QQ]; norm[s] = G[s][s];
    }
    __syncthreads();
    if (tid < QQ) {
        int q = tid, qm1 = (q + QQ - 1) % QQ;
        const float* gq = G[qm1];
        int best = -1; float bv = -1e30f;
        for (int s = 0; s < QQ; ++s) {
            if (s == qm1) continue;
            float val = norm[s] - (sumdot[s] - gq[s]) * (2.f / 99.f);
            if (val > bv) { bv = val; best = s; }
        }
        far_rm[n * QQ + q] = best;
    } else if (tid >= 128 && tid < 128 + QQ) {
        int q = tid - 128, qm1 = (q + QQ - 1) % QQ;
        const float* gq = G[qm1];
        int best = -1; float bv = -1e30f;
        for (int s = 0; s < SM; ++s) {
            if (s == qm1) continue;
            float val = norm[s] - (sumdot[s] - gq[s] + meandot[s]) * (2.f / 100.f);
            if (val > bv) { bv = val; best = s; }
        }
        far_md[n * QQ + q] = best;
    }
}

// ---------------- stage B scores + PV, per (n,h): q rows come from P_all ----------------
__global__ __launch_bounds__(64)
void smhaB_scores(const float* __restrict__ P_all, const int* __restrict__ far0,
                  float* __restrict__ attnB, float* __restrict__ rsB,
                  float* __restrict__ pvB) {
    int h = blockIdx.x, n = blockIdx.y;
    int lane = threadIdx.x;
    const float* base = P_all + (size_t)n * SM * PW;
    __shared__ float q[2][DH];
    __shared__ float at[2][104];
    __shared__ float rsv[2];
    if (lane < 2 * DH) {
        int t = lane >> 5, d = lane & 31;
        int row = t ? far0[n] : QQ;
        q[t][d] = base[(size_t)row * PW + h * DH + d];
    }
    __syncthreads();
    const float scl = 0.17677669529663687f;
    float p0 = 0.f, p1 = 0.f;
    for (int s = lane; s < 104; s += 64) {
        if (s < QQ) {
            const float4* kr = (const float4*)(base + (size_t)s * PW + CC + h * DH);
            float d0 = 0.f, d1 = 0.f;
#pragma unroll
            for (int j = 0; j < 8; ++j) {
                float4 k4 = kr[j];
                d0 += q[0][4 * j] * k4.x + q[0][4 * j + 1] * k4.y + q[0][4 * j + 2] * k4.z + q[0][4 * j + 3] * k4.w;
                d1 += q[1][4 * j] * k4.x + q[1][4 * j + 1] * k4.y + q[1][4 * j + 2] * k4.z + q[1][4 * j + 3] * k4.w;
            }
            float a0 = 1.f / (1.f + __expf(-d0 * scl));
            float a1 = 1.f / (1.f + __expf(-d1 * scl));
            at[0][s] = a0; at[1][s] = a1;
            p0 += a0; p1 += a1;
            attnB[(((size_t)n * HH + h) * 2 + 0) * 104 + s] = a0;
            attnB[(((size_t)n * HH + h) * 2 + 1) * 104 + s] = a1;
        } else {
            at[0][s] = 0.f; at[1][s] = 0.f;
        }
    }
#pragma unroll
    for (int off = 32; off > 0; off >>= 1) {
        p0 += __shfl_down(p0, off);
        p1 += __shfl_down(p1, off);
    }
    if (lane == 0) {
        rsv[0] = p0; rsv[1] = p1;
        rsB[((size_t)n * HH + h) * 2 + 0] = p0;
        rsB[((size_t)n * HH + h) * 2 + 1] = p1;
    }
    __syncthreads();
    int t = lane >> 5, d = lane & 31;
    float inv = 1.f / (rsv[t] + 1e-4f);
    float acc = 0.f;
    const float* vb = base + 2 * CC + h * DH + d;
    for (int s = 0; s < QQ; ++s) acc += at[t][s] * vb[(size_t)s * PW];
    pvB[((size_t)n * 2 + t) * CC + h * DH + d] = acc * inv;
}

// ---------------- stage B final: assign, si/di, out-proj of 2 rows, cd/cs ----------------
__global__ void smhaB_final(const float* __restrict__ attnB, const float* __restrict__ rsB,
                            const float* __restrict__ pvB, const float* __restrict__ ow,
                            const float* __restrict__ ob, float* __restrict__ out_assign,
                            float* __restrict__ out_sidx, float* __restrict__ out_didx,
                            float* __restrict__ cd, float* __restrict__ cs) {
    int n = blockIdx.x; int tid = threadIdx.x;
    __shared__ int sdi[2];
    __shared__ float pvs[2][CC];
    pvs[0][tid] = pvB[((size_t)n * 2 + 0) * CC + tid];
    pvs[1][tid] = pvB[((size_t)n * 2 + 1) * CC + tid];
    if (tid == 0) {
        float c0 = 0.f, c1v = 0.f;
        for (int h = 0; h < HH; ++h) {
            c0  += rsB[((size_t)n * HH + h) * 2 + 0];
            c1v += rsB[((size_t)n * HH + h) * 2 + 1];
        }
        int si = (c1v < c0) ? 1 : 0;
        int di = (c1v > c0) ? 1 : 0;
        sdi[0] = si; sdi[1] = di;
        out_sidx[n] = (float)si;
        out_didx[n] = (float)di;
    }
    for (int idx = tid; idx < 2 * QQ; idx += 256) {
        int t = idx / QQ, s = idx % QQ;
        float m = 0.f;
        for (int h = 0; h < HH; ++h) m += attnB[(((size_t)n * HH + h) * 2 + t) * 104 + s];
        out_assign[(size_t)n * 2 * QQ + idx] = m * 0.125f;
    }
    __syncthreads();
    // out-projection of the two pv rows, col = tid
    const float4* wr4 = (const float4*)(ow + (size_t)tid * CC);
    const float4* p0 = (const float4*)&pvs[0][0];
    const float4* p1 = (const float4*)&pvs[1][0];
    float a0 = ob[tid], a1 = ob[tid];
#pragma unroll 8
    for (int k = 0; k < 64; ++k) {
        float4 w = wr4[k], x0 = p0[k], x1 = p1[k];
        a0 += x0.x * w.x + x0.y * w.y + x0.z * w.z + x0.w * w.w;
        a1 += x1.x * w.x + x1.y * w.y + x1.z * w.z + x1.w * w.w;
    }
    cd[(size_t)n * CC + tid] = sdi[1] ? a1 : a0;
    cs[(size_t)n * CC + tid] = sdi[0] ? a1 : a0;
}

// ---------------- MFMA attention (both branches): one block per (n,h), 4 waves ----------------
__global__ __launch_bounds__(256)
void attn_mfma(const float* __restrict__ P_all, const float* __restrict__ Psum0,
               const int* __restrict__ far_rm, const int* __restrict__ far_md,
               float* __restrict__ pv, float* __restrict__ rowsum) {
    int h = blockIdx.x, n = blockIdx.y;
    int tid = threadIdx.x;
    int w = tid >> 6, lane = tid & 63;
    int fr = lane & 15, hi = lane >> 4;
    int d0 = hi * 8;
    __shared__ unsigned short Kh[112 * 40];
    __shared__ unsigned short Kl[112 * 40];
    __shared__ unsigned short Vt[32 * 136];
    __shared__ unsigned short Pb[4][64 * 40];
    __shared__ float rsL[4][112];
    const float* base = P_all + (size_t)n * SM * PW;
    for (int idx = tid; idx < 112 * 8; idx += 256) {
        int key = idx >> 3, d4 = (idx & 7) * 4;
        float4 kv = {0.f, 0.f, 0.f, 0.f}, vv = {0.f, 0.f, 0.f, 0.f};
        if (key < SM) {
            kv = *(const float4*)&base[(size_t)key * PW + CC + h * DH + d4];
            vv = *(const float4*)&base[(size_t)key * PW + 2 * CC + h * DH + d4];
        }
        ushort4 h4, l4;
        h4.x = f2bf(kv.x); l4.x = f2bf(kv.x - bf2f(h4.x));
        h4.y = f2bf(kv.y); l4.y = f2bf(kv.y - bf2f(h4.y));
        h4.z = f2bf(kv.z); l4.z = f2bf(kv.z - bf2f(h4.z));
        h4.w = f2bf(kv.w); l4.w = f2bf(kv.w - bf2f(h4.w));
        *(ushort4*)&Kh[key * 40 + d4] = h4;
        *(ushort4*)&Kl[key * 40 + d4] = l4;
        Vt[(d4 + 0) * 136 + key] = f2bf(vv.x);
        Vt[(d4 + 1) * 136 + key] = f2bf(vv.y);
        Vt[(d4 + 2) * 136 + key] = f2bf(vv.z);
        Vt[(d4 + 3) * 136 + key] = f2bf(vv.w);
    }
    for (int idx = tid; idx < 32 * 16; idx += 256) {
        int d = idx >> 4, key = 112 + (idx & 15);
        Vt[d * 136 + key] = 0;
    }
    __syncthreads();
    const float* Psum0n = Psum0 + n * CC;
    int rowbase = w * 100;
    unsigned short* Pw = Pb[w];
    const float scl = 0.17677669529663687f;
#pragma unroll
    for (int qg = 0; qg < 2; ++qg) {
        const int nq = qg ? 3 : 4;
        const int qt0 = qg * 4;
        s16x8 qh[4], ql[4];
        int mk[4], sb[4];
#pragma unroll
        for (int qi = 0; qi < 4; ++qi) {
            if (qi >= nq) { mk[qi] = -1; sb[qi] = 0; continue; }
            int lq = (qt0 + qi) * 16 + fr;
            int row = rowbase + (lq < QQ ? lq : QQ - 1);
            int b = row >= TT;
            int t = row - b * TT;
            int q = t >> 1;
            mk[qi] = q; sb[qi] = b ? SM : QQ;
            float qv[8];
            if (t & 1) {
                int f = (b ? far_md : far_rm)[n * QQ + q];
                const float4* pr = (const float4*)(base + (size_t)f * PW + h * DH + d0);
                float4 v0 = pr[0], v1 = pr[1];
                qv[0] = v0.x; qv[1] = v0.y; qv[2] = v0.z; qv[3] = v0.w;
                qv[4] = v1.x; qv[5] = v1.y; qv[6] = v1.z; qv[7] = v1.w;
            } else {
                int qm1 = (q + QQ - 1) % QQ;
                const float4* ps = (const float4*)(Psum0n + h * DH + d0);
                const float4* pm = (const float4*)(base + (size_t)qm1 * PW + h * DH + d0);
                const float4* pmn = (const float4*)(base + (size_t)QQ * PW + h * DH + d0);
                float invd = b ? 0.01f : (1.f / 99.f);
                float bb = b ? 1.f : 0.f;
                float4 a0 = ps[0], c0 = pm[0], m0 = pmn[0];
                float4 a1 = ps[1], c1 = pm[1], m1 = pmn[1];
                qv[0] = (a0.x - c0.x + bb * m0.x) * invd;
                qv[1] = (a0.y - c0.y + bb * m0.y) * invd;
                qv[2] = (a0.z - c0.z + bb * m0.z) * invd;
                qv[3] = (a0.w - c0.w + bb * m0.w) * invd;
                qv[4] = (a1.x - c1.x + bb * m1.x) * invd;
                qv[5] = (a1.y - c1.y + bb * m1.y) * invd;
                qv[6] = (a1.z - c1.z + bb * m1.z) * invd;
                qv[7] = (a1.w - c1.w + bb * m1.w) * invd;
            }
            s16x8 qhv, qlv;
#pragma unroll
            for (int j = 0; j < 8; ++j) {
                unsigned short hh = f2bf(qv[j]);
                qhv[j] = (short)hh;
                qlv[j] = (short)f2bf(qv[j] - bf2f(hh));
            }
            qh[qi] = qhv; ql[qi] = qlv;
        }
        f32x4 pvacc[4][2];
#pragma unroll
        for (int qi = 0; qi < 4; ++qi) {
            pvacc[qi][0] = (f32x4){0.f, 0.f, 0.f, 0.f};
            pvacc[qi][1] = (f32x4){0.f, 0.f, 0.f, 0.f};
        }
        float rs[4] = {0.f, 0.f, 0.f, 0.f};
#pragma unroll
        for (int kc = 0; kc < 4; ++kc) {
            int k0 = kc * 32;
            {
                s16x8 ah = *(const s16x8*)&Kh[(k0 + fr) * 40 + d0];
                s16x8 al = *(const s16x8*)&Kl[(k0 + fr) * 40 + d0];
#pragma unroll
                for (int qi = 0; qi < nq; ++qi) {
                    f32x4 s0 = (f32x4){0.f, 0.f, 0.f, 0.f};
                    s0 = __builtin_amdgcn_mfma_f32_16x16x32_bf16(ah, qh[qi], s0, 0, 0, 0);
                    s0 = __builtin_amdgcn_mfma_f32_16x16x32_bf16(ah, ql[qi], s0, 0, 0, 0);
                    s0 = __builtin_amdgcn_mfma_f32_16x16x32_bf16(al, qh[qi], s0, 0, 0, 0);
                    int kb0 = k0 + 4 * hi;
                    float a0 = (kb0 + 0 < sb[qi] && kb0 + 0 != mk[qi]) ? 1.f / (1.f + __expf(-s0[0] * scl)) : 0.f;
                    float a1 = (kb0 + 1 < sb[qi] && kb0 + 1 != mk[qi]) ? 1.f / (1.f + __expf(-s0[1] * scl)) : 0.f;
                    float a2 = (kb0 + 2 < sb[qi] && kb0 + 2 != mk[qi]) ? 1.f / (1.f + __expf(-s0[2] * scl)) : 0.f;
                    float a3 = (kb0 + 3 < sb[qi] && kb0 + 3 != mk[qi]) ? 1.f / (1.f + __expf(-s0[3] * scl)) : 0.f;
                    rs[qi] += a0 + a1 + a2 + a3;
                    ushort4 p4;
                    p4.x = f2bf(a0); p4.y = f2bf(a1); p4.z = f2bf(a2); p4.w = f2bf(a3);
                    *(ushort4*)&Pw[(qi * 16 + fr) * 40 + 4 * hi] = p4;
                }
            }
            if (kc < 3) {
                s16x8 ah = *(const s16x8*)&Kh[(k0 + 16 + fr) * 40 + d0];
                s16x8 al = *(const s16x8*)&Kl[(k0 + 16 + fr) * 40 + d0];
#pragma unroll
                for (int qi = 0; qi < nq; ++qi) {
                    f32x4 s1 = (f32x4){0.f, 0.f, 0.f, 0.f};
                    s1 = __builtin_amdgcn_mfma_f32_16x16x32_bf16(ah, qh[qi], s1, 0, 0, 0);
                    s1 = __builtin_amdgcn_mfma_f32_16x16x32_bf16(ah, ql[qi], s1, 0, 0, 0);
                    s1 = __builtin_amdgcn_mfma_f32_16x16x32_bf16(al, qh[qi], s1, 0, 0, 0);
                    int kb1 = k0 + 16 + 4 * hi;
                    float a0 = (kb1 + 0 < sb[qi] && kb1 + 0 != mk[qi]) ? 1.f / (1.f + __expf(-s1[0] * scl)) : 0.f;
                    float a1 = (kb1 + 1 < sb[qi] && kb1 + 1 != mk[qi]) ? 1.f / (1.f + __expf(-s1[1] * scl)) : 0.f;
                    float a2 = (kb1 + 2 < sb[qi] && kb1 + 2 != mk[qi]) ? 1.f / (1.f + __expf(-s1[2] * scl)) : 0.f;
                    float a3 = (kb1 + 3 < sb[qi] && kb1 + 3 != mk[qi]) ? 1.f / (1.f + __expf(-s1[3] * scl)) : 0.f;
                    rs[qi] += a0 + a1 + a2 + a3;
                    ushort4 p4;
                    p4.x = f2bf(a0); p4.y = f2bf(a1); p4.z = f2bf(a2); p4.w = f2bf(a3);
                    *(ushort4*)&Pw[(qi * 16 + fr) * 40 + 16 + 4 * hi] = p4;
                }
            } else {
                ushort4 z; z.x = 0; z.y = 0; z.z = 0; z.w = 0;
#pragma unroll
                for (int qi = 0; qi < nq; ++qi)
                    *(ushort4*)&Pw[(qi * 16 + fr) * 40 + 16 + 4 * hi] = z;
            }
            s16x8 vb0 = *(const s16x8*)&Vt[(0 * 16 + fr) * 136 + k0 + d0];
            s16x8 vb1 = *(const s16x8*)&Vt[(1 * 16 + fr) * 136 + k0 + d0];
#pragma unroll
            for (int qi = 0; qi < nq; ++qi) {
                s16x8 pa = *(const s16x8*)&Pw[(qi * 16 + fr) * 40 + d0];
                pvacc[qi][0] = __builtin_amdgcn_mfma_f32_16x16x32_bf16(pa, vb0, pvacc[qi][0], 0, 0, 0);
                pvacc[qi][1] = __builtin_amdgcn_mfma_f32_16x16x32_bf16(pa, vb1, pvacc[qi][1], 0, 0, 0);
            }
        }
#pragma unroll
        for (int qi = 0; qi < nq; ++qi) {
            float r2 = rs[qi] + __shfl_xor(rs[qi], 16);
            r2 += __shfl_xor(r2, 32);
            int lq = (qt0 + qi) * 16 + fr;
            if (hi == 0) {
                rsL[w][lq] = r2;
                if (lq < QQ) rowsum[((size_t)n * HH + h) * TB + rowbase + lq] = r2;
            }
        }
#pragma unroll
        for (int qi = 0; qi < nq; ++qi) {
            float iv[4];
#pragma unroll
            for (int r = 0; r < 4; ++r) {
                int lq = (qt0 + qi) * 16 + 4 * hi + r;
                iv[r] = 1.f / (rsL[w][lq < 112 ? lq : 111] + 1e-4f);
            }
#pragma unroll
            for (int dt = 0; dt < 2; ++dt) {
#pragma unroll
                for (int r = 0; r < 4; ++r) {
                    int lq = (qt0 + qi) * 16 + 4 * hi + r;
                    if (lq < QQ)
                        pv[((size_t)n * TB + rowbase + lq) * CC + h * DH + dt * 16 + fr] = pvacc[qi][dt][r] * iv[r];
                }
            }
        }
    }
}

// ---------------- fused out-projection + shift: 64 rows x 256 cols per block, 8 waves ----------------
__global__ __launch_bounds__(512)
void outshift(const float* __restrict__ pv, const float* __restrict__ ow,
              const float* __restrict__ ob, const float* __restrict__ cd,
              const float* __restrict__ cs, const float* __restrict__ rowsum,
              float* __restrict__ out_srm, float* __restrict__ out_smd) {
    __shared__ unsigned short Ahs[64][LDK], Als[64][LDK];
    __shared__ unsigned short Bhs[256][LDK], Bls[256][LDK];
    __shared__ float redcd[64][8], redcs[64][8];
    int tid = threadIdx.x;
    int lane = tid & 63, wave = tid >> 6;      // 8 waves, wave owns 32-col slice
    int wn = wave * 32;
    int fr = lane & 15, kb = lane >> 4;
    int bm = blockIdx.x * 64;
    int arow = tid >> 3, ak = (tid & 7) * 4;   // A: 8 threads/row, 4 k each
    int brow = tid >> 1, bk = (tid & 1) * 16;  // B: 2 threads/row, 16 k each
    const float* pA = pv + (size_t)(bm + arow) * CC + ak;
    const float* pB = ow + (size_t)brow * CC + bk;
    f32x4 acc[4][2];
#pragma unroll
    for (int mi = 0; mi < 4; ++mi)
#pragma unroll
        for (int ni = 0; ni < 2; ++ni)
            acc[mi][ni] = (f32x4){0.f, 0.f, 0.f, 0.f};
    for (int k0 = 0; k0 < CC; k0 += 32) {
        float4 av = *(const float4*)(pA + k0);
        float4 wv[4];
#pragma unroll
        for (int j = 0; j < 4; ++j) wv[j] = *(const float4*)(pB + k0 + 4 * j);
        __syncthreads();
        {
            ushort4 h4, l4;
            h4.x = f2bf(av.x); l4.x = f2bf(av.x - bf2f(h4.x));
            h4.y = f2bf(av.y); l4.y = f2bf(av.y - bf2f(h4.y));
            h4.z = f2bf(av.z); l4.z = f2bf(av.z - bf2f(h4.z));
            h4.w = f2bf(av.w); l4.w = f2bf(av.w - bf2f(h4.w));
            *(ushort4*)&Ahs[arow][ak] = h4;
            *(ushort4*)&Als[arow][ak] = l4;
        }
#pragma unroll
        for (int j = 0; j < 4; ++j) {
            ushort4 h4, l4;
            h4.x = f2bf(wv[j].x); l4.x = f2bf(wv[j].x - bf2f(h4.x));
            h4.y = f2bf(wv[j].y); l4.y = f2bf(wv[j].y - bf2f(h4.y));
            h4.z = f2bf(wv[j].z); l4.z = f2bf(wv[j].z - bf2f(h4.z));
            h4.w = f2bf(wv[j].w); l4.w = f2bf(wv[j].w - bf2f(h4.w));
            *(ushort4*)&Bhs[brow][bk + 4 * j] = h4;
            *(ushort4*)&Bls[brow][bk + 4 * j] = l4;
        }
        __syncthreads();
        s16x8 fah[4], fal[4], fbh[2], fbl[2];
#pragma unroll
        for (int mi = 0; mi < 4; ++mi) {
            fah[mi] = *(const s16x8*)&Ahs[mi * 16 + fr][kb * 8];
            fal[mi] = *(const s16x8*)&Als[mi * 16 + fr][kb * 8];
        }
#pragma unroll
        for (int ni = 0; ni < 2; ++ni) {
            fbh[ni] = *(const s16x8*)&Bhs[wn + ni * 16 + fr][kb * 8];
            fbl[ni] = *(const s16x8*)&Bls[wn + ni * 16 + fr][kb * 8];
        }
#pragma unroll
        for (int mi = 0; mi < 4; ++mi)
#pragma unroll
            for (int ni = 0; ni < 2; ++ni) {
                acc[mi][ni] = __builtin_amdgcn_mfma_f32_16x16x32_bf16(fah[mi], fbh[ni], acc[mi][ni], 0, 0, 0);
                acc[mi][ni] = __builtin_amdgcn_mfma_f32_16x16x32_bf16(fah[mi], fbl[ni], acc[mi][ni], 0, 0, 0);
                acc[mi][ni] = __builtin_amdgcn_mfma_f32_16x16x32_bf16(fal[mi], fbh[ni], acc[mi][ni], 0, 0, 0);
            }
    }
    // epilogue: per-row partial squared distances over this wave's 32 cols
#pragma unroll
    for (int mi = 0; mi < 4; ++mi) {
#pragma unroll
        for (int r = 0; r < 4; ++r) {
            int lm = mi * 16 + kb * 4 + r;
            int g = bm + lm;
            int n = g / TB;
            float pcd = 0.f, pcs = 0.f;
#pragma unroll
            for (int ni = 0; ni < 2; ++ni) {
                int col = wn + ni * 16 + fr;
                float val = acc[mi][ni][r] + ob[col];
                float d1 = val - cd[(size_t)n * CC + col];
                float d2 = val - cs[(size_t)n * CC + col];
                pcd += d1 * d1;
                pcs += d2 * d2;
            }
#pragma unroll
            for (int m2 = 1; m2 < 16; m2 <<= 1) {
                pcd += __shfl_xor(pcd, m2);
                pcs += __shfl_xor(pcs, m2);
            }
            if (fr == 0) {
                redcd[lm][wave] = pcd;
                redcs[lm][wave] = pcs;
            }
        }
    }
    __syncthreads();
    if (tid < 32) {
        int g = bm + 2 * tid;
        int n = g / TB;
        int rem = g % TB;
        int b = rem / TT;
        int t = rem % TT;
        int q = t >> 1;
        float c0 = 0.f, c1v = 0.f;
        for (int h = 0; h < HH; ++h) {
            c0  += rowsum[((size_t)n * HH + h) * TB + rem];
            c1v += rowsum[((size_t)n * HH + h) * TB + rem + 1];
        }
        int si = (c1v < c0) ? 1 : 0;
        int di = (c1v > c0) ? 1 : 0;
        int ld = 2 * tid + di, ls = 2 * tid + si;
        float dd = 0.f, ds = 0.f;
#pragma unroll
        for (int wv2 = 0; wv2 < 8; ++wv2) { dd += redcd[ld][wv2]; ds += redcs[ls][wv2]; }
        (b ? out_smd : out_srm)[n * QQ + q] = sqrtf(dd + 1e-12f) + sqrtf(ds + 1e-12f);
    }
}

extern "C" void kernel_launch(void* const* d_in, const int* in_sizes, int n_in,
                              void* d_out, int out_size, void* d_ws, size_t ws_size,
                              hipStream_t stream) {
    const float* hs_pair = (const float*)d_in[0];
    const float* ipw = (const float*)d_in[1];
    const float* ipb = (const float*)d_in[2];
    const float* ow  = (const float*)d_in[3];
    const float* ob  = (const float*)d_in[4];
    const float* hs = hs_pair + (size_t)5 * NB * QQ * CC;  // hs_pair[-1]

    float* ws = (float*)d_ws;
    size_t o = 0;
    float* kv_ext  = ws + o; o += (size_t)NB * SM * CC;
    float* P_all   = ws + o; o += (size_t)NB * SM * PW;
    float* Psum0   = ws + o; o += NB * CC;
    int*   far0    = (int*)(ws + o); o += NB;
    int*   far_rm  = (int*)(ws + o); o += NB * QQ;
    int*   far_md  = (int*)(ws + o); o += NB * QQ;
    float* cd      = ws + o; o += NB * CC;
    float* cs      = ws + o; o += NB * CC;
    float* pv      = ws + o; o += (size_t)NB * TB * CC;
    float* rowsum  = ws + o; o += (size_t)NB * HH * TB;
    float* attnB   = ws + o; o += (size_t)NB * HH * 2 * 104;
    float* rsB     = ws + o; o += (size_t)NB * HH * 2;
    float* pvB     = ws + o; o += (size_t)2 * NB * CC;
    if (o * sizeof(float) > ws_size) return;

    float* out = (float*)d_out;
    float* out_assign = out;
    float* out_sidx   = out + 6400;
    float* out_didx   = out + 6432;
    float* out_srm    = out + 6464;
    float* out_smd    = out + 9664;

    prep_kernel<<<NB, 256, 0, stream>>>(hs, far0, kv_ext);
    gemm_mfma<<<dim3((NB * SM + 127) / 128, PW / 128), 256, 0, stream>>>(
        kv_ext, ipw, ipb, P_all, NB * SM, PW);
    gramfar<<<NB, 256, 0, stream>>>(kv_ext, P_all, Psum0, far_rm, far_md);
    smhaB_scores<<<dim3(HH, NB), 64, 0, stream>>>(P_all, far0, attnB, rsB, pvB);
    smhaB_final<<<NB, 256, 0, stream>>>(attnB, rsB, pvB, ow, ob, out_assign,
                                        out_sidx, out_didx, cd, cs);
    attn_mfma<<<dim3(HH, NB), 256, 0, stream>>>(P_all, Psum0, far_rm, far_md, pv, rowsum);
    outshift<<<NB * TB / 64, 512, 0, stream>>>(pv, ow, ob, cd, cs, rowsum, out_srm, out_smd);
}

// Round 11
// 119.698 us; speedup vs baseline: 3.4962x; 1.1751x over previous
//
#include <hip/hip_runtime.h>
#include <math.h>

#define NB 32
#define QQ 100
#define CC 256
#define HH 8
#define DH 32
#define SM 101   // kv rows per batch (100 points + mean)
#define TT 200   // branch queries per batch
#define TB 400   // both branches
#define PW 768   // P_all row width (q|k|v projections)

typedef __attribute__((ext_vector_type(8))) short s16x8;
typedef __attribute__((ext_vector_type(4))) float f32x4;

// truncation split: hi = top 16 bits, lo = bf16-trunc of exact residual.
// (x - as_float(u & 0xffff0000)) is exact in f32 -> compensated 3-MFMA error ~2^-16.
__device__ inline unsigned short f2bft(float x) {
    return (unsigned short)(__float_as_uint(x) >> 16);
}
__device__ inline ushort2 tsplit(float x) {
    unsigned u = __float_as_uint(x);
    float l = x - __uint_as_float(u & 0xffff0000u);
    ushort2 r;
    r.x = (unsigned short)(u >> 16);
    r.y = (unsigned short)(__float_as_uint(l) >> 16);
    return r;
}

// ---------------- mean rows: meanF[n][c] = mean_q hs[n][q][c] ----------------
__global__ __launch_bounds__(256)
void meanrow_kernel(const float* __restrict__ hs, float* __restrict__ meanF) {
    int n = blockIdx.x, cb = blockIdx.y;
    int tid = threadIdx.x;
    int c = cb * 128 + (tid & 127), rh = tid >> 7;
    __shared__ float part[2][128];
    const float* h = hs + (size_t)n * QQ * CC;
    float s = 0.f;
    for (int q = rh * 50; q < rh * 50 + 50; ++q) s += h[(size_t)q * CC + c];
    part[rh][tid & 127] = s;
    __syncthreads();
    if (rh == 0) meanF[(size_t)n * CC + c] = (part[0][tid & 127] + part[1][tid & 127]) * 0.01f;
}

// ---------------- split-bf16 MFMA GEMM (A rows from hs/meanF): out = A @ W^T + bias ----------------
#define LDK 40
__global__ __launch_bounds__(256, 2)
void gemm_mfma(const float* __restrict__ hs, const float* __restrict__ meanF,
               const float* __restrict__ W_g, const float* __restrict__ bias,
               float* __restrict__ out, int M, int Nout) {
    __shared__ unsigned short Ahs[128][LDK], Als[128][LDK], Bhs[128][LDK], Bls[128][LDK];
    int tid = threadIdx.x;
    int lane = tid & 63, wave = tid >> 6;
    int wm = (wave >> 1) * 64, wn = (wave & 1) * 64;
    int fr = lane & 15, kb = lane >> 4;
    int bm = blockIdx.x * 128, bn = blockIdx.y * 128;
    int srow = tid >> 1, scol = (tid & 1) * 16;
    int am = bm + srow; if (am >= M) am = M - 1;
    int an = am / SM, ar = am - an * SM;
    const float* pA = (ar < QQ) ? hs + ((size_t)an * QQ + ar) * CC + scol
                                : meanF + (size_t)an * CC + scol;
    const float* pW = W_g + (size_t)(bn + srow) * CC + scol;
    f32x4 acc[4][4];
#pragma unroll
    for (int mi = 0; mi < 4; ++mi)
#pragma unroll
        for (int ni = 0; ni < 4; ++ni)
            acc[mi][ni] = (f32x4){0.f, 0.f, 0.f, 0.f};
    for (int k0 = 0; k0 < CC; k0 += 32) {
        float4 av[4], wv[4];
#pragma unroll
        for (int j = 0; j < 4; ++j) {
            av[j] = *(const float4*)(pA + k0 + 4 * j);
            wv[j] = *(const float4*)(pW + k0 + 4 * j);
        }
        __syncthreads();
#pragma unroll
        for (int j = 0; j < 4; ++j) {
            ushort2 sx = tsplit(av[j].x), sy = tsplit(av[j].y), sz = tsplit(av[j].z), sw = tsplit(av[j].w);
            ushort4 h4; h4.x = sx.x; h4.y = sy.x; h4.z = sz.x; h4.w = sw.x;
            ushort4 l4; l4.x = sx.y; l4.y = sy.y; l4.z = sz.y; l4.w = sw.y;
            *(ushort4*)&Ahs[srow][scol + 4 * j] = h4;
            *(ushort4*)&Als[srow][scol + 4 * j] = l4;
            ushort2 tx = tsplit(wv[j].x), ty = tsplit(wv[j].y), tz = tsplit(wv[j].z), tw = tsplit(wv[j].w);
            ushort4 wh4; wh4.x = tx.x; wh4.y = ty.x; wh4.z = tz.x; wh4.w = tw.x;
            ushort4 wl4; wl4.x = tx.y; wl4.y = ty.y; wl4.z = tz.y; wl4.w = tw.y;
            *(ushort4*)&Bhs[srow][scol + 4 * j] = wh4;
            *(ushort4*)&Bls[srow][scol + 4 * j] = wl4;
        }
        __syncthreads();
        s16x8 fah[4], fal[4], fbh[4], fbl[4];
#pragma unroll
        for (int mi = 0; mi < 4; ++mi) {
            fah[mi] = *(const s16x8*)&Ahs[wm + mi * 16 + fr][kb * 8];
            fal[mi] = *(const s16x8*)&Als[wm + mi * 16 + fr][kb * 8];
        }
#pragma unroll
        for (int ni = 0; ni < 4; ++ni) {
            fbh[ni] = *(const s16x8*)&Bhs[wn + ni * 16 + fr][kb * 8];
            fbl[ni] = *(const s16x8*)&Bls[wn + ni * 16 + fr][kb * 8];
        }
#pragma unroll
        for (int mi = 0; mi < 4; ++mi)
#pragma unroll
            for (int ni = 0; ni < 4; ++ni) {
                acc[mi][ni] = __builtin_amdgcn_mfma_f32_16x16x32_bf16(fah[mi], fbh[ni], acc[mi][ni], 0, 0, 0);
                acc[mi][ni] = __builtin_amdgcn_mfma_f32_16x16x32_bf16(fah[mi], fbl[ni], acc[mi][ni], 0, 0, 0);
                acc[mi][ni] = __builtin_amdgcn_mfma_f32_16x16x32_bf16(fal[mi], fbh[ni], acc[mi][ni], 0, 0, 0);
            }
    }
#pragma unroll
    for (int mi = 0; mi < 4; ++mi) {
        int mb = bm + wm + mi * 16 + kb * 4;
#pragma unroll
        for (int r = 0; r < 4; ++r) {
            int m = mb + r;
            if (m < M) {
#pragma unroll
                for (int ni = 0; ni < 4; ++ni) {
                    int col = bn + wn + ni * 16 + fr;
                    out[(size_t)m * Nout + col] = acc[mi][ni][r] + bias[col];
                }
            }
        }
    }
}

// ---------------- fused Gram + far0 + far_rm/md + psum, per batch, 512 threads ----------------
__global__ __launch_bounds__(512, 2)
void gramfar(const float* __restrict__ hs, const float* __restrict__ meanF,
             const float* __restrict__ P_all, float* __restrict__ Psum0,
             int* __restrict__ far0, int* __restrict__ far_rm,
             int* __restrict__ far_md) {
    int n = blockIdx.x;
    int tid = threadIdx.x;
    int wave = tid >> 6, lane = tid & 63;
    int fr = lane & 15, kb = lane >> 4;
    __shared__ float G[SM][104];
    __shared__ unsigned short Ah[112][LDK], Al[112][LDK];
    __shared__ float sumdot[104], meandot[104], norm[104];
    __shared__ float psumP[2][CC];
    // psum: Psum0[n][c] = sum_{q<100} P_all[n][q][c]
    {
        int c = tid & 255, half = tid >> 8;
        const float* basep = P_all + (size_t)n * SM * PW + c;
        float accp = 0.f;
        for (int q = half * 50; q < half * 50 + 50; ++q) accp += basep[(size_t)q * PW];
        psumP[half][c] = accp;
    }
    __syncthreads();
    if (tid < 256) Psum0[(size_t)n * CC + tid] = psumP[0][tid] + psumP[1][tid];
    const float* hb = hs + (size_t)n * QQ * CC;
    const float* mb = meanF + (size_t)n * CC;
    f32x4 acc[7];
#pragma unroll
    for (int u = 0; u < 7; ++u) acc[u] = (f32x4){0.f, 0.f, 0.f, 0.f};
    for (int k0 = 0; k0 < CC; k0 += 32) {
        __syncthreads();
        if (tid < 224) {
            int row = tid >> 1, kk = (tid & 1) * 16;
            float4 v[4];
            if (row < SM) {
                const float* rp = (row < QQ) ? hb + (size_t)row * CC : mb;
#pragma unroll
                for (int j = 0; j < 4; ++j) v[j] = *(const float4*)(rp + k0 + kk + 4 * j);
            } else {
#pragma unroll
                for (int j = 0; j < 4; ++j) v[j] = (float4){0.f, 0.f, 0.f, 0.f};
            }
#pragma unroll
            for (int j = 0; j < 4; ++j) {
                ushort2 sx = tsplit(v[j].x), sy = tsplit(v[j].y), sz = tsplit(v[j].z), sw = tsplit(v[j].w);
                ushort4 h4; h4.x = sx.x; h4.y = sy.x; h4.z = sz.x; h4.w = sw.x;
                ushort4 l4; l4.x = sx.y; l4.y = sy.y; l4.z = sz.y; l4.w = sw.y;
                *(ushort4*)&Ah[row][kk + 4 * j] = h4;
                *(ushort4*)&Al[row][kk + 4 * j] = l4;
            }
        }
        __syncthreads();
#pragma unroll
        for (int u = 0; u < 7; ++u) {
            int tl = wave + u * 8;
            if (tl < 49) {
                int ti = tl / 7, tj = tl % 7;
                s16x8 ah = *(const s16x8*)&Ah[ti * 16 + fr][kb * 8];
                s16x8 al = *(const s16x8*)&Al[ti * 16 + fr][kb * 8];
                s16x8 bh = *(const s16x8*)&Ah[tj * 16 + fr][kb * 8];
                s16x8 bl = *(const s16x8*)&Al[tj * 16 + fr][kb * 8];
                acc[u] = __builtin_amdgcn_mfma_f32_16x16x32_bf16(ah, bh, acc[u], 0, 0, 0);
                acc[u] = __builtin_amdgcn_mfma_f32_16x16x32_bf16(ah, bl, acc[u], 0, 0, 0);
                acc[u] = __builtin_amdgcn_mfma_f32_16x16x32_bf16(al, bh, acc[u], 0, 0, 0);
            }
        }
    }
    __syncthreads();
#pragma unroll
    for (int u = 0; u < 7; ++u) {
        int tl = wave + u * 8;
        if (tl < 49) {
            int ti = tl / 7, tj = tl % 7;
#pragma unroll
            for (int r = 0; r < 4; ++r) {
                int m = ti * 16 + kb * 4 + r;
                int col = tj * 16 + fr;
                if (m < SM && col < SM) G[m][col] = acc[u][r];
            }
        }
    }
    __syncthreads();
    for (int s = tid; s < SM; s += 512) {
        float a = 0.f;
        for (int q = 0; q < QQ; ++q) a += G[s][q];
        sumdot[s] = a; meandot[s] = G[s][QQ]; norm[s] = G[s][s];
    }
    __syncthreads();
    if (tid < QQ) {
        int q = tid, qm1 = (q + QQ - 1) % QQ;
        const float* gq = G[qm1];
        int best = -1; float bv = -1e30f;
        for (int s = 0; s < QQ; ++s) {
            if (s == qm1) continue;
            float val = norm[s] - (sumdot[s] - gq[s]) * (2.f / 99.f);
            if (val > bv) { bv = val; best = s; }
        }
        far_rm[n * QQ + q] = best;
    } else if (tid >= 128 && tid < 128 + QQ) {
        int q = tid - 128, qm1 = (q + QQ - 1) % QQ;
        const float* gq = G[qm1];
        int best = -1; float bv = -1e30f;
        for (int s = 0; s < SM; ++s) {
            if (s == qm1) continue;
            float val = norm[s] - (sumdot[s] - gq[s] + meandot[s]) * (2.f / 100.f);
            if (val > bv) { bv = val; best = s; }
        }
        far_md[n * QQ + q] = best;
    } else if (tid == 256) {
        // stage-A far point: argmax_q ||c1 - kv_q||^2 = argmax norm[q] - 0.02*sumdot[q]
        int best = 0; float bv = -1e30f;
        for (int q = 0; q < QQ; ++q) {
            float val = norm[q] - 0.02f * sumdot[q];
            if (val > bv) { bv = val; best = q; }
        }
        far0[n] = best;
    }
}

// ---------------- stage B fused: scores + PV + assign + si/di + out-proj + cd/cs ----------------
__global__ __launch_bounds__(512)
void smhaB_kernel(const float* __restrict__ P_all, const int* __restrict__ far0,
                  const float* __restrict__ ow, const float* __restrict__ ob,
                  float* __restrict__ out_assign, float* __restrict__ out_sidx,
                  float* __restrict__ out_didx, float* __restrict__ cd,
                  float* __restrict__ cs) {
    int n = blockIdx.x;
    int tid = threadIdx.x;
    int h = tid >> 6, lane = tid & 63;
    __shared__ float at[HH][2][104];
    __shared__ float qsh[HH][2][DH];
    __shared__ float rsh[HH][2];
    __shared__ float pvs[2][CC];
    __shared__ int sdi[2];
    const float* base = P_all + (size_t)n * SM * PW;
    if (lane < 2 * DH) {
        int t = lane >> 5, d = lane & 31;
        int row = t ? far0[n] : QQ;
        qsh[h][t][d] = base[(size_t)row * PW + h * DH + d];
    }
    const float scl = 0.17677669529663687f;
    float p0 = 0.f, p1 = 0.f;
    for (int s = lane; s < 104; s += 64) {
        float a0v = 0.f, a1v = 0.f;
        if (s < QQ) {
            const float4* kr = (const float4*)(base + (size_t)s * PW + CC + h * DH);
            float d0 = 0.f, d1 = 0.f;
#pragma unroll
            for (int j = 0; j < 8; ++j) {
                float4 k4 = kr[j];
                d0 += qsh[h][0][4 * j] * k4.x + qsh[h][0][4 * j + 1] * k4.y
                    + qsh[h][0][4 * j + 2] * k4.z + qsh[h][0][4 * j + 3] * k4.w;
                d1 += qsh[h][1][4 * j] * k4.x + qsh[h][1][4 * j + 1] * k4.y
                    + qsh[h][1][4 * j + 2] * k4.z + qsh[h][1][4 * j + 3] * k4.w;
            }
            a0v = 1.f / (1.f + __expf(-d0 * scl));
            a1v = 1.f / (1.f + __expf(-d1 * scl));
            p0 += a0v; p1 += a1v;
        }
        at[h][0][s] = a0v;
        at[h][1][s] = a1v;
    }
#pragma unroll
    for (int off = 32; off > 0; off >>= 1) {
        p0 += __shfl_down(p0, off);
        p1 += __shfl_down(p1, off);
    }
    if (lane == 0) { rsh[h][0] = p0; rsh[h][1] = p1; }
    // PV for this head (wave-private data)
    {
        int t = lane >> 5, d = lane & 31;
        float rv = (t ? p1 : p0);
        rv = __shfl(rv, 0);   // broadcast wave-reduced sums
        float inv = 1.f / (rv + 1e-4f);
        float acc = 0.f;
        const float* vb = base + 2 * CC + h * DH + d;
        for (int s = 0; s < QQ; ++s) acc += at[h][t][s] * vb[(size_t)s * PW];
        pvs[t][h * DH + d] = acc * inv;
    }
    __syncthreads();
    if (tid == 0) {
        float c0 = 0.f, c1v = 0.f;
        for (int h2 = 0; h2 < HH; ++h2) { c0 += rsh[h2][0]; c1v += rsh[h2][1]; }
        int si = (c1v < c0) ? 1 : 0;
        int di = (c1v > c0) ? 1 : 0;
        sdi[0] = si; sdi[1] = di;
        out_sidx[n] = (float)si;
        out_didx[n] = (float)di;
    }
    __syncthreads();
    if (tid < 2 * QQ) {
        int t = tid / QQ, s = tid % QQ;
        float m = 0.f;
#pragma unroll
        for (int h2 = 0; h2 < HH; ++h2) m += at[h2][t][s];
        out_assign[(size_t)n * 2 * QQ + tid] = m * 0.125f;
    }
    {
        int t = tid >> 8, c = tid & 255;
        const float4* wr4 = (const float4*)(ow + (size_t)c * CC);
        const float4* pz = (const float4*)&pvs[t][0];
        float a = ob[c];
#pragma unroll 8
        for (int k = 0; k < 64; ++k) {
            float4 w = wr4[k], x = pz[k];
            a += x.x * w.x + x.y * w.y + x.z * w.z + x.w * w.w;
        }
        if (t == sdi[1]) cd[(size_t)n * CC + c] = a;
        if (t == sdi[0]) cs[(size_t)n * CC + c] = a;
    }
}

// ---------------- MFMA attention (both branches): one block per (n,h), 4 waves ----------------
__global__ __launch_bounds__(256)
void attn_mfma(const float* __restrict__ P_all, const float* __restrict__ Psum0,
               const int* __restrict__ far_rm, const int* __restrict__ far_md,
               float* __restrict__ pv, float* __restrict__ rowsum) {
    int h = blockIdx.x, n = blockIdx.y;
    int tid = threadIdx.x;
    int w = tid >> 6, lane = tid & 63;
    int fr = lane & 15, hi = lane >> 4;
    int d0 = hi * 8;
    __shared__ unsigned short Kh[112 * 40];
    __shared__ unsigned short Kl[112 * 40];
    __shared__ unsigned short Vt[32 * 136];
    __shared__ unsigned short Pb[4][64 * 40];
    __shared__ float rsL[4][112];
    const float* base = P_all + (size_t)n * SM * PW;
    for (int idx = tid; idx < 112 * 8; idx += 256) {
        int key = idx >> 3, d4 = (idx & 7) * 4;
        float4 kv = {0.f, 0.f, 0.f, 0.f}, vv = {0.f, 0.f, 0.f, 0.f};
        if (key < SM) {
            kv = *(const float4*)&base[(size_t)key * PW + CC + h * DH + d4];
            vv = *(const float4*)&base[(size_t)key * PW + 2 * CC + h * DH + d4];
        }
        ushort2 sx = tsplit(kv.x), sy = tsplit(kv.y), sz = tsplit(kv.z), sw = tsplit(kv.w);
        ushort4 h4; h4.x = sx.x; h4.y = sy.x; h4.z = sz.x; h4.w = sw.x;
        ushort4 l4; l4.x = sx.y; l4.y = sy.y; l4.z = sz.y; l4.w = sw.y;
        *(ushort4*)&Kh[key * 40 + d4] = h4;
        *(ushort4*)&Kl[key * 40 + d4] = l4;
        Vt[(d4 + 0) * 136 + key] = f2bft(vv.x);
        Vt[(d4 + 1) * 136 + key] = f2bft(vv.y);
        Vt[(d4 + 2) * 136 + key] = f2bft(vv.z);
        Vt[(d4 + 3) * 136 + key] = f2bft(vv.w);
    }
    for (int idx = tid; idx < 32 * 16; idx += 256) {
        int d = idx >> 4, key = 112 + (idx & 15);
        Vt[d * 136 + key] = 0;
    }
    __syncthreads();
    const float* Psum0n = Psum0 + n * CC;
    int rowbase = w * 100;
    unsigned short* Pw = Pb[w];
    const float scl = 0.17677669529663687f;
#pragma unroll
    for (int qg = 0; qg < 2; ++qg) {
        const int nq = qg ? 3 : 4;
        const int qt0 = qg * 4;
        s16x8 qh[4], ql[4];
        int mk[4], sb[4];
#pragma unroll
        for (int qi = 0; qi < 4; ++qi) {
            if (qi >= nq) { mk[qi] = -1; sb[qi] = 0; continue; }
            int lq = (qt0 + qi) * 16 + fr;
            int row = rowbase + (lq < QQ ? lq : QQ - 1);
            int b = row >= TT;
            int t = row - b * TT;
            int q = t >> 1;
            mk[qi] = q; sb[qi] = b ? SM : QQ;
            float qv[8];
            if (t & 1) {
                int f = (b ? far_md : far_rm)[n * QQ + q];
                const float4* pr = (const float4*)(base + (size_t)f * PW + h * DH + d0);
                float4 v0 = pr[0], v1 = pr[1];
                qv[0] = v0.x; qv[1] = v0.y; qv[2] = v0.z; qv[3] = v0.w;
                qv[4] = v1.x; qv[5] = v1.y; qv[6] = v1.z; qv[7] = v1.w;
            } else {
                int qm1 = (q + QQ - 1) % QQ;
                const float4* ps = (const float4*)(Psum0n + h * DH + d0);
                const float4* pm = (const float4*)(base + (size_t)qm1 * PW + h * DH + d0);
                const float4* pmn = (const float4*)(base + (size_t)QQ * PW + h * DH + d0);
                float invd = b ? 0.01f : (1.f / 99.f);
                float bb = b ? 1.f : 0.f;
                float4 a0 = ps[0], c0 = pm[0], m0 = pmn[0];
                float4 a1 = ps[1], c1 = pm[1], m1 = pmn[1];
                qv[0] = (a0.x - c0.x + bb * m0.x) * invd;
                qv[1] = (a0.y - c0.y + bb * m0.y) * invd;
                qv[2] = (a0.z - c0.z + bb * m0.z) * invd;
                qv[3] = (a0.w - c0.w + bb * m0.w) * invd;
                qv[4] = (a1.x - c1.x + bb * m1.x) * invd;
                qv[5] = (a1.y - c1.y + bb * m1.y) * invd;
                qv[6] = (a1.z - c1.z + bb * m1.z) * invd;
                qv[7] = (a1.w - c1.w + bb * m1.w) * invd;
            }
            s16x8 qhv, qlv;
#pragma unroll
            for (int j = 0; j < 8; ++j) {
                ushort2 sp = tsplit(qv[j]);
                qhv[j] = (short)sp.x;
                qlv[j] = (short)sp.y;
            }
            qh[qi] = qhv; ql[qi] = qlv;
        }
        f32x4 pvacc[4][2];
#pragma unroll
        for (int qi = 0; qi < 4; ++qi) {
            pvacc[qi][0] = (f32x4){0.f, 0.f, 0.f, 0.f};
            pvacc[qi][1] = (f32x4){0.f, 0.f, 0.f, 0.f};
        }
        float rs[4] = {0.f, 0.f, 0.f, 0.f};
#pragma unroll
        for (int kc = 0; kc < 4; ++kc) {
            int k0 = kc * 32;
            {
                s16x8 ah = *(const s16x8*)&Kh[(k0 + fr) * 40 + d0];
                s16x8 al = *(const s16x8*)&Kl[(k0 + fr) * 40 + d0];
#pragma unroll
                for (int qi = 0; qi < nq; ++qi) {
                    f32x4 s0 = (f32x4){0.f, 0.f, 0.f, 0.f};
                    s0 = __builtin_amdgcn_mfma_f32_16x16x32_bf16(ah, qh[qi], s0, 0, 0, 0);
                    s0 = __builtin_amdgcn_mfma_f32_16x16x32_bf16(ah, ql[qi], s0, 0, 0, 0);
                    s0 = __builtin_amdgcn_mfma_f32_16x16x32_bf16(al, qh[qi], s0, 0, 0, 0);
                    int kb0 = k0 + 4 * hi;
                    float a0 = (kb0 + 0 < sb[qi] && kb0 + 0 != mk[qi]) ? 1.f / (1.f + __expf(-s0[0] * scl)) : 0.f;
                    float a1 = (kb0 + 1 < sb[qi] && kb0 + 1 != mk[qi]) ? 1.f / (1.f + __expf(-s0[1] * scl)) : 0.f;
                    float a2 = (kb0 + 2 < sb[qi] && kb0 + 2 != mk[qi]) ? 1.f / (1.f + __expf(-s0[2] * scl)) : 0.f;
                    float a3 = (kb0 + 3 < sb[qi] && kb0 + 3 != mk[qi]) ? 1.f / (1.f + __expf(-s0[3] * scl)) : 0.f;
                    rs[qi] += a0 + a1 + a2 + a3;
                    ushort4 p4;
                    p4.x = f2bft(a0); p4.y = f2bft(a1); p4.z = f2bft(a2); p4.w = f2bft(a3);
                    *(ushort4*)&Pw[(qi * 16 + fr) * 40 + 4 * hi] = p4;
                }
            }
            if (kc < 3) {
                s16x8 ah = *(const s16x8*)&Kh[(k0 + 16 + fr) * 40 + d0];
                s16x8 al = *(const s16x8*)&Kl[(k0 + 16 + fr) * 40 + d0];
#pragma unroll
                for (int qi = 0; qi < nq; ++qi) {
                    f32x4 s1 = (f32x4){0.f, 0.f, 0.f, 0.f};
                    s1 = __builtin_amdgcn_mfma_f32_16x16x32_bf16(ah, qh[qi], s1, 0, 0, 0);
                    s1 = __builtin_amdgcn_mfma_f32_16x16x32_bf16(ah, ql[qi], s1, 0, 0, 0);
                    s1 = __builtin_amdgcn_mfma_f32_16x16x32_bf16(al, qh[qi], s1, 0, 0, 0);
                    int kb1 = k0 + 16 + 4 * hi;
                    float a0 = (kb1 + 0 < sb[qi] && kb1 + 0 != mk[qi]) ? 1.f / (1.f + __expf(-s1[0] * scl)) : 0.f;
                    float a1 = (kb1 + 1 < sb[qi] && kb1 + 1 != mk[qi]) ? 1.f / (1.f + __expf(-s1[1] * scl)) : 0.f;
                    float a2 = (kb1 + 2 < sb[qi] && kb1 + 2 != mk[qi]) ? 1.f / (1.f + __expf(-s1[2] * scl)) : 0.f;
                    float a3 = (kb1 + 3 < sb[qi] && kb1 + 3 != mk[qi]) ? 1.f / (1.f + __expf(-s1[3] * scl)) : 0.f;
                    rs[qi] += a0 + a1 + a2 + a3;
                    ushort4 p4;
                    p4.x = f2bft(a0); p4.y = f2bft(a1); p4.z = f2bft(a2); p4.w = f2bft(a3);
                    *(ushort4*)&Pw[(qi * 16 + fr) * 40 + 16 + 4 * hi] = p4;
                }
            } else {
                ushort4 z; z.x = 0; z.y = 0; z.z = 0; z.w = 0;
#pragma unroll
                for (int qi = 0; qi < nq; ++qi)
                    *(ushort4*)&Pw[(qi * 16 + fr) * 40 + 16 + 4 * hi] = z;
            }
            s16x8 vb0 = *(const s16x8*)&Vt[(0 * 16 + fr) * 136 + k0 + d0];
            s16x8 vb1 = *(const s16x8*)&Vt[(1 * 16 + fr) * 136 + k0 + d0];
#pragma unroll
            for (int qi = 0; qi < nq; ++qi) {
                s16x8 pa = *(const s16x8*)&Pw[(qi * 16 + fr) * 40 + d0];
                pvacc[qi][0] = __builtin_amdgcn_mfma_f32_16x16x32_bf16(pa, vb0, pvacc[qi][0], 0, 0, 0);
                pvacc[qi][1] = __builtin_amdgcn_mfma_f32_16x16x32_bf16(pa, vb1, pvacc[qi][1], 0, 0, 0);
            }
        }
#pragma unroll
        for (int qi = 0; qi < nq; ++qi) {
            float r2 = rs[qi] + __shfl_xor(rs[qi], 16);
            r2 += __shfl_xor(r2, 32);
            int lq = (qt0 + qi) * 16 + fr;
            if (hi == 0) {
                rsL[w][lq] = r2;
                if (lq < QQ) rowsum[((size_t)n * HH + h) * TB + rowbase + lq] = r2;
            }
        }
#pragma unroll
        for (int qi = 0; qi < nq; ++qi) {
            float iv[4];
#pragma unroll
            for (int r = 0; r < 4; ++r) {
                int lq = (qt0 + qi) * 16 + 4 * hi + r;
                iv[r] = 1.f / (rsL[w][lq < 112 ? lq : 111] + 1e-4f);
            }
#pragma unroll
            for (int dt = 0; dt < 2; ++dt) {
#pragma unroll
                for (int r = 0; r < 4; ++r) {
                    int lq = (qt0 + qi) * 16 + 4 * hi + r;
                    if (lq < QQ)
                        pv[((size_t)n * TB + rowbase + lq) * CC + h * DH + dt * 16 + fr] = pvacc[qi][dt][r] * iv[r];
                }
            }
        }
    }
}

// ---------------- fused out-projection + shift: 64 rows x 256 cols per block, 8 waves ----------------
__global__ __launch_bounds__(512)
void outshift(const float* __restrict__ pv, const float* __restrict__ ow,
              const float* __restrict__ ob, const float* __restrict__ cd,
              const float* __restrict__ cs, const float* __restrict__ rowsum,
              float* __restrict__ out_srm, float* __restrict__ out_smd) {
    __shared__ unsigned short Ahs[64][LDK], Als[64][LDK];
    __shared__ unsigned short Bhs[256][LDK], Bls[256][LDK];
    __shared__ float redcd[64][8], redcs[64][8];
    int tid = threadIdx.x;
    int lane = tid & 63, wave = tid >> 6;
    int wn = wave * 32;
    int fr = lane & 15, kb = lane >> 4;
    int bm = blockIdx.x * 64;
    int arow = tid >> 3, ak = (tid & 7) * 4;
    int brow = tid >> 1, bk = (tid & 1) * 16;
    const float* pA = pv + (size_t)(bm + arow) * CC + ak;
    const float* pB = ow + (size_t)brow * CC + bk;
    f32x4 acc[4][2];
#pragma unroll
    for (int mi = 0; mi < 4; ++mi)
#pragma unroll
        for (int ni = 0; ni < 2; ++ni)
            acc[mi][ni] = (f32x4){0.f, 0.f, 0.f, 0.f};
    for (int k0 = 0; k0 < CC; k0 += 32) {
        float4 av = *(const float4*)(pA + k0);
        float4 wv[4];
#pragma unroll
        for (int j = 0; j < 4; ++j) wv[j] = *(const float4*)(pB + k0 + 4 * j);
        __syncthreads();
        {
            ushort2 sx = tsplit(av.x), sy = tsplit(av.y), sz = tsplit(av.z), sw = tsplit(av.w);
            ushort4 h4; h4.x = sx.x; h4.y = sy.x; h4.z = sz.x; h4.w = sw.x;
            ushort4 l4; l4.x = sx.y; l4.y = sy.y; l4.z = sz.y; l4.w = sw.y;
            *(ushort4*)&Ahs[arow][ak] = h4;
            *(ushort4*)&Als[arow][ak] = l4;
        }
#pragma unroll
        for (int j = 0; j < 4; ++j) {
            ushort2 sx = tsplit(wv[j].x), sy = tsplit(wv[j].y), sz = tsplit(wv[j].z), sw = tsplit(wv[j].w);
            ushort4 h4; h4.x = sx.x; h4.y = sy.x; h4.z = sz.x; h4.w = sw.x;
            ushort4 l4; l4.x = sx.y; l4.y = sy.y; l4.z = sz.y; l4.w = sw.y;
            *(ushort4*)&Bhs[brow][bk + 4 * j] = h4;
            *(ushort4*)&Bls[brow][bk + 4 * j] = l4;
        }
        __syncthreads();
        s16x8 fah[4], fal[4], fbh[2], fbl[2];
#pragma unroll
        for (int mi = 0; mi < 4; ++mi) {
            fah[mi] = *(const s16x8*)&Ahs[mi * 16 + fr][kb * 8];
            fal[mi] = *(const s16x8*)&Als[mi * 16 + fr][kb * 8];
        }
#pragma unroll
        for (int ni = 0; ni < 2; ++ni) {
            fbh[ni] = *(const s16x8*)&Bhs[wn + ni * 16 + fr][kb * 8];
            fbl[ni] = *(const s16x8*)&Bls[wn + ni * 16 + fr][kb * 8];
        }
#pragma unroll
        for (int mi = 0; mi < 4; ++mi)
#pragma unroll
            for (int ni = 0; ni < 2; ++ni) {
                acc[mi][ni] = __builtin_amdgcn_mfma_f32_16x16x32_bf16(fah[mi], fbh[ni], acc[mi][ni], 0, 0, 0);
                acc[mi][ni] = __builtin_amdgcn_mfma_f32_16x16x32_bf16(fah[mi], fbl[ni], acc[mi][ni], 0, 0, 0);
                acc[mi][ni] = __builtin_amdgcn_mfma_f32_16x16x32_bf16(fal[mi], fbh[ni], acc[mi][ni], 0, 0, 0);
            }
    }
#pragma unroll
    for (int mi = 0; mi < 4; ++mi) {
#pragma unroll
        for (int r = 0; r < 4; ++r) {
            int lm = mi * 16 + kb * 4 + r;
            int g = bm + lm;
            int n = g / TB;
            float pcd = 0.f, pcs = 0.f;
#pragma unroll
            for (int ni = 0; ni < 2; ++ni) {
                int col = wn + ni * 16 + fr;
                float val = acc[mi][ni][r] + ob[col];
                float d1 = val - cd[(size_t)n * CC + col];
                float d2 = val - cs[(size_t)n * CC + col];
                pcd += d1 * d1;
                pcs += d2 * d2;
            }
#pragma unroll
            for (int m2 = 1; m2 < 16; m2 <<= 1) {
                pcd += __shfl_xor(pcd, m2);
                pcs += __shfl_xor(pcs, m2);
            }
            if (fr == 0) {
                redcd[lm][wave] = pcd;
                redcs[lm][wave] = pcs;
            }
        }
    }
    __syncthreads();
    if (tid < 32) {
        int g = bm + 2 * tid;
        int n = g / TB;
        int rem = g % TB;
        int b = rem / TT;
        int t = rem % TT;
        int q = t >> 1;
        float c0 = 0.f, c1v = 0.f;
        for (int h = 0; h < HH; ++h) {
            c0  += rowsum[((size_t)n * HH + h) * TB + rem];
            c1v += rowsum[((size_t)n * HH + h) * TB + rem + 1];
        }
        int si = (c1v < c0) ? 1 : 0;
        int di = (c1v > c0) ? 1 : 0;
        int ld = 2 * tid + di, ls = 2 * tid + si;
        float dd = 0.f, ds = 0.f;
#pragma unroll
        for (int wv2 = 0; wv2 < 8; ++wv2) { dd += redcd[ld][wv2]; ds += redcs[ls][wv2]; }
        (b ? out_smd : out_srm)[n * QQ + q] = sqrtf(dd + 1e-12f) + sqrtf(ds + 1e-12f);
    }
}

extern "C" void kernel_launch(void* const* d_in, const int* in_sizes, int n_in,
                              void* d_out, int out_size, void* d_ws, size_t ws_size,
                              hipStream_t stream) {
    const float* hs_pair = (const float*)d_in[0];
    const float* ipw = (const float*)d_in[1];
    const float* ipb = (const float*)d_in[2];
    const float* ow  = (const float*)d_in[3];
    const float* ob  = (const float*)d_in[4];
    const float* hs = hs_pair + (size_t)5 * NB * QQ * CC;  // hs_pair[-1]

    float* ws = (float*)d_ws;
    size_t o = 0;
    float* meanF   = ws + o; o += NB * CC;
    float* P_all   = ws + o; o += (size_t)NB * SM * PW;
    float* Psum0   = ws + o; o += NB * CC;
    int*   far0    = (int*)(ws + o); o += NB;
    int*   far_rm  = (int*)(ws + o); o += NB * QQ;
    int*   far_md  = (int*)(ws + o); o += NB * QQ;
    float* cd      = ws + o; o += NB * CC;
    float* cs      = ws + o; o += NB * CC;
    float* pv      = ws + o; o += (size_t)NB * TB * CC;
    float* rowsum  = ws + o; o += (size_t)NB * HH * TB;
    if (o * sizeof(float) > ws_size) return;

    float* out = (float*)d_out;
    float* out_assign = out;
    float* out_sidx   = out + 6400;
    float* out_didx   = out + 6432;
    float* out_srm    = out + 6464;
    float* out_smd    = out + 9664;

    meanrow_kernel<<<dim3(NB, 2), 256, 0, stream>>>(hs, meanF);
    gemm_mfma<<<dim3((NB * SM + 127) / 128, PW / 128), 256, 0, stream>>>(
        hs, meanF, ipw, ipb, P_all, NB * SM, PW);
    gramfar<<<NB, 512, 0, stream>>>(hs, meanF, P_all, Psum0, far0, far_rm, far_md);
    smhaB_kernel<<<NB, 512, 0, stream>>>(P_all, far0, ow, ob, out_assign,
                                         out_sidx, out_didx, cd, cs);
    attn_mfma<<<dim3(HH, NB), 256, 0, stream>>>(P_all, Psum0, far_rm, far_md, pv, rowsum);
    outshift<<<NB * TB / 64, 512, 0, stream>>>(pv, ow, ob, cd, cs, rowsum, out_srm, out_smd);
}

// Round 12
// 116.823 us; speedup vs baseline: 3.5822x; 1.0246x over previous
//
#include <hip/hip_runtime.h>
#include <math.h>

#define NB 32
#define QQ 100
#define CC 256
#define HH 8
#define DH 32
#define SM 101   // kv rows per batch (100 points + mean)
#define TT 200   // branch queries per batch
#define TB 400   // both branches
#define PW 768   // P_all row width (q|k|v projections)

typedef __attribute__((ext_vector_type(8))) short s16x8;
typedef __attribute__((ext_vector_type(4))) float f32x4;

// truncation split: hi = top 16 bits, lo = bf16-trunc of exact residual (compensated, bias-free pair)
__device__ inline ushort2 tsplit(float x) {
    unsigned u = __float_as_uint(x);
    float l = x - __uint_as_float(u & 0xffff0000u);
    ushort2 r;
    r.x = (unsigned short)(u >> 16);
    r.y = (unsigned short)(__float_as_uint(l) >> 16);
    return r;
}
// RNE bf16 (unbiased) for single-bf16 quantities (P, V)
__device__ inline unsigned short f2bf(float x) {
    unsigned u = __float_as_uint(x);
    return (unsigned short)((u + 0x7fffu + ((u >> 16) & 1u)) >> 16);
}

// ---------------- mean rows: meanF[n][c] = mean_q hs[n][q][c] ----------------
__global__ __launch_bounds__(256)
void meanrow_kernel(const float* __restrict__ hs, float* __restrict__ meanF) {
    int n = blockIdx.x, cb = blockIdx.y;
    int tid = threadIdx.x;
    int c = cb * 128 + (tid & 127), rh = tid >> 7;
    __shared__ float part[2][128];
    const float* h = hs + (size_t)n * QQ * CC;
    float s = 0.f;
    for (int q = rh * 50; q < rh * 50 + 50; ++q) s += h[(size_t)q * CC + c];
    part[rh][tid & 127] = s;
    __syncthreads();
    if (rh == 0) meanF[(size_t)n * CC + c] = (part[0][tid & 127] + part[1][tid & 127]) * 0.01f;
}

// ---------------- split-bf16 MFMA GEMM (A rows from hs/meanF): out = A @ W^T + bias ----------------
#define LDK 40
__global__ __launch_bounds__(256, 2)
void gemm_mfma(const float* __restrict__ hs, const float* __restrict__ meanF,
               const float* __restrict__ W_g, const float* __restrict__ bias,
               float* __restrict__ out, int M, int Nout) {
    __shared__ unsigned short Ahs[128][LDK], Als[128][LDK], Bhs[128][LDK], Bls[128][LDK];
    int tid = threadIdx.x;
    int lane = tid & 63, wave = tid >> 6;
    int wm = (wave >> 1) * 64, wn = (wave & 1) * 64;
    int fr = lane & 15, kb = lane >> 4;
    int bm = blockIdx.x * 128, bn = blockIdx.y * 128;
    int srow = tid >> 1, scol = (tid & 1) * 16;
    int am = bm + srow; if (am >= M) am = M - 1;
    int an = am / SM, ar = am - an * SM;
    const float* pA = (ar < QQ) ? hs + ((size_t)an * QQ + ar) * CC + scol
                                : meanF + (size_t)an * CC + scol;
    const float* pW = W_g + (size_t)(bn + srow) * CC + scol;
    f32x4 acc[4][4];
#pragma unroll
    for (int mi = 0; mi < 4; ++mi)
#pragma unroll
        for (int ni = 0; ni < 4; ++ni)
            acc[mi][ni] = (f32x4){0.f, 0.f, 0.f, 0.f};
    for (int k0 = 0; k0 < CC; k0 += 32) {
        float4 av[4], wv[4];
#pragma unroll
        for (int j = 0; j < 4; ++j) {
            av[j] = *(const float4*)(pA + k0 + 4 * j);
            wv[j] = *(const float4*)(pW + k0 + 4 * j);
        }
        __syncthreads();
#pragma unroll
        for (int j = 0; j < 4; ++j) {
            ushort2 sx = tsplit(av[j].x), sy = tsplit(av[j].y), sz = tsplit(av[j].z), sw = tsplit(av[j].w);
            ushort4 h4; h4.x = sx.x; h4.y = sy.x; h4.z = sz.x; h4.w = sw.x;
            ushort4 l4; l4.x = sx.y; l4.y = sy.y; l4.z = sz.y; l4.w = sw.y;
            *(ushort4*)&Ahs[srow][scol + 4 * j] = h4;
            *(ushort4*)&Als[srow][scol + 4 * j] = l4;
            ushort2 tx = tsplit(wv[j].x), ty = tsplit(wv[j].y), tz = tsplit(wv[j].z), tw = tsplit(wv[j].w);
            ushort4 wh4; wh4.x = tx.x; wh4.y = ty.x; wh4.z = tz.x; wh4.w = tw.x;
            ushort4 wl4; wl4.x = tx.y; wl4.y = ty.y; wl4.z = tz.y; wl4.w = tw.y;
            *(ushort4*)&Bhs[srow][scol + 4 * j] = wh4;
            *(ushort4*)&Bls[srow][scol + 4 * j] = wl4;
        }
        __syncthreads();
        s16x8 fah[4], fal[4], fbh[4], fbl[4];
#pragma unroll
        for (int mi = 0; mi < 4; ++mi) {
            fah[mi] = *(const s16x8*)&Ahs[wm + mi * 16 + fr][kb * 8];
            fal[mi] = *(const s16x8*)&Als[wm + mi * 16 + fr][kb * 8];
        }
#pragma unroll
        for (int ni = 0; ni < 4; ++ni) {
            fbh[ni] = *(const s16x8*)&Bhs[wn + ni * 16 + fr][kb * 8];
            fbl[ni] = *(const s16x8*)&Bls[wn + ni * 16 + fr][kb * 8];
        }
#pragma unroll
        for (int mi = 0; mi < 4; ++mi)
#pragma unroll
            for (int ni = 0; ni < 4; ++ni) {
                acc[mi][ni] = __builtin_amdgcn_mfma_f32_16x16x32_bf16(fah[mi], fbh[ni], acc[mi][ni], 0, 0, 0);
                acc[mi][ni] = __builtin_amdgcn_mfma_f32_16x16x32_bf16(fah[mi], fbl[ni], acc[mi][ni], 0, 0, 0);
                acc[mi][ni] = __builtin_amdgcn_mfma_f32_16x16x32_bf16(fal[mi], fbh[ni], acc[mi][ni], 0, 0, 0);
            }
    }
#pragma unroll
    for (int mi = 0; mi < 4; ++mi) {
        int mb = bm + wm + mi * 16 + kb * 4;
#pragma unroll
        for (int r = 0; r < 4; ++r) {
            int m = mb + r;
            if (m < M) {
#pragma unroll
                for (int ni = 0; ni < 4; ++ni) {
                    int col = bn + wn + ni * 16 + fr;
                    out[(size_t)m * Nout + col] = acc[mi][ni][r] + bias[col];
                }
            }
        }
    }
}

// ---------------- Gram strip: rows [ti*16, ti*16+16) x all 104 cols of G[n] ----------------
__global__ __launch_bounds__(256, 2)
void gram_strip(const float* __restrict__ hs, const float* __restrict__ meanF,
                float* __restrict__ G) {
    int ti = blockIdx.x, n = blockIdx.y;
    int tid = threadIdx.x;
    int wave = tid >> 6, lane = tid & 63;
    int fr = lane & 15, kb = lane >> 4;
    __shared__ unsigned short Ah[112][LDK], Al[112][LDK];
    const float* hb = hs + (size_t)n * QQ * CC;
    const float* mb = meanF + (size_t)n * CC;
    f32x4 acc[2];
    acc[0] = (f32x4){0.f, 0.f, 0.f, 0.f};
    acc[1] = (f32x4){0.f, 0.f, 0.f, 0.f};
    int tj0 = wave, tj1 = wave + 4;   // wave 3: tj1=7 invalid
    for (int k0 = 0; k0 < CC; k0 += 32) {
        __syncthreads();
        if (tid < 224) {
            int row = tid >> 1, kk = (tid & 1) * 16;
            float4 v[4];
            if (row < SM) {
                const float* rp = (row < QQ) ? hb + (size_t)row * CC : mb;
#pragma unroll
                for (int j = 0; j < 4; ++j) v[j] = *(const float4*)(rp + k0 + kk + 4 * j);
            } else {
#pragma unroll
                for (int j = 0; j < 4; ++j) v[j] = (float4){0.f, 0.f, 0.f, 0.f};
            }
#pragma unroll
            for (int j = 0; j < 4; ++j) {
                ushort2 sx = tsplit(v[j].x), sy = tsplit(v[j].y), sz = tsplit(v[j].z), sw = tsplit(v[j].w);
                ushort4 h4; h4.x = sx.x; h4.y = sy.x; h4.z = sz.x; h4.w = sw.x;
                ushort4 l4; l4.x = sx.y; l4.y = sy.y; l4.z = sz.y; l4.w = sw.y;
                *(ushort4*)&Ah[row][kk + 4 * j] = h4;
                *(ushort4*)&Al[row][kk + 4 * j] = l4;
            }
        }
        __syncthreads();
        s16x8 ah = *(const s16x8*)&Ah[ti * 16 + fr][kb * 8];
        s16x8 al = *(const s16x8*)&Al[ti * 16 + fr][kb * 8];
        {
            s16x8 bh = *(const s16x8*)&Ah[tj0 * 16 + fr][kb * 8];
            s16x8 bl = *(const s16x8*)&Al[tj0 * 16 + fr][kb * 8];
            acc[0] = __builtin_amdgcn_mfma_f32_16x16x32_bf16(ah, bh, acc[0], 0, 0, 0);
            acc[0] = __builtin_amdgcn_mfma_f32_16x16x32_bf16(ah, bl, acc[0], 0, 0, 0);
            acc[0] = __builtin_amdgcn_mfma_f32_16x16x32_bf16(al, bh, acc[0], 0, 0, 0);
        }
        if (tj1 < 7) {
            s16x8 bh = *(const s16x8*)&Ah[tj1 * 16 + fr][kb * 8];
            s16x8 bl = *(const s16x8*)&Al[tj1 * 16 + fr][kb * 8];
            acc[1] = __builtin_amdgcn_mfma_f32_16x16x32_bf16(ah, bh, acc[1], 0, 0, 0);
            acc[1] = __builtin_amdgcn_mfma_f32_16x16x32_bf16(ah, bl, acc[1], 0, 0, 0);
            acc[1] = __builtin_amdgcn_mfma_f32_16x16x32_bf16(al, bh, acc[1], 0, 0, 0);
        }
    }
    // D: row(of strip) = kb*4 + r (within A-tile), col = tj*16 + fr
    float* Gn = G + (size_t)n * SM * 104;
#pragma unroll
    for (int u = 0; u < 2; ++u) {
        int tj = u ? tj1 : tj0;
        if (tj >= 7) continue;
#pragma unroll
        for (int r = 0; r < 4; ++r) {
            int m = ti * 16 + kb * 4 + r;
            int col = tj * 16 + fr;
            if (m < SM && col < SM) Gn[(size_t)m * 104 + col] = (u ? acc[1] : acc[0])[r];
        }
    }
}

// ---------------- farsel: stats + far0/far_rm/far_md + psum, per batch ----------------
__global__ __launch_bounds__(256)
void farsel(const float* __restrict__ G, const float* __restrict__ P_all,
            float* __restrict__ Psum0, int* __restrict__ far0,
            int* __restrict__ far_rm, int* __restrict__ far_md) {
    int n = blockIdx.x;
    int tid = threadIdx.x;
    __shared__ float sumdot[104], meandot[104], norm[104];
    const float* Gn = G + (size_t)n * SM * 104;
    // psum: Psum0[n][c] = sum_{q<100} P_all[n][q][c]
    {
        const float* basep = P_all + (size_t)n * SM * PW + tid;
        float accp = 0.f;
        for (int q = 0; q < QQ; ++q) accp += basep[(size_t)q * PW];
        Psum0[(size_t)n * CC + tid] = accp;
    }
    if (tid < SM) {
        const float* row = Gn + (size_t)tid * 104;
        float a = 0.f;
        for (int q = 0; q < QQ; ++q) a += row[q];
        sumdot[tid] = a; meandot[tid] = row[QQ]; norm[tid] = row[tid];
    }
    __syncthreads();
    if (tid < QQ) {
        int q = tid, qm1 = (q + QQ - 1) % QQ;
        const float* gq = Gn + (size_t)qm1 * 104;
        int best = -1; float bv = -1e30f;
        for (int s = 0; s < QQ; ++s) {
            if (s == qm1) continue;
            float val = norm[s] - (sumdot[s] - gq[s]) * (2.f / 99.f);
            if (val > bv) { bv = val; best = s; }
        }
        far_rm[n * QQ + q] = best;
    } else if (tid >= 128 && tid < 128 + QQ) {
        int q = tid - 128, qm1 = (q + QQ - 1) % QQ;
        const float* gq = Gn + (size_t)qm1 * 104;
        int best = -1; float bv = -1e30f;
        for (int s = 0; s < SM; ++s) {
            if (s == qm1) continue;
            float val = norm[s] - (sumdot[s] - gq[s] + meandot[s]) * (2.f / 100.f);
            if (val > bv) { bv = val; best = s; }
        }
        far_md[n * QQ + q] = best;
    } else if (tid == 100) {
        int best = 0; float bv = -1e30f;
        for (int q = 0; q < QQ; ++q) {
            float val = norm[q] - 0.02f * sumdot[q];
            if (val > bv) { bv = val; best = q; }
        }
        far0[n] = best;
    }
}

// ---------------- stage B fused: scores + PV + assign + si/di + out-proj + cd/cs ----------------
__global__ __launch_bounds__(512)
void smhaB_kernel(const float* __restrict__ P_all, const int* __restrict__ far0,
                  const float* __restrict__ ow, const float* __restrict__ ob,
                  float* __restrict__ out_assign, float* __restrict__ out_sidx,
                  float* __restrict__ out_didx, float* __restrict__ cd,
                  float* __restrict__ cs) {
    int n = blockIdx.x;
    int tid = threadIdx.x;
    int h = tid >> 6, lane = tid & 63;
    __shared__ float at[HH][2][104];
    __shared__ float qsh[HH][2][DH];
    __shared__ float rsh[HH][2];
    __shared__ float pvs[2][CC];
    __shared__ int sdi[2];
    const float* base = P_all + (size_t)n * SM * PW;
    if (lane < 2 * DH) {
        int t = lane >> 5, d = lane & 31;
        int row = t ? far0[n] : QQ;
        qsh[h][t][d] = base[(size_t)row * PW + h * DH + d];
    }
    const float scl = 0.17677669529663687f;
    float p0 = 0.f, p1 = 0.f;
    for (int s = lane; s < 104; s += 64) {
        float a0v = 0.f, a1v = 0.f;
        if (s < QQ) {
            const float4* kr = (const float4*)(base + (size_t)s * PW + CC + h * DH);
            float d0 = 0.f, d1 = 0.f;
#pragma unroll
            for (int j = 0; j < 8; ++j) {
                float4 k4 = kr[j];
                d0 += qsh[h][0][4 * j] * k4.x + qsh[h][0][4 * j + 1] * k4.y
                    + qsh[h][0][4 * j + 2] * k4.z + qsh[h][0][4 * j + 3] * k4.w;
                d1 += qsh[h][1][4 * j] * k4.x + qsh[h][1][4 * j + 1] * k4.y
                    + qsh[h][1][4 * j + 2] * k4.z + qsh[h][1][4 * j + 3] * k4.w;
            }
            a0v = 1.f / (1.f + __expf(-d0 * scl));
            a1v = 1.f / (1.f + __expf(-d1 * scl));
            p0 += a0v; p1 += a1v;
        }
        at[h][0][s] = a0v;
        at[h][1][s] = a1v;
    }
#pragma unroll
    for (int off = 32; off > 0; off >>= 1) {
        p0 += __shfl_down(p0, off);
        p1 += __shfl_down(p1, off);
    }
    if (lane == 0) { rsh[h][0] = p0; rsh[h][1] = p1; }
    {
        int t = lane >> 5, d = lane & 31;
        float rv = (t ? p1 : p0);
        rv = __shfl(rv, 0);
        float inv = 1.f / (rv + 1e-4f);
        float acc = 0.f;
        const float* vb = base + 2 * CC + h * DH + d;
        for (int s = 0; s < QQ; ++s) acc += at[h][t][s] * vb[(size_t)s * PW];
        pvs[t][h * DH + d] = acc * inv;
    }
    __syncthreads();
    if (tid == 0) {
        float c0 = 0.f, c1v = 0.f;
        for (int h2 = 0; h2 < HH; ++h2) { c0 += rsh[h2][0]; c1v += rsh[h2][1]; }
        int si = (c1v < c0) ? 1 : 0;
        int di = (c1v > c0) ? 1 : 0;
        sdi[0] = si; sdi[1] = di;
        out_sidx[n] = (float)si;
        out_didx[n] = (float)di;
    }
    __syncthreads();
    if (tid < 2 * QQ) {
        int t = tid / QQ, s = tid % QQ;
        float m = 0.f;
#pragma unroll
        for (int h2 = 0; h2 < HH; ++h2) m += at[h2][t][s];
        out_assign[(size_t)n * 2 * QQ + tid] = m * 0.125f;
    }
    {
        int t = tid >> 8, c = tid & 255;
        const float4* wr4 = (const float4*)(ow + (size_t)c * CC);
        const float4* pz = (const float4*)&pvs[t][0];
        float a = ob[c];
#pragma unroll 8
        for (int k = 0; k < 64; ++k) {
            float4 w = wr4[k], x = pz[k];
            a += x.x * w.x + x.y * w.y + x.z * w.z + x.w * w.w;
        }
        if (t == sdi[1]) cd[(size_t)n * CC + c] = a;
        if (t == sdi[0]) cs[(size_t)n * CC + c] = a;
    }
}

// ---------------- MFMA attention: one block per (n,h), 8 waves x 50 rows ----------------
__global__ __launch_bounds__(512)
void attn_mfma(const float* __restrict__ P_all, const float* __restrict__ Psum0,
               const int* __restrict__ far_rm, const int* __restrict__ far_md,
               float* __restrict__ pv, float* __restrict__ rowsum) {
    int h = blockIdx.x, n = blockIdx.y;
    int tid = threadIdx.x;
    int w = tid >> 6, lane = tid & 63;
    int fr = lane & 15, hi = lane >> 4;
    int d0 = hi * 8;
    __shared__ unsigned short Kh[112 * 40];
    __shared__ unsigned short Kl[112 * 40];
    __shared__ unsigned short Vt[32 * 136];
    __shared__ unsigned short Pb[8][64 * 40];
    __shared__ float rsL[8][64];
    const float* base = P_all + (size_t)n * SM * PW;
    for (int idx = tid; idx < 112 * 8; idx += 512) {
        int key = idx >> 3, d4 = (idx & 7) * 4;
        float4 kv = {0.f, 0.f, 0.f, 0.f}, vv = {0.f, 0.f, 0.f, 0.f};
        if (key < SM) {
            kv = *(const float4*)&base[(size_t)key * PW + CC + h * DH + d4];
            vv = *(const float4*)&base[(size_t)key * PW + 2 * CC + h * DH + d4];
        }
        ushort2 sx = tsplit(kv.x), sy = tsplit(kv.y), sz = tsplit(kv.z), sw = tsplit(kv.w);
        ushort4 h4; h4.x = sx.x; h4.y = sy.x; h4.z = sz.x; h4.w = sw.x;
        ushort4 l4; l4.x = sx.y; l4.y = sy.y; l4.z = sz.y; l4.w = sw.y;
        *(ushort4*)&Kh[key * 40 + d4] = h4;
        *(ushort4*)&Kl[key * 40 + d4] = l4;
        Vt[(d4 + 0) * 136 + key] = f2bf(vv.x);
        Vt[(d4 + 1) * 136 + key] = f2bf(vv.y);
        Vt[(d4 + 2) * 136 + key] = f2bf(vv.z);
        Vt[(d4 + 3) * 136 + key] = f2bf(vv.w);
    }
    for (int idx = tid; idx < 32 * 16; idx += 512) {
        int d = idx >> 4, key = 112 + (idx & 15);
        Vt[d * 136 + key] = 0;
    }
    __syncthreads();
    const float* Psum0n = Psum0 + n * CC;
    int rowbase = w * 50;
    unsigned short* Pw = Pb[w];
    const float scl = 0.17677669529663687f;
    s16x8 qh[4], ql[4];
    int mk[4], sb[4];
#pragma unroll
    for (int qi = 0; qi < 4; ++qi) {
        int lq = qi * 16 + fr;
        int row = rowbase + (lq < 50 ? lq : 49);
        int b = row >= TT;
        int t = row - b * TT;
        int q = t >> 1;
        mk[qi] = q; sb[qi] = b ? SM : QQ;
        float qv[8];
        if (t & 1) {
            int f = (b ? far_md : far_rm)[n * QQ + q];
            const float4* pr = (const float4*)(base + (size_t)f * PW + h * DH + d0);
            float4 v0 = pr[0], v1 = pr[1];
            qv[0] = v0.x; qv[1] = v0.y; qv[2] = v0.z; qv[3] = v0.w;
            qv[4] = v1.x; qv[5] = v1.y; qv[6] = v1.z; qv[7] = v1.w;
        } else {
            int qm1 = (q + QQ - 1) % QQ;
            const float4* ps = (const float4*)(Psum0n + h * DH + d0);
            const float4* pm = (const float4*)(base + (size_t)qm1 * PW + h * DH + d0);
            const float4* pmn = (const float4*)(base + (size_t)QQ * PW + h * DH + d0);
            float invd = b ? 0.01f : (1.f / 99.f);
            float bb = b ? 1.f : 0.f;
            float4 a0 = ps[0], c0 = pm[0], m0 = pmn[0];
            float4 a1 = ps[1], c1 = pm[1], m1 = pmn[1];
            qv[0] = (a0.x - c0.x + bb * m0.x) * invd;
            qv[1] = (a0.y - c0.y + bb * m0.y) * invd;
            qv[2] = (a0.z - c0.z + bb * m0.z) * invd;
            qv[3] = (a0.w - c0.w + bb * m0.w) * invd;
            qv[4] = (a1.x - c1.x + bb * m1.x) * invd;
            qv[5] = (a1.y - c1.y + bb * m1.y) * invd;
            qv[6] = (a1.z - c1.z + bb * m1.z) * invd;
            qv[7] = (a1.w - c1.w + bb * m1.w) * invd;
        }
        s16x8 qhv, qlv;
#pragma unroll
        for (int j = 0; j < 8; ++j) {
            ushort2 sp = tsplit(qv[j]);
            qhv[j] = (short)sp.x;
            qlv[j] = (short)sp.y;
        }
        qh[qi] = qhv; ql[qi] = qlv;
    }
    f32x4 pvacc[4][2];
#pragma unroll
    for (int qi = 0; qi < 4; ++qi) {
        pvacc[qi][0] = (f32x4){0.f, 0.f, 0.f, 0.f};
        pvacc[qi][1] = (f32x4){0.f, 0.f, 0.f, 0.f};
    }
    float rs[4] = {0.f, 0.f, 0.f, 0.f};
#pragma unroll
    for (int kc = 0; kc < 4; ++kc) {
        int k0 = kc * 32;
        {
            s16x8 ah = *(const s16x8*)&Kh[(k0 + fr) * 40 + d0];
            s16x8 al = *(const s16x8*)&Kl[(k0 + fr) * 40 + d0];
#pragma unroll
            for (int qi = 0; qi < 4; ++qi) {
                f32x4 s0 = (f32x4){0.f, 0.f, 0.f, 0.f};
                s0 = __builtin_amdgcn_mfma_f32_16x16x32_bf16(ah, qh[qi], s0, 0, 0, 0);
                s0 = __builtin_amdgcn_mfma_f32_16x16x32_bf16(ah, ql[qi], s0, 0, 0, 0);
                s0 = __builtin_amdgcn_mfma_f32_16x16x32_bf16(al, qh[qi], s0, 0, 0, 0);
                int kb0 = k0 + 4 * hi;
                float a0 = (kb0 + 0 < sb[qi] && kb0 + 0 != mk[qi]) ? 1.f / (1.f + __expf(-s0[0] * scl)) : 0.f;
                float a1 = (kb0 + 1 < sb[qi] && kb0 + 1 != mk[qi]) ? 1.f / (1.f + __expf(-s0[1] * scl)) : 0.f;
                float a2 = (kb0 + 2 < sb[qi] && kb0 + 2 != mk[qi]) ? 1.f / (1.f + __expf(-s0[2] * scl)) : 0.f;
                float a3 = (kb0 + 3 < sb[qi] && kb0 + 3 != mk[qi]) ? 1.f / (1.f + __expf(-s0[3] * scl)) : 0.f;
                rs[qi] += a0 + a1 + a2 + a3;
                ushort4 p4;
                p4.x = f2bf(a0); p4.y = f2bf(a1); p4.z = f2bf(a2); p4.w = f2bf(a3);
                *(ushort4*)&Pw[(qi * 16 + fr) * 40 + 4 * hi] = p4;
            }
        }
        if (kc < 3) {
            s16x8 ah = *(const s16x8*)&Kh[(k0 + 16 + fr) * 40 + d0];
            s16x8 al = *(const s16x8*)&Kl[(k0 + 16 + fr) * 40 + d0];
#pragma unroll
            for (int qi = 0; qi < 4; ++qi) {
                f32x4 s1 = (f32x4){0.f, 0.f, 0.f, 0.f};
                s1 = __builtin_amdgcn_mfma_f32_16x16x32_bf16(ah, qh[qi], s1, 0, 0, 0);
                s1 = __builtin_amdgcn_mfma_f32_16x16x32_bf16(ah, ql[qi], s1, 0, 0, 0);
                s1 = __builtin_amdgcn_mfma_f32_16x16x32_bf16(al, qh[qi], s1, 0, 0, 0);
                int kb1 = k0 + 16 + 4 * hi;
                float a0 = (kb1 + 0 < sb[qi] && kb1 + 0 != mk[qi]) ? 1.f / (1.f + __expf(-s1[0] * scl)) : 0.f;
                float a1 = (kb1 + 1 < sb[qi] && kb1 + 1 != mk[qi]) ? 1.f / (1.f + __expf(-s1[1] * scl)) : 0.f;
                float a2 = (kb1 + 2 < sb[qi] && kb1 + 2 != mk[qi]) ? 1.f / (1.f + __expf(-s1[2] * scl)) : 0.f;
                float a3 = (kb1 + 3 < sb[qi] && kb1 + 3 != mk[qi]) ? 1.f / (1.f + __expf(-s1[3] * scl)) : 0.f;
                rs[qi] += a0 + a1 + a2 + a3;
                ushort4 p4;
                p4.x = f2bf(a0); p4.y = f2bf(a1); p4.z = f2bf(a2); p4.w = f2bf(a3);
                *(ushort4*)&Pw[(qi * 16 + fr) * 40 + 16 + 4 * hi] = p4;
            }
        } else {
            ushort4 z; z.x = 0; z.y = 0; z.z = 0; z.w = 0;
#pragma unroll
            for (int qi = 0; qi < 4; ++qi)
                *(ushort4*)&Pw[(qi * 16 + fr) * 40 + 16 + 4 * hi] = z;
        }
        s16x8 vb0 = *(const s16x8*)&Vt[(0 * 16 + fr) * 136 + k0 + d0];
        s16x8 vb1 = *(const s16x8*)&Vt[(1 * 16 + fr) * 136 + k0 + d0];
#pragma unroll
        for (int qi = 0; qi < 4; ++qi) {
            s16x8 pa = *(const s16x8*)&Pw[(qi * 16 + fr) * 40 + d0];
            pvacc[qi][0] = __builtin_amdgcn_mfma_f32_16x16x32_bf16(pa, vb0, pvacc[qi][0], 0, 0, 0);
            pvacc[qi][1] = __builtin_amdgcn_mfma_f32_16x16x32_bf16(pa, vb1, pvacc[qi][1], 0, 0, 0);
        }
    }
#pragma unroll
    for (int qi = 0; qi < 4; ++qi) {
        float r2 = rs[qi] + __shfl_xor(rs[qi], 16);
        r2 += __shfl_xor(r2, 32);
        int lq = qi * 16 + fr;
        if (hi == 0) {
            rsL[w][lq] = r2;
            if (lq < 50) rowsum[((size_t)n * HH + h) * TB + rowbase + lq] = r2;
        }
    }
#pragma unroll
    for (int qi = 0; qi < 4; ++qi) {
        float iv[4];
#pragma unroll
        for (int r = 0; r < 4; ++r) {
            int lq = qi * 16 + 4 * hi + r;
            iv[r] = 1.f / (rsL[w][lq] + 1e-4f);
        }
#pragma unroll
        for (int dt = 0; dt < 2; ++dt) {
#pragma unroll
            for (int r = 0; r < 4; ++r) {
                int lq = qi * 16 + 4 * hi + r;
                if (lq < 50)
                    pv[((size_t)n * TB + rowbase + lq) * CC + h * DH + dt * 16 + fr] = pvacc[qi][dt][r] * iv[r];
            }
        }
    }
}

// ---------------- fused out-projection + shift: 64 rows x 256 cols per block, 8 waves ----------------
__global__ __launch_bounds__(512)
void outshift(const float* __restrict__ pv, const float* __restrict__ ow,
              const float* __restrict__ ob, const float* __restrict__ cd,
              const float* __restrict__ cs, const float* __restrict__ rowsum,
              float* __restrict__ out_srm, float* __restrict__ out_smd) {
    __shared__ unsigned short Ahs[64][LDK], Als[64][LDK];
    __shared__ unsigned short Bhs[256][LDK], Bls[256][LDK];
    __shared__ float redcd[64][8], redcs[64][8];
    int tid = threadIdx.x;
    int lane = tid & 63, wave = tid >> 6;
    int wn = wave * 32;
    int fr = lane & 15, kb = lane >> 4;
    int bm = blockIdx.x * 64;
    int arow = tid >> 3, ak = (tid & 7) * 4;
    int brow = tid >> 1, bk = (tid & 1) * 16;
    const float* pA = pv + (size_t)(bm + arow) * CC + ak;
    const float* pB = ow + (size_t)brow * CC + bk;
    f32x4 acc[4][2];
#pragma unroll
    for (int mi = 0; mi < 4; ++mi)
#pragma unroll
        for (int ni = 0; ni < 2; ++ni)
            acc[mi][ni] = (f32x4){0.f, 0.f, 0.f, 0.f};
    for (int k0 = 0; k0 < CC; k0 += 32) {
        float4 av = *(const float4*)(pA + k0);
        float4 wv[4];
#pragma unroll
        for (int j = 0; j < 4; ++j) wv[j] = *(const float4*)(pB + k0 + 4 * j);
        __syncthreads();
        {
            ushort2 sx = tsplit(av.x), sy = tsplit(av.y), sz = tsplit(av.z), sw = tsplit(av.w);
            ushort4 h4; h4.x = sx.x; h4.y = sy.x; h4.z = sz.x; h4.w = sw.x;
            ushort4 l4; l4.x = sx.y; l4.y = sy.y; l4.z = sz.y; l4.w = sw.y;
            *(ushort4*)&Ahs[arow][ak] = h4;
            *(ushort4*)&Als[arow][ak] = l4;
        }
#pragma unroll
        for (int j = 0; j < 4; ++j) {
            ushort2 sx = tsplit(wv[j].x), sy = tsplit(wv[j].y), sz = tsplit(wv[j].z), sw = tsplit(wv[j].w);
            ushort4 h4; h4.x = sx.x; h4.y = sy.x; h4.z = sz.x; h4.w = sw.x;
            ushort4 l4; l4.x = sx.y; l4.y = sy.y; l4.z = sz.y; l4.w = sw.y;
            *(ushort4*)&Bhs[brow][bk + 4 * j] = h4;
            *(ushort4*)&Bls[brow][bk + 4 * j] = l4;
        }
        __syncthreads();
        s16x8 fah[4], fal[4], fbh[2], fbl[2];
#pragma unroll
        for (int mi = 0; mi < 4; ++mi) {
            fah[mi] = *(const s16x8*)&Ahs[mi * 16 + fr][kb * 8];
            fal[mi] = *(const s16x8*)&Als[mi * 16 + fr][kb * 8];
        }
#pragma unroll
        for (int ni = 0; ni < 2; ++ni) {
            fbh[ni] = *(const s16x8*)&Bhs[wn + ni * 16 + fr][kb * 8];
            fbl[ni] = *(const s16x8*)&Bls[wn + ni * 16 + fr][kb * 8];
        }
#pragma unroll
        for (int mi = 0; mi < 4; ++mi)
#pragma unroll
            for (int ni = 0; ni < 2; ++ni) {
                acc[mi][ni] = __builtin_amdgcn_mfma_f32_16x16x32_bf16(fah[mi], fbh[ni], acc[mi][ni], 0, 0, 0);
                acc[mi][ni] = __builtin_amdgcn_mfma_f32_16x16x32_bf16(fah[mi], fbl[ni], acc[mi][ni], 0, 0, 0);
                acc[mi][ni] = __builtin_amdgcn_mfma_f32_16x16x32_bf16(fal[mi], fbh[ni], acc[mi][ni], 0, 0, 0);
            }
    }
#pragma unroll
    for (int mi = 0; mi < 4; ++mi) {
#pragma unroll
        for (int r = 0; r < 4; ++r) {
            int lm = mi * 16 + kb * 4 + r;
            int g = bm + lm;
            int n = g / TB;
            float pcd = 0.f, pcs = 0.f;
#pragma unroll
            for (int ni = 0; ni < 2; ++ni) {
                int col = wn + ni * 16 + fr;
                float val = acc[mi][ni][r] + ob[col];
                float d1 = val - cd[(size_t)n * CC + col];
                float d2 = val - cs[(size_t)n * CC + col];
                pcd += d1 * d1;
                pcs += d2 * d2;
            }
#pragma unroll
            for (int m2 = 1; m2 < 16; m2 <<= 1) {
                pcd += __shfl_xor(pcd, m2);
                pcs += __shfl_xor(pcs, m2);
            }
            if (fr == 0) {
                redcd[lm][wave] = pcd;
                redcs[lm][wave] = pcs;
            }
        }
    }
    __syncthreads();
    if (tid < 32) {
        int g = bm + 2 * tid;
        int n = g / TB;
        int rem = g % TB;
        int b = rem / TT;
        int t = rem % TT;
        int q = t >> 1;
        float c0 = 0.f, c1v = 0.f;
        for (int h = 0; h < HH; ++h) {
            c0  += rowsum[((size_t)n * HH + h) * TB + rem];
            c1v += rowsum[((size_t)n * HH + h) * TB + rem + 1];
        }
        int si = (c1v < c0) ? 1 : 0;
        int di = (c1v > c0) ? 1 : 0;
        int ld = 2 * tid + di, ls = 2 * tid + si;
        float dd = 0.f, ds = 0.f;
#pragma unroll
        for (int wv2 = 0; wv2 < 8; ++wv2) { dd += redcd[ld][wv2]; ds += redcs[ls][wv2]; }
        (b ? out_smd : out_srm)[n * QQ + q] = sqrtf(dd + 1e-12f) + sqrtf(ds + 1e-12f);
    }
}

extern "C" void kernel_launch(void* const* d_in, const int* in_sizes, int n_in,
                              void* d_out, int out_size, void* d_ws, size_t ws_size,
                              hipStream_t stream) {
    const float* hs_pair = (const float*)d_in[0];
    const float* ipw = (const float*)d_in[1];
    const float* ipb = (const float*)d_in[2];
    const float* ow  = (const float*)d_in[3];
    const float* ob  = (const float*)d_in[4];
    const float* hs = hs_pair + (size_t)5 * NB * QQ * CC;  // hs_pair[-1]

    float* ws = (float*)d_ws;
    size_t o = 0;
    float* meanF   = ws + o; o += NB * CC;
    float* P_all   = ws + o; o += (size_t)NB * SM * PW;
    float* Psum0   = ws + o; o += NB * CC;
    float* G       = ws + o; o += (size_t)NB * SM * 104;
    int*   far0    = (int*)(ws + o); o += NB;
    int*   far_rm  = (int*)(ws + o); o += NB * QQ;
    int*   far_md  = (int*)(ws + o); o += NB * QQ;
    float* cd      = ws + o; o += NB * CC;
    float* cs      = ws + o; o += NB * CC;
    float* pv      = ws + o; o += (size_t)NB * TB * CC;
    float* rowsum  = ws + o; o += (size_t)NB * HH * TB;
    if (o * sizeof(float) > ws_size) return;

    float* out = (float*)d_out;
    float* out_assign = out;
    float* out_sidx   = out + 6400;
    float* out_didx   = out + 6432;
    float* out_srm    = out + 6464;
    float* out_smd    = out + 9664;

    meanrow_kernel<<<dim3(NB, 2), 256, 0, stream>>>(hs, meanF);
    gemm_mfma<<<dim3((NB * SM + 127) / 128, PW / 128), 256, 0, stream>>>(
        hs, meanF, ipw, ipb, P_all, NB * SM, PW);
    gram_strip<<<dim3(7, NB), 256, 0, stream>>>(hs, meanF, G);
    farsel<<<NB, 256, 0, stream>>>(G, P_all, Psum0, far0, far_rm, far_md);
    smhaB_kernel<<<NB, 512, 0, stream>>>(P_all, far0, ow, ob, out_assign,
                                         out_sidx, out_didx, cd, cs);
    attn_mfma<<<dim3(HH, NB), 512, 0, stream>>>(P_all, Psum0, far_rm, far_md, pv, rowsum);
    outshift<<<NB * TB / 64, 512, 0, stream>>>(pv, ow, ob, cd, cs, rowsum, out_srm, out_smd);
}

// Round 13
// 110.558 us; speedup vs baseline: 3.7852x; 1.0567x over previous
//
#include <hip/hip_runtime.h>
#include <math.h>

#define NB 32
#define QQ 100
#define CC 256
#define HH 8
#define DH 32
#define SM 101   // kv rows per batch (100 points + mean)
#define TT 200   // branch queries per batch
#define TB 400   // both branches
#define PW 768   // P_all row width (q|k|v projections)

typedef __attribute__((ext_vector_type(8))) short s16x8;
typedef __attribute__((ext_vector_type(4))) float f32x4;

// RNE bf16
__device__ inline unsigned short f2bf(float x) {
    unsigned u = __float_as_uint(x);
    return (unsigned short)((u + 0x7fffu + ((u >> 16) & 1u)) >> 16);
}
__device__ inline float bf2f(unsigned short h) {
    return __uint_as_float(((unsigned)h) << 16);
}
// RNE split: hi = RNE(x), lo = RNE(x - hi). Residual sign is random -> the
// dropped lo*lo term in the 3-MFMA scheme stays unbiased (~2^-18 noise).
__device__ inline ushort2 rsplit(float x) {
    ushort2 r;
    r.x = f2bf(x);
    r.y = f2bf(x - bf2f(r.x));
    return r;
}

// ---------------- meanF + stage-A far point ----------------
__global__ __launch_bounds__(256)
void meanfar0(const float* __restrict__ hs, float* __restrict__ meanF,
              int* __restrict__ far0) {
    int n = blockIdx.x;
    int c = threadIdx.x;
    const float* h = hs + (size_t)n * QQ * CC;
    float s = 0.f;
    for (int q = 0; q < QQ; ++q) s += h[q * CC + c];
    float c1 = s * 0.01f;
    meanF[(size_t)n * CC + c] = c1;
    __shared__ float c1s[CC];
    __shared__ float dls[QQ];
    c1s[c] = c1;
    __syncthreads();
    int wave = c >> 6, lane = c & 63;
    for (int q = wave; q < QQ; q += 4) {
        float p = 0.f;
        for (int cc = lane; cc < CC; cc += 64) {
            float d = c1s[cc] - h[q * CC + cc];
            p += d * d;
        }
        for (int off = 32; off > 0; off >>= 1) p += __shfl_down(p, off);
        if (lane == 0) dls[q] = p;
    }
    __syncthreads();
    if (c == 0) {
        int best = 0; float bv = dls[0];
        for (int q = 1; q < QQ; ++q) if (dls[q] > bv) { bv = dls[q]; best = q; }
        far0[n] = best;
    }
}

// ---------------- fused projection GEMM + Gram strips, one launch ----------------
#define LDK 40
#define GEMM_BX 26   // ceil(3232/128)
#define GEMM_BY 6    // 768/128
#define GEMM_NBLK (GEMM_BX * GEMM_BY)
__global__ __launch_bounds__(256, 2)
void projgram(const float* __restrict__ hs, const float* __restrict__ meanF,
              const float* __restrict__ W_g, const float* __restrict__ bias,
              float* __restrict__ out, float* __restrict__ G) {
    __shared__ unsigned short u16buf[4 * 128 * LDK];   // 40 KB, shared by both paths
    int tid = threadIdx.x;
    int lane = tid & 63, wave = tid >> 6;
    int fr = lane & 15, kb = lane >> 4;
    if (blockIdx.x < GEMM_NBLK) {
        // ---- GEMM path: out = A @ W^T + bias, A rows from hs/meanF ----
        unsigned short* Ahs = u16buf;
        unsigned short* Als = u16buf + 128 * LDK;
        unsigned short* Bhs = u16buf + 2 * 128 * LDK;
        unsigned short* Bls = u16buf + 3 * 128 * LDK;
        const int M = NB * SM;
        int bm = (blockIdx.x % GEMM_BX) * 128, bn = (blockIdx.x / GEMM_BX) * 128;
        int wm = (wave >> 1) * 64, wn = (wave & 1) * 64;
        int srow = tid >> 1, scol = (tid & 1) * 16;
        int am = bm + srow; if (am >= M) am = M - 1;
        int an = am / SM, ar = am - an * SM;
        const float* pA = (ar < QQ) ? hs + ((size_t)an * QQ + ar) * CC + scol
                                    : meanF + (size_t)an * CC + scol;
        const float* pW = W_g + (size_t)(bn + srow) * CC + scol;
        f32x4 acc[4][4];
#pragma unroll
        for (int mi = 0; mi < 4; ++mi)
#pragma unroll
            for (int ni = 0; ni < 4; ++ni)
                acc[mi][ni] = (f32x4){0.f, 0.f, 0.f, 0.f};
        for (int k0 = 0; k0 < CC; k0 += 32) {
            float4 av[4], wv[4];
#pragma unroll
            for (int j = 0; j < 4; ++j) {
                av[j] = *(const float4*)(pA + k0 + 4 * j);
                wv[j] = *(const float4*)(pW + k0 + 4 * j);
            }
            __syncthreads();
#pragma unroll
            for (int j = 0; j < 4; ++j) {
                ushort2 sx = rsplit(av[j].x), sy = rsplit(av[j].y), sz = rsplit(av[j].z), sw = rsplit(av[j].w);
                ushort4 h4; h4.x = sx.x; h4.y = sy.x; h4.z = sz.x; h4.w = sw.x;
                ushort4 l4; l4.x = sx.y; l4.y = sy.y; l4.z = sz.y; l4.w = sw.y;
                *(ushort4*)&Ahs[srow * LDK + scol + 4 * j] = h4;
                *(ushort4*)&Als[srow * LDK + scol + 4 * j] = l4;
                ushort2 tx = rsplit(wv[j].x), ty = rsplit(wv[j].y), tz = rsplit(wv[j].z), tw = rsplit(wv[j].w);
                ushort4 wh4; wh4.x = tx.x; wh4.y = ty.x; wh4.z = tz.x; wh4.w = tw.x;
                ushort4 wl4; wl4.x = tx.y; wl4.y = ty.y; wl4.z = tz.y; wl4.w = tw.y;
                *(ushort4*)&Bhs[srow * LDK + scol + 4 * j] = wh4;
                *(ushort4*)&Bls[srow * LDK + scol + 4 * j] = wl4;
            }
            __syncthreads();
            s16x8 fah[4], fal[4], fbh[4], fbl[4];
#pragma unroll
            for (int mi = 0; mi < 4; ++mi) {
                fah[mi] = *(const s16x8*)&Ahs[(wm + mi * 16 + fr) * LDK + kb * 8];
                fal[mi] = *(const s16x8*)&Als[(wm + mi * 16 + fr) * LDK + kb * 8];
            }
#pragma unroll
            for (int ni = 0; ni < 4; ++ni) {
                fbh[ni] = *(const s16x8*)&Bhs[(wn + ni * 16 + fr) * LDK + kb * 8];
                fbl[ni] = *(const s16x8*)&Bls[(wn + ni * 16 + fr) * LDK + kb * 8];
            }
#pragma unroll
            for (int mi = 0; mi < 4; ++mi)
#pragma unroll
                for (int ni = 0; ni < 4; ++ni) {
                    acc[mi][ni] = __builtin_amdgcn_mfma_f32_16x16x32_bf16(fah[mi], fbh[ni], acc[mi][ni], 0, 0, 0);
                    acc[mi][ni] = __builtin_amdgcn_mfma_f32_16x16x32_bf16(fah[mi], fbl[ni], acc[mi][ni], 0, 0, 0);
                    acc[mi][ni] = __builtin_amdgcn_mfma_f32_16x16x32_bf16(fal[mi], fbh[ni], acc[mi][ni], 0, 0, 0);
                }
        }
#pragma unroll
        for (int mi = 0; mi < 4; ++mi) {
            int mb = bm + wm + mi * 16 + kb * 4;
#pragma unroll
            for (int r = 0; r < 4; ++r) {
                int m = mb + r;
                if (m < M) {
#pragma unroll
                    for (int ni = 0; ni < 4; ++ni) {
                        int col = bn + wn + ni * 16 + fr;
                        out[(size_t)m * PW + col] = acc[mi][ni][r] + bias[col];
                    }
                }
            }
        }
    } else {
        // ---- Gram strip path: rows [ti*16, ti*16+16) x all cols of G[n] ----
        int bi = blockIdx.x - GEMM_NBLK;
        int ti = bi % 7, n = bi / 7;
        unsigned short* Ah = u16buf;
        unsigned short* Al = u16buf + 112 * LDK;
        const float* hb = hs + (size_t)n * QQ * CC;
        const float* mb = meanF + (size_t)n * CC;
        f32x4 acc[2];
        acc[0] = (f32x4){0.f, 0.f, 0.f, 0.f};
        acc[1] = (f32x4){0.f, 0.f, 0.f, 0.f};
        int tj0 = wave, tj1 = wave + 4;
        for (int k0 = 0; k0 < CC; k0 += 32) {
            __syncthreads();
            if (tid < 224) {
                int row = tid >> 1, kk = (tid & 1) * 16;
                float4 v[4];
                if (row < SM) {
                    const float* rp = (row < QQ) ? hb + (size_t)row * CC : mb;
#pragma unroll
                    for (int j = 0; j < 4; ++j) v[j] = *(const float4*)(rp + k0 + kk + 4 * j);
                } else {
#pragma unroll
                    for (int j = 0; j < 4; ++j) v[j] = (float4){0.f, 0.f, 0.f, 0.f};
                }
#pragma unroll
                for (int j = 0; j < 4; ++j) {
                    ushort2 sx = rsplit(v[j].x), sy = rsplit(v[j].y), sz = rsplit(v[j].z), sw = rsplit(v[j].w);
                    ushort4 h4; h4.x = sx.x; h4.y = sy.x; h4.z = sz.x; h4.w = sw.x;
                    ushort4 l4; l4.x = sx.y; l4.y = sy.y; l4.z = sz.y; l4.w = sw.y;
                    *(ushort4*)&Ah[row * LDK + kk + 4 * j] = h4;
                    *(ushort4*)&Al[row * LDK + kk + 4 * j] = l4;
                }
            }
            __syncthreads();
            s16x8 ah = *(const s16x8*)&Ah[(ti * 16 + fr) * LDK + kb * 8];
            s16x8 al = *(const s16x8*)&Al[(ti * 16 + fr) * LDK + kb * 8];
            {
                s16x8 bh = *(const s16x8*)&Ah[(tj0 * 16 + fr) * LDK + kb * 8];
                s16x8 bl = *(const s16x8*)&Al[(tj0 * 16 + fr) * LDK + kb * 8];
                acc[0] = __builtin_amdgcn_mfma_f32_16x16x32_bf16(ah, bh, acc[0], 0, 0, 0);
                acc[0] = __builtin_amdgcn_mfma_f32_16x16x32_bf16(ah, bl, acc[0], 0, 0, 0);
                acc[0] = __builtin_amdgcn_mfma_f32_16x16x32_bf16(al, bh, acc[0], 0, 0, 0);
            }
            if (tj1 < 7) {
                s16x8 bh = *(const s16x8*)&Ah[(tj1 * 16 + fr) * LDK + kb * 8];
                s16x8 bl = *(const s16x8*)&Al[(tj1 * 16 + fr) * LDK + kb * 8];
                acc[1] = __builtin_amdgcn_mfma_f32_16x16x32_bf16(ah, bh, acc[1], 0, 0, 0);
                acc[1] = __builtin_amdgcn_mfma_f32_16x16x32_bf16(ah, bl, acc[1], 0, 0, 0);
                acc[1] = __builtin_amdgcn_mfma_f32_16x16x32_bf16(al, bh, acc[1], 0, 0, 0);
            }
        }
        float* Gn = G + (size_t)n * SM * 104;
#pragma unroll
        for (int u = 0; u < 2; ++u) {
            int tj = u ? tj1 : tj0;
            if (tj >= 7) continue;
#pragma unroll
            for (int r = 0; r < 4; ++r) {
                int m = ti * 16 + kb * 4 + r;
                int col = tj * 16 + fr;
                if (m < SM && col < SM) Gn[(size_t)m * 104 + col] = (u ? acc[1] : acc[0])[r];
            }
        }
    }
}

// ---------------- selB: farsel (blocks 0..31) | stage-B SMHA (blocks 32..63) ----------------
__global__ __launch_bounds__(512)
void selB(const float* __restrict__ G, const float* __restrict__ P_all,
          const int* __restrict__ far0, const float* __restrict__ ow,
          const float* __restrict__ ob, float* __restrict__ Psum0,
          int* __restrict__ far_rm, int* __restrict__ far_md,
          float* __restrict__ out_assign, float* __restrict__ out_sidx,
          float* __restrict__ out_didx, float* __restrict__ cd,
          float* __restrict__ cs) {
    int tid = threadIdx.x;
    if (blockIdx.x < NB) {
        // ---- farsel path ----
        int n = blockIdx.x;
        __shared__ float sumdot[104], meandot[104], norm[104];
        __shared__ float psumP[2][CC];
        const float* Gn = G + (size_t)n * SM * 104;
        {
            int c = tid & 255, half = tid >> 8;
            const float* basep = P_all + (size_t)n * SM * PW + c;
            float accp = 0.f;
            for (int q = half * 50; q < half * 50 + 50; ++q) accp += basep[(size_t)q * PW];
            psumP[half][c] = accp;
        }
        if (tid < SM) {
            const float* row = Gn + (size_t)tid * 104;
            float a = 0.f;
            for (int q = 0; q < QQ; ++q) a += row[q];
            sumdot[tid] = a; meandot[tid] = row[QQ]; norm[tid] = row[tid];
        }
        __syncthreads();
        if (tid < 256) Psum0[(size_t)n * CC + tid] = psumP[0][tid] + psumP[1][tid];
        if (tid < QQ) {
            int q = tid, qm1 = (q + QQ - 1) % QQ;
            const float* gq = Gn + (size_t)qm1 * 104;
            int best = -1; float bv = -1e30f;
            for (int s = 0; s < QQ; ++s) {
                if (s == qm1) continue;
                float val = norm[s] - (sumdot[s] - gq[s]) * (2.f / 99.f);
                if (val > bv) { bv = val; best = s; }
            }
            far_rm[n * QQ + q] = best;
        } else if (tid >= 128 && tid < 128 + QQ) {
            int q = tid - 128, qm1 = (q + QQ - 1) % QQ;
            const float* gq = Gn + (size_t)qm1 * 104;
            int best = -1; float bv = -1e30f;
            for (int s = 0; s < SM; ++s) {
                if (s == qm1) continue;
                float val = norm[s] - (sumdot[s] - gq[s] + meandot[s]) * (2.f / 100.f);
                if (val > bv) { bv = val; best = s; }
            }
            far_md[n * QQ + q] = best;
        }
    } else {
        // ---- stage B SMHA path ----
        int n = blockIdx.x - NB;
        int h = tid >> 6, lane = tid & 63;
        __shared__ float at[HH][2][104];
        __shared__ float qsh[HH][2][DH];
        __shared__ float rsh[HH][2];
        __shared__ float pvs[2][CC];
        __shared__ int sdi[2];
        const float* base = P_all + (size_t)n * SM * PW;
        if (lane < 2 * DH) {
            int t = lane >> 5, d = lane & 31;
            int row = t ? far0[n] : QQ;
            qsh[h][t][d] = base[(size_t)row * PW + h * DH + d];
        }
        const float scl = 0.17677669529663687f;
        float p0 = 0.f, p1 = 0.f;
        for (int s = lane; s < 104; s += 64) {
            float a0v = 0.f, a1v = 0.f;
            if (s < QQ) {
                const float4* kr = (const float4*)(base + (size_t)s * PW + CC + h * DH);
                float d0 = 0.f, d1 = 0.f;
#pragma unroll
                for (int j = 0; j < 8; ++j) {
                    float4 k4 = kr[j];
                    d0 += qsh[h][0][4 * j] * k4.x + qsh[h][0][4 * j + 1] * k4.y
                        + qsh[h][0][4 * j + 2] * k4.z + qsh[h][0][4 * j + 3] * k4.w;
                    d1 += qsh[h][1][4 * j] * k4.x + qsh[h][1][4 * j + 1] * k4.y
                        + qsh[h][1][4 * j + 2] * k4.z + qsh[h][1][4 * j + 3] * k4.w;
                }
                a0v = 1.f / (1.f + __expf(-d0 * scl));
                a1v = 1.f / (1.f + __expf(-d1 * scl));
                p0 += a0v; p1 += a1v;
            }
            at[h][0][s] = a0v;
            at[h][1][s] = a1v;
        }
#pragma unroll
        for (int off = 32; off > 0; off >>= 1) {
            p0 += __shfl_down(p0, off);
            p1 += __shfl_down(p1, off);
        }
        if (lane == 0) { rsh[h][0] = p0; rsh[h][1] = p1; }
        {
            int t = lane >> 5, d = lane & 31;
            float rv = (t ? p1 : p0);
            rv = __shfl(rv, 0);
            float inv = 1.f / (rv + 1e-4f);
            float acc = 0.f;
            const float* vb = base + 2 * CC + h * DH + d;
            for (int s = 0; s < QQ; ++s) acc += at[h][t][s] * vb[(size_t)s * PW];
            pvs[t][h * DH + d] = acc * inv;
        }
        __syncthreads();
        if (tid == 0) {
            float c0 = 0.f, c1v = 0.f;
            for (int h2 = 0; h2 < HH; ++h2) { c0 += rsh[h2][0]; c1v += rsh[h2][1]; }
            int si = (c1v < c0) ? 1 : 0;
            int di = (c1v > c0) ? 1 : 0;
            sdi[0] = si; sdi[1] = di;
            out_sidx[n] = (float)si;
            out_didx[n] = (float)di;
        }
        __syncthreads();
        if (tid < 2 * QQ) {
            int t = tid / QQ, s = tid % QQ;
            float m = 0.f;
#pragma unroll
            for (int h2 = 0; h2 < HH; ++h2) m += at[h2][t][s];
            out_assign[(size_t)n * 2 * QQ + tid] = m * 0.125f;
        }
        {
            int t = tid >> 8, c = tid & 255;
            const float4* wr4 = (const float4*)(ow + (size_t)c * CC);
            const float4* pz = (const float4*)&pvs[t][0];
            float a = ob[c];
#pragma unroll 8
            for (int k = 0; k < 64; ++k) {
                float4 w = wr4[k], x = pz[k];
                a += x.x * w.x + x.y * w.y + x.z * w.z + x.w * w.w;
            }
            if (t == sdi[1]) cd[(size_t)n * CC + c] = a;
            if (t == sdi[0]) cs[(size_t)n * CC + c] = a;
        }
    }
}

// ---------------- MFMA attention: one block per (n,h), 8 waves x 50 rows ----------------
__global__ __launch_bounds__(512)
void attn_mfma(const float* __restrict__ P_all, const float* __restrict__ Psum0,
               const int* __restrict__ far_rm, const int* __restrict__ far_md,
               float* __restrict__ pv, float* __restrict__ rowsum) {
    int h = blockIdx.x, n = blockIdx.y;
    int tid = threadIdx.x;
    int w = tid >> 6, lane = tid & 63;
    int fr = lane & 15, hi = lane >> 4;
    int d0 = hi * 8;
    __shared__ unsigned short Kh[112 * 40];
    __shared__ unsigned short Kl[112 * 40];
    __shared__ unsigned short Vt[32 * 136];
    __shared__ unsigned short Pb[8][64 * 40];
    __shared__ float rsL[8][64];
    const float* base = P_all + (size_t)n * SM * PW;
    for (int idx = tid; idx < 112 * 8; idx += 512) {
        int key = idx >> 3, d4 = (idx & 7) * 4;
        float4 kv = {0.f, 0.f, 0.f, 0.f}, vv = {0.f, 0.f, 0.f, 0.f};
        if (key < SM) {
            kv = *(const float4*)&base[(size_t)key * PW + CC + h * DH + d4];
            vv = *(const float4*)&base[(size_t)key * PW + 2 * CC + h * DH + d4];
        }
        ushort2 sx = rsplit(kv.x), sy = rsplit(kv.y), sz = rsplit(kv.z), sw = rsplit(kv.w);
        ushort4 h4; h4.x = sx.x; h4.y = sy.x; h4.z = sz.x; h4.w = sw.x;
        ushort4 l4; l4.x = sx.y; l4.y = sy.y; l4.z = sz.y; l4.w = sw.y;
        *(ushort4*)&Kh[key * 40 + d4] = h4;
        *(ushort4*)&Kl[key * 40 + d4] = l4;
        Vt[(d4 + 0) * 136 + key] = f2bf(vv.x);
        Vt[(d4 + 1) * 136 + key] = f2bf(vv.y);
        Vt[(d4 + 2) * 136 + key] = f2bf(vv.z);
        Vt[(d4 + 3) * 136 + key] = f2bf(vv.w);
    }
    for (int idx = tid; idx < 32 * 16; idx += 512) {
        int d = idx >> 4, key = 112 + (idx & 15);
        Vt[d * 136 + key] = 0;
    }
    __syncthreads();
    const float* Psum0n = Psum0 + n * CC;
    int rowbase = w * 50;
    unsigned short* Pw = Pb[w];
    const float scl = 0.17677669529663687f;
    s16x8 qh[4], ql[4];
    int mk[4], sb[4];
#pragma unroll
    for (int qi = 0; qi < 4; ++qi) {
        int lq = qi * 16 + fr;
        int row = rowbase + (lq < 50 ? lq : 49);
        int b = row >= TT;
        int t = row - b * TT;
        int q = t >> 1;
        mk[qi] = q; sb[qi] = b ? SM : QQ;
        float qv[8];
        if (t & 1) {
            int f = (b ? far_md : far_rm)[n * QQ + q];
            const float4* pr = (const float4*)(base + (size_t)f * PW + h * DH + d0);
            float4 v0 = pr[0], v1 = pr[1];
            qv[0] = v0.x; qv[1] = v0.y; qv[2] = v0.z; qv[3] = v0.w;
            qv[4] = v1.x; qv[5] = v1.y; qv[6] = v1.z; qv[7] = v1.w;
        } else {
            int qm1 = (q + QQ - 1) % QQ;
            const float4* ps = (const float4*)(Psum0n + h * DH + d0);
            const float4* pm = (const float4*)(base + (size_t)qm1 * PW + h * DH + d0);
            const float4* pmn = (const float4*)(base + (size_t)QQ * PW + h * DH + d0);
            float invd = b ? 0.01f : (1.f / 99.f);
            float bb = b ? 1.f : 0.f;
            float4 a0 = ps[0], c0 = pm[0], m0 = pmn[0];
            float4 a1 = ps[1], c1 = pm[1], m1 = pmn[1];
            qv[0] = (a0.x - c0.x + bb * m0.x) * invd;
            qv[1] = (a0.y - c0.y + bb * m0.y) * invd;
            qv[2] = (a0.z - c0.z + bb * m0.z) * invd;
            qv[3] = (a0.w - c0.w + bb * m0.w) * invd;
            qv[4] = (a1.x - c1.x + bb * m1.x) * invd;
            qv[5] = (a1.y - c1.y + bb * m1.y) * invd;
            qv[6] = (a1.z - c1.z + bb * m1.z) * invd;
            qv[7] = (a1.w - c1.w + bb * m1.w) * invd;
        }
        s16x8 qhv, qlv;
#pragma unroll
        for (int j = 0; j < 8; ++j) {
            ushort2 sp = rsplit(qv[j]);
            qhv[j] = (short)sp.x;
            qlv[j] = (short)sp.y;
        }
        qh[qi] = qhv; ql[qi] = qlv;
    }
    f32x4 pvacc[4][2];
#pragma unroll
    for (int qi = 0; qi < 4; ++qi) {
        pvacc[qi][0] = (f32x4){0.f, 0.f, 0.f, 0.f};
        pvacc[qi][1] = (f32x4){0.f, 0.f, 0.f, 0.f};
    }
    float rs[4] = {0.f, 0.f, 0.f, 0.f};
#pragma unroll
    for (int kc = 0; kc < 4; ++kc) {
        int k0 = kc * 32;
        {
            s16x8 ah = *(const s16x8*)&Kh[(k0 + fr) * 40 + d0];
            s16x8 al = *(const s16x8*)&Kl[(k0 + fr) * 40 + d0];
#pragma unroll
            for (int qi = 0; qi < 4; ++qi) {
                f32x4 s0 = (f32x4){0.f, 0.f, 0.f, 0.f};
                s0 = __builtin_amdgcn_mfma_f32_16x16x32_bf16(ah, qh[qi], s0, 0, 0, 0);
                s0 = __builtin_amdgcn_mfma_f32_16x16x32_bf16(ah, ql[qi], s0, 0, 0, 0);
                s0 = __builtin_amdgcn_mfma_f32_16x16x32_bf16(al, qh[qi], s0, 0, 0, 0);
                int kb0 = k0 + 4 * hi;
                float a0 = (kb0 + 0 < sb[qi] && kb0 + 0 != mk[qi]) ? 1.f / (1.f + __expf(-s0[0] * scl)) : 0.f;
                float a1 = (kb0 + 1 < sb[qi] && kb0 + 1 != mk[qi]) ? 1.f / (1.f + __expf(-s0[1] * scl)) : 0.f;
                float a2 = (kb0 + 2 < sb[qi] && kb0 + 2 != mk[qi]) ? 1.f / (1.f + __expf(-s0[2] * scl)) : 0.f;
                float a3 = (kb0 + 3 < sb[qi] && kb0 + 3 != mk[qi]) ? 1.f / (1.f + __expf(-s0[3] * scl)) : 0.f;
                rs[qi] += a0 + a1 + a2 + a3;
                ushort4 p4;
                p4.x = f2bf(a0); p4.y = f2bf(a1); p4.z = f2bf(a2); p4.w = f2bf(a3);
                *(ushort4*)&Pw[(qi * 16 + fr) * 40 + 4 * hi] = p4;
            }
        }
        if (kc < 3) {
            s16x8 ah = *(const s16x8*)&Kh[(k0 + 16 + fr) * 40 + d0];
            s16x8 al = *(const s16x8*)&Kl[(k0 + 16 + fr) * 40 + d0];
#pragma unroll
            for (int qi = 0; qi < 4; ++qi) {
                f32x4 s1 = (f32x4){0.f, 0.f, 0.f, 0.f};
                s1 = __builtin_amdgcn_mfma_f32_16x16x32_bf16(ah, qh[qi], s1, 0, 0, 0);
                s1 = __builtin_amdgcn_mfma_f32_16x16x32_bf16(ah, ql[qi], s1, 0, 0, 0);
                s1 = __builtin_amdgcn_mfma_f32_16x16x32_bf16(al, qh[qi], s1, 0, 0, 0);
                int kb1 = k0 + 16 + 4 * hi;
                float a0 = (kb1 + 0 < sb[qi] && kb1 + 0 != mk[qi]) ? 1.f / (1.f + __expf(-s1[0] * scl)) : 0.f;
                float a1 = (kb1 + 1 < sb[qi] && kb1 + 1 != mk[qi]) ? 1.f / (1.f + __expf(-s1[1] * scl)) : 0.f;
                float a2 = (kb1 + 2 < sb[qi] && kb1 + 2 != mk[qi]) ? 1.f / (1.f + __expf(-s1[2] * scl)) : 0.f;
                float a3 = (kb1 + 3 < sb[qi] && kb1 + 3 != mk[qi]) ? 1.f / (1.f + __expf(-s1[3] * scl)) : 0.f;
                rs[qi] += a0 + a1 + a2 + a3;
                ushort4 p4;
                p4.x = f2bf(a0); p4.y = f2bf(a1); p4.z = f2bf(a2); p4.w = f2bf(a3);
                *(ushort4*)&Pw[(qi * 16 + fr) * 40 + 16 + 4 * hi] = p4;
            }
        } else {
            ushort4 z; z.x = 0; z.y = 0; z.z = 0; z.w = 0;
#pragma unroll
            for (int qi = 0; qi < 4; ++qi)
                *(ushort4*)&Pw[(qi * 16 + fr) * 40 + 16 + 4 * hi] = z;
        }
        s16x8 vb0 = *(const s16x8*)&Vt[(0 * 16 + fr) * 136 + k0 + d0];
        s16x8 vb1 = *(const s16x8*)&Vt[(1 * 16 + fr) * 136 + k0 + d0];
#pragma unroll
        for (int qi = 0; qi < 4; ++qi) {
            s16x8 pa = *(const s16x8*)&Pw[(qi * 16 + fr) * 40 + d0];
            pvacc[qi][0] = __builtin_amdgcn_mfma_f32_16x16x32_bf16(pa, vb0, pvacc[qi][0], 0, 0, 0);
            pvacc[qi][1] = __builtin_amdgcn_mfma_f32_16x16x32_bf16(pa, vb1, pvacc[qi][1], 0, 0, 0);
        }
    }
#pragma unroll
    for (int qi = 0; qi < 4; ++qi) {
        float r2 = rs[qi] + __shfl_xor(rs[qi], 16);
        r2 += __shfl_xor(r2, 32);
        int lq = qi * 16 + fr;
        if (hi == 0) {
            rsL[w][lq] = r2;
            if (lq < 50) rowsum[((size_t)n * HH + h) * TB + rowbase + lq] = r2;
        }
    }
#pragma unroll
    for (int qi = 0; qi < 4; ++qi) {
        float iv[4];
#pragma unroll
        for (int r = 0; r < 4; ++r) {
            int lq = qi * 16 + 4 * hi + r;
            iv[r] = 1.f / (rsL[w][lq] + 1e-4f);
        }
#pragma unroll
        for (int dt = 0; dt < 2; ++dt) {
#pragma unroll
            for (int r = 0; r < 4; ++r) {
                int lq = qi * 16 + 4 * hi + r;
                if (lq < 50)
                    pv[((size_t)n * TB + rowbase + lq) * CC + h * DH + dt * 16 + fr] = pvacc[qi][dt][r] * iv[r];
            }
        }
    }
}

// ---------------- fused out-projection + shift: 64 rows x 256 cols per block, 8 waves ----------------
__global__ __launch_bounds__(512)
void outshift(const float* __restrict__ pv, const float* __restrict__ ow,
              const float* __restrict__ ob, const float* __restrict__ cd,
              const float* __restrict__ cs, const float* __restrict__ rowsum,
              float* __restrict__ out_srm, float* __restrict__ out_smd) {
    __shared__ unsigned short Ahs[64][LDK], Als[64][LDK];
    __shared__ unsigned short Bhs[256][LDK], Bls[256][LDK];
    __shared__ float redcd[64][8], redcs[64][8];
    int tid = threadIdx.x;
    int lane = tid & 63, wave = tid >> 6;
    int wn = wave * 32;
    int fr = lane & 15, kb = lane >> 4;
    int bm = blockIdx.x * 64;
    int arow = tid >> 3, ak = (tid & 7) * 4;
    int brow = tid >> 1, bk = (tid & 1) * 16;
    const float* pA = pv + (size_t)(bm + arow) * CC + ak;
    const float* pB = ow + (size_t)brow * CC + bk;
    f32x4 acc[4][2];
#pragma unroll
    for (int mi = 0; mi < 4; ++mi)
#pragma unroll
        for (int ni = 0; ni < 2; ++ni)
            acc[mi][ni] = (f32x4){0.f, 0.f, 0.f, 0.f};
    for (int k0 = 0; k0 < CC; k0 += 32) {
        float4 av = *(const float4*)(pA + k0);
        float4 wv[4];
#pragma unroll
        for (int j = 0; j < 4; ++j) wv[j] = *(const float4*)(pB + k0 + 4 * j);
        __syncthreads();
        {
            ushort2 sx = rsplit(av.x), sy = rsplit(av.y), sz = rsplit(av.z), sw = rsplit(av.w);
            ushort4 h4; h4.x = sx.x; h4.y = sy.x; h4.z = sz.x; h4.w = sw.x;
            ushort4 l4; l4.x = sx.y; l4.y = sy.y; l4.z = sz.y; l4.w = sw.y;
            *(ushort4*)&Ahs[arow][ak] = h4;
            *(ushort4*)&Als[arow][ak] = l4;
        }
#pragma unroll
        for (int j = 0; j < 4; ++j) {
            ushort2 sx = rsplit(wv[j].x), sy = rsplit(wv[j].y), sz = rsplit(wv[j].z), sw = rsplit(wv[j].w);
            ushort4 h4; h4.x = sx.x; h4.y = sy.x; h4.z = sz.x; h4.w = sw.x;
            ushort4 l4; l4.x = sx.y; l4.y = sy.y; l4.z = sz.y; l4.w = sw.y;
            *(ushort4*)&Bhs[brow][bk + 4 * j] = h4;
            *(ushort4*)&Bls[brow][bk + 4 * j] = l4;
        }
        __syncthreads();
        s16x8 fah[4], fal[4], fbh[2], fbl[2];
#pragma unroll
        for (int mi = 0; mi < 4; ++mi) {
            fah[mi] = *(const s16x8*)&Ahs[mi * 16 + fr][kb * 8];
            fal[mi] = *(const s16x8*)&Als[mi * 16 + fr][kb * 8];
        }
#pragma unroll
        for (int ni = 0; ni < 2; ++ni) {
            fbh[ni] = *(const s16x8*)&Bhs[wn + ni * 16 + fr][kb * 8];
            fbl[ni] = *(const s16x8*)&Bls[wn + ni * 16 + fr][kb * 8];
        }
#pragma unroll
        for (int mi = 0; mi < 4; ++mi)
#pragma unroll
            for (int ni = 0; ni < 2; ++ni) {
                acc[mi][ni] = __builtin_amdgcn_mfma_f32_16x16x32_bf16(fah[mi], fbh[ni], acc[mi][ni], 0, 0, 0);
                acc[mi][ni] = __builtin_amdgcn_mfma_f32_16x16x32_bf16(fah[mi], fbl[ni], acc[mi][ni], 0, 0, 0);
                acc[mi][ni] = __builtin_amdgcn_mfma_f32_16x16x32_bf16(fal[mi], fbh[ni], acc[mi][ni], 0, 0, 0);
            }
    }
#pragma unroll
    for (int mi = 0; mi < 4; ++mi) {
#pragma unroll
        for (int r = 0; r < 4; ++r) {
            int lm = mi * 16 + kb * 4 + r;
            int g = bm + lm;
            int n = g / TB;
            float pcd = 0.f, pcs = 0.f;
#pragma unroll
            for (int ni = 0; ni < 2; ++ni) {
                int col = wn + ni * 16 + fr;
                float val = acc[mi][ni][r] + ob[col];
                float d1 = val - cd[(size_t)n * CC + col];
                float d2 = val - cs[(size_t)n * CC + col];
                pcd += d1 * d1;
                pcs += d2 * d2;
            }
#pragma unroll
            for (int m2 = 1; m2 < 16; m2 <<= 1) {
                pcd += __shfl_xor(pcd, m2);
                pcs += __shfl_xor(pcs, m2);
            }
            if (fr == 0) {
                redcd[lm][wave] = pcd;
                redcs[lm][wave] = pcs;
            }
        }
    }
    __syncthreads();
    if (tid < 32) {
        int g = bm + 2 * tid;
        int n = g / TB;
        int rem = g % TB;
        int b = rem / TT;
        int t = rem % TT;
        int q = t >> 1;
        float c0 = 0.f, c1v = 0.f;
        for (int h = 0; h < HH; ++h) {
            c0  += rowsum[((size_t)n * HH + h) * TB + rem];
            c1v += rowsum[((size_t)n * HH + h) * TB + rem + 1];
        }
        int si = (c1v < c0) ? 1 : 0;
        int di = (c1v > c0) ? 1 : 0;
        int ld = 2 * tid + di, ls = 2 * tid + si;
        float dd = 0.f, ds = 0.f;
#pragma unroll
        for (int wv2 = 0; wv2 < 8; ++wv2) { dd += redcd[ld][wv2]; ds += redcs[ls][wv2]; }
        (b ? out_smd : out_srm)[n * QQ + q] = sqrtf(dd + 1e-12f) + sqrtf(ds + 1e-12f);
    }
}

extern "C" void kernel_launch(void* const* d_in, const int* in_sizes, int n_in,
                              void* d_out, int out_size, void* d_ws, size_t ws_size,
                              hipStream_t stream) {
    const float* hs_pair = (const float*)d_in[0];
    const float* ipw = (const float*)d_in[1];
    const float* ipb = (const float*)d_in[2];
    const float* ow  = (const float*)d_in[3];
    const float* ob  = (const float*)d_in[4];
    const float* hs = hs_pair + (size_t)5 * NB * QQ * CC;  // hs_pair[-1]

    float* ws = (float*)d_ws;
    size_t o = 0;
    float* meanF   = ws + o; o += NB * CC;
    float* P_all   = ws + o; o += (size_t)NB * SM * PW;
    float* Psum0   = ws + o; o += NB * CC;
    float* G       = ws + o; o += (size_t)NB * SM * 104;
    int*   far0    = (int*)(ws + o); o += NB;
    int*   far_rm  = (int*)(ws + o); o += NB * QQ;
    int*   far_md  = (int*)(ws + o); o += NB * QQ;
    float* cd      = ws + o; o += NB * CC;
    float* cs      = ws + o; o += NB * CC;
    float* pv      = ws + o; o += (size_t)NB * TB * CC;
    float* rowsum  = ws + o; o += (size_t)NB * HH * TB;
    if (o * sizeof(float) > ws_size) return;

    float* out = (float*)d_out;
    float* out_assign = out;
    float* out_sidx   = out + 6400;
    float* out_didx   = out + 6432;
    float* out_srm    = out + 6464;
    float* out_smd    = out + 9664;

    meanfar0<<<NB, 256, 0, stream>>>(hs, meanF, far0);
    projgram<<<GEMM_NBLK + 7 * NB, 256, 0, stream>>>(hs, meanF, ipw, ipb, P_all, G);
    selB<<<2 * NB, 512, 0, stream>>>(G, P_all, far0, ow, ob, Psum0, far_rm, far_md,
                                     out_assign, out_sidx, out_didx, cd, cs);
    attn_mfma<<<dim3(HH, NB), 512, 0, stream>>>(P_all, Psum0, far_rm, far_md, pv, rowsum);
    outshift<<<NB * TB / 64, 512, 0, stream>>>(pv, ow, ob, cd, cs, rowsum, out_srm, out_smd);
}